// Round 5
// baseline (511.700 us; speedup 1.0000x reference)
//
#include <hip/hip_runtime.h>
#include <math.h>

typedef unsigned short u16;
typedef unsigned int u32;
typedef __bf16 bf16x8 __attribute__((ext_vector_type(8)));
typedef float f32x4 __attribute__((ext_vector_type(4)));
typedef u16 u16x4 __attribute__((ext_vector_type(4)));

constexpr int B = 8, NQ = 256, LT = 512, NV = 4096;
constexpr int D = 1024, H = 16, DFF = 2048, FTXT = 4096, HD = 64;

__device__ __forceinline__ u16 f2b(float f) {
  u32 u = __builtin_bit_cast(u32, f);
  return (u16)((u + 0x7fffu + ((u >> 16) & 1u)) >> 16);   // RNE
}
__device__ __forceinline__ float b2f(u16 b) {
  u32 u = ((u32)b) << 16;
  return __builtin_bit_cast(float, u);
}
__device__ __forceinline__ void gload16(const void* g, void* l) {
  __builtin_amdgcn_global_load_lds(
      (const __attribute__((address_space(1))) u32*)g,
      (__attribute__((address_space(3))) u32*)l, 16, 0, 0);
}

// ---------------------------------------------------------------------------
// 8-phase 128x256 bf16 GEMM for the KV projection (T2+T3+T4+T5):
// C[M,N] = A[M,K] @ Bw[N,K]^T + bias, bf16 out. 512 thr = 8 waves (2M x 4N).
// BK=64, 3-deep LDS tile pipeline (144 KiB), counted vmcnt(6) at tile end
// (never 0 mid-loop), XOR-swizzled LDS (slot ^= row&7, both-sides), setprio
// around MFMA clusters. Requires M%128==0, N%256==0, K%64==0, K/64 >= 2.
// ---------------------------------------------------------------------------
__global__ __launch_bounds__(512, 2)
void gemm_kv8(const u16* __restrict__ A, const u16* __restrict__ Bw,
              const float* __restrict__ bias, u16* __restrict__ Cb,
              int M, int N, int K, int lda, int ldb, int ldc)
{
  constexpr int BM = 128, BN = 256, BK = 64;
  __shared__ __align__(16) u16 As[3][BM * BK];   // 16 KB each
  __shared__ __align__(16) u16 Bs[3][BN * BK];   // 32 KB each

  // XCD-bijective swizzle
  const int gx = gridDim.x, gy = gridDim.y;
  const int nwg = gx * gy;
  const int flat = blockIdx.y * gx + blockIdx.x;
  const int qq = nwg >> 3, rr = nwg & 7;
  const int xcd = flat & 7, lid = flat >> 3;
  const int wg = (xcd < rr ? xcd * (qq + 1) : rr * (qq + 1) + (xcd - rr) * qq) + lid;
  const int bx = wg % gx, by = wg / gx;
  const int m0 = by * BM, n0 = bx * BN;

  const int t = threadIdx.x;
  const int w = t >> 6, l = t & 63;
  const int wr = w >> 2, wc = w & 3;         // 2 x 4 waves
  const int nt = K / BK;

  const int srow = t >> 3;                   // staging row 0..63 within group
  const int schunk = (t & 7) ^ (srow & 7);   // inverse-swizzled source 16B chunk

  auto stageA = [&](int buf, int kt) {       // 2 gloads
    const long long k0 = (long long)kt * BK + schunk * 8;
    #pragma unroll
    for (int i = 0; i < 2; ++i)
      gload16(&A[(long long)(m0 + i * 64 + srow) * lda + k0],
              &As[buf][i * 4096 + w * 512]);
  };
  auto stageB = [&](int buf, int kt, int half) {  // 2 gloads
    const long long k0 = (long long)kt * BK + schunk * 8;
    #pragma unroll
    for (int i = 0; i < 2; ++i) {
      const int ii = half * 2 + i;
      gload16(&Bw[(long long)(n0 + ii * 64 + srow) * ldb + k0],
              &Bs[buf][ii * 4096 + w * 512]);
    }
  };
  auto rdA = [&](int buf, int fm, int ks) -> bf16x8 {
    const int r = wr * 64 + fm * 16 + (l & 15);
    const int s = (ks * 4 + (l >> 4)) ^ (r & 7);
    return *reinterpret_cast<const bf16x8*>(&As[buf][r * 64 + s * 8]);
  };
  auto rdB = [&](int buf, int fn, int ks) -> bf16x8 {
    const int r = wc * 64 + fn * 16 + (l & 15);
    const int s = (ks * 4 + (l >> 4)) ^ (r & 7);
    return *reinterpret_cast<const bf16x8*>(&Bs[buf][r * 64 + s * 8]);
  };

  f32x4 acc[4][4] = {};
  bf16x8 af[4];

  // prologue: tiles 0 and 1 in flight (12 loads); drain tile 0 (to 6)
  stageA(0, 0); stageB(0, 0, 0); stageB(0, 0, 1);
  stageA(1, 1); stageB(1, 1, 0); stageB(1, 1, 1);
  asm volatile("s_waitcnt vmcnt(6)" ::: "memory");
  asm volatile("s_barrier" ::: "memory");

  for (int kt = 0; kt < nt; ++kt) {
    const int c = kt % 3;
    const int nb = (kt + 2) % 3;
    const bool iss = (kt + 2) < nt;

    // ---- phase 0: ks0 x fn{0,1} ----
    #pragma unroll
    for (int fm = 0; fm < 4; ++fm) af[fm] = rdA(c, fm, 0);
    bf16x8 b0 = rdB(c, 0, 0), b1 = rdB(c, 1, 0);
    if (iss) stageA(nb, kt + 2);
    asm volatile("s_barrier" ::: "memory");
    __builtin_amdgcn_s_setprio(1);
    #pragma unroll
    for (int fm = 0; fm < 4; ++fm) {
      acc[fm][0] = __builtin_amdgcn_mfma_f32_16x16x32_bf16(af[fm], b0, acc[fm][0], 0, 0, 0);
      acc[fm][1] = __builtin_amdgcn_mfma_f32_16x16x32_bf16(af[fm], b1, acc[fm][1], 0, 0, 0);
    }
    __builtin_amdgcn_s_setprio(0);
    asm volatile("s_barrier" ::: "memory");

    // ---- phase 1: ks0 x fn{2,3} ----
    b0 = rdB(c, 2, 0); b1 = rdB(c, 3, 0);
    if (iss) stageB(nb, kt + 2, 0);
    asm volatile("s_barrier" ::: "memory");
    __builtin_amdgcn_s_setprio(1);
    #pragma unroll
    for (int fm = 0; fm < 4; ++fm) {
      acc[fm][2] = __builtin_amdgcn_mfma_f32_16x16x32_bf16(af[fm], b0, acc[fm][2], 0, 0, 0);
      acc[fm][3] = __builtin_amdgcn_mfma_f32_16x16x32_bf16(af[fm], b1, acc[fm][3], 0, 0, 0);
    }
    __builtin_amdgcn_s_setprio(0);
    asm volatile("s_barrier" ::: "memory");

    // ---- phase 2: ks1 x fn{0,1} ----
    #pragma unroll
    for (int fm = 0; fm < 4; ++fm) af[fm] = rdA(c, fm, 1);
    b0 = rdB(c, 0, 1); b1 = rdB(c, 1, 1);
    if (iss) stageB(nb, kt + 2, 1);
    asm volatile("s_barrier" ::: "memory");
    __builtin_amdgcn_s_setprio(1);
    #pragma unroll
    for (int fm = 0; fm < 4; ++fm) {
      acc[fm][0] = __builtin_amdgcn_mfma_f32_16x16x32_bf16(af[fm], b0, acc[fm][0], 0, 0, 0);
      acc[fm][1] = __builtin_amdgcn_mfma_f32_16x16x32_bf16(af[fm], b1, acc[fm][1], 0, 0, 0);
    }
    __builtin_amdgcn_s_setprio(0);
    asm volatile("s_barrier" ::: "memory");

    // ---- phase 3: ks1 x fn{2,3} + tile-end counted wait ----
    b0 = rdB(c, 2, 1); b1 = rdB(c, 3, 1);
    asm volatile("s_barrier" ::: "memory");
    __builtin_amdgcn_s_setprio(1);
    #pragma unroll
    for (int fm = 0; fm < 4; ++fm) {
      acc[fm][2] = __builtin_amdgcn_mfma_f32_16x16x32_bf16(af[fm], b0, acc[fm][2], 0, 0, 0);
      acc[fm][3] = __builtin_amdgcn_mfma_f32_16x16x32_bf16(af[fm], b1, acc[fm][3], 0, 0, 0);
    }
    __builtin_amdgcn_s_setprio(0);
    if (kt < nt - 2)       asm volatile("s_waitcnt vmcnt(6)" ::: "memory");
    else if (kt == nt - 2) asm volatile("s_waitcnt vmcnt(0)" ::: "memory");
    asm volatile("s_barrier" ::: "memory");
  }

  // epilogue: bias + bf16 store
  const int cl = l & 15, rl4 = (l >> 4) * 4;
  #pragma unroll
  for (int fm = 0; fm < 4; ++fm) {
    #pragma unroll
    for (int r = 0; r < 4; ++r) {
      const long long row = m0 + wr * 64 + fm * 16 + rl4 + r;
      #pragma unroll
      for (int fn = 0; fn < 4; ++fn) {
        const int col = n0 + wc * 64 + fn * 16 + cl;
        Cb[row * (long long)ldc + col] = f2b(acc[fm][fn][r] + bias[col]);
      }
    }
  }
}

// ---------------------------------------------------------------------------
// 2-phase bf16 MFMA GEMM (all other shapes): C = alpha*A@B^T (+bias)(+res)...
// BSRC: 0 = B bf16 [N][K] via global_load_lds; 1 = B f32 [N][K] reg-staged;
//       2 = B f32 [K][N] reg-staged + transpose. Batched via bz decomposition.
// ---------------------------------------------------------------------------
constexpr int E_BIAS = 1, E_RES = 2, E_RELU = 4, E_WF32 = 8, E_WB16 = 16;

template<int BM, int BN, int WM, int WN, int EPI, int BSRC>
__global__ __launch_bounds__(256)
void gemm_bf16(const u16* __restrict__ A, const void* __restrict__ Bw,
               const float* __restrict__ bias, const float* __restrict__ res,
               float* __restrict__ C, u16* __restrict__ Cb,
               int K, int lda, int ldb, int ldc, int nbz2,
               long long sA1, long long sA2, long long sB1, long long sB2,
               long long sC1, long long sC2, float alpha)
{
  static_assert(BSRC == 0 || BN == 128, "reg-staged B assumes BN=128");
  constexpr int SM = BM / WM, SN = BN / WN;
  constexpr int FM = SM / 16, FN = SN / 16;
  constexpr int PA = BM / 64, PB = BN / 64;
  __shared__ __align__(16) u16 As[2][BM * 32];
  __shared__ __align__(16) u16 Bs[2][BN * 32];

  const int gx = gridDim.x, gy = gridDim.y;
  const int nwg = gx * gy * gridDim.z;
  const int flat = (blockIdx.z * gy + blockIdx.y) * gx + blockIdx.x;
  const int qq = nwg >> 3, rr = nwg & 7;
  const int xcd = flat & 7, lid = flat >> 3;
  const int wg = (xcd < rr ? xcd * (qq + 1) : rr * (qq + 1) + (xcd - rr) * qq) + lid;
  const int bx = wg % gx;
  const int tmp1 = wg / gx;
  const int by = tmp1 % gy, bz = tmp1 / gy;

  const int t = threadIdx.x;
  const int w = t >> 6, l = t & 63;
  const int wr = w / WN, wc = w % WN;
  const int m0 = by * BM, n0 = bx * BN;
  const long long offA = (long long)(bz / nbz2) * sA1 + (long long)(bz % nbz2) * sA2;
  const long long offB = (long long)(bz / nbz2) * sB1 + (long long)(bz % nbz2) * sB2;
  const long long offC = (long long)(bz / nbz2) * sC1 + (long long)(bz % nbz2) * sC2;
  const u16* Ab = A + offA;

  const int srow = t >> 2;
  const int sk   = (t & 3) * 8;

  auto stageA = [&](int buf, int k0) {
    #pragma unroll
    for (int p = 0; p < PA; ++p)
      gload16(&Ab[(long long)(m0 + p * 64 + srow) * lda + k0 + sk],
              &As[buf][p * 2048 + w * 512]);
  };
  auto stageB_g = [&](int buf, int k0) {
    const u16* Bb = (const u16*)Bw + offB;
    #pragma unroll
    for (int p = 0; p < PB; ++p)
      gload16(&Bb[(long long)(n0 + p * 64 + srow) * ldb + k0 + sk],
              &Bs[buf][p * 2048 + w * 512]);
  };
  auto loadB = [&](float4* rg, int k0) {
    const float* Bf = (const float*)Bw + offB;
    if constexpr (BSRC == 1) {
      const int r = t >> 1, c0 = (t & 1) * 16;
      #pragma unroll
      for (int c = 0; c < 4; ++c)
        rg[c] = *reinterpret_cast<const float4*>(
            &Bf[(long long)(n0 + r) * ldb + k0 + c0 + c * 4]);
    } else {
      const int kk = t >> 3;
      #pragma unroll
      for (int p = 0; p < 4; ++p)
        rg[p] = *reinterpret_cast<const float4*>(
            &Bf[(long long)(k0 + kk) * ldb + n0 + (t & 7) * 4 + 32 * p]);
    }
  };
  auto writeB = [&](int buf, const float4* rg) {
    if constexpr (BSRC == 1) {
      const int r = t >> 1, c0 = (t & 1) * 16;
      #pragma unroll
      for (int c = 0; c < 4; ++c) {
        u16x4 o = {f2b(rg[c].x), f2b(rg[c].y), f2b(rg[c].z), f2b(rg[c].w)};
        *reinterpret_cast<u16x4*>(&Bs[buf][r * 32 + c0 + c * 4]) = o;
      }
    } else {
      const int kk = t >> 3;
      #pragma unroll
      for (int p = 0; p < 4; ++p) {
        const int nn = (t & 7) * 4 + 32 * p;
        Bs[buf][(nn + 0) * 32 + kk] = f2b(rg[p].x);
        Bs[buf][(nn + 1) * 32 + kk] = f2b(rg[p].y);
        Bs[buf][(nn + 2) * 32 + kk] = f2b(rg[p].z);
        Bs[buf][(nn + 3) * 32 + kk] = f2b(rg[p].w);
      }
    }
  };

  f32x4 acc[FM][FN] = {};

  stageA(0, 0);
  if constexpr (BSRC == 0) {
    stageB_g(0, 0);
  } else {
    float4 rg[4];
    loadB(rg, 0);
    writeB(0, rg);
  }

  int cur = 0;
  for (int k0 = 0; k0 < K; k0 += 32) {
    __syncthreads();
    const bool pf = (k0 + 32 < K);
    float4 rg[4];
    if (pf) {
      stageA(cur ^ 1, k0 + 32);
      if constexpr (BSRC == 0) stageB_g(cur ^ 1, k0 + 32);
      else                     loadB(rg, k0 + 32);
    }

    bf16x8 af[FM], bfr[FN];
    #pragma unroll
    for (int i = 0; i < FM; ++i)
      af[i] = *reinterpret_cast<const bf16x8*>(
          &As[cur][(wr * SM + i * 16 + (l & 15)) * 32 + (l >> 4) * 8]);
    #pragma unroll
    for (int j = 0; j < FN; ++j)
      bfr[j] = *reinterpret_cast<const bf16x8*>(
          &Bs[cur][(wc * SN + j * 16 + (l & 15)) * 32 + (l >> 4) * 8]);
    #pragma unroll
    for (int i = 0; i < FM; ++i)
      #pragma unroll
      for (int j = 0; j < FN; ++j)
        acc[i][j] = __builtin_amdgcn_mfma_f32_16x16x32_bf16(af[i], bfr[j], acc[i][j], 0, 0, 0);

    if constexpr (BSRC != 0) {
      if (pf) writeB(cur ^ 1, rg);
    }
    cur ^= 1;
  }

  const int c_l = l & 15, r_l4 = (l >> 4) * 4;
  #pragma unroll
  for (int i = 0; i < FM; ++i) {
    #pragma unroll
    for (int r = 0; r < 4; ++r) {
      const long long row = m0 + wr * SM + i * 16 + r_l4 + r;
      #pragma unroll
      for (int j = 0; j < FN; ++j) {
        const int col = n0 + wc * SN + j * 16 + c_l;
        float v = acc[i][j][r] * alpha;
        if (EPI & E_BIAS) v += bias[col];
        if (EPI & E_RES)  v += res[row * (long long)ldc + col];
        if (EPI & E_RELU) v = fmaxf(v, 0.f);
        const long long co = offC + row * (long long)ldc + col;
        if (EPI & E_WF32) C[co] = v;
        if (EPI & E_WB16) Cb[co] = f2b(v);
      }
    }
  }
}

// ---------------------------------------------------------------------------
__global__ __launch_bounds__(256)
void cvt_bf16(const float* __restrict__ in, u16* __restrict__ out)
{
  const long long i = ((long long)blockIdx.x * 256 + threadIdx.x) * 4;
  float4 x = *reinterpret_cast<const float4*>(&in[i]);
  u16x4 o = {f2b(x.x), f2b(x.y), f2b(x.z), f2b(x.w)};
  *reinterpret_cast<u16x4*>(&out[i]) = o;
}

__global__ __launch_bounds__(256)
void cvt_add_bf16(const float* __restrict__ a, const float* __restrict__ b,
                  u16* __restrict__ out)
{
  const long long i = ((long long)blockIdx.x * 256 + threadIdx.x) * 4;
  float4 x = *reinterpret_cast<const float4*>(&a[i]);
  float4 y = *reinterpret_cast<const float4*>(&b[i]);
  u16x4 o = {f2b(x.x + y.x), f2b(x.y + y.y), f2b(x.z + y.z), f2b(x.w + y.w)};
  *reinterpret_cast<u16x4*>(&out[i]) = o;
}

__global__ __launch_bounds__(256)
void transpose_u16(const u16* __restrict__ in, u16* __restrict__ out,
                   int R, int C, int ldin, long long sbin, long long sbout)
{
  __shared__ u16 tile[32][34];
  const int b = blockIdx.z;
  const int r0 = blockIdx.y * 32, c0 = blockIdx.x * 32;
  const int tx = threadIdx.x & 31, ty = threadIdx.x >> 5;
  const u16* ib = in + (long long)b * sbin;
  u16* ob = out + (long long)b * sbout;
  #pragma unroll
  for (int p = 0; p < 4; ++p) {
    int r = ty + p * 8;
    tile[r][tx] = ib[(long long)(r0 + r) * ldin + c0 + tx];
  }
  __syncthreads();
  #pragma unroll
  for (int p = 0; p < 4; ++p) {
    int c = ty + p * 8;
    ob[(long long)(c0 + c) * R + r0 + tx] = tile[tx][c];
  }
}

// ---------------------------------------------------------------------------
__global__ __launch_bounds__(256)
void txt_softmax_mean(const float* __restrict__ sc, const int* __restrict__ mask,
                      u16* __restrict__ wout, float* __restrict__ out1)
{
  __shared__ float red[8];
  const int t = threadIdx.x, l = t & 63, w = t >> 6;
  const int bq = blockIdx.x;
  const int b = bq >> 8, q = bq & 255;
  const int* mr = mask + b * LT;
  const bool msk0 = mr[t] != 0, msk1 = mr[t + 256] != 0;
  float a0 = 0.f, a1 = 0.f;
  for (int h = 0; h < H; ++h) {
    const long long ro = (((long long)(b * H + h)) * NQ + q) * LT;
    const float* sr = sc + ro;
    float x0 = msk0 ? -INFINITY : sr[t];
    float x1 = msk1 ? -INFINITY : sr[t + 256];
    float mx = fmaxf(x0, x1);
    #pragma unroll
    for (int o = 32; o > 0; o >>= 1) mx = fmaxf(mx, __shfl_xor(mx, o, 64));
    if (l == 0) red[w] = mx;
    __syncthreads();
    mx = fmaxf(fmaxf(red[0], red[1]), fmaxf(red[2], red[3]));
    float e0 = __expf(x0 - mx), e1 = __expf(x1 - mx);
    float s = e0 + e1;
    #pragma unroll
    for (int o = 32; o > 0; o >>= 1) s += __shfl_xor(s, o, 64);
    if (l == 0) red[4 + w] = s;
    __syncthreads();
    s = red[4] + red[5] + red[6] + red[7];
    const float inv = 1.f / s;
    const float w0 = e0 * inv, w1 = e1 * inv;
    u16* wr = wout + ro;
    wr[t] = f2b(w0); wr[t + 256] = f2b(w1);
    a0 += w0; a1 += w1;
  }
  float* o1 = out1 + (long long)bq * LT;
  o1[t]       = a0 * (1.f / H);
  o1[t + 256] = a1 * (1.f / H);
}

// ---------------------------------------------------------------------------
__global__ __launch_bounds__(256)
void ln_kernel(const float* __restrict__ x, const float* __restrict__ g,
               const float* __restrict__ bia, float* __restrict__ y,
               u16* __restrict__ yb, float scale)
{
  __shared__ float tmp[256];
  const int t = threadIdx.x;
  const long long off = (long long)blockIdx.x * D;
  float4 x4 = *reinterpret_cast<const float4*>(&x[off + t * 4]);
  tmp[t] = x4.x + x4.y + x4.z + x4.w;
  __syncthreads();
  for (int o = 128; o > 0; o >>= 1) { if (t < o) tmp[t] += tmp[t + o]; __syncthreads(); }
  const float mean = tmp[0] * (1.f / D);
  __syncthreads();
  float d0 = x4.x - mean, d1 = x4.y - mean, d2 = x4.z - mean, d3 = x4.w - mean;
  tmp[t] = d0 * d0 + d1 * d1 + d2 * d2 + d3 * d3;
  __syncthreads();
  for (int o = 128; o > 0; o >>= 1) { if (t < o) tmp[t] += tmp[t + o]; __syncthreads(); }
  const float rs = rsqrtf(tmp[0] * (1.f / D) + 1e-5f);
  float4 g4 = *reinterpret_cast<const float4*>(&g[t * 4]);
  float4 b4 = *reinterpret_cast<const float4*>(&bia[t * 4]);
  float o0 = (d0 * rs * g4.x + b4.x) * scale;
  float o1 = (d1 * rs * g4.y + b4.y) * scale;
  float o2 = (d2 * rs * g4.z + b4.z) * scale;
  float o3 = (d3 * rs * g4.w + b4.w) * scale;
  if (y) {
    float4 o4 = {o0, o1, o2, o3};
    *reinterpret_cast<float4*>(&y[off + t * 4]) = o4;
  }
  if (yb) {
    u16x4 ob = {f2b(o0), f2b(o1), f2b(o2), f2b(o3)};
    *reinterpret_cast<u16x4*>(&yb[off + t * 4]) = ob;
  }
}

// ---------------------------------------------------------------------------
__global__ __launch_bounds__(256)
void vox_softmax(float* __restrict__ s, const int* __restrict__ mask,
                 u16* __restrict__ wb)
{
  __shared__ float tmp[256];
  const int t = threadIdx.x;
  const int row = blockIdx.x, b = row / NQ;
  float* sr = s + (long long)row * NV;
  u16* wr = wb + (long long)row * NV;
  const int* mr = mask + b * NV;
  float vals[16];
  float lm = -INFINITY;
  #pragma unroll
  for (int j = 0; j < 16; ++j) {
    int n = t + j * 256;
    float x = mr[n] ? -INFINITY : sr[n];
    vals[j] = x;
    lm = fmaxf(lm, x);
  }
  tmp[t] = lm;
  __syncthreads();
  for (int o = 128; o > 0; o >>= 1) { if (t < o) tmp[t] = fmaxf(tmp[t], tmp[t + o]); __syncthreads(); }
  const float mx = tmp[0];
  __syncthreads();
  float ls = 0.f;
  #pragma unroll
  for (int j = 0; j < 16; ++j) { vals[j] = __expf(vals[j] - mx); ls += vals[j]; }
  tmp[t] = ls;
  __syncthreads();
  for (int o = 128; o > 0; o >>= 1) { if (t < o) tmp[t] += tmp[t + o]; __syncthreads(); }
  const float inv = 1.f / tmp[0];
  #pragma unroll
  for (int j = 0; j < 16; ++j) {
    float v = vals[j] * inv;
    sr[t + j * 256] = v;
    wr[t + j * 256] = f2b(v);
  }
}

__global__ __launch_bounds__(256)
void splitk_reduce(const float* __restrict__ part, float* __restrict__ out)
{
  const long long i = ((long long)blockIdx.x * 256 + threadIdx.x) * 4;
  const long long nd = (long long)NQ * D;
  const long long b = i / nd;
  const long long o = i - b * nd;
  const float* p = part + b * 4 * nd + o;
  float4 s0 = *reinterpret_cast<const float4*>(&p[0]);
  float4 s1 = *reinterpret_cast<const float4*>(&p[nd]);
  float4 s2 = *reinterpret_cast<const float4*>(&p[2 * nd]);
  float4 s3 = *reinterpret_cast<const float4*>(&p[3 * nd]);
  float4 r = {s0.x + s1.x + s2.x + s3.x, s0.y + s1.y + s2.y + s3.y,
              s0.z + s1.z + s2.z + s3.z, s0.w + s1.w + s2.w + s3.w};
  *reinterpret_cast<float4*>(&out[i]) = r;
}

// ---------------------------------------------------------------------------
extern "C" void kernel_launch(void* const* d_in, const int* in_sizes, int n_in,
                              void* d_out, int out_size, void* d_ws, size_t ws_size,
                              hipStream_t stream)
{
  const float* tgt   = (const float*)d_in[0];
  const float* mtxt  = (const float*)d_in[1];
  const float* vox   = (const float*)d_in[2];
  const float* qpos  = (const float*)d_in[3];
  const int*   mtx_m = (const int*)d_in[4];
  const int*   vox_m = (const int*)d_in[5];
  const float* Wq = (const float*)d_in[6];  const float* bq = (const float*)d_in[7];
  const float* Wk = (const float*)d_in[8];  const float* bk = (const float*)d_in[9];
  const float* Wv = (const float*)d_in[10]; const float* bv = (const float*)d_in[11];
  const float* Wo = (const float*)d_in[12]; const float* bo = (const float*)d_in[13];
  const float* W1 = (const float*)d_in[14]; const float* b1 = (const float*)d_in[15];
  const float* W2 = (const float*)d_in[16]; const float* b2 = (const float*)d_in[17];
  const float* ln1g = (const float*)d_in[18]; const float* ln1b = (const float*)d_in[19];
  const float* ln2g = (const float*)d_in[20]; const float* ln2b = (const float*)d_in[21];

  float* out0 = (float*)d_out;                       // attn_output  [B,NQ,D]
  float* out1 = out0 + (long long)B * NQ * D;        // txt_cross    [B,NQ,LT]
  float* out2 = out1 + (long long)B * NQ * LT;       // attn_weights [B,NQ,NV]

  char* base = (char*)d_ws;
  constexpr size_t MB = 1ull << 20;
  u16*   kvW   = (u16*)(base + 0 * MB);     // 16  [Wk;Wv] stacked [2048][4096]
  u16*   Wq_b  = (u16*)(base + 16 * MB);    // 2
  u16*   Wo_b  = (u16*)(base + 18 * MB);    // 2
  u16*   W1_b  = (u16*)(base + 20 * MB);    // 4
  u16*   W2_b  = (u16*)(base + 24 * MB);    // 4
  u16*   tq_b  = (u16*)(base + 28 * MB);    // 4
  u16*   q_b   = (u16*)(base + 32 * MB);    // 4
  u16*   kv_b  = (u16*)(base + 36 * MB);    // 16  [B*LT][2048] (k | v)
  u16*   vT_b  = (u16*)(base + 52 * MB);    // 8   [B][D][LT]
  u16*   ctx_b = (u16*)(base + 60 * MB);    // 4
  float* x1p   = (float*)(base + 64 * MB);  // 8
  float* x1f   = (float*)(base + 72 * MB);  // 8
  u16*   x1_b  = (u16*)(base + 80 * MB);    // 4
  u16*   ff1_b = (u16*)(base + 84 * MB);    // 8
  float* x2p   = (float*)(base + 92 * MB);  // 8
  u16*   x2s_b = (u16*)(base + 100 * MB);   // 4
  u16*   mtxt_b = (u16*)(base + 104 * MB);  // 32  dead after KV proj
  float* scores = (float*)(base + 136 * MB);// 64  dead after txt_softmax_mean
  u16*   w_b    = (u16*)(base + 200 * MB);  // 32  dead after ctx gemm
  float* bkv    = (float*)(base + 136 * MB);// 8KB, dead before scores written
  u16*   wvox_b = (u16*)(base + 0 * MB);    // 16  overlays kvW (dead)
  float* part   = (float*)(base + 16 * MB); // 32  overlays Wq..kv_b head (dead)

  const dim3 blk(256);
  const long long sQ = (long long)NQ * D;
  const long long sSC = (long long)NQ * LT;
  const long long nd = (long long)NQ * D;

  // 1) weight/input conversions
  cvt_bf16<<<dim3((D * D) / 1024), blk, 0, stream>>>(Wq, Wq_b);
  cvt_bf16<<<dim3((D * FTXT) / 1024), blk, 0, stream>>>(Wk, kvW);
  cvt_bf16<<<dim3((D * FTXT) / 1024), blk, 0, stream>>>(Wv, kvW + (long long)D * FTXT);
  cvt_bf16<<<dim3((D * D) / 1024), blk, 0, stream>>>(Wo, Wo_b);
  cvt_bf16<<<dim3((DFF * D) / 1024), blk, 0, stream>>>(W1, W1_b);
  cvt_bf16<<<dim3((D * DFF) / 1024), blk, 0, stream>>>(W2, W2_b);
  hipMemcpyAsync(bkv, bk, D * sizeof(float), hipMemcpyDeviceToDevice, stream);
  hipMemcpyAsync(bkv + D, bv, D * sizeof(float), hipMemcpyDeviceToDevice, stream);
  cvt_add_bf16<<<dim3((B * NQ * D) / 1024), blk, 0, stream>>>(tgt, qpos, tq_b);
  cvt_bf16<<<dim3((B * LT * FTXT) / 1024), blk, 0, stream>>>(mtxt, mtxt_b);

  // 2) q = tq @ Wq^T + bq  (512 blocks, 2-phase)
  gemm_bf16<64,64,2,2, E_BIAS|E_WB16, 0><<<dim3(D/64, (B*NQ)/64, 1), blk, 0, stream>>>(
      tq_b, Wq_b, bq, nullptr, nullptr, q_b, D, D, D, D, 1, 0,0,0,0,0,0, 1.f);
  //    kv = mtxt @ [Wk;Wv]^T + [bk;bv]  (8-phase, 128x256, 256 blocks)
  gemm_kv8<<<dim3(2048/256, (B*LT)/128), dim3(512), 0, stream>>>(
      mtxt_b, kvW, bkv, kv_b, B*LT, 2048, FTXT, FTXT, FTXT, 2048);

  // 3) vT[b][d][l] = v[b][l][d]
  transpose_u16<<<dim3(D/32, LT/32, B), blk, 0, stream>>>(
      kv_b + 1024, vT_b, LT, D, 2048, (long long)LT * 2048, (long long)D * LT);

  // 4) scores[b,h,q,l] = (q_h . k_h) / 8   (1024 blocks)
  gemm_bf16<128,128,2,2, E_WF32, 0><<<dim3(LT/128, NQ/128, B*H), blk, 0, stream>>>(
      q_b, kv_b, nullptr, nullptr, scores, nullptr, HD, D, 2048, LT, H,
      sQ, HD, (long long)LT * 2048, HD, (long long)H * sSC, sSC, 0.125f);

  // 5) fused softmax + head-mean
  txt_softmax_mean<<<dim3(B*NQ), blk, 0, stream>>>(scores, mtx_m, w_b, out1);

  // 6) ctx = w_h @ v_h  (512 blocks)
  gemm_bf16<64,64,2,2, E_WB16, 0><<<dim3(HD/64, NQ/64, B*H), blk, 0, stream>>>(
      w_b, vT_b, nullptr, nullptr, nullptr, ctx_b, LT, LT, LT, D, H,
      (long long)H * sSC, sSC, (long long)D * LT, (long long)HD * LT, sQ, HD, 1.f);

  // 7) x1p = tgt + ctx @ Wo^T + bo  (512 blocks)
  gemm_bf16<64,64,2,2, E_BIAS|E_RES|E_WF32, 0><<<dim3(D/64, (B*NQ)/64, 1), blk, 0, stream>>>(
      ctx_b, Wo_b, bo, tgt, x1p, nullptr, D, D, D, D, 1, 0,0,0,0,0,0, 1.f);

  // 8) LN1 -> x1 (f32 + bf16)
  ln_kernel<<<dim3(B*NQ), blk, 0, stream>>>(x1p, ln1g, ln1b, x1f, x1_b, 1.f);

  // 9) ff1 = relu(x1 @ W1^T + b1)  (512 blocks)
  gemm_bf16<128,64,2,2, E_BIAS|E_RELU|E_WB16, 0><<<dim3(DFF/64, (B*NQ)/128, 1), blk, 0, stream>>>(
      x1_b, W1_b, b1, nullptr, nullptr, ff1_b, D, D, D, DFF, 1, 0,0,0,0,0,0, 1.f);

  // 10) x2p = x1 + ff1 @ W2^T + b2  (512 blocks)
  gemm_bf16<64,64,2,2, E_BIAS|E_RES|E_WF32, 0><<<dim3(D/64, (B*NQ)/64, 1), blk, 0, stream>>>(
      ff1_b, W2_b, b2, x1f, x2p, nullptr, DFF, DFF, DFF, D, 1, 0,0,0,0,0,0, 1.f);

  // 11) LN2 -> x2s (bf16, /sqrt(D))
  ln_kernel<<<dim3(B*NQ), blk, 0, stream>>>(x2p, ln2g, ln2b, nullptr, x2s_b, 0.03125f);

  // 12) out2 = x2s @ vox^T — B staged directly from f32 vox (1024 blocks)
  gemm_bf16<64,128,2,2, E_WF32, 1><<<dim3(NV/128, NQ/64, B), blk, 0, stream>>>(
      x2s_b, vox, nullptr, nullptr, out2, nullptr, D, D, D, NV, 1,
      sQ, 0, (long long)NV * D, 0, (long long)NQ * NV, 0, 1.f);

  // 13) masked softmax in place; bf16 weights
  vox_softmax<<<dim3(B*NQ), blk, 0, stream>>>(out2, vox_m, wvox_b);

  // 14) out0 partials: split-K=4 over NV; B transpose-staged from f32 vox
  gemm_bf16<64,128,2,2, E_WF32, 2><<<dim3(D/128, NQ/64, B*4), blk, 0, stream>>>(
      wvox_b, vox, nullptr, nullptr, part, nullptr, NV/4, NV, D, D, 4,
      (long long)NQ * NV, 1024, (long long)NV * D, (long long)1024 * D,
      4 * nd, nd, 1.f);
  splitk_reduce<<<dim3((B * NQ * D) / 1024), blk, 0, stream>>>(part, out0);
}

// Round 6
// 459.454 us; speedup vs baseline: 1.1137x; 1.1137x over previous
//
#include <hip/hip_runtime.h>
#include <math.h>

typedef unsigned short u16;
typedef unsigned int u32;
typedef __bf16 bf16x8 __attribute__((ext_vector_type(8)));
typedef float f32x4 __attribute__((ext_vector_type(4)));
typedef u16 u16x4 __attribute__((ext_vector_type(4)));

constexpr int B = 8, NQ = 256, LT = 512, NV = 4096;
constexpr int D = 1024, H = 16, DFF = 2048, FTXT = 4096, HD = 64;

__device__ __forceinline__ u16 f2b(float f) {
  u32 u = __builtin_bit_cast(u32, f);
  return (u16)((u + 0x7fffu + ((u >> 16) & 1u)) >> 16);   // RNE
}
__device__ __forceinline__ float b2f(u16 b) {
  u32 u = ((u32)b) << 16;
  return __builtin_bit_cast(float, u);
}
__device__ __forceinline__ void gload16(const void* g, void* l) {
  __builtin_amdgcn_global_load_lds(
      (const __attribute__((address_space(1))) u32*)g,
      (__attribute__((address_space(3))) u32*)l, 16, 0, 0);
}

// ===========================================================================
// Faithful 256x256 8-phase bf16 GEMM (m201 template) for the KV projection.
// part[z][4096][2048] += A[4096][4096(z-half)] @ Bw[2048][4096(z-half)]^T
// 512 thr = 8 waves. BK=64. LDS: A,B each [2dbuf][2half][128][64] = 128 KiB.
// Phase = block C-quadrant (qm,qn) x K=64: per wave 4x2 frags x 2 k = 16 MFMA.
// Per phase: 12 ds_read_b128 + stage 1 half-tile (2 gload_lds) + 2 barriers.
// Counted vmcnt(4) at phases 4 & 8 only (never 0 mid-loop).
// LDS XOR-swizzle slot^ (row&7), both-sides (linear dest + pre-swz source).
// ===========================================================================
__global__ __launch_bounds__(512, 2)
void gemm_kv256(const u16* __restrict__ A, const u16* __restrict__ Bw,
                float* __restrict__ part)
{
  __shared__ __align__(16) u16 As[4 * 8192];   // [db*2+half][128][64]
  __shared__ __align__(16) u16 Bs[4 * 8192];

  // XCD-bijective swizzle over the 8*16*2 = 256-block grid
  const int gx = 8, gy = 16;
  const int nwg = 256;
  const int flat = (blockIdx.z * gy + blockIdx.y) * gx + blockIdx.x;
  const int qq = nwg >> 3;
  const int xcd = flat & 7, lid = flat >> 3;
  const int wg = xcd * qq + lid;
  const int bx = wg % gx;
  const int by = (wg / gx) % gy;
  const int z  = wg / (gx * gy);
  const int m0 = by * 256, n0 = bx * 256;
  const long long kbase = (long long)z * 2048;

  const int t = threadIdx.x;
  const int w = t >> 6, l = t & 63;
  const int wr64 = (w >> 2) * 64;       // wave row-slice within quadrant
  const int wc32 = (w & 3) * 32;        // wave col-slice within quadrant
  const int l15 = l & 15, l4 = l >> 4, l7 = l & 7;

  // stage half-tile (2 gloads/thread): rows h*128..+128, k-tile `tile`
  auto stA = [&](int db, int h, int tile) {
    const long long kk = kbase + tile * 64 + (((t & 7) ^ ((t >> 3) & 7)) * 8);
    #pragma unroll
    for (int i = 0; i < 2; ++i)
      gload16(&A[(long long)(m0 + h * 128 + (t >> 3) + 64 * i) * 4096 + kk],
              &As[(db * 2 + h) * 8192 + (w * 8 + 64 * i) * 64]);
  };
  auto stB = [&](int db, int h, int tile) {
    const long long kk = kbase + tile * 64 + (((t & 7) ^ ((t >> 3) & 7)) * 8);
    #pragma unroll
    for (int i = 0; i < 2; ++i)
      gload16(&Bw[(long long)(n0 + h * 128 + (t >> 3) + 64 * i) * 4096 + kk],
              &Bs[(db * 2 + h) * 8192 + (w * 8 + 64 * i) * 64]);
  };

#define RDA(db,qm,fm,ks) \
  (*reinterpret_cast<const bf16x8*>(&As[((db)*2+(qm))*8192 + \
      (wr64 + (fm)*16 + l15)*64 + ((((ks)*4 + l4) ^ l7) * 8)]))
#define RDB(db,qn,fn,ks) \
  (*reinterpret_cast<const bf16x8*>(&Bs[((db)*2+(qn))*8192 + \
      (wc32 + (fn)*16 + l15)*64 + ((((ks)*4 + l4) ^ l7) * 8)]))

  f32x4 acc[2][2][4][2] = {};

#define PHASE(db, qm, qn, STAGE_STMT, WAIT_STMT)                            \
  do {                                                                      \
    bf16x8 a_[4][2], b_[2][2];                                              \
    _Pragma("unroll")                                                       \
    for (int fm_ = 0; fm_ < 4; ++fm_) {                                     \
      a_[fm_][0] = RDA(db, qm, fm_, 0);                                     \
      a_[fm_][1] = RDA(db, qm, fm_, 1);                                     \
    }                                                                       \
    b_[0][0] = RDB(db, qn, 0, 0); b_[0][1] = RDB(db, qn, 0, 1);             \
    b_[1][0] = RDB(db, qn, 1, 0); b_[1][1] = RDB(db, qn, 1, 1);             \
    STAGE_STMT;                                                             \
    asm volatile("s_barrier" ::: "memory");                                 \
    __builtin_amdgcn_s_setprio(1);                                          \
    _Pragma("unroll")                                                       \
    for (int fm_ = 0; fm_ < 4; ++fm_) {                                     \
      _Pragma("unroll")                                                     \
      for (int fn_ = 0; fn_ < 2; ++fn_) {                                   \
        acc[qm][qn][fm_][fn_] = __builtin_amdgcn_mfma_f32_16x16x32_bf16(    \
            a_[fm_][0], b_[fn_][0], acc[qm][qn][fm_][fn_], 0, 0, 0);        \
        acc[qm][qn][fm_][fn_] = __builtin_amdgcn_mfma_f32_16x16x32_bf16(    \
            a_[fm_][1], b_[fn_][1], acc[qm][qn][fm_][fn_], 0, 0, 0);        \
      }                                                                     \
    }                                                                       \
    __builtin_amdgcn_s_setprio(0);                                          \
    WAIT_STMT;                                                              \
    asm volatile("s_barrier" ::: "memory");                                 \
  } while (0)

  // prologue: tile0 all 4 halves + tile1 h0 (A,B); drain tile0, keep 4 in flight
  stA(0, 0, 0); stB(0, 0, 0); stA(0, 1, 0); stB(0, 1, 0);
  stA(1, 0, 1); stB(1, 0, 1);
  asm volatile("s_waitcnt vmcnt(4)" ::: "memory");
  asm volatile("s_barrier" ::: "memory");

  // nt = 32 K-tiles per z-part -> 16 iterations of 2 tiles (8 phases)
  for (int j = 0; j < 16; ++j) {
    const bool s2 = (j < 15);
    const int t1 = 2 * j + 1, t2 = 2 * j + 2, t3 = 2 * j + 3;
    PHASE(0, 0, 0, stA(1, 1, t1), );
    PHASE(0, 0, 1, stB(1, 1, t1), );
    PHASE(0, 1, 0, if (s2) stA(0, 0, t2), );
    PHASE(0, 1, 1, if (s2) stB(0, 0, t2),
          if (s2) { asm volatile("s_waitcnt vmcnt(4)" ::: "memory"); }
          else    { asm volatile("s_waitcnt vmcnt(0)" ::: "memory"); } );
    PHASE(1, 0, 0, if (s2) stA(0, 1, t2), );
    PHASE(1, 0, 1, if (s2) stB(0, 1, t2), );
    PHASE(1, 1, 0, if (s2) stA(1, 0, t3), );
    PHASE(1, 1, 1, if (s2) stB(1, 0, t3),
          if (s2) { asm volatile("s_waitcnt vmcnt(4)" ::: "memory"); } );
  }
#undef PHASE
#undef RDA
#undef RDB

  // epilogue: f32 partial store
  float* P = part + (long long)z * (4096LL * 2048);
  #pragma unroll
  for (int qm = 0; qm < 2; ++qm)
    #pragma unroll
    for (int qn = 0; qn < 2; ++qn)
      #pragma unroll
      for (int fm = 0; fm < 4; ++fm)
        #pragma unroll
        for (int r = 0; r < 4; ++r) {
          const long long row = m0 + qm * 128 + wr64 + fm * 16 + l4 * 4 + r;
          #pragma unroll
          for (int fn = 0; fn < 2; ++fn) {
            const int col = n0 + qn * 128 + wc32 + fn * 16 + l15;
            P[row * 2048 + col] = acc[qm][qn][fm][fn][r];
          }
        }
}

// reduce split-K partials + bias -> bf16 kv
__global__ __launch_bounds__(256)
void kv_reduce(const float* __restrict__ part, const float* __restrict__ bkv,
               u16* __restrict__ kvb)
{
  const long long i = ((long long)blockIdx.x * 256 + threadIdx.x) * 4;
  const int col = (int)(i & 2047);
  float4 p0 = *reinterpret_cast<const float4*>(&part[i]);
  float4 p1 = *reinterpret_cast<const float4*>(&part[i + 4096LL * 2048]);
  float4 bb = *reinterpret_cast<const float4*>(&bkv[col]);
  u16x4 o = {f2b(p0.x + p1.x + bb.x), f2b(p0.y + p1.y + bb.y),
             f2b(p0.z + p1.z + bb.z), f2b(p0.w + p1.w + bb.w)};
  *reinterpret_cast<u16x4*>(&kvb[i]) = o;
}

// ---------------------------------------------------------------------------
// 2-phase bf16 MFMA GEMM (all other shapes) — unchanged from R4.
// ---------------------------------------------------------------------------
constexpr int E_BIAS = 1, E_RES = 2, E_RELU = 4, E_WF32 = 8, E_WB16 = 16;

template<int BM, int BN, int WM, int WN, int EPI, int BSRC>
__global__ __launch_bounds__(256)
void gemm_bf16(const u16* __restrict__ A, const void* __restrict__ Bw,
               const float* __restrict__ bias, const float* __restrict__ res,
               float* __restrict__ C, u16* __restrict__ Cb,
               int K, int lda, int ldb, int ldc, int nbz2,
               long long sA1, long long sA2, long long sB1, long long sB2,
               long long sC1, long long sC2, float alpha)
{
  static_assert(BSRC == 0 || BN == 128, "reg-staged B assumes BN=128");
  constexpr int SM = BM / WM, SN = BN / WN;
  constexpr int FM = SM / 16, FN = SN / 16;
  constexpr int PA = BM / 64, PB = BN / 64;
  __shared__ __align__(16) u16 As[2][BM * 32];
  __shared__ __align__(16) u16 Bs[2][BN * 32];

  const int gx = gridDim.x, gy = gridDim.y;
  const int nwg = gx * gy * gridDim.z;
  const int flat = (blockIdx.z * gy + blockIdx.y) * gx + blockIdx.x;
  const int qq = nwg >> 3, rr = nwg & 7;
  const int xcd = flat & 7, lid = flat >> 3;
  const int wg = (xcd < rr ? xcd * (qq + 1) : rr * (qq + 1) + (xcd - rr) * qq) + lid;
  const int bx = wg % gx;
  const int tmp1 = wg / gx;
  const int by = tmp1 % gy, bz = tmp1 / gy;

  const int t = threadIdx.x;
  const int w = t >> 6, l = t & 63;
  const int wr = w / WN, wc = w % WN;
  const int m0 = by * BM, n0 = bx * BN;
  const long long offA = (long long)(bz / nbz2) * sA1 + (long long)(bz % nbz2) * sA2;
  const long long offB = (long long)(bz / nbz2) * sB1 + (long long)(bz % nbz2) * sB2;
  const long long offC = (long long)(bz / nbz2) * sC1 + (long long)(bz % nbz2) * sC2;
  const u16* Ab = A + offA;

  const int srow = t >> 2;
  const int sk   = (t & 3) * 8;

  auto stageA = [&](int buf, int k0) {
    #pragma unroll
    for (int p = 0; p < PA; ++p)
      gload16(&Ab[(long long)(m0 + p * 64 + srow) * lda + k0 + sk],
              &As[buf][p * 2048 + w * 512]);
  };
  auto stageB_g = [&](int buf, int k0) {
    const u16* Bb = (const u16*)Bw + offB;
    #pragma unroll
    for (int p = 0; p < PB; ++p)
      gload16(&Bb[(long long)(n0 + p * 64 + srow) * ldb + k0 + sk],
              &Bs[buf][p * 2048 + w * 512]);
  };
  auto loadB = [&](float4* rg, int k0) {
    const float* Bf = (const float*)Bw + offB;
    if constexpr (BSRC == 1) {
      const int r = t >> 1, c0 = (t & 1) * 16;
      #pragma unroll
      for (int c = 0; c < 4; ++c)
        rg[c] = *reinterpret_cast<const float4*>(
            &Bf[(long long)(n0 + r) * ldb + k0 + c0 + c * 4]);
    } else {
      const int kk = t >> 3;
      #pragma unroll
      for (int p = 0; p < 4; ++p)
        rg[p] = *reinterpret_cast<const float4*>(
            &Bf[(long long)(k0 + kk) * ldb + n0 + (t & 7) * 4 + 32 * p]);
    }
  };
  auto writeB = [&](int buf, const float4* rg) {
    if constexpr (BSRC == 1) {
      const int r = t >> 1, c0 = (t & 1) * 16;
      #pragma unroll
      for (int c = 0; c < 4; ++c) {
        u16x4 o = {f2b(rg[c].x), f2b(rg[c].y), f2b(rg[c].z), f2b(rg[c].w)};
        *reinterpret_cast<u16x4*>(&Bs[buf][r * 32 + c0 + c * 4]) = o;
      }
    } else {
      const int kk = t >> 3;
      #pragma unroll
      for (int p = 0; p < 4; ++p) {
        const int nn = (t & 7) * 4 + 32 * p;
        Bs[buf][(nn + 0) * 32 + kk] = f2b(rg[p].x);
        Bs[buf][(nn + 1) * 32 + kk] = f2b(rg[p].y);
        Bs[buf][(nn + 2) * 32 + kk] = f2b(rg[p].z);
        Bs[buf][(nn + 3) * 32 + kk] = f2b(rg[p].w);
      }
    }
  };

  f32x4 acc[FM][FN] = {};

  stageA(0, 0);
  if constexpr (BSRC == 0) {
    stageB_g(0, 0);
  } else {
    float4 rg[4];
    loadB(rg, 0);
    writeB(0, rg);
  }

  int cur = 0;
  for (int k0 = 0; k0 < K; k0 += 32) {
    __syncthreads();
    const bool pf = (k0 + 32 < K);
    float4 rg[4];
    if (pf) {
      stageA(cur ^ 1, k0 + 32);
      if constexpr (BSRC == 0) stageB_g(cur ^ 1, k0 + 32);
      else                     loadB(rg, k0 + 32);
    }

    bf16x8 af[FM], bfr[FN];
    #pragma unroll
    for (int i = 0; i < FM; ++i)
      af[i] = *reinterpret_cast<const bf16x8*>(
          &As[cur][(wr * SM + i * 16 + (l & 15)) * 32 + (l >> 4) * 8]);
    #pragma unroll
    for (int j = 0; j < FN; ++j)
      bfr[j] = *reinterpret_cast<const bf16x8*>(
          &Bs[cur][(wc * SN + j * 16 + (l & 15)) * 32 + (l >> 4) * 8]);
    #pragma unroll
    for (int i = 0; i < FM; ++i)
      #pragma unroll
      for (int j = 0; j < FN; ++j)
        acc[i][j] = __builtin_amdgcn_mfma_f32_16x16x32_bf16(af[i], bfr[j], acc[i][j], 0, 0, 0);

    if constexpr (BSRC != 0) {
      if (pf) writeB(cur ^ 1, rg);
    }
    cur ^= 1;
  }

  const int c_l = l & 15, r_l4 = (l >> 4) * 4;
  #pragma unroll
  for (int i = 0; i < FM; ++i) {
    #pragma unroll
    for (int r = 0; r < 4; ++r) {
      const long long row = m0 + wr * SM + i * 16 + r_l4 + r;
      #pragma unroll
      for (int j = 0; j < FN; ++j) {
        const int col = n0 + wc * SN + j * 16 + c_l;
        float v = acc[i][j][r] * alpha;
        if (EPI & E_BIAS) v += bias[col];
        if (EPI & E_RES)  v += res[row * (long long)ldc + col];
        if (EPI & E_RELU) v = fmaxf(v, 0.f);
        const long long co = offC + row * (long long)ldc + col;
        if (EPI & E_WF32) C[co] = v;
        if (EPI & E_WB16) Cb[co] = f2b(v);
      }
    }
  }
}

// ---------------------------------------------------------------------------
// fused multi-segment f32 -> bf16 conversion (weights + memory_txt)
// ---------------------------------------------------------------------------
struct Cvt7 { const float* s[7]; u16* d[7]; int cum[8]; };

__global__ __launch_bounds__(256)
void cvt_multi(Cvt7 a)
{
  const int bidx = blockIdx.x;
  int seg = 0;
  #pragma unroll
  for (int k = 1; k < 7; ++k) if (bidx >= a.cum[k]) seg = k;
  const long long off = ((long long)(bidx - a.cum[seg]) * 256 + threadIdx.x) * 4;
  float4 x = *reinterpret_cast<const float4*>(a.s[seg] + off);
  u16x4 o = {f2b(x.x), f2b(x.y), f2b(x.z), f2b(x.w)};
  *reinterpret_cast<u16x4*>(a.d[seg] + off) = o;
}

__global__ __launch_bounds__(256)
void cvt_add_bf16(const float* __restrict__ a, const float* __restrict__ b,
                  u16* __restrict__ out)
{
  const long long i = ((long long)blockIdx.x * 256 + threadIdx.x) * 4;
  float4 x = *reinterpret_cast<const float4*>(&a[i]);
  float4 y = *reinterpret_cast<const float4*>(&b[i]);
  u16x4 o = {f2b(x.x + y.x), f2b(x.y + y.y), f2b(x.z + y.z), f2b(x.w + y.w)};
  *reinterpret_cast<u16x4*>(&out[i]) = o;
}

__global__ __launch_bounds__(256)
void transpose_u16(const u16* __restrict__ in, u16* __restrict__ out,
                   int R, int C, int ldin, long long sbin, long long sbout)
{
  __shared__ u16 tile[32][34];
  const int b = blockIdx.z;
  const int r0 = blockIdx.y * 32, c0 = blockIdx.x * 32;
  const int tx = threadIdx.x & 31, ty = threadIdx.x >> 5;
  const u16* ib = in + (long long)b * sbin;
  u16* ob = out + (long long)b * sbout;
  #pragma unroll
  for (int p = 0; p < 4; ++p) {
    int r = ty + p * 8;
    tile[r][tx] = ib[(long long)(r0 + r) * ldin + c0 + tx];
  }
  __syncthreads();
  #pragma unroll
  for (int p = 0; p < 4; ++p) {
    int c = ty + p * 8;
    ob[(long long)(c0 + c) * R + r0 + tx] = tile[tx][c];
  }
}

// ---------------------------------------------------------------------------
__global__ __launch_bounds__(256)
void txt_softmax_mean(const float* __restrict__ sc, const int* __restrict__ mask,
                      u16* __restrict__ wout, float* __restrict__ out1)
{
  __shared__ float red[8];
  const int t = threadIdx.x, l = t & 63, w = t >> 6;
  const int bq = blockIdx.x;
  const int b = bq >> 8, q = bq & 255;
  const int* mr = mask + b * LT;
  const bool msk0 = mr[t] != 0, msk1 = mr[t + 256] != 0;
  float a0 = 0.f, a1 = 0.f;
  for (int h = 0; h < H; ++h) {
    const long long ro = (((long long)(b * H + h)) * NQ + q) * LT;
    const float* sr = sc + ro;
    float x0 = msk0 ? -INFINITY : sr[t];
    float x1 = msk1 ? -INFINITY : sr[t + 256];
    float mx = fmaxf(x0, x1);
    #pragma unroll
    for (int o = 32; o > 0; o >>= 1) mx = fmaxf(mx, __shfl_xor(mx, o, 64));
    if (l == 0) red[w] = mx;
    __syncthreads();
    mx = fmaxf(fmaxf(red[0], red[1]), fmaxf(red[2], red[3]));
    float e0 = __expf(x0 - mx), e1 = __expf(x1 - mx);
    float s = e0 + e1;
    #pragma unroll
    for (int o = 32; o > 0; o >>= 1) s += __shfl_xor(s, o, 64);
    if (l == 0) red[4 + w] = s;
    __syncthreads();
    s = red[4] + red[5] + red[6] + red[7];
    const float inv = 1.f / s;
    const float w0 = e0 * inv, w1 = e1 * inv;
    u16* wr = wout + ro;
    wr[t] = f2b(w0); wr[t + 256] = f2b(w1);
    a0 += w0; a1 += w1;
  }
  float* o1 = out1 + (long long)bq * LT;
  o1[t]       = a0 * (1.f / H);
  o1[t + 256] = a1 * (1.f / H);
}

// ---------------------------------------------------------------------------
__global__ __launch_bounds__(256)
void ln_kernel(const float* __restrict__ x, const float* __restrict__ g,
               const float* __restrict__ bia, float* __restrict__ y,
               u16* __restrict__ yb, float scale)
{
  __shared__ float tmp[256];
  const int t = threadIdx.x;
  const long long off = (long long)blockIdx.x * D;
  float4 x4 = *reinterpret_cast<const float4*>(&x[off + t * 4]);
  tmp[t] = x4.x + x4.y + x4.z + x4.w;
  __syncthreads();
  for (int o = 128; o > 0; o >>= 1) { if (t < o) tmp[t] += tmp[t + o]; __syncthreads(); }
  const float mean = tmp[0] * (1.f / D);
  __syncthreads();
  float d0 = x4.x - mean, d1 = x4.y - mean, d2 = x4.z - mean, d3 = x4.w - mean;
  tmp[t] = d0 * d0 + d1 * d1 + d2 * d2 + d3 * d3;
  __syncthreads();
  for (int o = 128; o > 0; o >>= 1) { if (t < o) tmp[t] += tmp[t + o]; __syncthreads(); }
  const float rs = rsqrtf(tmp[0] * (1.f / D) + 1e-5f);
  float4 g4 = *reinterpret_cast<const float4*>(&g[t * 4]);
  float4 b4 = *reinterpret_cast<const float4*>(&bia[t * 4]);
  float o0 = (d0 * rs * g4.x + b4.x) * scale;
  float o1 = (d1 * rs * g4.y + b4.y) * scale;
  float o2 = (d2 * rs * g4.z + b4.z) * scale;
  float o3 = (d3 * rs * g4.w + b4.w) * scale;
  if (y) {
    float4 o4 = {o0, o1, o2, o3};
    *reinterpret_cast<float4*>(&y[off + t * 4]) = o4;
  }
  if (yb) {
    u16x4 ob = {f2b(o0), f2b(o1), f2b(o2), f2b(o3)};
    *reinterpret_cast<u16x4*>(&yb[off + t * 4]) = ob;
  }
}

// ---------------------------------------------------------------------------
__global__ __launch_bounds__(256)
void vox_softmax(float* __restrict__ s, const int* __restrict__ mask,
                 u16* __restrict__ wb)
{
  __shared__ float tmp[256];
  const int t = threadIdx.x;
  const int row = blockIdx.x, b = row / NQ;
  float* sr = s + (long long)row * NV;
  u16* wr = wb + (long long)row * NV;
  const int* mr = mask + b * NV;
  float vals[16];
  float lm = -INFINITY;
  #pragma unroll
  for (int j = 0; j < 16; ++j) {
    int n = t + j * 256;
    float x = mr[n] ? -INFINITY : sr[n];
    vals[j] = x;
    lm = fmaxf(lm, x);
  }
  tmp[t] = lm;
  __syncthreads();
  for (int o = 128; o > 0; o >>= 1) { if (t < o) tmp[t] = fmaxf(tmp[t], tmp[t + o]); __syncthreads(); }
  const float mx = tmp[0];
  __syncthreads();
  float ls = 0.f;
  #pragma unroll
  for (int j = 0; j < 16; ++j) { vals[j] = __expf(vals[j] - mx); ls += vals[j]; }
  tmp[t] = ls;
  __syncthreads();
  for (int o = 128; o > 0; o >>= 1) { if (t < o) tmp[t] += tmp[t + o]; __syncthreads(); }
  const float inv = 1.f / tmp[0];
  #pragma unroll
  for (int j = 0; j < 16; ++j) {
    float v = vals[j] * inv;
    sr[t + j * 256] = v;
    wr[t + j * 256] = f2b(v);
  }
}

__global__ __launch_bounds__(256)
void splitk_reduce(const float* __restrict__ part, float* __restrict__ out)
{
  const long long i = ((long long)blockIdx.x * 256 + threadIdx.x) * 4;
  const long long nd = (long long)NQ * D;
  const long long b = i / nd;
  const long long o = i - b * nd;
  const float* p = part + b * 4 * nd + o;
  float4 s0 = *reinterpret_cast<const float4*>(&p[0]);
  float4 s1 = *reinterpret_cast<const float4*>(&p[nd]);
  float4 s2 = *reinterpret_cast<const float4*>(&p[2 * nd]);
  float4 s3 = *reinterpret_cast<const float4*>(&p[3 * nd]);
  float4 r = {s0.x + s1.x + s2.x + s3.x, s0.y + s1.y + s2.y + s3.y,
              s0.z + s1.z + s2.z + s3.z, s0.w + s1.w + s2.w + s3.w};
  *reinterpret_cast<float4*>(&out[i]) = r;
}

// ---------------------------------------------------------------------------
extern "C" void kernel_launch(void* const* d_in, const int* in_sizes, int n_in,
                              void* d_out, int out_size, void* d_ws, size_t ws_size,
                              hipStream_t stream)
{
  const float* tgt   = (const float*)d_in[0];
  const float* mtxt  = (const float*)d_in[1];
  const float* vox   = (const float*)d_in[2];
  const float* qpos  = (const float*)d_in[3];
  const int*   mtx_m = (const int*)d_in[4];
  const int*   vox_m = (const int*)d_in[5];
  const float* Wq = (const float*)d_in[6];  const float* bq = (const float*)d_in[7];
  const float* Wk = (const float*)d_in[8];  const float* bk = (const float*)d_in[9];
  const float* Wv = (const float*)d_in[10]; const float* bv = (const float*)d_in[11];
  const float* Wo = (const float*)d_in[12]; const float* bo = (const float*)d_in[13];
  const float* W1 = (const float*)d_in[14]; const float* b1 = (const float*)d_in[15];
  const float* W2 = (const float*)d_in[16]; const float* b2 = (const float*)d_in[17];
  const float* ln1g = (const float*)d_in[18]; const float* ln1b = (const float*)d_in[19];
  const float* ln2g = (const float*)d_in[20]; const float* ln2b = (const float*)d_in[21];

  float* out0 = (float*)d_out;                       // attn_output  [B,NQ,D]
  float* out1 = out0 + (long long)B * NQ * D;        // txt_cross    [B,NQ,LT]
  float* out2 = out1 + (long long)B * NQ * LT;       // attn_weights [B,NQ,NV]

  char* base = (char*)d_ws;
  constexpr size_t MB = 1ull << 20;
  u16*   kvW   = (u16*)(base + 0 * MB);     // 16  [Wk;Wv] stacked [2048][4096]
  u16*   Wq_b  = (u16*)(base + 16 * MB);    // 2
  u16*   Wo_b  = (u16*)(base + 18 * MB);    // 2
  u16*   W1_b  = (u16*)(base + 20 * MB);    // 4
  u16*   W2_b  = (u16*)(base + 24 * MB);    // 4
  u16*   tq_b  = (u16*)(base + 28 * MB);    // 4
  u16*   q_b   = (u16*)(base + 32 * MB);    // 4
  u16*   kv_b  = (u16*)(base + 36 * MB);    // 16  [B*LT][2048] (k | v)
  u16*   vT_b  = (u16*)(base + 52 * MB);    // 8   [B][D][LT]
  u16*   ctx_b = (u16*)(base + 60 * MB);    // 4
  float* x1p   = (float*)(base + 64 * MB);  // 8
  float* x1f   = (float*)(base + 72 * MB);  // 8
  u16*   x1_b  = (u16*)(base + 80 * MB);    // 4
  u16*   ff1_b = (u16*)(base + 84 * MB);    // 8
  float* x2p   = (float*)(base + 92 * MB);  // 8
  u16*   x2s_b = (u16*)(base + 100 * MB);   // 4
  u16*   mtxt_b = (u16*)(base + 104 * MB);  // 32  dead after KV proj
  float* kvpart = (float*)(base + 136 * MB);// 64  dead after kv_reduce
  float* scores = (float*)(base + 136 * MB);// 64  (after kv_reduce) dead after softmax
  float* bkv    = (float*)(base + 200 * MB);// 8KB (within w_b region, dead before w_b)
  u16*   w_b    = (u16*)(base + 200 * MB);  // 32  dead after ctx gemm
  u16*   wvox_b = (u16*)(base + 0 * MB);    // 16  overlays kvW (dead)
  float* part   = (float*)(base + 16 * MB); // 32  overlays Wq..kv_b head (dead)

  const dim3 blk(256);
  const long long sQ = (long long)NQ * D;
  const long long sSC = (long long)NQ * LT;
  const long long nd = (long long)NQ * D;

  // 1) conversions: one fused kernel for 6 weights + memory_txt
  Cvt7 ca;
  ca.s[0] = Wq;   ca.d[0] = Wq_b;
  ca.s[1] = Wk;   ca.d[1] = kvW;
  ca.s[2] = Wv;   ca.d[2] = kvW + (long long)D * FTXT;
  ca.s[3] = Wo;   ca.d[3] = Wo_b;
  ca.s[4] = W1;   ca.d[4] = W1_b;
  ca.s[5] = W2;   ca.d[5] = W2_b;
  ca.s[6] = mtxt; ca.d[6] = mtxt_b;
  ca.cum[0] = 0;     ca.cum[1] = 1024;  ca.cum[2] = 5120;  ca.cum[3] = 9216;
  ca.cum[4] = 10240; ca.cum[5] = 12288; ca.cum[6] = 14336; ca.cum[7] = 30720;
  cvt_multi<<<dim3(30720), blk, 0, stream>>>(ca);
  hipMemcpyAsync(bkv, bk, D * sizeof(float), hipMemcpyDeviceToDevice, stream);
  hipMemcpyAsync(bkv + D, bv, D * sizeof(float), hipMemcpyDeviceToDevice, stream);
  cvt_add_bf16<<<dim3((B * NQ * D) / 1024), blk, 0, stream>>>(tgt, qpos, tq_b);

  // 2) q = tq @ Wq^T + bq  (512 blocks, 2-phase)
  gemm_bf16<64,64,2,2, E_BIAS|E_WB16, 0><<<dim3(D/64, (B*NQ)/64, 1), blk, 0, stream>>>(
      tq_b, Wq_b, bq, nullptr, nullptr, q_b, D, D, D, D, 1, 0,0,0,0,0,0, 1.f);
  //    kv partials = mtxt @ [Wk;Wv]^T  (8-phase 256x256, split-K=2, 256 blocks)
  gemm_kv256<<<dim3(8, 16, 2), dim3(512), 0, stream>>>(mtxt_b, kvW, kvpart);
  //    kv = sum partials + [bk;bv], bf16
  kv_reduce<<<dim3((4096 * 2048) / 1024), blk, 0, stream>>>(kvpart, bkv, kv_b);

  // 3) vT[b][d][l] = v[b][l][d]
  transpose_u16<<<dim3(D/32, LT/32, B), blk, 0, stream>>>(
      kv_b + 1024, vT_b, LT, D, 2048, (long long)LT * 2048, (long long)D * LT);

  // 4) scores[b,h,q,l] = (q_h . k_h) / 8   (1024 blocks)
  gemm_bf16<128,128,2,2, E_WF32, 0><<<dim3(LT/128, NQ/128, B*H), blk, 0, stream>>>(
      q_b, kv_b, nullptr, nullptr, scores, nullptr, HD, D, 2048, LT, H,
      sQ, HD, (long long)LT * 2048, HD, (long long)H * sSC, sSC, 0.125f);

  // 5) fused softmax + head-mean
  txt_softmax_mean<<<dim3(B*NQ), blk, 0, stream>>>(scores, mtx_m, w_b, out1);

  // 6) ctx = w_h @ v_h  (512 blocks)
  gemm_bf16<64,64,2,2, E_WB16, 0><<<dim3(HD/64, NQ/64, B*H), blk, 0, stream>>>(
      w_b, vT_b, nullptr, nullptr, nullptr, ctx_b, LT, LT, LT, D, H,
      (long long)H * sSC, sSC, (long long)D * LT, (long long)HD * LT, sQ, HD, 1.f);

  // 7) x1p = tgt + ctx @ Wo^T + bo  (512 blocks)
  gemm_bf16<64,64,2,2, E_BIAS|E_RES|E_WF32, 0><<<dim3(D/64, (B*NQ)/64, 1), blk, 0, stream>>>(
      ctx_b, Wo_b, bo, tgt, x1p, nullptr, D, D, D, D, 1, 0,0,0,0,0,0, 1.f);

  // 8) LN1 -> x1 (f32 + bf16)
  ln_kernel<<<dim3(B*NQ), blk, 0, stream>>>(x1p, ln1g, ln1b, x1f, x1_b, 1.f);

  // 9) ff1 = relu(x1 @ W1^T + b1)  (512 blocks)
  gemm_bf16<128,64,2,2, E_BIAS|E_RELU|E_WB16, 0><<<dim3(DFF/64, (B*NQ)/128, 1), blk, 0, stream>>>(
      x1_b, W1_b, b1, nullptr, nullptr, ff1_b, D, D, D, DFF, 1, 0,0,0,0,0,0, 1.f);

  // 10) x2p = x1 + ff1 @ W2^T + b2  (512 blocks)
  gemm_bf16<64,64,2,2, E_BIAS|E_RES|E_WF32, 0><<<dim3(D/64, (B*NQ)/64, 1), blk, 0, stream>>>(
      ff1_b, W2_b, b2, x1f, x2p, nullptr, DFF, DFF, DFF, D, 1, 0,0,0,0,0,0, 1.f);

  // 11) LN2 -> x2s (bf16, /sqrt(D))
  ln_kernel<<<dim3(B*NQ), blk, 0, stream>>>(x2p, ln2g, ln2b, nullptr, x2s_b, 0.03125f);

  // 12) out2 = x2s @ vox^T — B staged directly from f32 vox (1024 blocks)
  gemm_bf16<64,128,2,2, E_WF32, 1><<<dim3(NV/128, NQ/64, B), blk, 0, stream>>>(
      x2s_b, vox, nullptr, nullptr, out2, nullptr, D, D, D, NV, 1,
      sQ, 0, (long long)NV * D, 0, (long long)NQ * NV, 0, 1.f);

  // 13) masked softmax in place; bf16 weights
  vox_softmax<<<dim3(B*NQ), blk, 0, stream>>>(out2, vox_m, wvox_b);

  // 14) out0 partials: split-K=4 over NV; B transpose-staged from f32 vox
  gemm_bf16<64,128,2,2, E_WF32, 2><<<dim3(D/128, NQ/64, B*4), blk, 0, stream>>>(
      wvox_b, vox, nullptr, nullptr, part, nullptr, NV/4, NV, D, D, 4,
      (long long)NQ * NV, 1024, (long long)NV * D, (long long)1024 * D,
      4 * nd, nd, 1.f);
  splitk_reduce<<<dim3((B * NQ * D) / 1024), blk, 0, stream>>>(part, out0);
}

// Round 7
// 449.303 us; speedup vs baseline: 1.1389x; 1.0226x over previous
//
#include <hip/hip_runtime.h>
#include <math.h>

typedef unsigned short u16;
typedef unsigned int u32;
typedef __bf16 bf16x8 __attribute__((ext_vector_type(8)));
typedef float f32x4 __attribute__((ext_vector_type(4)));
typedef u16 u16x4 __attribute__((ext_vector_type(4)));

constexpr int B = 8, NQ = 256, LT = 512, NV = 4096;
constexpr int D = 1024, H = 16, DFF = 2048, FTXT = 4096, HD = 64;

__device__ __forceinline__ u16 f2b(float f) {
  u32 u = __builtin_bit_cast(u32, f);
  return (u16)((u + 0x7fffu + ((u >> 16) & 1u)) >> 16);   // RNE
}
__device__ __forceinline__ float b2f(u16 b) {
  u32 u = ((u32)b) << 16;
  return __builtin_bit_cast(float, u);
}
__device__ __forceinline__ void gload16(const void* g, void* l) {
  __builtin_amdgcn_global_load_lds(
      (const __attribute__((address_space(1))) u32*)g,
      (__attribute__((address_space(3))) u32*)l, 16, 0, 0);
}

// ===========================================================================
// 256x256 8-phase bf16 GEMM (m201 template) for the KV projection.
// part[z][4096][2048] = A[4096][2048 @ z*2048] @ Bw[2048][same]^T
// ===========================================================================
__global__ __launch_bounds__(512, 2)
void gemm_kv256(const u16* __restrict__ A, const u16* __restrict__ Bw,
                float* __restrict__ part)
{
  __shared__ __align__(16) u16 As[4 * 8192];   // [db*2+half][128][64]
  __shared__ __align__(16) u16 Bs[4 * 8192];

  const int gx = 8, gy = 16;
  const int nwg = 256;
  const int flat = (blockIdx.z * gy + blockIdx.y) * gx + blockIdx.x;
  const int qq = nwg >> 3;
  const int xcd = flat & 7, lid = flat >> 3;
  const int wg = xcd * qq + lid;
  const int bx = wg % gx;
  const int by = (wg / gx) % gy;
  const int z  = wg / (gx * gy);
  const int m0 = by * 256, n0 = bx * 256;
  const long long kbase = (long long)z * 2048;

  const int t = threadIdx.x;
  const int w = t >> 6, l = t & 63;
  const int wr64 = (w >> 2) * 64;
  const int wc32 = (w & 3) * 32;
  const int l15 = l & 15, l4 = l >> 4, l7 = l & 7;

  auto stA = [&](int db, int h, int tile) {
    const long long kk = kbase + tile * 64 + (((t & 7) ^ ((t >> 3) & 7)) * 8);
    #pragma unroll
    for (int i = 0; i < 2; ++i)
      gload16(&A[(long long)(m0 + h * 128 + (t >> 3) + 64 * i) * 4096 + kk],
              &As[(db * 2 + h) * 8192 + (w * 8 + 64 * i) * 64]);
  };
  auto stB = [&](int db, int h, int tile) {
    const long long kk = kbase + tile * 64 + (((t & 7) ^ ((t >> 3) & 7)) * 8);
    #pragma unroll
    for (int i = 0; i < 2; ++i)
      gload16(&Bw[(long long)(n0 + h * 128 + (t >> 3) + 64 * i) * 4096 + kk],
              &Bs[(db * 2 + h) * 8192 + (w * 8 + 64 * i) * 64]);
  };

#define RDA(db,qm,fm,ks) \
  (*reinterpret_cast<const bf16x8*>(&As[((db)*2+(qm))*8192 + \
      (wr64 + (fm)*16 + l15)*64 + ((((ks)*4 + l4) ^ l7) * 8)]))
#define RDB(db,qn,fn,ks) \
  (*reinterpret_cast<const bf16x8*>(&Bs[((db)*2+(qn))*8192 + \
      (wc32 + (fn)*16 + l15)*64 + ((((ks)*4 + l4) ^ l7) * 8)]))

  f32x4 acc[2][2][4][2] = {};

#define PHASE(db, qm, qn, STAGE_STMT, WAIT_STMT)                            \
  do {                                                                      \
    bf16x8 a_[4][2], b_[2][2];                                              \
    _Pragma("unroll")                                                       \
    for (int fm_ = 0; fm_ < 4; ++fm_) {                                     \
      a_[fm_][0] = RDA(db, qm, fm_, 0);                                     \
      a_[fm_][1] = RDA(db, qm, fm_, 1);                                     \
    }                                                                       \
    b_[0][0] = RDB(db, qn, 0, 0); b_[0][1] = RDB(db, qn, 0, 1);             \
    b_[1][0] = RDB(db, qn, 1, 0); b_[1][1] = RDB(db, qn, 1, 1);             \
    STAGE_STMT;                                                             \
    asm volatile("s_barrier" ::: "memory");                                 \
    __builtin_amdgcn_s_setprio(1);                                          \
    _Pragma("unroll")                                                       \
    for (int fm_ = 0; fm_ < 4; ++fm_) {                                     \
      _Pragma("unroll")                                                     \
      for (int fn_ = 0; fn_ < 2; ++fn_) {                                   \
        acc[qm][qn][fm_][fn_] = __builtin_amdgcn_mfma_f32_16x16x32_bf16(    \
            a_[fm_][0], b_[fn_][0], acc[qm][qn][fm_][fn_], 0, 0, 0);        \
        acc[qm][qn][fm_][fn_] = __builtin_amdgcn_mfma_f32_16x16x32_bf16(    \
            a_[fm_][1], b_[fn_][1], acc[qm][qn][fm_][fn_], 0, 0, 0);        \
      }                                                                     \
    }                                                                       \
    __builtin_amdgcn_s_setprio(0);                                          \
    WAIT_STMT;                                                              \
    asm volatile("s_barrier" ::: "memory");                                 \
  } while (0)

  stA(0, 0, 0); stB(0, 0, 0); stA(0, 1, 0); stB(0, 1, 0);
  stA(1, 0, 1); stB(1, 0, 1);
  asm volatile("s_waitcnt vmcnt(4)" ::: "memory");
  asm volatile("s_barrier" ::: "memory");

  for (int j = 0; j < 16; ++j) {
    const bool s2 = (j < 15);
    const int t1 = 2 * j + 1, t2 = 2 * j + 2, t3 = 2 * j + 3;
    PHASE(0, 0, 0, stA(1, 1, t1), );
    PHASE(0, 0, 1, stB(1, 1, t1), );
    PHASE(0, 1, 0, if (s2) stA(0, 0, t2), );
    PHASE(0, 1, 1, if (s2) stB(0, 0, t2),
          if (s2) { asm volatile("s_waitcnt vmcnt(4)" ::: "memory"); }
          else    { asm volatile("s_waitcnt vmcnt(0)" ::: "memory"); } );
    PHASE(1, 0, 0, if (s2) stA(0, 1, t2), );
    PHASE(1, 0, 1, if (s2) stB(0, 1, t2), );
    PHASE(1, 1, 0, if (s2) stA(1, 0, t3), );
    PHASE(1, 1, 1, if (s2) stB(1, 0, t3),
          if (s2) { asm volatile("s_waitcnt vmcnt(4)" ::: "memory"); } );
  }
#undef PHASE
#undef RDA
#undef RDB

  float* P = part + (long long)z * (4096LL * 2048);
  #pragma unroll
  for (int qm = 0; qm < 2; ++qm)
    #pragma unroll
    for (int qn = 0; qn < 2; ++qn)
      #pragma unroll
      for (int fm = 0; fm < 4; ++fm)
        #pragma unroll
        for (int r = 0; r < 4; ++r) {
          const long long row = m0 + qm * 128 + wr64 + fm * 16 + l4 * 4 + r;
          #pragma unroll
          for (int fn = 0; fn < 2; ++fn) {
            const int col = n0 + qn * 128 + wc32 + fn * 16 + l15;
            P[row * 2048 + col] = acc[qm][qn][fm][fn][r];
          }
        }
}

__global__ __launch_bounds__(256)
void kv_reduce(const float* __restrict__ part, const float* __restrict__ bkv,
               u16* __restrict__ kvb)
{
  const long long i = ((long long)blockIdx.x * 256 + threadIdx.x) * 4;
  const int col = (int)(i & 2047);
  float4 p0 = *reinterpret_cast<const float4*>(&part[i]);
  float4 p1 = *reinterpret_cast<const float4*>(&part[i + 4096LL * 2048]);
  float4 bb = *reinterpret_cast<const float4*>(&bkv[col]);
  u16x4 o = {f2b(p0.x + p1.x + bb.x), f2b(p0.y + p1.y + bb.y),
             f2b(p0.z + p1.z + bb.z), f2b(p0.w + p1.w + bb.w)};
  *reinterpret_cast<u16x4*>(&kvb[i]) = o;
}

// ---------------------------------------------------------------------------
// 2-phase bf16 MFMA GEMM (bf16 B via global_load_lds only).
// ---------------------------------------------------------------------------
constexpr int E_BIAS = 1, E_RES = 2, E_RELU = 4, E_WF32 = 8, E_WB16 = 16;

template<int BM, int BN, int WM, int WN, int EPI>
__global__ __launch_bounds__(256)
void gemm_bf16(const u16* __restrict__ A, const u16* __restrict__ Bw,
               const float* __restrict__ bias, const float* __restrict__ res,
               float* __restrict__ C, u16* __restrict__ Cb,
               int K, int lda, int ldb, int ldc, int nbz2,
               long long sA1, long long sA2, long long sB1, long long sB2,
               long long sC1, long long sC2, float alpha)
{
  constexpr int SM = BM / WM, SN = BN / WN;
  constexpr int FM = SM / 16, FN = SN / 16;
  constexpr int PA = BM / 64, PB = BN / 64;
  __shared__ __align__(16) u16 As[2][BM * 32];
  __shared__ __align__(16) u16 Bs[2][BN * 32];

  const int gx = gridDim.x, gy = gridDim.y;
  const int nwg = gx * gy * gridDim.z;
  const int flat = (blockIdx.z * gy + blockIdx.y) * gx + blockIdx.x;
  const int qq = nwg >> 3, rr = nwg & 7;
  const int xcd = flat & 7, lid = flat >> 3;
  const int wg = (xcd < rr ? xcd * (qq + 1) : rr * (qq + 1) + (xcd - rr) * qq) + lid;
  const int bx = wg % gx;
  const int tmp1 = wg / gx;
  const int by = tmp1 % gy, bz = tmp1 / gy;

  const int t = threadIdx.x;
  const int w = t >> 6, l = t & 63;
  const int wr = w / WN, wc = w % WN;
  const int m0 = by * BM, n0 = bx * BN;
  const long long offA = (long long)(bz / nbz2) * sA1 + (long long)(bz % nbz2) * sA2;
  const long long offB = (long long)(bz / nbz2) * sB1 + (long long)(bz % nbz2) * sB2;
  const long long offC = (long long)(bz / nbz2) * sC1 + (long long)(bz % nbz2) * sC2;
  const u16* Ab = A + offA;
  const u16* Bb = Bw + offB;

  const int srow = t >> 2;
  const int sk   = (t & 3) * 8;

  auto stageA = [&](int buf, int k0) {
    #pragma unroll
    for (int p = 0; p < PA; ++p)
      gload16(&Ab[(long long)(m0 + p * 64 + srow) * lda + k0 + sk],
              &As[buf][p * 2048 + w * 512]);
  };
  auto stageB = [&](int buf, int k0) {
    #pragma unroll
    for (int p = 0; p < PB; ++p)
      gload16(&Bb[(long long)(n0 + p * 64 + srow) * ldb + k0 + sk],
              &Bs[buf][p * 2048 + w * 512]);
  };

  f32x4 acc[FM][FN] = {};

  stageA(0, 0);
  stageB(0, 0);

  int cur = 0;
  for (int k0 = 0; k0 < K; k0 += 32) {
    __syncthreads();
    const bool pf = (k0 + 32 < K);
    if (pf) {
      stageA(cur ^ 1, k0 + 32);
      stageB(cur ^ 1, k0 + 32);
    }

    bf16x8 af[FM], bfr[FN];
    #pragma unroll
    for (int i = 0; i < FM; ++i)
      af[i] = *reinterpret_cast<const bf16x8*>(
          &As[cur][(wr * SM + i * 16 + (l & 15)) * 32 + (l >> 4) * 8]);
    #pragma unroll
    for (int j = 0; j < FN; ++j)
      bfr[j] = *reinterpret_cast<const bf16x8*>(
          &Bs[cur][(wc * SN + j * 16 + (l & 15)) * 32 + (l >> 4) * 8]);
    #pragma unroll
    for (int i = 0; i < FM; ++i)
      #pragma unroll
      for (int j = 0; j < FN; ++j)
        acc[i][j] = __builtin_amdgcn_mfma_f32_16x16x32_bf16(af[i], bfr[j], acc[i][j], 0, 0, 0);
    cur ^= 1;
  }

  const int c_l = l & 15, r_l4 = (l >> 4) * 4;
  #pragma unroll
  for (int i = 0; i < FM; ++i) {
    #pragma unroll
    for (int r = 0; r < 4; ++r) {
      const long long row = m0 + wr * SM + i * 16 + r_l4 + r;
      #pragma unroll
      for (int j = 0; j < FN; ++j) {
        const int col = n0 + wc * SN + j * 16 + c_l;
        float v = acc[i][j][r] * alpha;
        if (EPI & E_BIAS) v += bias[col];
        if (EPI & E_RES)  v += res[row * (long long)ldc + col];
        if (EPI & E_RELU) v = fmaxf(v, 0.f);
        const long long co = offC + row * (long long)ldc + col;
        if (EPI & E_WF32) C[co] = v;
        if (EPI & E_WB16) Cb[co] = f2b(v);
      }
    }
  }
}

// ---------------------------------------------------------------------------
// vox f32 [B][NV][D] -> vb bf16 [B][NV][D]  AND  vt bf16 [B][D][NV]
// One read of the f32 data produces both bf16 copies. (R3's known-good kernel)
// ---------------------------------------------------------------------------
__global__ __launch_bounds__(256)
void vox_prep(const float* __restrict__ in, u16* __restrict__ vb,
              u16* __restrict__ vt)
{
  __shared__ u16 tile[64][68];
  const int b = blockIdx.z;
  const int n0 = blockIdx.y * 64;
  const int d0 = blockIdx.x * 64;
  const int t = threadIdx.x;
  const int tr = t >> 4;
  const int tc = (t & 15) * 4;
  const float* ib = in + (long long)b * NV * D;
  u16* vbb = vb + (long long)b * NV * D;
  u16* vtb = vt + (long long)b * NV * D;
  #pragma unroll
  for (int p = 0; p < 4; ++p) {
    int r = tr + p * 16;
    float4 x = *reinterpret_cast<const float4*>(&ib[(long long)(n0 + r) * D + d0 + tc]);
    u16x4 o = {f2b(x.x), f2b(x.y), f2b(x.z), f2b(x.w)};
    *reinterpret_cast<u16x4*>(&vbb[(long long)(n0 + r) * D + d0 + tc]) = o;
    *reinterpret_cast<u16x4*>(&tile[r][tc]) = o;
  }
  __syncthreads();
  #pragma unroll
  for (int p = 0; p < 4; ++p) {
    int c = tr + p * 16;
    u16x4 o = {tile[tc + 0][c], tile[tc + 1][c], tile[tc + 2][c], tile[tc + 3][c]};
    *reinterpret_cast<u16x4*>(&vtb[(long long)(d0 + c) * NV + n0 + tc]) = o;
  }
}

// ---------------------------------------------------------------------------
struct Cvt7 { const float* s[7]; u16* d[7]; int cum[8]; };

__global__ __launch_bounds__(256)
void cvt_multi(Cvt7 a)
{
  const int bidx = blockIdx.x;
  int seg = 0;
  #pragma unroll
  for (int k = 1; k < 7; ++k) if (bidx >= a.cum[k]) seg = k;
  const long long off = ((long long)(bidx - a.cum[seg]) * 256 + threadIdx.x) * 4;
  float4 x = *reinterpret_cast<const float4*>(a.s[seg] + off);
  u16x4 o = {f2b(x.x), f2b(x.y), f2b(x.z), f2b(x.w)};
  *reinterpret_cast<u16x4*>(a.d[seg] + off) = o;
}

__global__ __launch_bounds__(256)
void cvt_add_bf16(const float* __restrict__ a, const float* __restrict__ b,
                  u16* __restrict__ out)
{
  const long long i = ((long long)blockIdx.x * 256 + threadIdx.x) * 4;
  float4 x = *reinterpret_cast<const float4*>(&a[i]);
  float4 y = *reinterpret_cast<const float4*>(&b[i]);
  u16x4 o = {f2b(x.x + y.x), f2b(x.y + y.y), f2b(x.z + y.z), f2b(x.w + y.w)};
  *reinterpret_cast<u16x4*>(&out[i]) = o;
}

__global__ __launch_bounds__(256)
void transpose_u16(const u16* __restrict__ in, u16* __restrict__ out,
                   int R, int C, int ldin, long long sbin, long long sbout)
{
  __shared__ u16 tile[32][34];
  const int b = blockIdx.z;
  const int r0 = blockIdx.y * 32, c0 = blockIdx.x * 32;
  const int tx = threadIdx.x & 31, ty = threadIdx.x >> 5;
  const u16* ib = in + (long long)b * sbin;
  u16* ob = out + (long long)b * sbout;
  #pragma unroll
  for (int p = 0; p < 4; ++p) {
    int r = ty + p * 8;
    tile[r][tx] = ib[(long long)(r0 + r) * ldin + c0 + tx];
  }
  __syncthreads();
  #pragma unroll
  for (int p = 0; p < 4; ++p) {
    int c = ty + p * 8;
    ob[(long long)(c0 + c) * R + r0 + tx] = tile[tx][c];
  }
}

// ---------------------------------------------------------------------------
__global__ __launch_bounds__(256)
void txt_softmax_mean(const float* __restrict__ sc, const int* __restrict__ mask,
                      u16* __restrict__ wout, float* __restrict__ out1)
{
  __shared__ float red[8];
  const int t = threadIdx.x, l = t & 63, w = t >> 6;
  const int bq = blockIdx.x;
  const int b = bq >> 8, q = bq & 255;
  const int* mr = mask + b * LT;
  const bool msk0 = mr[t] != 0, msk1 = mr[t + 256] != 0;
  float a0 = 0.f, a1 = 0.f;
  for (int h = 0; h < H; ++h) {
    const long long ro = (((long long)(b * H + h)) * NQ + q) * LT;
    const float* sr = sc + ro;
    float x0 = msk0 ? -INFINITY : sr[t];
    float x1 = msk1 ? -INFINITY : sr[t + 256];
    float mx = fmaxf(x0, x1);
    #pragma unroll
    for (int o = 32; o > 0; o >>= 1) mx = fmaxf(mx, __shfl_xor(mx, o, 64));
    if (l == 0) red[w] = mx;
    __syncthreads();
    mx = fmaxf(fmaxf(red[0], red[1]), fmaxf(red[2], red[3]));
    float e0 = __expf(x0 - mx), e1 = __expf(x1 - mx);
    float s = e0 + e1;
    #pragma unroll
    for (int o = 32; o > 0; o >>= 1) s += __shfl_xor(s, o, 64);
    if (l == 0) red[4 + w] = s;
    __syncthreads();
    s = red[4] + red[5] + red[6] + red[7];
    const float inv = 1.f / s;
    const float w0 = e0 * inv, w1 = e1 * inv;
    u16* wr = wout + ro;
    wr[t] = f2b(w0); wr[t + 256] = f2b(w1);
    a0 += w0; a1 += w1;
  }
  float* o1 = out1 + (long long)bq * LT;
  o1[t]       = a0 * (1.f / H);
  o1[t + 256] = a1 * (1.f / H);
}

// ---------------------------------------------------------------------------
__global__ __launch_bounds__(256)
void ln_kernel(const float* __restrict__ x, const float* __restrict__ g,
               const float* __restrict__ bia, float* __restrict__ y,
               u16* __restrict__ yb, float scale)
{
  __shared__ float tmp[256];
  const int t = threadIdx.x;
  const long long off = (long long)blockIdx.x * D;
  float4 x4 = *reinterpret_cast<const float4*>(&x[off + t * 4]);
  tmp[t] = x4.x + x4.y + x4.z + x4.w;
  __syncthreads();
  for (int o = 128; o > 0; o >>= 1) { if (t < o) tmp[t] += tmp[t + o]; __syncthreads(); }
  const float mean = tmp[0] * (1.f / D);
  __syncthreads();
  float d0 = x4.x - mean, d1 = x4.y - mean, d2 = x4.z - mean, d3 = x4.w - mean;
  tmp[t] = d0 * d0 + d1 * d1 + d2 * d2 + d3 * d3;
  __syncthreads();
  for (int o = 128; o > 0; o >>= 1) { if (t < o) tmp[t] += tmp[t + o]; __syncthreads(); }
  const float rs = rsqrtf(tmp[0] * (1.f / D) + 1e-5f);
  float4 g4 = *reinterpret_cast<const float4*>(&g[t * 4]);
  float4 b4 = *reinterpret_cast<const float4*>(&bia[t * 4]);
  float o0 = (d0 * rs * g4.x + b4.x) * scale;
  float o1 = (d1 * rs * g4.y + b4.y) * scale;
  float o2 = (d2 * rs * g4.z + b4.z) * scale;
  float o3 = (d3 * rs * g4.w + b4.w) * scale;
  if (y) {
    float4 o4 = {o0, o1, o2, o3};
    *reinterpret_cast<float4*>(&y[off + t * 4]) = o4;
  }
  if (yb) {
    u16x4 ob = {f2b(o0), f2b(o1), f2b(o2), f2b(o3)};
    *reinterpret_cast<u16x4*>(&yb[off + t * 4]) = ob;
  }
}

// ---------------------------------------------------------------------------
__global__ __launch_bounds__(256)
void vox_softmax(float* __restrict__ s, const int* __restrict__ mask,
                 u16* __restrict__ wb)
{
  __shared__ float tmp[256];
  const int t = threadIdx.x;
  const int row = blockIdx.x, b = row / NQ;
  float* sr = s + (long long)row * NV;
  u16* wr = wb + (long long)row * NV;
  const int* mr = mask + b * NV;
  float vals[16];
  float lm = -INFINITY;
  #pragma unroll
  for (int j = 0; j < 16; ++j) {
    int n = t + j * 256;
    float x = mr[n] ? -INFINITY : sr[n];
    vals[j] = x;
    lm = fmaxf(lm, x);
  }
  tmp[t] = lm;
  __syncthreads();
  for (int o = 128; o > 0; o >>= 1) { if (t < o) tmp[t] = fmaxf(tmp[t], tmp[t + o]); __syncthreads(); }
  const float mx = tmp[0];
  __syncthreads();
  float ls = 0.f;
  #pragma unroll
  for (int j = 0; j < 16; ++j) { vals[j] = __expf(vals[j] - mx); ls += vals[j]; }
  tmp[t] = ls;
  __syncthreads();
  for (int o = 128; o > 0; o >>= 1) { if (t < o) tmp[t] += tmp[t + o]; __syncthreads(); }
  const float inv = 1.f / tmp[0];
  #pragma unroll
  for (int j = 0; j < 16; ++j) {
    float v = vals[j] * inv;
    sr[t + j * 256] = v;
    wr[t + j * 256] = f2b(v);
  }
}

__global__ __launch_bounds__(256)
void splitk_reduce(const float* __restrict__ part, float* __restrict__ out)
{
  const long long i = ((long long)blockIdx.x * 256 + threadIdx.x) * 4;
  const long long nd = (long long)NQ * D;
  const long long b = i / nd;
  const long long o = i - b * nd;
  const float* p = part + b * 4 * nd + o;
  float4 s0 = *reinterpret_cast<const float4*>(&p[0]);
  float4 s1 = *reinterpret_cast<const float4*>(&p[nd]);
  float4 s2 = *reinterpret_cast<const float4*>(&p[2 * nd]);
  float4 s3 = *reinterpret_cast<const float4*>(&p[3 * nd]);
  float4 r = {s0.x + s1.x + s2.x + s3.x, s0.y + s1.y + s2.y + s3.y,
              s0.z + s1.z + s2.z + s3.z, s0.w + s1.w + s2.w + s3.w};
  *reinterpret_cast<float4*>(&out[i]) = r;
}

// ---------------------------------------------------------------------------
extern "C" void kernel_launch(void* const* d_in, const int* in_sizes, int n_in,
                              void* d_out, int out_size, void* d_ws, size_t ws_size,
                              hipStream_t stream)
{
  const float* tgt   = (const float*)d_in[0];
  const float* mtxt  = (const float*)d_in[1];
  const float* vox   = (const float*)d_in[2];
  const float* qpos  = (const float*)d_in[3];
  const int*   mtx_m = (const int*)d_in[4];
  const int*   vox_m = (const int*)d_in[5];
  const float* Wq = (const float*)d_in[6];  const float* bq = (const float*)d_in[7];
  const float* Wk = (const float*)d_in[8];  const float* bk = (const float*)d_in[9];
  const float* Wv = (const float*)d_in[10]; const float* bv = (const float*)d_in[11];
  const float* Wo = (const float*)d_in[12]; const float* bo = (const float*)d_in[13];
  const float* W1 = (const float*)d_in[14]; const float* b1 = (const float*)d_in[15];
  const float* W2 = (const float*)d_in[16]; const float* b2 = (const float*)d_in[17];
  const float* ln1g = (const float*)d_in[18]; const float* ln1b = (const float*)d_in[19];
  const float* ln2g = (const float*)d_in[20]; const float* ln2b = (const float*)d_in[21];

  float* out0 = (float*)d_out;                       // attn_output  [B,NQ,D]
  float* out1 = out0 + (long long)B * NQ * D;        // txt_cross    [B,NQ,LT]
  float* out2 = out1 + (long long)B * NQ * LT;       // attn_weights [B,NQ,NV]

  char* base = (char*)d_ws;
  constexpr size_t MB = 1ull << 20;
  u16*   kvW   = (u16*)(base + 0 * MB);     // 16  [Wk;Wv] stacked
  u16*   Wq_b  = (u16*)(base + 16 * MB);    // 2
  u16*   Wo_b  = (u16*)(base + 18 * MB);    // 2
  u16*   W1_b  = (u16*)(base + 20 * MB);    // 4
  u16*   W2_b  = (u16*)(base + 24 * MB);    // 4
  u16*   tq_b  = (u16*)(base + 28 * MB);    // 4
  u16*   q_b   = (u16*)(base + 32 * MB);    // 4
  u16*   kv_b  = (u16*)(base + 36 * MB);    // 16  [B*LT][2048]
  u16*   vT_b  = (u16*)(base + 52 * MB);    // 8
  u16*   ctx_b = (u16*)(base + 60 * MB);    // 4
  float* x1p   = (float*)(base + 64 * MB);  // 8
  float* x1f   = (float*)(base + 72 * MB);  // 8
  u16*   x1_b  = (u16*)(base + 80 * MB);    // 4
  u16*   ff1_b = (u16*)(base + 84 * MB);    // 8
  float* x2p   = (float*)(base + 92 * MB);  // 8
  u16*   x2s_b = (u16*)(base + 100 * MB);   // 4
  u16*   mtxt_b = (u16*)(base + 104 * MB);  // 32  dead after kv256
  float* kvpart = (float*)(base + 136 * MB);// 64  dead after kv_reduce
  float* scores = (float*)(base + 136 * MB);// 64  dead after txt_softmax_mean
  float* bkv    = (float*)(base + 200 * MB);// 8KB (in w_b region, dead before w_b)
  u16*   w_b    = (u16*)(base + 200 * MB);  // 32  dead after ctx gemm
  u16*   vox_b  = (u16*)(base + 104 * MB);  // 64  overlays mtxt_b + scores head (dead after step 5/6)
  u16*   voxT_b = (u16*)(base + 168 * MB);  // 64  overlays scores tail + w_b (dead after step 6)
  u16*   wvox_b = (u16*)(base + 0 * MB);    // 16  overlays kvW (dead)
  float* part   = (float*)(base + 16 * MB); // 32  overlays Wq..q_b (dead)

  const dim3 blk(256);
  const long long sQ = (long long)NQ * D;
  const long long sSC = (long long)NQ * LT;
  const long long nd = (long long)NQ * D;

  // 1) conversions: fused weights + memory_txt; tq = tgt + qpos
  Cvt7 ca;
  ca.s[0] = Wq;   ca.d[0] = Wq_b;
  ca.s[1] = Wk;   ca.d[1] = kvW;
  ca.s[2] = Wv;   ca.d[2] = kvW + (long long)D * FTXT;
  ca.s[3] = Wo;   ca.d[3] = Wo_b;
  ca.s[4] = W1;   ca.d[4] = W1_b;
  ca.s[5] = W2;   ca.d[5] = W2_b;
  ca.s[6] = mtxt; ca.d[6] = mtxt_b;
  ca.cum[0] = 0;     ca.cum[1] = 1024;  ca.cum[2] = 5120;  ca.cum[3] = 9216;
  ca.cum[4] = 10240; ca.cum[5] = 12288; ca.cum[6] = 14336; ca.cum[7] = 30720;
  cvt_multi<<<dim3(30720), blk, 0, stream>>>(ca);
  hipMemcpyAsync(bkv, bk, D * sizeof(float), hipMemcpyDeviceToDevice, stream);
  hipMemcpyAsync(bkv + D, bv, D * sizeof(float), hipMemcpyDeviceToDevice, stream);
  cvt_add_bf16<<<dim3((B * NQ * D) / 1024), blk, 0, stream>>>(tgt, qpos, tq_b);

  // 2) q projection (2-phase) + kv projection (8-phase split-K=2 + reduce)
  gemm_bf16<64,64,2,2, E_BIAS|E_WB16><<<dim3(D/64, (B*NQ)/64, 1), blk, 0, stream>>>(
      tq_b, Wq_b, bq, nullptr, nullptr, q_b, D, D, D, D, 1, 0,0,0,0,0,0, 1.f);
  gemm_kv256<<<dim3(8, 16, 2), dim3(512), 0, stream>>>(mtxt_b, kvW, kvpart);
  kv_reduce<<<dim3((4096 * 2048) / 1024), blk, 0, stream>>>(kvpart, bkv, kv_b);

  // 3) vT[b][d][l] = v[b][l][d]
  transpose_u16<<<dim3(D/32, LT/32, B), blk, 0, stream>>>(
      kv_b + 1024, vT_b, LT, D, 2048, (long long)LT * 2048, (long long)D * LT);

  // 4) scores = q . k / 8
  gemm_bf16<128,128,2,2, E_WF32><<<dim3(LT/128, NQ/128, B*H), blk, 0, stream>>>(
      q_b, kv_b, nullptr, nullptr, scores, nullptr, HD, D, 2048, LT, H,
      sQ, HD, (long long)LT * 2048, HD, (long long)H * sSC, sSC, 0.125f);

  // 5) fused softmax + head-mean
  txt_softmax_mean<<<dim3(B*NQ), blk, 0, stream>>>(scores, mtx_m, w_b, out1);

  // 6) ctx = w_h @ v_h
  gemm_bf16<64,64,2,2, E_WB16><<<dim3(HD/64, NQ/64, B*H), blk, 0, stream>>>(
      w_b, vT_b, nullptr, nullptr, nullptr, ctx_b, LT, LT, LT, D, H,
      (long long)H * sSC, sSC, (long long)D * LT, (long long)HD * LT, sQ, HD, 1.f);

  // 7) vox -> vox_b + voxT_b (one f32 read; both regions dead now)
  vox_prep<<<dim3(D/64, NV/64, B), blk, 0, stream>>>(vox, vox_b, voxT_b);

  // 8) x1p = tgt + ctx @ Wo^T + bo
  gemm_bf16<64,64,2,2, E_BIAS|E_RES|E_WF32><<<dim3(D/64, (B*NQ)/64, 1), blk, 0, stream>>>(
      ctx_b, Wo_b, bo, tgt, x1p, nullptr, D, D, D, D, 1, 0,0,0,0,0,0, 1.f);

  // 9) LN1
  ln_kernel<<<dim3(B*NQ), blk, 0, stream>>>(x1p, ln1g, ln1b, x1f, x1_b, 1.f);

  // 10) ff1 = relu(x1 @ W1^T + b1)
  gemm_bf16<128,64,2,2, E_BIAS|E_RELU|E_WB16><<<dim3(DFF/64, (B*NQ)/128, 1), blk, 0, stream>>>(
      x1_b, W1_b, b1, nullptr, nullptr, ff1_b, D, D, D, DFF, 1, 0,0,0,0,0,0, 1.f);

  // 11) x2p = x1 + ff1 @ W2^T + b2
  gemm_bf16<64,64,2,2, E_BIAS|E_RES|E_WF32><<<dim3(D/64, (B*NQ)/64, 1), blk, 0, stream>>>(
      ff1_b, W2_b, b2, x1f, x2p, nullptr, DFF, DFF, DFF, D, 1, 0,0,0,0,0,0, 1.f);

  // 12) LN2 -> x2s (bf16, /sqrt(D))
  ln_kernel<<<dim3(B*NQ), blk, 0, stream>>>(x2p, ln2g, ln2b, nullptr, x2s_b, 0.03125f);

  // 13) out2 = x2s @ vox_b^T  (512 blocks, bf16 B via gload_lds)
  gemm_bf16<128,128,2,2, E_WF32><<<dim3(NV/128, NQ/128, B), blk, 0, stream>>>(
      x2s_b, vox_b, nullptr, nullptr, out2, nullptr, D, D, D, NV, 1,
      sQ, 0, (long long)NV * D, 0, (long long)NQ * NV, 0, 1.f);

  // 14) masked softmax in place; bf16 weights
  vox_softmax<<<dim3(B*NQ), blk, 0, stream>>>(out2, vox_m, wvox_b);

  // 15) out0 partials: split-K=4 over NV from voxT_b (512 blocks), then reduce
  gemm_bf16<128,128,2,2, E_WF32><<<dim3(D/128, NQ/128, B*4), blk, 0, stream>>>(
      wvox_b, voxT_b, nullptr, nullptr, part, nullptr, NV/4, NV, NV, D, 4,
      (long long)NQ * NV, 1024, (long long)D * NV, 1024, 4 * nd, nd, 1.f);
  splitk_reduce<<<dim3((B * NQ * D) / 1024), blk, 0, stream>>>(part, out0);
}

// Round 8
// 446.030 us; speedup vs baseline: 1.1472x; 1.0073x over previous
//
#include <hip/hip_runtime.h>
#include <math.h>

typedef unsigned short u16;
typedef unsigned int u32;
typedef __bf16 bf16x8 __attribute__((ext_vector_type(8)));
typedef float f32x4 __attribute__((ext_vector_type(4)));
typedef u16 u16x4 __attribute__((ext_vector_type(4)));

constexpr int B = 8, NQ = 256, LT = 512, NV = 4096;
constexpr int D = 1024, H = 16, DFF = 2048, FTXT = 4096, HD = 64;

__device__ __forceinline__ u16 f2b(float f) {
  u32 u = __builtin_bit_cast(u32, f);
  return (u16)((u + 0x7fffu + ((u >> 16) & 1u)) >> 16);   // RNE
}
__device__ __forceinline__ float b2f(u16 b) {
  u32 u = ((u32)b) << 16;
  return __builtin_bit_cast(float, u);
}
__device__ __forceinline__ void gload16(const void* g, void* l) {
  __builtin_amdgcn_global_load_lds(
      (const __attribute__((address_space(1))) u32*)g,
      (__attribute__((address_space(3))) u32*)l, 16, 0, 0);
}

// ===========================================================================
// 256x256 8-phase bf16 GEMM (m201 template) for the KV projection.
// part[z][4096][2048] = A[4096][2048 @ z*2048] @ Bw[2048][same]^T
// R8: A-fragment registers persist across the qn-phase pair of each quadrant
// row -> ds_reads per phase go 12,4,12,4 (was 12,12,12,12). Stage placement
// and vmcnt ledger unchanged from R7 (verified).
// ===========================================================================
__global__ __launch_bounds__(512, 2)
void gemm_kv256(const u16* __restrict__ A, const u16* __restrict__ Bw,
                float* __restrict__ part)
{
  __shared__ __align__(16) u16 As[4 * 8192];   // [db*2+half][128][64]
  __shared__ __align__(16) u16 Bs[4 * 8192];

  const int gx = 8, gy = 16;
  const int nwg = 256;
  const int flat = (blockIdx.z * gy + blockIdx.y) * gx + blockIdx.x;
  const int qq = nwg >> 3;
  const int xcd = flat & 7, lid = flat >> 3;
  const int wg = xcd * qq + lid;
  const int bx = wg % gx;
  const int by = (wg / gx) % gy;
  const int z  = wg / (gx * gy);
  const int m0 = by * 256, n0 = bx * 256;
  const long long kbase = (long long)z * 2048;

  const int t = threadIdx.x;
  const int w = t >> 6, l = t & 63;
  const int wr64 = (w >> 2) * 64;
  const int wc32 = (w & 3) * 32;
  const int l15 = l & 15, l4 = l >> 4, l7 = l & 7;

  auto stA = [&](int db, int h, int tile) {
    const long long kk = kbase + tile * 64 + (((t & 7) ^ ((t >> 3) & 7)) * 8);
    #pragma unroll
    for (int i = 0; i < 2; ++i)
      gload16(&A[(long long)(m0 + h * 128 + (t >> 3) + 64 * i) * 4096 + kk],
              &As[(db * 2 + h) * 8192 + (w * 8 + 64 * i) * 64]);
  };
  auto stB = [&](int db, int h, int tile) {
    const long long kk = kbase + tile * 64 + (((t & 7) ^ ((t >> 3) & 7)) * 8);
    #pragma unroll
    for (int i = 0; i < 2; ++i)
      gload16(&Bw[(long long)(n0 + h * 128 + (t >> 3) + 64 * i) * 4096 + kk],
              &Bs[(db * 2 + h) * 8192 + (w * 8 + 64 * i) * 64]);
  };

#define RDA(db,qm,fm,ks) \
  (*reinterpret_cast<const bf16x8*>(&As[((db)*2+(qm))*8192 + \
      (wr64 + (fm)*16 + l15)*64 + ((((ks)*4 + l4) ^ l7) * 8)]))
#define RDB(db,qn,fn,ks) \
  (*reinterpret_cast<const bf16x8*>(&Bs[((db)*2+(qn))*8192 + \
      (wc32 + (fn)*16 + l15)*64 + ((((ks)*4 + l4) ^ l7) * 8)]))

  f32x4 acc[2][2][4][2] = {};
  bf16x8 a_[4][2];            // persistent A fragments for current (db,qm)
  bf16x8 b_[2][2];

#define LOADA(db, qm)                                                        \
  do {                                                                       \
    _Pragma("unroll")                                                        \
    for (int fm_ = 0; fm_ < 4; ++fm_) {                                      \
      a_[fm_][0] = RDA(db, qm, fm_, 0);                                      \
      a_[fm_][1] = RDA(db, qm, fm_, 1);                                      \
    }                                                                        \
  } while (0)

#define LOADB(db, qn)                                                        \
  do {                                                                       \
    b_[0][0] = RDB(db, qn, 0, 0); b_[0][1] = RDB(db, qn, 0, 1);              \
    b_[1][0] = RDB(db, qn, 1, 0); b_[1][1] = RDB(db, qn, 1, 1);              \
  } while (0)

#define MMACL(qm, qn)                                                        \
  do {                                                                       \
    asm volatile("s_barrier" ::: "memory");                                  \
    __builtin_amdgcn_s_setprio(1);                                           \
    _Pragma("unroll")                                                        \
    for (int fm_ = 0; fm_ < 4; ++fm_) {                                      \
      _Pragma("unroll")                                                      \
      for (int fn_ = 0; fn_ < 2; ++fn_) {                                    \
        acc[qm][qn][fm_][fn_] = __builtin_amdgcn_mfma_f32_16x16x32_bf16(     \
            a_[fm_][0], b_[fn_][0], acc[qm][qn][fm_][fn_], 0, 0, 0);         \
        acc[qm][qn][fm_][fn_] = __builtin_amdgcn_mfma_f32_16x16x32_bf16(     \
            a_[fm_][1], b_[fn_][1], acc[qm][qn][fm_][fn_], 0, 0, 0);         \
      }                                                                      \
    }                                                                        \
    __builtin_amdgcn_s_setprio(0);                                           \
  } while (0)

  // prologue: tile0 all 4 halves + tile1 h0; drain tile0, keep 4 in flight
  stA(0, 0, 0); stB(0, 0, 0); stA(0, 1, 0); stB(0, 1, 0);
  stA(1, 0, 1); stB(1, 0, 1);
  asm volatile("s_waitcnt vmcnt(4)" ::: "memory");
  asm volatile("s_barrier" ::: "memory");

  for (int j = 0; j < 16; ++j) {
    const bool s2 = (j < 15);
    const int t1 = 2 * j + 1, t2 = 2 * j + 2, t3 = 2 * j + 3;

    // ---- db=0, quadrant row qm=0 ----
    LOADA(0, 0); LOADB(0, 0);
    stA(1, 1, t1);
    MMACL(0, 0);
    asm volatile("s_barrier" ::: "memory");
    LOADB(0, 1);
    stB(1, 1, t1);
    MMACL(0, 1);
    asm volatile("s_barrier" ::: "memory");
    // ---- db=0, quadrant row qm=1 ----
    LOADA(0, 1); LOADB(0, 0);
    if (s2) stA(0, 0, t2);
    MMACL(1, 0);
    asm volatile("s_barrier" ::: "memory");
    LOADB(0, 1);
    if (s2) stB(0, 0, t2);
    MMACL(1, 1);
    if (s2) { asm volatile("s_waitcnt vmcnt(4)" ::: "memory"); }
    else    { asm volatile("s_waitcnt vmcnt(0)" ::: "memory"); }
    asm volatile("s_barrier" ::: "memory");

    // ---- db=1, quadrant row qm=0 ----
    LOADA(1, 0); LOADB(1, 0);
    if (s2) stA(0, 1, t2);
    MMACL(0, 0);
    asm volatile("s_barrier" ::: "memory");
    LOADB(1, 1);
    if (s2) stB(0, 1, t2);
    MMACL(0, 1);
    asm volatile("s_barrier" ::: "memory");
    // ---- db=1, quadrant row qm=1 ----
    LOADA(1, 1); LOADB(1, 0);
    if (s2) stA(1, 0, t3);
    MMACL(1, 0);
    asm volatile("s_barrier" ::: "memory");
    LOADB(1, 1);
    if (s2) stB(1, 0, t3);
    MMACL(1, 1);
    if (s2) { asm volatile("s_waitcnt vmcnt(4)" ::: "memory"); }
    asm volatile("s_barrier" ::: "memory");
  }
#undef LOADA
#undef LOADB
#undef MMACL
#undef RDA
#undef RDB

  float* P = part + (long long)z * (4096LL * 2048);
  #pragma unroll
  for (int qm = 0; qm < 2; ++qm)
    #pragma unroll
    for (int qn = 0; qn < 2; ++qn)
      #pragma unroll
      for (int fm = 0; fm < 4; ++fm)
        #pragma unroll
        for (int r = 0; r < 4; ++r) {
          const long long row = m0 + qm * 128 + wr64 + fm * 16 + l4 * 4 + r;
          #pragma unroll
          for (int fn = 0; fn < 2; ++fn) {
            const int col = n0 + qn * 128 + wc32 + fn * 16 + l15;
            P[row * 2048 + col] = acc[qm][qn][fm][fn][r];
          }
        }
}

__global__ __launch_bounds__(256)
void kv_reduce(const float* __restrict__ part, const float* __restrict__ bkv,
               u16* __restrict__ kvb)
{
  const long long i = ((long long)blockIdx.x * 256 + threadIdx.x) * 4;
  const int col = (int)(i & 2047);
  float4 p0 = *reinterpret_cast<const float4*>(&part[i]);
  float4 p1 = *reinterpret_cast<const float4*>(&part[i + 4096LL * 2048]);
  float4 bb = *reinterpret_cast<const float4*>(&bkv[col]);
  u16x4 o = {f2b(p0.x + p1.x + bb.x), f2b(p0.y + p1.y + bb.y),
             f2b(p0.z + p1.z + bb.z), f2b(p0.w + p1.w + bb.w)};
  *reinterpret_cast<u16x4*>(&kvb[i]) = o;
}

// ---------------------------------------------------------------------------
// 2-phase bf16 MFMA GEMM (bf16 B via global_load_lds only).
// ---------------------------------------------------------------------------
constexpr int E_BIAS = 1, E_RES = 2, E_RELU = 4, E_WF32 = 8, E_WB16 = 16;

template<int BM, int BN, int WM, int WN, int EPI>
__global__ __launch_bounds__(256)
void gemm_bf16(const u16* __restrict__ A, const u16* __restrict__ Bw,
               const float* __restrict__ bias, const float* __restrict__ res,
               float* __restrict__ C, u16* __restrict__ Cb,
               int K, int lda, int ldb, int ldc, int nbz2,
               long long sA1, long long sA2, long long sB1, long long sB2,
               long long sC1, long long sC2, float alpha)
{
  constexpr int SM = BM / WM, SN = BN / WN;
  constexpr int FM = SM / 16, FN = SN / 16;
  constexpr int PA = BM / 64, PB = BN / 64;
  __shared__ __align__(16) u16 As[2][BM * 32];
  __shared__ __align__(16) u16 Bs[2][BN * 32];

  const int gx = gridDim.x, gy = gridDim.y;
  const int nwg = gx * gy * gridDim.z;
  const int flat = (blockIdx.z * gy + blockIdx.y) * gx + blockIdx.x;
  const int qq = nwg >> 3, rr = nwg & 7;
  const int xcd = flat & 7, lid = flat >> 3;
  const int wg = (xcd < rr ? xcd * (qq + 1) : rr * (qq + 1) + (xcd - rr) * qq) + lid;
  const int bx = wg % gx;
  const int tmp1 = wg / gx;
  const int by = tmp1 % gy, bz = tmp1 / gy;

  const int t = threadIdx.x;
  const int w = t >> 6, l = t & 63;
  const int wr = w / WN, wc = w % WN;
  const int m0 = by * BM, n0 = bx * BN;
  const long long offA = (long long)(bz / nbz2) * sA1 + (long long)(bz % nbz2) * sA2;
  const long long offB = (long long)(bz / nbz2) * sB1 + (long long)(bz % nbz2) * sB2;
  const long long offC = (long long)(bz / nbz2) * sC1 + (long long)(bz % nbz2) * sC2;
  const u16* Ab = A + offA;
  const u16* Bb = Bw + offB;

  const int srow = t >> 2;
  const int sk   = (t & 3) * 8;

  auto stageA = [&](int buf, int k0) {
    #pragma unroll
    for (int p = 0; p < PA; ++p)
      gload16(&Ab[(long long)(m0 + p * 64 + srow) * lda + k0 + sk],
              &As[buf][p * 2048 + w * 512]);
  };
  auto stageB = [&](int buf, int k0) {
    #pragma unroll
    for (int p = 0; p < PB; ++p)
      gload16(&Bb[(long long)(n0 + p * 64 + srow) * ldb + k0 + sk],
              &Bs[buf][p * 2048 + w * 512]);
  };

  f32x4 acc[FM][FN] = {};

  stageA(0, 0);
  stageB(0, 0);

  int cur = 0;
  for (int k0 = 0; k0 < K; k0 += 32) {
    __syncthreads();
    const bool pf = (k0 + 32 < K);
    if (pf) {
      stageA(cur ^ 1, k0 + 32);
      stageB(cur ^ 1, k0 + 32);
    }

    bf16x8 af[FM], bfr[FN];
    #pragma unroll
    for (int i = 0; i < FM; ++i)
      af[i] = *reinterpret_cast<const bf16x8*>(
          &As[cur][(wr * SM + i * 16 + (l & 15)) * 32 + (l >> 4) * 8]);
    #pragma unroll
    for (int j = 0; j < FN; ++j)
      bfr[j] = *reinterpret_cast<const bf16x8*>(
          &Bs[cur][(wc * SN + j * 16 + (l & 15)) * 32 + (l >> 4) * 8]);
    #pragma unroll
    for (int i = 0; i < FM; ++i)
      #pragma unroll
      for (int j = 0; j < FN; ++j)
        acc[i][j] = __builtin_amdgcn_mfma_f32_16x16x32_bf16(af[i], bfr[j], acc[i][j], 0, 0, 0);
    cur ^= 1;
  }

  const int c_l = l & 15, r_l4 = (l >> 4) * 4;
  #pragma unroll
  for (int i = 0; i < FM; ++i) {
    #pragma unroll
    for (int r = 0; r < 4; ++r) {
      const long long row = m0 + wr * SM + i * 16 + r_l4 + r;
      #pragma unroll
      for (int j = 0; j < FN; ++j) {
        const int col = n0 + wc * SN + j * 16 + c_l;
        float v = acc[i][j][r] * alpha;
        if (EPI & E_BIAS) v += bias[col];
        if (EPI & E_RES)  v += res[row * (long long)ldc + col];
        if (EPI & E_RELU) v = fmaxf(v, 0.f);
        const long long co = offC + row * (long long)ldc + col;
        if (EPI & E_WF32) C[co] = v;
        if (EPI & E_WB16) Cb[co] = f2b(v);
      }
    }
  }
}

// ---------------------------------------------------------------------------
// vox f32 [B][NV][D] -> vb bf16 [B][NV][D]  AND  vt bf16 [B][D][NV]
// ---------------------------------------------------------------------------
__global__ __launch_bounds__(256)
void vox_prep(const float* __restrict__ in, u16* __restrict__ vb,
              u16* __restrict__ vt)
{
  __shared__ u16 tile[64][68];
  const int b = blockIdx.z;
  const int n0 = blockIdx.y * 64;
  const int d0 = blockIdx.x * 64;
  const int t = threadIdx.x;
  const int tr = t >> 4;
  const int tc = (t & 15) * 4;
  const float* ib = in + (long long)b * NV * D;
  u16* vbb = vb + (long long)b * NV * D;
  u16* vtb = vt + (long long)b * NV * D;
  #pragma unroll
  for (int p = 0; p < 4; ++p) {
    int r = tr + p * 16;
    float4 x = *reinterpret_cast<const float4*>(&ib[(long long)(n0 + r) * D + d0 + tc]);
    u16x4 o = {f2b(x.x), f2b(x.y), f2b(x.z), f2b(x.w)};
    *reinterpret_cast<u16x4*>(&vbb[(long long)(n0 + r) * D + d0 + tc]) = o;
    *reinterpret_cast<u16x4*>(&tile[r][tc]) = o;
  }
  __syncthreads();
  #pragma unroll
  for (int p = 0; p < 4; ++p) {
    int c = tr + p * 16;
    u16x4 o = {tile[tc + 0][c], tile[tc + 1][c], tile[tc + 2][c], tile[tc + 3][c]};
    *reinterpret_cast<u16x4*>(&vtb[(long long)(d0 + c) * NV + n0 + tc]) = o;
  }
}

// ---------------------------------------------------------------------------
struct Cvt7 { const float* s[7]; u16* d[7]; int cum[8]; };

__global__ __launch_bounds__(256)
void cvt_multi(Cvt7 a)
{
  const int bidx = blockIdx.x;
  int seg = 0;
  #pragma unroll
  for (int k = 1; k < 7; ++k) if (bidx >= a.cum[k]) seg = k;
  const long long off = ((long long)(bidx - a.cum[seg]) * 256 + threadIdx.x) * 4;
  float4 x = *reinterpret_cast<const float4*>(a.s[seg] + off);
  u16x4 o = {f2b(x.x), f2b(x.y), f2b(x.z), f2b(x.w)};
  *reinterpret_cast<u16x4*>(a.d[seg] + off) = o;
}

__global__ __launch_bounds__(256)
void cvt_add_bf16(const float* __restrict__ a, const float* __restrict__ b,
                  u16* __restrict__ out)
{
  const long long i = ((long long)blockIdx.x * 256 + threadIdx.x) * 4;
  float4 x = *reinterpret_cast<const float4*>(&a[i]);
  float4 y = *reinterpret_cast<const float4*>(&b[i]);
  u16x4 o = {f2b(x.x + y.x), f2b(x.y + y.y), f2b(x.z + y.z), f2b(x.w + y.w)};
  *reinterpret_cast<u16x4*>(&out[i]) = o;
}

__global__ __launch_bounds__(256)
void transpose_u16(const u16* __restrict__ in, u16* __restrict__ out,
                   int R, int C, int ldin, long long sbin, long long sbout)
{
  __shared__ u16 tile[32][34];
  const int b = blockIdx.z;
  const int r0 = blockIdx.y * 32, c0 = blockIdx.x * 32;
  const int tx = threadIdx.x & 31, ty = threadIdx.x >> 5;
  const u16* ib = in + (long long)b * sbin;
  u16* ob = out + (long long)b * sbout;
  #pragma unroll
  for (int p = 0; p < 4; ++p) {
    int r = ty + p * 8;
    tile[r][tx] = ib[(long long)(r0 + r) * ldin + c0 + tx];
  }
  __syncthreads();
  #pragma unroll
  for (int p = 0; p < 4; ++p) {
    int c = ty + p * 8;
    ob[(long long)(c0 + c) * R + r0 + tx] = tile[tx][c];
  }
}

// ---------------------------------------------------------------------------
__global__ __launch_bounds__(256)
void txt_softmax_mean(const float* __restrict__ sc, const int* __restrict__ mask,
                      u16* __restrict__ wout, float* __restrict__ out1)
{
  __shared__ float red[8];
  const int t = threadIdx.x, l = t & 63, w = t >> 6;
  const int bq = blockIdx.x;
  const int b = bq >> 8, q = bq & 255;
  const int* mr = mask + b * LT;
  const bool msk0 = mr[t] != 0, msk1 = mr[t + 256] != 0;
  float a0 = 0.f, a1 = 0.f;
  for (int h = 0; h < H; ++h) {
    const long long ro = (((long long)(b * H + h)) * NQ + q) * LT;
    const float* sr = sc + ro;
    float x0 = msk0 ? -INFINITY : sr[t];
    float x1 = msk1 ? -INFINITY : sr[t + 256];
    float mx = fmaxf(x0, x1);
    #pragma unroll
    for (int o = 32; o > 0; o >>= 1) mx = fmaxf(mx, __shfl_xor(mx, o, 64));
    if (l == 0) red[w] = mx;
    __syncthreads();
    mx = fmaxf(fmaxf(red[0], red[1]), fmaxf(red[2], red[3]));
    float e0 = __expf(x0 - mx), e1 = __expf(x1 - mx);
    float s = e0 + e1;
    #pragma unroll
    for (int o = 32; o > 0; o >>= 1) s += __shfl_xor(s, o, 64);
    if (l == 0) red[4 + w] = s;
    __syncthreads();
    s = red[4] + red[5] + red[6] + red[7];
    const float inv = 1.f / s;
    const float w0 = e0 * inv, w1 = e1 * inv;
    u16* wr = wout + ro;
    wr[t] = f2b(w0); wr[t + 256] = f2b(w1);
    a0 += w0; a1 += w1;
  }
  float* o1 = out1 + (long long)bq * LT;
  o1[t]       = a0 * (1.f / H);
  o1[t + 256] = a1 * (1.f / H);
}

// ---------------------------------------------------------------------------
__global__ __launch_bounds__(256)
void ln_kernel(const float* __restrict__ x, const float* __restrict__ g,
               const float* __restrict__ bia, float* __restrict__ y,
               u16* __restrict__ yb, float scale)
{
  __shared__ float tmp[256];
  const int t = threadIdx.x;
  const long long off = (long long)blockIdx.x * D;
  float4 x4 = *reinterpret_cast<const float4*>(&x[off + t * 4]);
  tmp[t] = x4.x + x4.y + x4.z + x4.w;
  __syncthreads();
  for (int o = 128; o > 0; o >>= 1) { if (t < o) tmp[t] += tmp[t + o]; __syncthreads(); }
  const float mean = tmp[0] * (1.f / D);
  __syncthreads();
  float d0 = x4.x - mean, d1 = x4.y - mean, d2 = x4.z - mean, d3 = x4.w - mean;
  tmp[t] = d0 * d0 + d1 * d1 + d2 * d2 + d3 * d3;
  __syncthreads();
  for (int o = 128; o > 0; o >>= 1) { if (t < o) tmp[t] += tmp[t + o]; __syncthreads(); }
  const float rs = rsqrtf(tmp[0] * (1.f / D) + 1e-5f);
  float4 g4 = *reinterpret_cast<const float4*>(&g[t * 4]);
  float4 b4 = *reinterpret_cast<const float4*>(&bia[t * 4]);
  float o0 = (d0 * rs * g4.x + b4.x) * scale;
  float o1 = (d1 * rs * g4.y + b4.y) * scale;
  float o2 = (d2 * rs * g4.z + b4.z) * scale;
  float o3 = (d3 * rs * g4.w + b4.w) * scale;
  if (y) {
    float4 o4 = {o0, o1, o2, o3};
    *reinterpret_cast<float4*>(&y[off + t * 4]) = o4;
  }
  if (yb) {
    u16x4 ob = {f2b(o0), f2b(o1), f2b(o2), f2b(o3)};
    *reinterpret_cast<u16x4*>(&yb[off + t * 4]) = ob;
  }
}

// ---------------------------------------------------------------------------
__global__ __launch_bounds__(256)
void vox_softmax(float* __restrict__ s, const int* __restrict__ mask,
                 u16* __restrict__ wb)
{
  __shared__ float tmp[256];
  const int t = threadIdx.x;
  const int row = blockIdx.x, b = row / NQ;
  float* sr = s + (long long)row * NV;
  u16* wr = wb + (long long)row * NV;
  const int* mr = mask + b * NV;
  float vals[16];
  float lm = -INFINITY;
  #pragma unroll
  for (int j = 0; j < 16; ++j) {
    int n = t + j * 256;
    float x = mr[n] ? -INFINITY : sr[n];
    vals[j] = x;
    lm = fmaxf(lm, x);
  }
  tmp[t] = lm;
  __syncthreads();
  for (int o = 128; o > 0; o >>= 1) { if (t < o) tmp[t] = fmaxf(tmp[t], tmp[t + o]); __syncthreads(); }
  const float mx = tmp[0];
  __syncthreads();
  float ls = 0.f;
  #pragma unroll
  for (int j = 0; j < 16; ++j) { vals[j] = __expf(vals[j] - mx); ls += vals[j]; }
  tmp[t] = ls;
  __syncthreads();
  for (int o = 128; o > 0; o >>= 1) { if (t < o) tmp[t] += tmp[t + o]; __syncthreads(); }
  const float inv = 1.f / tmp[0];
  #pragma unroll
  for (int j = 0; j < 16; ++j) {
    float v = vals[j] * inv;
    sr[t + j * 256] = v;
    wr[t + j * 256] = f2b(v);
  }
}

__global__ __launch_bounds__(256)
void splitk_reduce(const float* __restrict__ part, float* __restrict__ out)
{
  const long long i = ((long long)blockIdx.x * 256 + threadIdx.x) * 4;
  const long long nd = (long long)NQ * D;
  const long long b = i / nd;
  const long long o = i - b * nd;
  const float* p = part + b * 4 * nd + o;
  float4 s0 = *reinterpret_cast<const float4*>(&p[0]);
  float4 s1 = *reinterpret_cast<const float4*>(&p[nd]);
  float4 s2 = *reinterpret_cast<const float4*>(&p[2 * nd]);
  float4 s3 = *reinterpret_cast<const float4*>(&p[3 * nd]);
  float4 r = {s0.x + s1.x + s2.x + s3.x, s0.y + s1.y + s2.y + s3.y,
              s0.z + s1.z + s2.z + s3.z, s0.w + s1.w + s2.w + s3.w};
  *reinterpret_cast<float4*>(&out[i]) = r;
}

// ---------------------------------------------------------------------------
extern "C" void kernel_launch(void* const* d_in, const int* in_sizes, int n_in,
                              void* d_out, int out_size, void* d_ws, size_t ws_size,
                              hipStream_t stream)
{
  const float* tgt   = (const float*)d_in[0];
  const float* mtxt  = (const float*)d_in[1];
  const float* vox   = (const float*)d_in[2];
  const float* qpos  = (const float*)d_in[3];
  const int*   mtx_m = (const int*)d_in[4];
  const int*   vox_m = (const int*)d_in[5];
  const float* Wq = (const float*)d_in[6];  const float* bq = (const float*)d_in[7];
  const float* Wk = (const float*)d_in[8];  const float* bk = (const float*)d_in[9];
  const float* Wv = (const float*)d_in[10]; const float* bv = (const float*)d_in[11];
  const float* Wo = (const float*)d_in[12]; const float* bo = (const float*)d_in[13];
  const float* W1 = (const float*)d_in[14]; const float* b1 = (const float*)d_in[15];
  const float* W2 = (const float*)d_in[16]; const float* b2 = (const float*)d_in[17];
  const float* ln1g = (const float*)d_in[18]; const float* ln1b = (const float*)d_in[19];
  const float* ln2g = (const float*)d_in[20]; const float* ln2b = (const float*)d_in[21];

  float* out0 = (float*)d_out;                       // attn_output  [B,NQ,D]
  float* out1 = out0 + (long long)B * NQ * D;        // txt_cross    [B,NQ,LT]
  float* out2 = out1 + (long long)B * NQ * LT;       // attn_weights [B,NQ,NV]

  char* base = (char*)d_ws;
  constexpr size_t MB = 1ull << 20;
  u16*   kvW   = (u16*)(base + 0 * MB);     // 16  [Wk;Wv] stacked
  u16*   Wq_b  = (u16*)(base + 16 * MB);    // 2
  u16*   Wo_b  = (u16*)(base + 18 * MB);    // 2
  u16*   W1_b  = (u16*)(base + 20 * MB);    // 4
  u16*   W2_b  = (u16*)(base + 24 * MB);    // 4
  u16*   tq_b  = (u16*)(base + 28 * MB);    // 4
  u16*   q_b   = (u16*)(base + 32 * MB);    // 4
  u16*   kv_b  = (u16*)(base + 36 * MB);    // 16  [B*LT][2048]
  u16*   vT_b  = (u16*)(base + 52 * MB);    // 8
  u16*   ctx_b = (u16*)(base + 60 * MB);    // 4
  float* x1p   = (float*)(base + 64 * MB);  // 8
  float* x1f   = (float*)(base + 72 * MB);  // 8
  u16*   x1_b  = (u16*)(base + 80 * MB);    // 4
  u16*   ff1_b = (u16*)(base + 84 * MB);    // 8
  float* x2p   = (float*)(base + 92 * MB);  // 8
  u16*   x2s_b = (u16*)(base + 100 * MB);   // 4
  u16*   mtxt_b = (u16*)(base + 104 * MB);  // 32  dead after kv256
  float* kvpart = (float*)(base + 136 * MB);// 64  dead after kv_reduce
  float* scores = (float*)(base + 136 * MB);// 64  dead after txt_softmax_mean
  float* bkv    = (float*)(base + 200 * MB);// 8KB (in w_b region, dead before w_b)
  u16*   w_b    = (u16*)(base + 200 * MB);  // 32  dead after ctx gemm
  u16*   vox_b  = (u16*)(base + 104 * MB);  // 64  overlays mtxt_b + scores head
  u16*   voxT_b = (u16*)(base + 168 * MB);  // 64  overlays scores tail + w_b
  u16*   wvox_b = (u16*)(base + 0 * MB);    // 16  overlays kvW (dead)
  float* part   = (float*)(base + 16 * MB); // 32  overlays Wq..q_b (dead)

  const dim3 blk(256);
  const long long sQ = (long long)NQ * D;
  const long long sSC = (long long)NQ * LT;
  const long long nd = (long long)NQ * D;

  // 1) conversions: fused weights + memory_txt; tq = tgt + qpos
  Cvt7 ca;
  ca.s[0] = Wq;   ca.d[0] = Wq_b;
  ca.s[1] = Wk;   ca.d[1] = kvW;
  ca.s[2] = Wv;   ca.d[2] = kvW + (long long)D * FTXT;
  ca.s[3] = Wo;   ca.d[3] = Wo_b;
  ca.s[4] = W1;   ca.d[4] = W1_b;
  ca.s[5] = W2;   ca.d[5] = W2_b;
  ca.s[6] = mtxt; ca.d[6] = mtxt_b;
  ca.cum[0] = 0;     ca.cum[1] = 1024;  ca.cum[2] = 5120;  ca.cum[3] = 9216;
  ca.cum[4] = 10240; ca.cum[5] = 12288; ca.cum[6] = 14336; ca.cum[7] = 30720;
  cvt_multi<<<dim3(30720), blk, 0, stream>>>(ca);
  hipMemcpyAsync(bkv, bk, D * sizeof(float), hipMemcpyDeviceToDevice, stream);
  hipMemcpyAsync(bkv + D, bv, D * sizeof(float), hipMemcpyDeviceToDevice, stream);
  cvt_add_bf16<<<dim3((B * NQ * D) / 1024), blk, 0, stream>>>(tgt, qpos, tq_b);

  // 2) q projection (2-phase) + kv projection (8-phase split-K=2 + reduce)
  gemm_bf16<64,64,2,2, E_BIAS|E_WB16><<<dim3(D/64, (B*NQ)/64, 1), blk, 0, stream>>>(
      tq_b, Wq_b, bq, nullptr, nullptr, q_b, D, D, D, D, 1, 0,0,0,0,0,0, 1.f);
  gemm_kv256<<<dim3(8, 16, 2), dim3(512), 0, stream>>>(mtxt_b, kvW, kvpart);
  kv_reduce<<<dim3((4096 * 2048) / 1024), blk, 0, stream>>>(kvpart, bkv, kv_b);

  // 3) vT[b][d][l] = v[b][l][d]
  transpose_u16<<<dim3(D/32, LT/32, B), blk, 0, stream>>>(
      kv_b + 1024, vT_b, LT, D, 2048, (long long)LT * 2048, (long long)D * LT);

  // 4) scores = q . k / 8
  gemm_bf16<128,128,2,2, E_WF32><<<dim3(LT/128, NQ/128, B*H), blk, 0, stream>>>(
      q_b, kv_b, nullptr, nullptr, scores, nullptr, HD, D, 2048, LT, H,
      sQ, HD, (long long)LT * 2048, HD, (long long)H * sSC, sSC, 0.125f);

  // 5) fused softmax + head-mean
  txt_softmax_mean<<<dim3(B*NQ), blk, 0, stream>>>(scores, mtx_m, w_b, out1);

  // 6) ctx = w_h @ v_h
  gemm_bf16<64,64,2,2, E_WB16><<<dim3(HD/64, NQ/64, B*H), blk, 0, stream>>>(
      w_b, vT_b, nullptr, nullptr, nullptr, ctx_b, LT, LT, LT, D, H,
      (long long)H * sSC, sSC, (long long)D * LT, (long long)HD * LT, sQ, HD, 1.f);

  // 7) vox -> vox_b + voxT_b (one f32 read)
  vox_prep<<<dim3(D/64, NV/64, B), blk, 0, stream>>>(vox, vox_b, voxT_b);

  // 8) x1p = tgt + ctx @ Wo^T + bo
  gemm_bf16<64,64,2,2, E_BIAS|E_RES|E_WF32><<<dim3(D/64, (B*NQ)/64, 1), blk, 0, stream>>>(
      ctx_b, Wo_b, bo, tgt, x1p, nullptr, D, D, D, D, 1, 0,0,0,0,0,0, 1.f);

  // 9) LN1
  ln_kernel<<<dim3(B*NQ), blk, 0, stream>>>(x1p, ln1g, ln1b, x1f, x1_b, 1.f);

  // 10) ff1 = relu(x1 @ W1^T + b1)
  gemm_bf16<128,64,2,2, E_BIAS|E_RELU|E_WB16><<<dim3(DFF/64, (B*NQ)/128, 1), blk, 0, stream>>>(
      x1_b, W1_b, b1, nullptr, nullptr, ff1_b, D, D, D, DFF, 1, 0,0,0,0,0,0, 1.f);

  // 11) x2p = x1 + ff1 @ W2^T + b2
  gemm_bf16<64,64,2,2, E_BIAS|E_RES|E_WF32><<<dim3(D/64, (B*NQ)/64, 1), blk, 0, stream>>>(
      ff1_b, W2_b, b2, x1f, x2p, nullptr, DFF, DFF, DFF, D, 1, 0,0,0,0,0,0, 1.f);

  // 12) LN2 -> x2s (bf16, /sqrt(D))
  ln_kernel<<<dim3(B*NQ), blk, 0, stream>>>(x2p, ln2g, ln2b, nullptr, x2s_b, 0.03125f);

  // 13) out2 = x2s @ vox_b^T
  gemm_bf16<128,128,2,2, E_WF32><<<dim3(NV/128, NQ/128, B), blk, 0, stream>>>(
      x2s_b, vox_b, nullptr, nullptr, out2, nullptr, D, D, D, NV, 1,
      sQ, 0, (long long)NV * D, 0, (long long)NQ * NV, 0, 1.f);

  // 14) masked softmax in place; bf16 weights
  vox_softmax<<<dim3(B*NQ), blk, 0, stream>>>(out2, vox_m, wvox_b);

  // 15) out0 partials: split-K=4 over NV from voxT_b, then reduce
  gemm_bf16<128,128,2,2, E_WF32><<<dim3(D/128, NQ/128, B*4), blk, 0, stream>>>(
      wvox_b, voxT_b, nullptr, nullptr, part, nullptr, NV/4, NV, NV, D, 4,
      (long long)NQ * NV, 1024, (long long)D * NV, 1024, 4 * nd, nd, 1.f);
  splitk_reduce<<<dim3((B * NQ * D) / 1024), blk, 0, stream>>>(part, out0);
}

// Round 9
// 432.607 us; speedup vs baseline: 1.1828x; 1.0310x over previous
//
#include <hip/hip_runtime.h>
#include <math.h>

typedef unsigned short u16;
typedef unsigned int u32;
typedef __bf16 bf16x8 __attribute__((ext_vector_type(8)));
typedef float f32x4 __attribute__((ext_vector_type(4)));
typedef u16 u16x4 __attribute__((ext_vector_type(4)));

constexpr int B = 8, NQ = 256, LT = 512, NV = 4096;
constexpr int D = 1024, H = 16, DFF = 2048, FTXT = 4096, HD = 64;

__device__ __forceinline__ u16 f2b(float f) {
  u32 u = __builtin_bit_cast(u32, f);
  return (u16)((u + 0x7fffu + ((u >> 16) & 1u)) >> 16);   // RNE
}
__device__ __forceinline__ float b2f(u16 b) {
  u32 u = ((u32)b) << 16;
  return __builtin_bit_cast(float, u);
}
__device__ __forceinline__ void gload16(const void* g, void* l) {
  __builtin_amdgcn_global_load_lds(
      (const __attribute__((address_space(1))) u32*)g,
      (__attribute__((address_space(3))) u32*)l, 16, 0, 0);
}

// ===========================================================================
// 256x128 8-phase bf16 GEMM for the KV projection, FULL K (no split-K).
// kv[4096][2048] = mtxt[4096][4096] @ kvW[2048][4096]^T + bias, bf16 out.
// 512 thr = 8 waves (2x4). BK=64, nt=64 tiles. LDS 96 KiB:
//   A [2db][2rowhalf][128][64], B [2db][128][64]. XOR-swizzle slot^(row&7).
// 4 phases per 2 k-tiles: (db,qm) quadrants; B-frags persist across qm-pair.
// vmcnt ledger: prologue 10 -> vmcnt(4); steady waits vmcnt(4) at P2/P4
// (drain current tile's 6, keep next tile's 4 A-loads in flight);
// tail j=31: vmcnt(0) at P2. Never 0 mid-loop otherwise.
// ===========================================================================
__global__ __launch_bounds__(512, 2)
void gemm_kv256b(const u16* __restrict__ A, const u16* __restrict__ Bw,
                 const float* __restrict__ bk_, const float* __restrict__ bv_,
                 u16* __restrict__ Cb)
{
  __shared__ __align__(16) u16 As[4 * 8192];   // [db*2+h][128][64]
  __shared__ __align__(16) u16 Bs[2 * 8192];   // [db][128][64]

  const int gx = 16, gy = 16;
  const int nwg = 256;
  const int flat = blockIdx.y * gx + blockIdx.x;
  const int qq = nwg >> 3;
  const int xcd = flat & 7, lid = flat >> 3;
  const int wg = xcd * qq + lid;
  const int bx = wg % gx;
  const int by = wg / gx;
  const int m0 = by * 256, n0 = bx * 128;
  const float* bias = (n0 < 1024) ? (bk_ + n0) : (bv_ + (n0 - 1024));

  const int t = threadIdx.x;
  const int w = t >> 6, l = t & 63;
  const int wr64 = (w >> 2) * 64;        // wave row-slice within 128-row quadrant
  const int wc32 = (w & 3) * 32;         // wave col-slice within 128 cols
  const int l15 = l & 15, l4 = l >> 4, l7 = l & 7;

  auto stA = [&](int db, int h, int tile) {   // 2 gloads: rows h*128..+128
    const long long kk = (long long)tile * 64 + (((t & 7) ^ ((t >> 3) & 7)) * 8);
    #pragma unroll
    for (int i = 0; i < 2; ++i)
      gload16(&A[(long long)(m0 + h * 128 + (t >> 3) + 64 * i) * 4096 + kk],
              &As[(db * 2 + h) * 8192 + (w * 8 + 64 * i) * 64]);
  };
  auto stB = [&](int db, int tile) {          // 2 gloads: all 128 n-rows
    const long long kk = (long long)tile * 64 + (((t & 7) ^ ((t >> 3) & 7)) * 8);
    #pragma unroll
    for (int i = 0; i < 2; ++i)
      gload16(&Bw[(long long)(n0 + (t >> 3) + 64 * i) * 4096 + kk],
              &Bs[db * 8192 + (w * 8 + 64 * i) * 64]);
  };

#define RDA(db,qm,fm,ks) \
  (*reinterpret_cast<const bf16x8*>(&As[((db)*2+(qm))*8192 + \
      (wr64 + (fm)*16 + l15)*64 + ((((ks)*4 + l4) ^ l7) * 8)]))
#define RDB(db,fn,ks) \
  (*reinterpret_cast<const bf16x8*>(&Bs[(db)*8192 + \
      (wc32 + (fn)*16 + l15)*64 + ((((ks)*4 + l4) ^ l7) * 8)]))

  f32x4 acc[2][4][2] = {};                 // [qm][fm][fn]
  bf16x8 a_[4][2];                         // per-phase A fragments
  bf16x8 b_[2][2];                         // persistent B fragments (qm-pair)

#define LOADA(db, qm)                                                        \
  do {                                                                       \
    _Pragma("unroll")                                                        \
    for (int fm_ = 0; fm_ < 4; ++fm_) {                                      \
      a_[fm_][0] = RDA(db, qm, fm_, 0);                                      \
      a_[fm_][1] = RDA(db, qm, fm_, 1);                                      \
    }                                                                        \
  } while (0)

#define LOADB(db)                                                            \
  do {                                                                       \
    b_[0][0] = RDB(db, 0, 0); b_[0][1] = RDB(db, 0, 1);                      \
    b_[1][0] = RDB(db, 1, 0); b_[1][1] = RDB(db, 1, 1);                      \
  } while (0)

#define MMACL(qm)                                                            \
  do {                                                                       \
    asm volatile("s_barrier" ::: "memory");                                  \
    __builtin_amdgcn_s_setprio(1);                                           \
    _Pragma("unroll")                                                        \
    for (int fm_ = 0; fm_ < 4; ++fm_) {                                      \
      _Pragma("unroll")                                                      \
      for (int fn_ = 0; fn_ < 2; ++fn_) {                                    \
        acc[qm][fm_][fn_] = __builtin_amdgcn_mfma_f32_16x16x32_bf16(         \
            a_[fm_][0], b_[fn_][0], acc[qm][fm_][fn_], 0, 0, 0);             \
        acc[qm][fm_][fn_] = __builtin_amdgcn_mfma_f32_16x16x32_bf16(         \
            a_[fm_][1], b_[fn_][1], acc[qm][fm_][fn_], 0, 0, 0);             \
      }                                                                      \
    }                                                                        \
    __builtin_amdgcn_s_setprio(0);                                           \
  } while (0)

  // prologue: tile0 (A h0,h1 + B = 6) + tile1 A halves (4) -> 10 in flight
  stA(0, 0, 0); stA(0, 1, 0); stB(0, 0);
  stA(1, 0, 1); stA(1, 1, 1);
  asm volatile("s_waitcnt vmcnt(4)" ::: "memory");
  asm volatile("s_barrier" ::: "memory");

  // nt = 64 tiles -> 32 iterations of 2 tiles (4 phases each)
  for (int j = 0; j < 32; ++j) {
    const bool s2 = (j < 31);
    const int t1 = 2 * j + 1, t2 = 2 * j + 2, t3 = 2 * j + 3;

    // P1 (db0, qm0)
    LOADA(0, 0); LOADB(0);
    stB(1, t1);
    MMACL(0);
    asm volatile("s_barrier" ::: "memory");
    // P2 (db0, qm1)  [B persists]
    LOADA(0, 1);
    if (s2) { stA(0, 0, t2); stA(0, 1, t2); }
    MMACL(1);
    if (s2) { asm volatile("s_waitcnt vmcnt(4)" ::: "memory"); }
    else    { asm volatile("s_waitcnt vmcnt(0)" ::: "memory"); }
    asm volatile("s_barrier" ::: "memory");
    // P3 (db1, qm0)
    LOADA(1, 0); LOADB(1);
    if (s2) stB(0, t2);
    MMACL(0);
    asm volatile("s_barrier" ::: "memory");
    // P4 (db1, qm1)
    LOADA(1, 1);
    if (s2) { stA(1, 0, t3); stA(1, 1, t3); }
    MMACL(1);
    if (s2) { asm volatile("s_waitcnt vmcnt(4)" ::: "memory"); }
    asm volatile("s_barrier" ::: "memory");
  }
#undef LOADA
#undef LOADB
#undef MMACL
#undef RDA
#undef RDB

  // epilogue: bias + bf16 store
  #pragma unroll
  for (int qm = 0; qm < 2; ++qm)
    #pragma unroll
    for (int fm = 0; fm < 4; ++fm)
      #pragma unroll
      for (int r = 0; r < 4; ++r) {
        const long long row = m0 + qm * 128 + wr64 + fm * 16 + l4 * 4 + r;
        #pragma unroll
        for (int fn = 0; fn < 2; ++fn) {
          const int lc = wc32 + fn * 16 + l15;
          Cb[row * 2048 + n0 + lc] = f2b(acc[qm][fm][fn][r] + bias[lc]);
        }
      }
}

// ---------------------------------------------------------------------------
// 2-phase bf16 MFMA GEMM (bf16 B via global_load_lds only).
// ---------------------------------------------------------------------------
constexpr int E_BIAS = 1, E_RES = 2, E_RELU = 4, E_WF32 = 8, E_WB16 = 16;

template<int BM, int BN, int WM, int WN, int EPI>
__global__ __launch_bounds__(256)
void gemm_bf16(const u16* __restrict__ A, const u16* __restrict__ Bw,
               const float* __restrict__ bias, const float* __restrict__ res,
               float* __restrict__ C, u16* __restrict__ Cb,
               int K, int lda, int ldb, int ldc, int nbz2,
               long long sA1, long long sA2, long long sB1, long long sB2,
               long long sC1, long long sC2, float alpha)
{
  constexpr int SM = BM / WM, SN = BN / WN;
  constexpr int FM = SM / 16, FN = SN / 16;
  constexpr int PA = BM / 64, PB = BN / 64;
  __shared__ __align__(16) u16 As[2][BM * 32];
  __shared__ __align__(16) u16 Bs[2][BN * 32];

  const int gx = gridDim.x, gy = gridDim.y;
  const int nwg = gx * gy * gridDim.z;
  const int flat = (blockIdx.z * gy + blockIdx.y) * gx + blockIdx.x;
  const int qq = nwg >> 3, rr = nwg & 7;
  const int xcd = flat & 7, lid = flat >> 3;
  const int wg = (xcd < rr ? xcd * (qq + 1) : rr * (qq + 1) + (xcd - rr) * qq) + lid;
  const int bx = wg % gx;
  const int tmp1 = wg / gx;
  const int by = tmp1 % gy, bz = tmp1 / gy;

  const int t = threadIdx.x;
  const int w = t >> 6, l = t & 63;
  const int wr = w / WN, wc = w % WN;
  const int m0 = by * BM, n0 = bx * BN;
  const long long offA = (long long)(bz / nbz2) * sA1 + (long long)(bz % nbz2) * sA2;
  const long long offB = (long long)(bz / nbz2) * sB1 + (long long)(bz % nbz2) * sB2;
  const long long offC = (long long)(bz / nbz2) * sC1 + (long long)(bz % nbz2) * sC2;
  const u16* Ab = A + offA;
  const u16* Bb = Bw + offB;

  const int srow = t >> 2;
  const int sk   = (t & 3) * 8;

  auto stageA = [&](int buf, int k0) {
    #pragma unroll
    for (int p = 0; p < PA; ++p)
      gload16(&Ab[(long long)(m0 + p * 64 + srow) * lda + k0 + sk],
              &As[buf][p * 2048 + w * 512]);
  };
  auto stageB = [&](int buf, int k0) {
    #pragma unroll
    for (int p = 0; p < PB; ++p)
      gload16(&Bb[(long long)(n0 + p * 64 + srow) * ldb + k0 + sk],
              &Bs[buf][p * 2048 + w * 512]);
  };

  f32x4 acc[FM][FN] = {};

  stageA(0, 0);
  stageB(0, 0);

  int cur = 0;
  for (int k0 = 0; k0 < K; k0 += 32) {
    __syncthreads();
    const bool pf = (k0 + 32 < K);
    if (pf) {
      stageA(cur ^ 1, k0 + 32);
      stageB(cur ^ 1, k0 + 32);
    }

    bf16x8 af[FM], bfr[FN];
    #pragma unroll
    for (int i = 0; i < FM; ++i)
      af[i] = *reinterpret_cast<const bf16x8*>(
          &As[cur][(wr * SM + i * 16 + (l & 15)) * 32 + (l >> 4) * 8]);
    #pragma unroll
    for (int j = 0; j < FN; ++j)
      bfr[j] = *reinterpret_cast<const bf16x8*>(
          &Bs[cur][(wc * SN + j * 16 + (l & 15)) * 32 + (l >> 4) * 8]);
    #pragma unroll
    for (int i = 0; i < FM; ++i)
      #pragma unroll
      for (int j = 0; j < FN; ++j)
        acc[i][j] = __builtin_amdgcn_mfma_f32_16x16x32_bf16(af[i], bfr[j], acc[i][j], 0, 0, 0);
    cur ^= 1;
  }

  const int c_l = l & 15, r_l4 = (l >> 4) * 4;
  #pragma unroll
  for (int i = 0; i < FM; ++i) {
    #pragma unroll
    for (int r = 0; r < 4; ++r) {
      const long long row = m0 + wr * SM + i * 16 + r_l4 + r;
      #pragma unroll
      for (int j = 0; j < FN; ++j) {
        const int col = n0 + wc * SN + j * 16 + c_l;
        float v = acc[i][j][r] * alpha;
        if (EPI & E_BIAS) v += bias[col];
        if (EPI & E_RES)  v += res[row * (long long)ldc + col];
        if (EPI & E_RELU) v = fmaxf(v, 0.f);
        const long long co = offC + row * (long long)ldc + col;
        if (EPI & E_WF32) C[co] = v;
        if (EPI & E_WB16) Cb[co] = f2b(v);
      }
    }
  }
}

// ---------------------------------------------------------------------------
// vox f32 [B][NV][D] -> vb bf16 [B][NV][D]  AND  vt bf16 [B][D][NV]
// ---------------------------------------------------------------------------
__global__ __launch_bounds__(256)
void vox_prep(const float* __restrict__ in, u16* __restrict__ vb,
              u16* __restrict__ vt)
{
  __shared__ u16 tile[64][68];
  const int b = blockIdx.z;
  const int n0 = blockIdx.y * 64;
  const int d0 = blockIdx.x * 64;
  const int t = threadIdx.x;
  const int tr = t >> 4;
  const int tc = (t & 15) * 4;
  const float* ib = in + (long long)b * NV * D;
  u16* vbb = vb + (long long)b * NV * D;
  u16* vtb = vt + (long long)b * NV * D;
  #pragma unroll
  for (int p = 0; p < 4; ++p) {
    int r = tr + p * 16;
    float4 x = *reinterpret_cast<const float4*>(&ib[(long long)(n0 + r) * D + d0 + tc]);
    u16x4 o = {f2b(x.x), f2b(x.y), f2b(x.z), f2b(x.w)};
    *reinterpret_cast<u16x4*>(&vbb[(long long)(n0 + r) * D + d0 + tc]) = o;
    *reinterpret_cast<u16x4*>(&tile[r][tc]) = o;
  }
  __syncthreads();
  #pragma unroll
  for (int p = 0; p < 4; ++p) {
    int c = tr + p * 16;
    u16x4 o = {tile[tc + 0][c], tile[tc + 1][c], tile[tc + 2][c], tile[tc + 3][c]};
    *reinterpret_cast<u16x4*>(&vtb[(long long)(d0 + c) * NV + n0 + tc]) = o;
  }
}

// ---------------------------------------------------------------------------
struct Cvt7 { const float* s[7]; u16* d[7]; int cum[8]; };

__global__ __launch_bounds__(256)
void cvt_multi(Cvt7 a)
{
  const int bidx = blockIdx.x;
  int seg = 0;
  #pragma unroll
  for (int k = 1; k < 7; ++k) if (bidx >= a.cum[k]) seg = k;
  const long long off = ((long long)(bidx - a.cum[seg]) * 256 + threadIdx.x) * 4;
  float4 x = *reinterpret_cast<const float4*>(a.s[seg] + off);
  u16x4 o = {f2b(x.x), f2b(x.y), f2b(x.z), f2b(x.w)};
  *reinterpret_cast<u16x4*>(a.d[seg] + off) = o;
}

__global__ __launch_bounds__(256)
void cvt_add_bf16(const float* __restrict__ a, const float* __restrict__ b,
                  u16* __restrict__ out)
{
  const long long i = ((long long)blockIdx.x * 256 + threadIdx.x) * 4;
  float4 x = *reinterpret_cast<const float4*>(&a[i]);
  float4 y = *reinterpret_cast<const float4*>(&b[i]);
  u16x4 o = {f2b(x.x + y.x), f2b(x.y + y.y), f2b(x.z + y.z), f2b(x.w + y.w)};
  *reinterpret_cast<u16x4*>(&out[i]) = o;
}

__global__ __launch_bounds__(256)
void transpose_u16(const u16* __restrict__ in, u16* __restrict__ out,
                   int R, int C, int ldin, long long sbin, long long sbout)
{
  __shared__ u16 tile[32][34];
  const int b = blockIdx.z;
  const int r0 = blockIdx.y * 32, c0 = blockIdx.x * 32;
  const int tx = threadIdx.x & 31, ty = threadIdx.x >> 5;
  const u16* ib = in + (long long)b * sbin;
  u16* ob = out + (long long)b * sbout;
  #pragma unroll
  for (int p = 0; p < 4; ++p) {
    int r = ty + p * 8;
    tile[r][tx] = ib[(long long)(r0 + r) * ldin + c0 + tx];
  }
  __syncthreads();
  #pragma unroll
  for (int p = 0; p < 4; ++p) {
    int c = ty + p * 8;
    ob[(long long)(c0 + c) * R + r0 + tx] = tile[tx][c];
  }
}

// ---------------------------------------------------------------------------
__global__ __launch_bounds__(256)
void txt_softmax_mean(const float* __restrict__ sc, const int* __restrict__ mask,
                      u16* __restrict__ wout, float* __restrict__ out1)
{
  __shared__ float red[8];
  const int t = threadIdx.x, l = t & 63, w = t >> 6;
  const int bq = blockIdx.x;
  const int b = bq >> 8, q = bq & 255;
  const int* mr = mask + b * LT;
  const bool msk0 = mr[t] != 0, msk1 = mr[t + 256] != 0;
  float a0 = 0.f, a1 = 0.f;
  for (int h = 0; h < H; ++h) {
    const long long ro = (((long long)(b * H + h)) * NQ + q) * LT;
    const float* sr = sc + ro;
    float x0 = msk0 ? -INFINITY : sr[t];
    float x1 = msk1 ? -INFINITY : sr[t + 256];
    float mx = fmaxf(x0, x1);
    #pragma unroll
    for (int o = 32; o > 0; o >>= 1) mx = fmaxf(mx, __shfl_xor(mx, o, 64));
    if (l == 0) red[w] = mx;
    __syncthreads();
    mx = fmaxf(fmaxf(red[0], red[1]), fmaxf(red[2], red[3]));
    float e0 = __expf(x0 - mx), e1 = __expf(x1 - mx);
    float s = e0 + e1;
    #pragma unroll
    for (int o = 32; o > 0; o >>= 1) s += __shfl_xor(s, o, 64);
    if (l == 0) red[4 + w] = s;
    __syncthreads();
    s = red[4] + red[5] + red[6] + red[7];
    const float inv = 1.f / s;
    const float w0 = e0 * inv, w1 = e1 * inv;
    u16* wr = wout + ro;
    wr[t] = f2b(w0); wr[t + 256] = f2b(w1);
    a0 += w0; a1 += w1;
  }
  float* o1 = out1 + (long long)bq * LT;
  o1[t]       = a0 * (1.f / H);
  o1[t + 256] = a1 * (1.f / H);
}

// ---------------------------------------------------------------------------
__global__ __launch_bounds__(256)
void ln_kernel(const float* __restrict__ x, const float* __restrict__ g,
               const float* __restrict__ bia, float* __restrict__ y,
               u16* __restrict__ yb, float scale)
{
  __shared__ float tmp[256];
  const int t = threadIdx.x;
  const long long off = (long long)blockIdx.x * D;
  float4 x4 = *reinterpret_cast<const float4*>(&x[off + t * 4]);
  tmp[t] = x4.x + x4.y + x4.z + x4.w;
  __syncthreads();
  for (int o = 128; o > 0; o >>= 1) { if (t < o) tmp[t] += tmp[t + o]; __syncthreads(); }
  const float mean = tmp[0] * (1.f / D);
  __syncthreads();
  float d0 = x4.x - mean, d1 = x4.y - mean, d2 = x4.z - mean, d3 = x4.w - mean;
  tmp[t] = d0 * d0 + d1 * d1 + d2 * d2 + d3 * d3;
  __syncthreads();
  for (int o = 128; o > 0; o >>= 1) { if (t < o) tmp[t] += tmp[t + o]; __syncthreads(); }
  const float rs = rsqrtf(tmp[0] * (1.f / D) + 1e-5f);
  float4 g4 = *reinterpret_cast<const float4*>(&g[t * 4]);
  float4 b4 = *reinterpret_cast<const float4*>(&bia[t * 4]);
  float o0 = (d0 * rs * g4.x + b4.x) * scale;
  float o1 = (d1 * rs * g4.y + b4.y) * scale;
  float o2 = (d2 * rs * g4.z + b4.z) * scale;
  float o3 = (d3 * rs * g4.w + b4.w) * scale;
  if (y) {
    float4 o4 = {o0, o1, o2, o3};
    *reinterpret_cast<float4*>(&y[off + t * 4]) = o4;
  }
  if (yb) {
    u16x4 ob = {f2b(o0), f2b(o1), f2b(o2), f2b(o3)};
    *reinterpret_cast<u16x4*>(&yb[off + t * 4]) = ob;
  }
}

// ---------------------------------------------------------------------------
__global__ __launch_bounds__(256)
void vox_softmax(float* __restrict__ s, const int* __restrict__ mask,
                 u16* __restrict__ wb)
{
  __shared__ float tmp[256];
  const int t = threadIdx.x;
  const int row = blockIdx.x, b = row / NQ;
  float* sr = s + (long long)row * NV;
  u16* wr = wb + (long long)row * NV;
  const int* mr = mask + b * NV;
  float vals[16];
  float lm = -INFINITY;
  #pragma unroll
  for (int j = 0; j < 16; ++j) {
    int n = t + j * 256;
    float x = mr[n] ? -INFINITY : sr[n];
    vals[j] = x;
    lm = fmaxf(lm, x);
  }
  tmp[t] = lm;
  __syncthreads();
  for (int o = 128; o > 0; o >>= 1) { if (t < o) tmp[t] = fmaxf(tmp[t], tmp[t + o]); __syncthreads(); }
  const float mx = tmp[0];
  __syncthreads();
  float ls = 0.f;
  #pragma unroll
  for (int j = 0; j < 16; ++j) { vals[j] = __expf(vals[j] - mx); ls += vals[j]; }
  tmp[t] = ls;
  __syncthreads();
  for (int o = 128; o > 0; o >>= 1) { if (t < o) tmp[t] += tmp[t + o]; __syncthreads(); }
  const float inv = 1.f / tmp[0];
  #pragma unroll
  for (int j = 0; j < 16; ++j) {
    float v = vals[j] * inv;
    sr[t + j * 256] = v;
    wr[t + j * 256] = f2b(v);
  }
}

__global__ __launch_bounds__(256)
void splitk_reduce(const float* __restrict__ part, float* __restrict__ out)
{
  const long long i = ((long long)blockIdx.x * 256 + threadIdx.x) * 4;
  const long long nd = (long long)NQ * D;
  const long long b = i / nd;
  const long long o = i - b * nd;
  const float* p = part + b * 4 * nd + o;
  float4 s0 = *reinterpret_cast<const float4*>(&p[0]);
  float4 s1 = *reinterpret_cast<const float4*>(&p[nd]);
  float4 s2 = *reinterpret_cast<const float4*>(&p[2 * nd]);
  float4 s3 = *reinterpret_cast<const float4*>(&p[3 * nd]);
  float4 r = {s0.x + s1.x + s2.x + s3.x, s0.y + s1.y + s2.y + s3.y,
              s0.z + s1.z + s2.z + s3.z, s0.w + s1.w + s2.w + s3.w};
  *reinterpret_cast<float4*>(&out[i]) = r;
}

// ---------------------------------------------------------------------------
extern "C" void kernel_launch(void* const* d_in, const int* in_sizes, int n_in,
                              void* d_out, int out_size, void* d_ws, size_t ws_size,
                              hipStream_t stream)
{
  const float* tgt   = (const float*)d_in[0];
  const float* mtxt  = (const float*)d_in[1];
  const float* vox   = (const float*)d_in[2];
  const float* qpos  = (const float*)d_in[3];
  const int*   mtx_m = (const int*)d_in[4];
  const int*   vox_m = (const int*)d_in[5];
  const float* Wq = (const float*)d_in[6];  const float* bq = (const float*)d_in[7];
  const float* Wk = (const float*)d_in[8];  const float* bk = (const float*)d_in[9];
  const float* Wv = (const float*)d_in[10]; const float* bv = (const float*)d_in[11];
  const float* Wo = (const float*)d_in[12]; const float* bo = (const float*)d_in[13];
  const float* W1 = (const float*)d_in[14]; const float* b1 = (const float*)d_in[15];
  const float* W2 = (const float*)d_in[16]; const float* b2 = (const float*)d_in[17];
  const float* ln1g = (const float*)d_in[18]; const float* ln1b = (const float*)d_in[19];
  const float* ln2g = (const float*)d_in[20]; const float* ln2b = (const float*)d_in[21];

  float* out0 = (float*)d_out;                       // attn_output  [B,NQ,D]
  float* out1 = out0 + (long long)B * NQ * D;        // txt_cross    [B,NQ,LT]
  float* out2 = out1 + (long long)B * NQ * LT;       // attn_weights [B,NQ,NV]

  char* base = (char*)d_ws;
  constexpr size_t MB = 1ull << 20;
  u16*   kvW   = (u16*)(base + 0 * MB);     // 16  [Wk;Wv] stacked
  u16*   Wq_b  = (u16*)(base + 16 * MB);    // 2
  u16*   Wo_b  = (u16*)(base + 18 * MB);    // 2
  u16*   W1_b  = (u16*)(base + 20 * MB);    // 4
  u16*   W2_b  = (u16*)(base + 24 * MB);    // 4
  u16*   tq_b  = (u16*)(base + 28 * MB);    // 4
  u16*   q_b   = (u16*)(base + 32 * MB);    // 4
  u16*   kv_b  = (u16*)(base + 36 * MB);    // 16  [B*LT][2048]
  u16*   vT_b  = (u16*)(base + 52 * MB);    // 8
  u16*   ctx_b = (u16*)(base + 60 * MB);    // 4
  float* x1p   = (float*)(base + 64 * MB);  // 8
  float* x1f   = (float*)(base + 72 * MB);  // 8
  u16*   x1_b  = (u16*)(base + 80 * MB);    // 4
  u16*   ff1_b = (u16*)(base + 84 * MB);    // 8
  float* x2p   = (float*)(base + 92 * MB);  // 8
  u16*   x2s_b = (u16*)(base + 100 * MB);   // 4
  u16*   mtxt_b = (u16*)(base + 104 * MB);  // 32  dead after kv256b
  float* scores = (float*)(base + 136 * MB);// 64  dead after txt_softmax_mean
  u16*   w_b    = (u16*)(base + 200 * MB);  // 32  dead after ctx gemm
  u16*   vox_b  = (u16*)(base + 104 * MB);  // 64  overlays mtxt_b + scores head
  u16*   voxT_b = (u16*)(base + 168 * MB);  // 64  overlays scores tail + w_b
  u16*   wvox_b = (u16*)(base + 0 * MB);    // 16  overlays kvW (dead)
  float* part   = (float*)(base + 16 * MB); // 32  overlays Wq..q_b (dead)

  const dim3 blk(256);
  const long long sQ = (long long)NQ * D;
  const long long sSC = (long long)NQ * LT;
  const long long nd = (long long)NQ * D;

  // 1) conversions: fused weights + memory_txt; tq = tgt + qpos
  Cvt7 ca;
  ca.s[0] = Wq;   ca.d[0] = Wq_b;
  ca.s[1] = Wk;   ca.d[1] = kvW;
  ca.s[2] = Wv;   ca.d[2] = kvW + (long long)D * FTXT;
  ca.s[3] = Wo;   ca.d[3] = Wo_b;
  ca.s[4] = W1;   ca.d[4] = W1_b;
  ca.s[5] = W2;   ca.d[5] = W2_b;
  ca.s[6] = mtxt; ca.d[6] = mtxt_b;
  ca.cum[0] = 0;     ca.cum[1] = 1024;  ca.cum[2] = 5120;  ca.cum[3] = 9216;
  ca.cum[4] = 10240; ca.cum[5] = 12288; ca.cum[6] = 14336; ca.cum[7] = 30720;
  cvt_multi<<<dim3(30720), blk, 0, stream>>>(ca);
  cvt_add_bf16<<<dim3((B * NQ * D) / 1024), blk, 0, stream>>>(tgt, qpos, tq_b);

  // 2) q projection (2-phase) + kv projection (8-phase 256x128, full K)
  gemm_bf16<64,64,2,2, E_BIAS|E_WB16><<<dim3(D/64, (B*NQ)/64, 1), blk, 0, stream>>>(
      tq_b, Wq_b, bq, nullptr, nullptr, q_b, D, D, D, D, 1, 0,0,0,0,0,0, 1.f);
  gemm_kv256b<<<dim3(16, 16), dim3(512), 0, stream>>>(mtxt_b, kvW, bk, bv, kv_b);

  // 3) vT[b][d][l] = v[b][l][d]
  transpose_u16<<<dim3(D/32, LT/32, B), blk, 0, stream>>>(
      kv_b + 1024, vT_b, LT, D, 2048, (long long)LT * 2048, (long long)D * LT);

  // 4) scores = q . k / 8
  gemm_bf16<128,128,2,2, E_WF32><<<dim3(LT/128, NQ/128, B*H), blk, 0, stream>>>(
      q_b, kv_b, nullptr, nullptr, scores, nullptr, HD, D, 2048, LT, H,
      sQ, HD, (long long)LT * 2048, HD, (long long)H * sSC, sSC, 0.125f);

  // 5) fused softmax + head-mean
  txt_softmax_mean<<<dim3(B*NQ), blk, 0, stream>>>(scores, mtx_m, w_b, out1);

  // 6) ctx = w_h @ v_h
  gemm_bf16<64,64,2,2, E_WB16><<<dim3(HD/64, NQ/64, B*H), blk, 0, stream>>>(
      w_b, vT_b, nullptr, nullptr, nullptr, ctx_b, LT, LT, LT, D, H,
      (long long)H * sSC, sSC, (long long)D * LT, (long long)HD * LT, sQ, HD, 1.f);

  // 7) vox -> vox_b + voxT_b (one f32 read)
  vox_prep<<<dim3(D/64, NV/64, B), blk, 0, stream>>>(vox, vox_b, voxT_b);

  // 8) x1p = tgt + ctx @ Wo^T + bo
  gemm_bf16<64,64,2,2, E_BIAS|E_RES|E_WF32><<<dim3(D/64, (B*NQ)/64, 1), blk, 0, stream>>>(
      ctx_b, Wo_b, bo, tgt, x1p, nullptr, D, D, D, D, 1, 0,0,0,0,0,0, 1.f);

  // 9) LN1
  ln_kernel<<<dim3(B*NQ), blk, 0, stream>>>(x1p, ln1g, ln1b, x1f, x1_b, 1.f);

  // 10) ff1 = relu(x1 @ W1^T + b1)
  gemm_bf16<128,64,2,2, E_BIAS|E_RELU|E_WB16><<<dim3(DFF/64, (B*NQ)/128, 1), blk, 0, stream>>>(
      x1_b, W1_b, b1, nullptr, nullptr, ff1_b, D, D, D, DFF, 1, 0,0,0,0,0,0, 1.f);

  // 11) x2p = x1 + ff1 @ W2^T + b2
  gemm_bf16<64,64,2,2, E_BIAS|E_RES|E_WF32><<<dim3(D/64, (B*NQ)/64, 1), blk, 0, stream>>>(
      ff1_b, W2_b, b2, x1f, x2p, nullptr, DFF, DFF, DFF, D, 1, 0,0,0,0,0,0, 1.f);

  // 12) LN2 -> x2s (bf16, /sqrt(D))
  ln_kernel<<<dim3(B*NQ), blk, 0, stream>>>(x2p, ln2g, ln2b, nullptr, x2s_b, 0.03125f);

  // 13) out2 = x2s @ vox_b^T
  gemm_bf16<128,128,2,2, E_WF32><<<dim3(NV/128, NQ/128, B), blk, 0, stream>>>(
      x2s_b, vox_b, nullptr, nullptr, out2, nullptr, D, D, D, NV, 1,
      sQ, 0, (long long)NV * D, 0, (long long)NQ * NV, 0, 1.f);

  // 14) masked softmax in place; bf16 weights
  vox_softmax<<<dim3(B*NQ), blk, 0, stream>>>(out2, vox_m, wvox_b);

  // 15) out0 partials: split-K=4 over NV from voxT_b, then reduce
  gemm_bf16<128,128,2,2, E_WF32><<<dim3(D/128, NQ/128, B*4), blk, 0, stream>>>(
      wvox_b, voxT_b, nullptr, nullptr, part, nullptr, NV/4, NV, NV, D, 4,
      (long long)NQ * NV, 1024, (long long)D * NV, 1024, 4 * nd, nd, 1.f);
  splitk_reduce<<<dim3((B * NQ * D) / 1024), blk, 0, stream>>>(part, out0);
}

// Round 10
// 427.204 us; speedup vs baseline: 1.1978x; 1.0126x over previous
//
#include <hip/hip_runtime.h>
#include <math.h>

typedef unsigned short u16;
typedef unsigned int u32;
typedef __bf16 bf16x8 __attribute__((ext_vector_type(8)));
typedef float f32x4 __attribute__((ext_vector_type(4)));
typedef u16 u16x4 __attribute__((ext_vector_type(4)));

constexpr int B = 8, NQ = 256, LT = 512, NV = 4096;
constexpr int D = 1024, H = 16, DFF = 2048, FTXT = 4096, HD = 64;

__device__ __forceinline__ u16 f2b(float f) {
  u32 u = __builtin_bit_cast(u32, f);
  return (u16)((u + 0x7fffu + ((u >> 16) & 1u)) >> 16);   // RNE
}
__device__ __forceinline__ float b2f(u16 b) {
  u32 u = ((u32)b) << 16;
  return __builtin_bit_cast(float, u);
}
__device__ __forceinline__ void gload16(const void* g, void* l) {
  __builtin_amdgcn_global_load_lds(
      (const __attribute__((address_space(1))) u32*)g,
      (__attribute__((address_space(3))) u32*)l, 16, 0, 0);
}

// ===========================================================================
// Shared 8-phase 256x128 machinery (R9-verified schedule):
// LDS 96 KiB: A [2db][2h][128][64], B [2db][128][64], XOR-swizzle slot^(row&7).
// 4 phases / 2 k-tiles, B-frags persist across qm-pair, vmcnt(4) at P2/P4.
// ===========================================================================

// --- KV projection: full K=4096, bf16 out + bias (unchanged from R9) ---
__global__ __launch_bounds__(512, 2)
void gemm_kv256b(const u16* __restrict__ A, const u16* __restrict__ Bw,
                 const float* __restrict__ bk_, const float* __restrict__ bv_,
                 u16* __restrict__ Cb)
{
  __shared__ __align__(16) u16 As[4 * 8192];
  __shared__ __align__(16) u16 Bs[2 * 8192];

  const int gx = 16;
  const int flat = blockIdx.y * gx + blockIdx.x;
  const int qq = 256 >> 3;
  const int xcd = flat & 7, lid = flat >> 3;
  const int wg = xcd * qq + lid;
  const int bx = wg % gx;
  const int by = wg / gx;
  const int m0 = by * 256, n0 = bx * 128;
  const float* bias = (n0 < 1024) ? (bk_ + n0) : (bv_ + (n0 - 1024));

  const int t = threadIdx.x;
  const int w = t >> 6, l = t & 63;
  const int wr64 = (w >> 2) * 64;
  const int wc32 = (w & 3) * 32;
  const int l15 = l & 15, l4 = l >> 4, l7 = l & 7;

  auto stA = [&](int db, int h, int tile) {
    const long long kk = (long long)tile * 64 + (((t & 7) ^ ((t >> 3) & 7)) * 8);
    #pragma unroll
    for (int i = 0; i < 2; ++i)
      gload16(&A[(long long)(m0 + h * 128 + (t >> 3) + 64 * i) * 4096 + kk],
              &As[(db * 2 + h) * 8192 + (w * 8 + 64 * i) * 64]);
  };
  auto stB = [&](int db, int tile) {
    const long long kk = (long long)tile * 64 + (((t & 7) ^ ((t >> 3) & 7)) * 8);
    #pragma unroll
    for (int i = 0; i < 2; ++i)
      gload16(&Bw[(long long)(n0 + (t >> 3) + 64 * i) * 4096 + kk],
              &Bs[db * 8192 + (w * 8 + 64 * i) * 64]);
  };

#define RDA(db,qm,fm,ks) \
  (*reinterpret_cast<const bf16x8*>(&As[((db)*2+(qm))*8192 + \
      (wr64 + (fm)*16 + l15)*64 + ((((ks)*4 + l4) ^ l7) * 8)]))
#define RDB(db,fn,ks) \
  (*reinterpret_cast<const bf16x8*>(&Bs[(db)*8192 + \
      (wc32 + (fn)*16 + l15)*64 + ((((ks)*4 + l4) ^ l7) * 8)]))

  f32x4 acc[2][4][2] = {};
  bf16x8 a_[4][2];
  bf16x8 b_[2][2];

#define LOADA(db, qm)                                                        \
  do {                                                                       \
    _Pragma("unroll")                                                        \
    for (int fm_ = 0; fm_ < 4; ++fm_) {                                      \
      a_[fm_][0] = RDA(db, qm, fm_, 0);                                      \
      a_[fm_][1] = RDA(db, qm, fm_, 1);                                      \
    }                                                                        \
  } while (0)
#define LOADB(db)                                                            \
  do {                                                                       \
    b_[0][0] = RDB(db, 0, 0); b_[0][1] = RDB(db, 0, 1);                      \
    b_[1][0] = RDB(db, 1, 0); b_[1][1] = RDB(db, 1, 1);                      \
  } while (0)
#define MMACL(qm)                                                            \
  do {                                                                       \
    asm volatile("s_barrier" ::: "memory");                                  \
    __builtin_amdgcn_s_setprio(1);                                           \
    _Pragma("unroll")                                                        \
    for (int fm_ = 0; fm_ < 4; ++fm_) {                                      \
      _Pragma("unroll")                                                      \
      for (int fn_ = 0; fn_ < 2; ++fn_) {                                    \
        acc[qm][fm_][fn_] = __builtin_amdgcn_mfma_f32_16x16x32_bf16(         \
            a_[fm_][0], b_[fn_][0], acc[qm][fm_][fn_], 0, 0, 0);             \
        acc[qm][fm_][fn_] = __builtin_amdgcn_mfma_f32_16x16x32_bf16(         \
            a_[fm_][1], b_[fn_][1], acc[qm][fm_][fn_], 0, 0, 0);             \
      }                                                                      \
    }                                                                        \
    __builtin_amdgcn_s_setprio(0);                                           \
  } while (0)

  stA(0, 0, 0); stA(0, 1, 0); stB(0, 0);
  stA(1, 0, 1); stA(1, 1, 1);
  asm volatile("s_waitcnt vmcnt(4)" ::: "memory");
  asm volatile("s_barrier" ::: "memory");

  for (int j = 0; j < 32; ++j) {
    const bool s2 = (j < 31);
    const int t1 = 2 * j + 1, t2 = 2 * j + 2, t3 = 2 * j + 3;
    LOADA(0, 0); LOADB(0);
    stB(1, t1);
    MMACL(0);
    asm volatile("s_barrier" ::: "memory");
    LOADA(0, 1);
    if (s2) { stA(0, 0, t2); stA(0, 1, t2); }
    MMACL(1);
    if (s2) { asm volatile("s_waitcnt vmcnt(4)" ::: "memory"); }
    else    { asm volatile("s_waitcnt vmcnt(0)" ::: "memory"); }
    asm volatile("s_barrier" ::: "memory");
    LOADA(1, 0); LOADB(1);
    if (s2) stB(0, t2);
    MMACL(0);
    asm volatile("s_barrier" ::: "memory");
    LOADA(1, 1);
    if (s2) { stA(1, 0, t3); stA(1, 1, t3); }
    MMACL(1);
    if (s2) { asm volatile("s_waitcnt vmcnt(4)" ::: "memory"); }
    asm volatile("s_barrier" ::: "memory");
  }
#undef LOADA
#undef LOADB
#undef MMACL
#undef RDA
#undef RDB

  #pragma unroll
  for (int qm = 0; qm < 2; ++qm)
    #pragma unroll
    for (int fm = 0; fm < 4; ++fm)
      #pragma unroll
      for (int r = 0; r < 4; ++r) {
        const long long row = m0 + qm * 128 + wr64 + fm * 16 + l4 * 4 + r;
        #pragma unroll
        for (int fn = 0; fn < 2; ++fn) {
          const int lc = wc32 + fn * 16 + l15;
          Cb[row * 2048 + n0 + lc] = f2b(acc[qm][fm][fn][r] + bias[lc]);
        }
      }
}

// --- Generalized 8-phase 256x128: C f32 = A[M][K]@Bw[N][K]^T, batched with
//     optional split-K (NZ2). Same schedule/ledger as gemm_kv256b. ---
template<int NZ2>
__global__ __launch_bounds__(512, 2)
void gemm8(const u16* __restrict__ A, const u16* __restrict__ Bw,
           float* __restrict__ C,
           int Ksub, int lda, int ldb, int ldc, int kstep,
           long long sA1, long long sB1, long long sC1, long long sC2)
{
  __shared__ __align__(16) u16 As[4 * 8192];
  __shared__ __align__(16) u16 Bs[2 * 8192];

  const int gx = gridDim.x, gy = gridDim.y;
  const int nwg = gx * gy * gridDim.z;
  const int flat = (blockIdx.z * gy + blockIdx.y) * gx + blockIdx.x;
  const int qq = nwg >> 3, rr = nwg & 7;
  const int xcd = flat & 7, lid = flat >> 3;
  const int wg = (xcd < rr ? xcd * (qq + 1) : rr * (qq + 1) + (xcd - rr) * qq) + lid;
  const int bx = wg % gx;
  const int tmp1 = wg / gx;
  const int by = tmp1 % gy, bz = tmp1 / gy;
  const int z1 = bz / NZ2, z2 = bz % NZ2;
  const int m0 = by * 256, n0 = bx * 128;
  const long long kbase = (long long)z2 * kstep;
  const u16* Ab = A + (long long)z1 * sA1;
  const u16* Bb = Bw + (long long)z1 * sB1;
  float* Cp = C + (long long)z1 * sC1 + (long long)z2 * sC2;

  const int t = threadIdx.x;
  const int w = t >> 6, l = t & 63;
  const int wr64 = (w >> 2) * 64;
  const int wc32 = (w & 3) * 32;
  const int l15 = l & 15, l4 = l >> 4, l7 = l & 7;

  auto stA = [&](int db, int h, int tile) {
    const long long kk = kbase + (long long)tile * 64 + (((t & 7) ^ ((t >> 3) & 7)) * 8);
    #pragma unroll
    for (int i = 0; i < 2; ++i)
      gload16(&Ab[(long long)(m0 + h * 128 + (t >> 3) + 64 * i) * lda + kk],
              &As[(db * 2 + h) * 8192 + (w * 8 + 64 * i) * 64]);
  };
  auto stB = [&](int db, int tile) {
    const long long kk = kbase + (long long)tile * 64 + (((t & 7) ^ ((t >> 3) & 7)) * 8);
    #pragma unroll
    for (int i = 0; i < 2; ++i)
      gload16(&Bb[(long long)(n0 + (t >> 3) + 64 * i) * ldb + kk],
              &Bs[db * 8192 + (w * 8 + 64 * i) * 64]);
  };

#define RDA(db,qm,fm,ks) \
  (*reinterpret_cast<const bf16x8*>(&As[((db)*2+(qm))*8192 + \
      (wr64 + (fm)*16 + l15)*64 + ((((ks)*4 + l4) ^ l7) * 8)]))
#define RDB(db,fn,ks) \
  (*reinterpret_cast<const bf16x8*>(&Bs[(db)*8192 + \
      (wc32 + (fn)*16 + l15)*64 + ((((ks)*4 + l4) ^ l7) * 8)]))

  f32x4 acc[2][4][2] = {};
  bf16x8 a_[4][2];
  bf16x8 b_[2][2];

#define LOADA(db, qm)                                                        \
  do {                                                                       \
    _Pragma("unroll")                                                        \
    for (int fm_ = 0; fm_ < 4; ++fm_) {                                      \
      a_[fm_][0] = RDA(db, qm, fm_, 0);                                      \
      a_[fm_][1] = RDA(db, qm, fm_, 1);                                      \
    }                                                                        \
  } while (0)
#define LOADB(db)                                                            \
  do {                                                                       \
    b_[0][0] = RDB(db, 0, 0); b_[0][1] = RDB(db, 0, 1);                      \
    b_[1][0] = RDB(db, 1, 0); b_[1][1] = RDB(db, 1, 1);                      \
  } while (0)
#define MMACL(qm)                                                            \
  do {                                                                       \
    asm volatile("s_barrier" ::: "memory");                                  \
    __builtin_amdgcn_s_setprio(1);                                           \
    _Pragma("unroll")                                                        \
    for (int fm_ = 0; fm_ < 4; ++fm_) {                                      \
      _Pragma("unroll")                                                      \
      for (int fn_ = 0; fn_ < 2; ++fn_) {                                    \
        acc[qm][fm_][fn_] = __builtin_amdgcn_mfma_f32_16x16x32_bf16(         \
            a_[fm_][0], b_[fn_][0], acc[qm][fm_][fn_], 0, 0, 0);             \
        acc[qm][fm_][fn_] = __builtin_amdgcn_mfma_f32_16x16x32_bf16(         \
            a_[fm_][1], b_[fn_][1], acc[qm][fm_][fn_], 0, 0, 0);             \
      }                                                                      \
    }                                                                        \
    __builtin_amdgcn_s_setprio(0);                                           \
  } while (0)

  stA(0, 0, 0); stA(0, 1, 0); stB(0, 0);
  stA(1, 0, 1); stA(1, 1, 1);
  asm volatile("s_waitcnt vmcnt(4)" ::: "memory");
  asm volatile("s_barrier" ::: "memory");

  const int niter = Ksub >> 7;   // (Ksub/64)/2 k-tile pairs
  for (int j = 0; j < niter; ++j) {
    const bool s2 = (j < niter - 1);
    const int t1 = 2 * j + 1, t2 = 2 * j + 2, t3 = 2 * j + 3;
    LOADA(0, 0); LOADB(0);
    stB(1, t1);
    MMACL(0);
    asm volatile("s_barrier" ::: "memory");
    LOADA(0, 1);
    if (s2) { stA(0, 0, t2); stA(0, 1, t2); }
    MMACL(1);
    if (s2) { asm volatile("s_waitcnt vmcnt(4)" ::: "memory"); }
    else    { asm volatile("s_waitcnt vmcnt(0)" ::: "memory"); }
    asm volatile("s_barrier" ::: "memory");
    LOADA(1, 0); LOADB(1);
    if (s2) stB(0, t2);
    MMACL(0);
    asm volatile("s_barrier" ::: "memory");
    LOADA(1, 1);
    if (s2) { stA(1, 0, t3); stA(1, 1, t3); }
    MMACL(1);
    if (s2) { asm volatile("s_waitcnt vmcnt(4)" ::: "memory"); }
    asm volatile("s_barrier" ::: "memory");
  }
#undef LOADA
#undef LOADB
#undef MMACL
#undef RDA
#undef RDB

  #pragma unroll
  for (int qm = 0; qm < 2; ++qm)
    #pragma unroll
    for (int fm = 0; fm < 4; ++fm)
      #pragma unroll
      for (int r = 0; r < 4; ++r) {
        const long long row = m0 + qm * 128 + wr64 + fm * 16 + l4 * 4 + r;
        #pragma unroll
        for (int fn = 0; fn < 2; ++fn) {
          const int lc = wc32 + fn * 16 + l15;
          Cp[row * (long long)ldc + n0 + lc] = acc[qm][fm][fn][r];
        }
      }
}

// ---------------------------------------------------------------------------
// 2-phase bf16 MFMA GEMM (bf16 B via global_load_lds only).
// ---------------------------------------------------------------------------
constexpr int E_BIAS = 1, E_RES = 2, E_RELU = 4, E_WF32 = 8, E_WB16 = 16;

template<int BM, int BN, int WM, int WN, int EPI>
__global__ __launch_bounds__(256)
void gemm_bf16(const u16* __restrict__ A, const u16* __restrict__ Bw,
               const float* __restrict__ bias, const float* __restrict__ res,
               float* __restrict__ C, u16* __restrict__ Cb,
               int K, int lda, int ldb, int ldc, int nbz2,
               long long sA1, long long sA2, long long sB1, long long sB2,
               long long sC1, long long sC2, float alpha)
{
  constexpr int SM = BM / WM, SN = BN / WN;
  constexpr int FM = SM / 16, FN = SN / 16;
  constexpr int PA = BM / 64, PB = BN / 64;
  __shared__ __align__(16) u16 As[2][BM * 32];
  __shared__ __align__(16) u16 Bs[2][BN * 32];

  const int gx = gridDim.x, gy = gridDim.y;
  const int nwg = gx * gy * gridDim.z;
  const int flat = (blockIdx.z * gy + blockIdx.y) * gx + blockIdx.x;
  const int qq = nwg >> 3, rr = nwg & 7;
  const int xcd = flat & 7, lid = flat >> 3;
  const int wg = (xcd < rr ? xcd * (qq + 1) : rr * (qq + 1) + (xcd - rr) * qq) + lid;
  const int bx = wg % gx;
  const int tmp1 = wg / gx;
  const int by = tmp1 % gy, bz = tmp1 / gy;

  const int t = threadIdx.x;
  const int w = t >> 6, l = t & 63;
  const int wr = w / WN, wc = w % WN;
  const int m0 = by * BM, n0 = bx * BN;
  const long long offA = (long long)(bz / nbz2) * sA1 + (long long)(bz % nbz2) * sA2;
  const long long offB = (long long)(bz / nbz2) * sB1 + (long long)(bz % nbz2) * sB2;
  const long long offC = (long long)(bz / nbz2) * sC1 + (long long)(bz % nbz2) * sC2;
  const u16* Ab = A + offA;
  const u16* Bb = Bw + offB;

  const int srow = t >> 2;
  const int sk   = (t & 3) * 8;

  auto stageA = [&](int buf, int k0) {
    #pragma unroll
    for (int p = 0; p < PA; ++p)
      gload16(&Ab[(long long)(m0 + p * 64 + srow) * lda + k0 + sk],
              &As[buf][p * 2048 + w * 512]);
  };
  auto stageB = [&](int buf, int k0) {
    #pragma unroll
    for (int p = 0; p < PB; ++p)
      gload16(&Bb[(long long)(n0 + p * 64 + srow) * ldb + k0 + sk],
              &Bs[buf][p * 2048 + w * 512]);
  };

  f32x4 acc[FM][FN] = {};

  stageA(0, 0);
  stageB(0, 0);

  int cur = 0;
  for (int k0 = 0; k0 < K; k0 += 32) {
    __syncthreads();
    const bool pf = (k0 + 32 < K);
    if (pf) {
      stageA(cur ^ 1, k0 + 32);
      stageB(cur ^ 1, k0 + 32);
    }

    bf16x8 af[FM], bfr[FN];
    #pragma unroll
    for (int i = 0; i < FM; ++i)
      af[i] = *reinterpret_cast<const bf16x8*>(
          &As[cur][(wr * SM + i * 16 + (l & 15)) * 32 + (l >> 4) * 8]);
    #pragma unroll
    for (int j = 0; j < FN; ++j)
      bfr[j] = *reinterpret_cast<const bf16x8*>(
          &Bs[cur][(wc * SN + j * 16 + (l & 15)) * 32 + (l >> 4) * 8]);
    #pragma unroll
    for (int i = 0; i < FM; ++i)
      #pragma unroll
      for (int j = 0; j < FN; ++j)
        acc[i][j] = __builtin_amdgcn_mfma_f32_16x16x32_bf16(af[i], bfr[j], acc[i][j], 0, 0, 0);
    cur ^= 1;
  }

  const int c_l = l & 15, r_l4 = (l >> 4) * 4;
  #pragma unroll
  for (int i = 0; i < FM; ++i) {
    #pragma unroll
    for (int r = 0; r < 4; ++r) {
      const long long row = m0 + wr * SM + i * 16 + r_l4 + r;
      #pragma unroll
      for (int j = 0; j < FN; ++j) {
        const int col = n0 + wc * SN + j * 16 + c_l;
        float v = acc[i][j][r] * alpha;
        if (EPI & E_BIAS) v += bias[col];
        if (EPI & E_RES)  v += res[row * (long long)ldc + col];
        if (EPI & E_RELU) v = fmaxf(v, 0.f);
        const long long co = offC + row * (long long)ldc + col;
        if (EPI & E_WF32) C[co] = v;
        if (EPI & E_WB16) Cb[co] = f2b(v);
      }
    }
  }
}

// ---------------------------------------------------------------------------
// vox f32 [B][NV][D] -> vb bf16 [B][NV][D]  AND  vt bf16 [B][D][NV]
// ---------------------------------------------------------------------------
__global__ __launch_bounds__(256)
void vox_prep(const float* __restrict__ in, u16* __restrict__ vb,
              u16* __restrict__ vt)
{
  __shared__ u16 tile[64][68];
  const int b = blockIdx.z;
  const int n0 = blockIdx.y * 64;
  const int d0 = blockIdx.x * 64;
  const int t = threadIdx.x;
  const int tr = t >> 4;
  const int tc = (t & 15) * 4;
  const float* ib = in + (long long)b * NV * D;
  u16* vbb = vb + (long long)b * NV * D;
  u16* vtb = vt + (long long)b * NV * D;
  #pragma unroll
  for (int p = 0; p < 4; ++p) {
    int r = tr + p * 16;
    float4 x = *reinterpret_cast<const float4*>(&ib[(long long)(n0 + r) * D + d0 + tc]);
    u16x4 o = {f2b(x.x), f2b(x.y), f2b(x.z), f2b(x.w)};
    *reinterpret_cast<u16x4*>(&vbb[(long long)(n0 + r) * D + d0 + tc]) = o;
    *reinterpret_cast<u16x4*>(&tile[r][tc]) = o;
  }
  __syncthreads();
  #pragma unroll
  for (int p = 0; p < 4; ++p) {
    int c = tr + p * 16;
    u16x4 o = {tile[tc + 0][c], tile[tc + 1][c], tile[tc + 2][c], tile[tc + 3][c]};
    *reinterpret_cast<u16x4*>(&vtb[(long long)(d0 + c) * NV + n0 + tc]) = o;
  }
}

// ---------------------------------------------------------------------------
struct Cvt7 { const float* s[7]; u16* d[7]; int cum[8]; };

__global__ __launch_bounds__(256)
void cvt_multi(Cvt7 a)
{
  const int bidx = blockIdx.x;
  int seg = 0;
  #pragma unroll
  for (int k = 1; k < 7; ++k) if (bidx >= a.cum[k]) seg = k;
  const long long off = ((long long)(bidx - a.cum[seg]) * 256 + threadIdx.x) * 4;
  float4 x = *reinterpret_cast<const float4*>(a.s[seg] + off);
  u16x4 o = {f2b(x.x), f2b(x.y), f2b(x.z), f2b(x.w)};
  *reinterpret_cast<u16x4*>(a.d[seg] + off) = o;
}

__global__ __launch_bounds__(256)
void cvt_add_bf16(const float* __restrict__ a, const float* __restrict__ b,
                  u16* __restrict__ out)
{
  const long long i = ((long long)blockIdx.x * 256 + threadIdx.x) * 4;
  float4 x = *reinterpret_cast<const float4*>(&a[i]);
  float4 y = *reinterpret_cast<const float4*>(&b[i]);
  u16x4 o = {f2b(x.x + y.x), f2b(x.y + y.y), f2b(x.z + y.z), f2b(x.w + y.w)};
  *reinterpret_cast<u16x4*>(&out[i]) = o;
}

__global__ __launch_bounds__(256)
void transpose_u16(const u16* __restrict__ in, u16* __restrict__ out,
                   int R, int C, int ldin, long long sbin, long long sbout)
{
  __shared__ u16 tile[32][34];
  const int b = blockIdx.z;
  const int r0 = blockIdx.y * 32, c0 = blockIdx.x * 32;
  const int tx = threadIdx.x & 31, ty = threadIdx.x >> 5;
  const u16* ib = in + (long long)b * sbin;
  u16* ob = out + (long long)b * sbout;
  #pragma unroll
  for (int p = 0; p < 4; ++p) {
    int r = ty + p * 8;
    tile[r][tx] = ib[(long long)(r0 + r) * ldin + c0 + tx];
  }
  __syncthreads();
  #pragma unroll
  for (int p = 0; p < 4; ++p) {
    int c = ty + p * 8;
    ob[(long long)(c0 + c) * R + r0 + tx] = tile[tx][c];
  }
}

// ---------------------------------------------------------------------------
__global__ __launch_bounds__(256)
void txt_softmax_mean(const float* __restrict__ sc, const int* __restrict__ mask,
                      u16* __restrict__ wout, float* __restrict__ out1)
{
  __shared__ float red[8];
  const int t = threadIdx.x, l = t & 63, w = t >> 6;
  const int bq = blockIdx.x;
  const int b = bq >> 8, q = bq & 255;
  const int* mr = mask + b * LT;
  const bool msk0 = mr[t] != 0, msk1 = mr[t + 256] != 0;
  float a0 = 0.f, a1 = 0.f;
  for (int h = 0; h < H; ++h) {
    const long long ro = (((long long)(b * H + h)) * NQ + q) * LT;
    const float* sr = sc + ro;
    float x0 = msk0 ? -INFINITY : sr[t];
    float x1 = msk1 ? -INFINITY : sr[t + 256];
    float mx = fmaxf(x0, x1);
    #pragma unroll
    for (int o = 32; o > 0; o >>= 1) mx = fmaxf(mx, __shfl_xor(mx, o, 64));
    if (l == 0) red[w] = mx;
    __syncthreads();
    mx = fmaxf(fmaxf(red[0], red[1]), fmaxf(red[2], red[3]));
    float e0 = __expf(x0 - mx), e1 = __expf(x1 - mx);
    float s = e0 + e1;
    #pragma unroll
    for (int o = 32; o > 0; o >>= 1) s += __shfl_xor(s, o, 64);
    if (l == 0) red[4 + w] = s;
    __syncthreads();
    s = red[4] + red[5] + red[6] + red[7];
    const float inv = 1.f / s;
    const float w0 = e0 * inv, w1 = e1 * inv;
    u16* wr = wout + ro;
    wr[t] = f2b(w0); wr[t + 256] = f2b(w1);
    a0 += w0; a1 += w1;
  }
  float* o1 = out1 + (long long)bq * LT;
  o1[t]       = a0 * (1.f / H);
  o1[t + 256] = a1 * (1.f / H);
}

// ---------------------------------------------------------------------------
__global__ __launch_bounds__(256)
void ln_kernel(const float* __restrict__ x, const float* __restrict__ g,
               const float* __restrict__ bia, float* __restrict__ y,
               u16* __restrict__ yb, float scale)
{
  __shared__ float tmp[256];
  const int t = threadIdx.x;
  const long long off = (long long)blockIdx.x * D;
  float4 x4 = *reinterpret_cast<const float4*>(&x[off + t * 4]);
  tmp[t] = x4.x + x4.y + x4.z + x4.w;
  __syncthreads();
  for (int o = 128; o > 0; o >>= 1) { if (t < o) tmp[t] += tmp[t + o]; __syncthreads(); }
  const float mean = tmp[0] * (1.f / D);
  __syncthreads();
  float d0 = x4.x - mean, d1 = x4.y - mean, d2 = x4.z - mean, d3 = x4.w - mean;
  tmp[t] = d0 * d0 + d1 * d1 + d2 * d2 + d3 * d3;
  __syncthreads();
  for (int o = 128; o > 0; o >>= 1) { if (t < o) tmp[t] += tmp[t + o]; __syncthreads(); }
  const float rs = rsqrtf(tmp[0] * (1.f / D) + 1e-5f);
  float4 g4 = *reinterpret_cast<const float4*>(&g[t * 4]);
  float4 b4 = *reinterpret_cast<const float4*>(&bia[t * 4]);
  float o0 = (d0 * rs * g4.x + b4.x) * scale;
  float o1 = (d1 * rs * g4.y + b4.y) * scale;
  float o2 = (d2 * rs * g4.z + b4.z) * scale;
  float o3 = (d3 * rs * g4.w + b4.w) * scale;
  if (y) {
    float4 o4 = {o0, o1, o2, o3};
    *reinterpret_cast<float4*>(&y[off + t * 4]) = o4;
  }
  if (yb) {
    u16x4 ob = {f2b(o0), f2b(o1), f2b(o2), f2b(o3)};
    *reinterpret_cast<u16x4*>(&yb[off + t * 4]) = ob;
  }
}

// ---------------------------------------------------------------------------
__global__ __launch_bounds__(256)
void vox_softmax(float* __restrict__ s, const int* __restrict__ mask,
                 u16* __restrict__ wb)
{
  __shared__ float tmp[256];
  const int t = threadIdx.x;
  const int row = blockIdx.x, b = row / NQ;
  float* sr = s + (long long)row * NV;
  u16* wr = wb + (long long)row * NV;
  const int* mr = mask + b * NV;
  float vals[16];
  float lm = -INFINITY;
  #pragma unroll
  for (int j = 0; j < 16; ++j) {
    int n = t + j * 256;
    float x = mr[n] ? -INFINITY : sr[n];
    vals[j] = x;
    lm = fmaxf(lm, x);
  }
  tmp[t] = lm;
  __syncthreads();
  for (int o = 128; o > 0; o >>= 1) { if (t < o) tmp[t] = fmaxf(tmp[t], tmp[t + o]); __syncthreads(); }
  const float mx = tmp[0];
  __syncthreads();
  float ls = 0.f;
  #pragma unroll
  for (int j = 0; j < 16; ++j) { vals[j] = __expf(vals[j] - mx); ls += vals[j]; }
  tmp[t] = ls;
  __syncthreads();
  for (int o = 128; o > 0; o >>= 1) { if (t < o) tmp[t] += tmp[t + o]; __syncthreads(); }
  const float inv = 1.f / tmp[0];
  #pragma unroll
  for (int j = 0; j < 16; ++j) {
    float v = vals[j] * inv;
    sr[t + j * 256] = v;
    wr[t + j * 256] = f2b(v);
  }
}

__global__ __launch_bounds__(256)
void splitk_reduce(const float* __restrict__ part, float* __restrict__ out)
{
  const long long i = ((long long)blockIdx.x * 256 + threadIdx.x) * 4;
  const long long nd = (long long)NQ * D;
  const long long b = i / nd;
  const long long o = i - b * nd;
  const float* p = part + b * 4 * nd + o;
  float4 s0 = *reinterpret_cast<const float4*>(&p[0]);
  float4 s1 = *reinterpret_cast<const float4*>(&p[nd]);
  float4 s2 = *reinterpret_cast<const float4*>(&p[2 * nd]);
  float4 s3 = *reinterpret_cast<const float4*>(&p[3 * nd]);
  float4 r = {s0.x + s1.x + s2.x + s3.x, s0.y + s1.y + s2.y + s3.y,
              s0.z + s1.z + s2.z + s3.z, s0.w + s1.w + s2.w + s3.w};
  *reinterpret_cast<float4*>(&out[i]) = r;
}

// ---------------------------------------------------------------------------
extern "C" void kernel_launch(void* const* d_in, const int* in_sizes, int n_in,
                              void* d_out, int out_size, void* d_ws, size_t ws_size,
                              hipStream_t stream)
{
  const float* tgt   = (const float*)d_in[0];
  const float* mtxt  = (const float*)d_in[1];
  const float* vox   = (const float*)d_in[2];
  const float* qpos  = (const float*)d_in[3];
  const int*   mtx_m = (const int*)d_in[4];
  const int*   vox_m = (const int*)d_in[5];
  const float* Wq = (const float*)d_in[6];  const float* bq = (const float*)d_in[7];
  const float* Wk = (const float*)d_in[8];  const float* bk = (const float*)d_in[9];
  const float* Wv = (const float*)d_in[10]; const float* bv = (const float*)d_in[11];
  const float* Wo = (const float*)d_in[12]; const float* bo = (const float*)d_in[13];
  const float* W1 = (const float*)d_in[14]; const float* b1 = (const float*)d_in[15];
  const float* W2 = (const float*)d_in[16]; const float* b2 = (const float*)d_in[17];
  const float* ln1g = (const float*)d_in[18]; const float* ln1b = (const float*)d_in[19];
  const float* ln2g = (const float*)d_in[20]; const float* ln2b = (const float*)d_in[21];

  float* out0 = (float*)d_out;                       // attn_output  [B,NQ,D]
  float* out1 = out0 + (long long)B * NQ * D;        // txt_cross    [B,NQ,LT]
  float* out2 = out1 + (long long)B * NQ * LT;       // attn_weights [B,NQ,NV]

  char* base = (char*)d_ws;
  constexpr size_t MB = 1ull << 20;
  u16*   kvW   = (u16*)(base + 0 * MB);     // 16  [Wk;Wv] stacked
  u16*   Wq_b  = (u16*)(base + 16 * MB);    // 2
  u16*   Wo_b  = (u16*)(base + 18 * MB);    // 2
  u16*   W1_b  = (u16*)(base + 20 * MB);    // 4
  u16*   W2_b  = (u16*)(base + 24 * MB);    // 4
  u16*   tq_b  = (u16*)(base + 28 * MB);    // 4
  u16*   q_b   = (u16*)(base + 32 * MB);    // 4
  u16*   kv_b  = (u16*)(base + 36 * MB);    // 16  [B*LT][2048]
  u16*   vT_b  = (u16*)(base + 52 * MB);    // 8
  u16*   ctx_b = (u16*)(base + 60 * MB);    // 4
  float* x1p   = (float*)(base + 64 * MB);  // 8
  float* x1f   = (float*)(base + 72 * MB);  // 8
  u16*   x1_b  = (u16*)(base + 80 * MB);    // 4
  u16*   ff1_b = (u16*)(base + 84 * MB);    // 8
  float* x2p   = (float*)(base + 92 * MB);  // 8
  u16*   x2s_b = (u16*)(base + 100 * MB);   // 4
  u16*   mtxt_b = (u16*)(base + 104 * MB);  // 32  dead after kv256b
  float* scores = (float*)(base + 136 * MB);// 64  dead after txt_softmax_mean
  u16*   w_b    = (u16*)(base + 200 * MB);  // 32  dead after ctx gemm
  u16*   vox_b  = (u16*)(base + 104 * MB);  // 64  overlays mtxt_b + scores head
  u16*   voxT_b = (u16*)(base + 168 * MB);  // 64  overlays scores tail + w_b
  u16*   wvox_b = (u16*)(base + 0 * MB);    // 16  overlays kvW (dead)
  float* part   = (float*)(base + 16 * MB); // 32  overlays Wq..q_b (dead)

  const dim3 blk(256);
  const long long sQ = (long long)NQ * D;
  const long long sSC = (long long)NQ * LT;
  const long long nd = (long long)NQ * D;

  // 1) conversions: fused weights + memory_txt; tq = tgt + qpos
  Cvt7 ca;
  ca.s[0] = Wq;   ca.d[0] = Wq_b;
  ca.s[1] = Wk;   ca.d[1] = kvW;
  ca.s[2] = Wv;   ca.d[2] = kvW + (long long)D * FTXT;
  ca.s[3] = Wo;   ca.d[3] = Wo_b;
  ca.s[4] = W1;   ca.d[4] = W1_b;
  ca.s[5] = W2;   ca.d[5] = W2_b;
  ca.s[6] = mtxt; ca.d[6] = mtxt_b;
  ca.cum[0] = 0;     ca.cum[1] = 1024;  ca.cum[2] = 5120;  ca.cum[3] = 9216;
  ca.cum[4] = 10240; ca.cum[5] = 12288; ca.cum[6] = 14336; ca.cum[7] = 30720;
  cvt_multi<<<dim3(30720), blk, 0, stream>>>(ca);
  cvt_add_bf16<<<dim3((B * NQ * D) / 1024), blk, 0, stream>>>(tgt, qpos, tq_b);

  // 2) q projection (2-phase) + kv projection (8-phase 256x128, full K)
  gemm_bf16<64,64,2,2, E_BIAS|E_WB16><<<dim3(D/64, (B*NQ)/64, 1), blk, 0, stream>>>(
      tq_b, Wq_b, bq, nullptr, nullptr, q_b, D, D, D, D, 1, 0,0,0,0,0,0, 1.f);
  gemm_kv256b<<<dim3(16, 16), dim3(512), 0, stream>>>(mtxt_b, kvW, bk, bv, kv_b);

  // 3) vT[b][d][l] = v[b][l][d]
  transpose_u16<<<dim3(D/32, LT/32, B), blk, 0, stream>>>(
      kv_b + 1024, vT_b, LT, D, 2048, (long long)LT * 2048, (long long)D * LT);

  // 4) scores = q . k / 8
  gemm_bf16<128,128,2,2, E_WF32><<<dim3(LT/128, NQ/128, B*H), blk, 0, stream>>>(
      q_b, kv_b, nullptr, nullptr, scores, nullptr, HD, D, 2048, LT, H,
      sQ, HD, (long long)LT * 2048, HD, (long long)H * sSC, sSC, 0.125f);

  // 5) fused softmax + head-mean
  txt_softmax_mean<<<dim3(B*NQ), blk, 0, stream>>>(scores, mtx_m, w_b, out1);

  // 6) ctx = w_h @ v_h
  gemm_bf16<64,64,2,2, E_WB16><<<dim3(HD/64, NQ/64, B*H), blk, 0, stream>>>(
      w_b, vT_b, nullptr, nullptr, nullptr, ctx_b, LT, LT, LT, D, H,
      (long long)H * sSC, sSC, (long long)D * LT, (long long)HD * LT, sQ, HD, 1.f);

  // 7) vox -> vox_b + voxT_b (one f32 read)
  vox_prep<<<dim3(D/64, NV/64, B), blk, 0, stream>>>(vox, vox_b, voxT_b);

  // 8) x1p = tgt + ctx @ Wo^T + bo
  gemm_bf16<64,64,2,2, E_BIAS|E_RES|E_WF32><<<dim3(D/64, (B*NQ)/64, 1), blk, 0, stream>>>(
      ctx_b, Wo_b, bo, tgt, x1p, nullptr, D, D, D, D, 1, 0,0,0,0,0,0, 1.f);

  // 9) LN1
  ln_kernel<<<dim3(B*NQ), blk, 0, stream>>>(x1p, ln1g, ln1b, x1f, x1_b, 1.f);

  // 10) ff1 = relu(x1 @ W1^T + b1)
  gemm_bf16<128,64,2,2, E_BIAS|E_RELU|E_WB16><<<dim3(DFF/64, (B*NQ)/128, 1), blk, 0, stream>>>(
      x1_b, W1_b, b1, nullptr, nullptr, ff1_b, D, D, D, DFF, 1, 0,0,0,0,0,0, 1.f);

  // 11) x2p = x1 + ff1 @ W2^T + b2
  gemm_bf16<64,64,2,2, E_BIAS|E_RES|E_WF32><<<dim3(D/64, (B*NQ)/64, 1), blk, 0, stream>>>(
      ff1_b, W2_b, b2, x1f, x2p, nullptr, DFF, DFF, DFF, D, 1, 0,0,0,0,0,0, 1.f);

  // 12) LN2 -> x2s (bf16, /sqrt(D))
  ln_kernel<<<dim3(B*NQ), blk, 0, stream>>>(x2p, ln2g, ln2b, nullptr, x2s_b, 0.03125f);

  // 13) out2 = x2s @ vox_b^T  (8-phase 256x128: grid 32x1x8 = 256 blocks)
  gemm8<1><<<dim3(NV/128, 1, B), dim3(512), 0, stream>>>(
      x2s_b, vox_b, out2, D, D, D, NV, 0,
      sQ, (long long)NV * D, (long long)NQ * NV, 0);

  // 14) masked softmax in place; bf16 weights
  vox_softmax<<<dim3(B*NQ), blk, 0, stream>>>(out2, vox_m, wvox_b);

  // 15) out0 partials: 8-phase split-K=4 (grid 8x1x32 = 256 blocks) + reduce
  gemm8<4><<<dim3(D/128, 1, B*4), dim3(512), 0, stream>>>(
      wvox_b, voxT_b, part, NV/4, NV, NV, D, NV/4,
      (long long)NQ * NV, (long long)D * NV, 4 * nd, nd);
  splitk_reduce<<<dim3((B * NQ * D) / 1024), blk, 0, stream>>>(part, out0);
}

// Round 11
// 417.644 us; speedup vs baseline: 1.2252x; 1.0229x over previous
//
#include <hip/hip_runtime.h>
#include <math.h>

typedef unsigned short u16;
typedef unsigned int u32;
typedef __bf16 bf16x8 __attribute__((ext_vector_type(8)));
typedef float f32x4 __attribute__((ext_vector_type(4)));
typedef u16 u16x4 __attribute__((ext_vector_type(4)));
typedef u16 u16x2 __attribute__((ext_vector_type(2)));

constexpr int B = 8, NQ = 256, LT = 512, NV = 4096;
constexpr int D = 1024, H = 16, DFF = 2048, FTXT = 4096, HD = 64;

__device__ __forceinline__ u16 f2b(float f) {
  u32 u = __builtin_bit_cast(u32, f);
  return (u16)((u + 0x7fffu + ((u >> 16) & 1u)) >> 16);   // RNE
}
__device__ __forceinline__ float b2f(u16 b) {
  u32 u = ((u32)b) << 16;
  return __builtin_bit_cast(float, u);
}
__device__ __forceinline__ void gload16(const void* g, void* l) {
  __builtin_amdgcn_global_load_lds(
      (const __attribute__((address_space(1))) u32*)g,
      (__attribute__((address_space(3))) u32*)l, 16, 0, 0);
}

// ===========================================================================
// Shared 8-phase 256x128 machinery (R9-verified schedule):
// LDS 96 KiB: A [2db][2h][128][64], B [2db][128][64], XOR-swizzle slot^(row&7).
// 4 phases / 2 k-tiles, B-frags persist across qm-pair, vmcnt(4) at P2/P4.
// ===========================================================================

// --- KV projection: full K=4096, bf16 out + bias ---
__global__ __launch_bounds__(512, 2)
void gemm_kv256b(const u16* __restrict__ A, const u16* __restrict__ Bw,
                 const float* __restrict__ bk_, const float* __restrict__ bv_,
                 u16* __restrict__ Cb)
{
  __shared__ __align__(16) u16 As[4 * 8192];
  __shared__ __align__(16) u16 Bs[2 * 8192];

  const int gx = 16;
  const int flat = blockIdx.y * gx + blockIdx.x;
  const int qq = 256 >> 3;
  const int xcd = flat & 7, lid = flat >> 3;
  const int wg = xcd * qq + lid;
  const int bx = wg % gx;
  const int by = wg / gx;
  const int m0 = by * 256, n0 = bx * 128;
  const float* bias = (n0 < 1024) ? (bk_ + n0) : (bv_ + (n0 - 1024));

  const int t = threadIdx.x;
  const int w = t >> 6, l = t & 63;
  const int wr64 = (w >> 2) * 64;
  const int wc32 = (w & 3) * 32;
  const int l15 = l & 15, l4 = l >> 4, l7 = l & 7;

  auto stA = [&](int db, int h, int tile) {
    const long long kk = (long long)tile * 64 + (((t & 7) ^ ((t >> 3) & 7)) * 8);
    #pragma unroll
    for (int i = 0; i < 2; ++i)
      gload16(&A[(long long)(m0 + h * 128 + (t >> 3) + 64 * i) * 4096 + kk],
              &As[(db * 2 + h) * 8192 + (w * 8 + 64 * i) * 64]);
  };
  auto stB = [&](int db, int tile) {
    const long long kk = (long long)tile * 64 + (((t & 7) ^ ((t >> 3) & 7)) * 8);
    #pragma unroll
    for (int i = 0; i < 2; ++i)
      gload16(&Bw[(long long)(n0 + (t >> 3) + 64 * i) * 4096 + kk],
              &Bs[db * 8192 + (w * 8 + 64 * i) * 64]);
  };

#define RDA(db,qm,fm,ks) \
  (*reinterpret_cast<const bf16x8*>(&As[((db)*2+(qm))*8192 + \
      (wr64 + (fm)*16 + l15)*64 + ((((ks)*4 + l4) ^ l7) * 8)]))
#define RDB(db,fn,ks) \
  (*reinterpret_cast<const bf16x8*>(&Bs[(db)*8192 + \
      (wc32 + (fn)*16 + l15)*64 + ((((ks)*4 + l4) ^ l7) * 8)]))

  f32x4 acc[2][4][2] = {};
  bf16x8 a_[4][2];
  bf16x8 b_[2][2];

#define LOADA(db, qm)                                                        \
  do {                                                                       \
    _Pragma("unroll")                                                        \
    for (int fm_ = 0; fm_ < 4; ++fm_) {                                      \
      a_[fm_][0] = RDA(db, qm, fm_, 0);                                      \
      a_[fm_][1] = RDA(db, qm, fm_, 1);                                      \
    }                                                                        \
  } while (0)
#define LOADB(db)                                                            \
  do {                                                                       \
    b_[0][0] = RDB(db, 0, 0); b_[0][1] = RDB(db, 0, 1);                      \
    b_[1][0] = RDB(db, 1, 0); b_[1][1] = RDB(db, 1, 1);                      \
  } while (0)
#define MMACL(qm)                                                            \
  do {                                                                       \
    asm volatile("s_barrier" ::: "memory");                                  \
    __builtin_amdgcn_s_setprio(1);                                           \
    _Pragma("unroll")                                                        \
    for (int fm_ = 0; fm_ < 4; ++fm_) {                                      \
      _Pragma("unroll")                                                      \
      for (int fn_ = 0; fn_ < 2; ++fn_) {                                    \
        acc[qm][fm_][fn_] = __builtin_amdgcn_mfma_f32_16x16x32_bf16(         \
            a_[fm_][0], b_[fn_][0], acc[qm][fm_][fn_], 0, 0, 0);             \
        acc[qm][fm_][fn_] = __builtin_amdgcn_mfma_f32_16x16x32_bf16(         \
            a_[fm_][1], b_[fn_][1], acc[qm][fm_][fn_], 0, 0, 0);             \
      }                                                                      \
    }                                                                        \
    __builtin_amdgcn_s_setprio(0);                                           \
  } while (0)

  stA(0, 0, 0); stA(0, 1, 0); stB(0, 0);
  stA(1, 0, 1); stA(1, 1, 1);
  asm volatile("s_waitcnt vmcnt(4)" ::: "memory");
  asm volatile("s_barrier" ::: "memory");

  for (int j = 0; j < 32; ++j) {
    const bool s2 = (j < 31);
    const int t1 = 2 * j + 1, t2 = 2 * j + 2, t3 = 2 * j + 3;
    LOADA(0, 0); LOADB(0);
    stB(1, t1);
    MMACL(0);
    asm volatile("s_barrier" ::: "memory");
    LOADA(0, 1);
    if (s2) { stA(0, 0, t2); stA(0, 1, t2); }
    MMACL(1);
    if (s2) { asm volatile("s_waitcnt vmcnt(4)" ::: "memory"); }
    else    { asm volatile("s_waitcnt vmcnt(0)" ::: "memory"); }
    asm volatile("s_barrier" ::: "memory");
    LOADA(1, 0); LOADB(1);
    if (s2) stB(0, t2);
    MMACL(0);
    asm volatile("s_barrier" ::: "memory");
    LOADA(1, 1);
    if (s2) { stA(1, 0, t3); stA(1, 1, t3); }
    MMACL(1);
    if (s2) { asm volatile("s_waitcnt vmcnt(4)" ::: "memory"); }
    asm volatile("s_barrier" ::: "memory");
  }
#undef LOADA
#undef LOADB
#undef MMACL
#undef RDA
#undef RDB

  #pragma unroll
  for (int qm = 0; qm < 2; ++qm)
    #pragma unroll
    for (int fm = 0; fm < 4; ++fm)
      #pragma unroll
      for (int r = 0; r < 4; ++r) {
        const long long row = m0 + qm * 128 + wr64 + fm * 16 + l4 * 4 + r;
        #pragma unroll
        for (int fn = 0; fn < 2; ++fn) {
          const int lc = wc32 + fn * 16 + l15;
          Cb[row * 2048 + n0 + lc] = f2b(acc[qm][fm][fn][r] + bias[lc]);
        }
      }
}

// --- Generalized 8-phase 256x128: C f32 = A[M][K]@Bw[N][K]^T, batched with
//     optional split-K (NZ2). Same schedule/ledger as gemm_kv256b. ---
template<int NZ2>
__global__ __launch_bounds__(512, 2)
void gemm8(const u16* __restrict__ A, const u16* __restrict__ Bw,
           float* __restrict__ C,
           int Ksub, int lda, int ldb, int ldc, int kstep,
           long long sA1, long long sB1, long long sC1, long long sC2)
{
  __shared__ __align__(16) u16 As[4 * 8192];
  __shared__ __align__(16) u16 Bs[2 * 8192];

  const int gx = gridDim.x, gy = gridDim.y;
  const int nwg = gx * gy * gridDim.z;
  const int flat = (blockIdx.z * gy + blockIdx.y) * gx + blockIdx.x;
  const int qq = nwg >> 3, rr = nwg & 7;
  const int xcd = flat & 7, lid = flat >> 3;
  const int wg = (xcd < rr ? xcd * (qq + 1) : rr * (qq + 1) + (xcd - rr) * qq) + lid;
  const int bx = wg % gx;
  const int tmp1 = wg / gx;
  const int by = tmp1 % gy, bz = tmp1 / gy;
  const int z1 = bz / NZ2, z2 = bz % NZ2;
  const int m0 = by * 256, n0 = bx * 128;
  const long long kbase = (long long)z2 * kstep;
  const u16* Ab = A + (long long)z1 * sA1;
  const u16* Bb = Bw + (long long)z1 * sB1;
  float* Cp = C + (long long)z1 * sC1 + (long long)z2 * sC2;

  const int t = threadIdx.x;
  const int w = t >> 6, l = t & 63;
  const int wr64 = (w >> 2) * 64;
  const int wc32 = (w & 3) * 32;
  const int l15 = l & 15, l4 = l >> 4, l7 = l & 7;

  auto stA = [&](int db, int h, int tile) {
    const long long kk = kbase + (long long)tile * 64 + (((t & 7) ^ ((t >> 3) & 7)) * 8);
    #pragma unroll
    for (int i = 0; i < 2; ++i)
      gload16(&Ab[(long long)(m0 + h * 128 + (t >> 3) + 64 * i) * lda + kk],
              &As[(db * 2 + h) * 8192 + (w * 8 + 64 * i) * 64]);
  };
  auto stB = [&](int db, int tile) {
    const long long kk = kbase + (long long)tile * 64 + (((t & 7) ^ ((t >> 3) & 7)) * 8);
    #pragma unroll
    for (int i = 0; i < 2; ++i)
      gload16(&Bb[(long long)(n0 + (t >> 3) + 64 * i) * ldb + kk],
              &Bs[db * 8192 + (w * 8 + 64 * i) * 64]);
  };

#define RDA(db,qm,fm,ks) \
  (*reinterpret_cast<const bf16x8*>(&As[((db)*2+(qm))*8192 + \
      (wr64 + (fm)*16 + l15)*64 + ((((ks)*4 + l4) ^ l7) * 8)]))
#define RDB(db,fn,ks) \
  (*reinterpret_cast<const bf16x8*>(&Bs[(db)*8192 + \
      (wc32 + (fn)*16 + l15)*64 + ((((ks)*4 + l4) ^ l7) * 8)]))

  f32x4 acc[2][4][2] = {};
  bf16x8 a_[4][2];
  bf16x8 b_[2][2];

#define LOADA(db, qm)                                                        \
  do {                                                                       \
    _Pragma("unroll")                                                        \
    for (int fm_ = 0; fm_ < 4; ++fm_) {                                      \
      a_[fm_][0] = RDA(db, qm, fm_, 0);                                      \
      a_[fm_][1] = RDA(db, qm, fm_, 1);                                      \
    }                                                                        \
  } while (0)
#define LOADB(db)                                                            \
  do {                                                                       \
    b_[0][0] = RDB(db, 0, 0); b_[0][1] = RDB(db, 0, 1);                      \
    b_[1][0] = RDB(db, 1, 0); b_[1][1] = RDB(db, 1, 1);                      \
  } while (0)
#define MMACL(qm)                                                            \
  do {                                                                       \
    asm volatile("s_barrier" ::: "memory");                                  \
    __builtin_amdgcn_s_setprio(1);                                           \
    _Pragma("unroll")                                                        \
    for (int fm_ = 0; fm_ < 4; ++fm_) {                                      \
      _Pragma("unroll")                                                      \
      for (int fn_ = 0; fn_ < 2; ++fn_) {                                    \
        acc[qm][fm_][fn_] = __builtin_amdgcn_mfma_f32_16x16x32_bf16(         \
            a_[fm_][0], b_[fn_][0], acc[qm][fm_][fn_], 0, 0, 0);             \
        acc[qm][fm_][fn_] = __builtin_amdgcn_mfma_f32_16x16x32_bf16(         \
            a_[fm_][1], b_[fn_][1], acc[qm][fm_][fn_], 0, 0, 0);             \
      }                                                                      \
    }                                                                        \
    __builtin_amdgcn_s_setprio(0);                                           \
  } while (0)

  stA(0, 0, 0); stA(0, 1, 0); stB(0, 0);
  stA(1, 0, 1); stA(1, 1, 1);
  asm volatile("s_waitcnt vmcnt(4)" ::: "memory");
  asm volatile("s_barrier" ::: "memory");

  const int niter = Ksub >> 7;
  for (int j = 0; j < niter; ++j) {
    const bool s2 = (j < niter - 1);
    const int t1 = 2 * j + 1, t2 = 2 * j + 2, t3 = 2 * j + 3;
    LOADA(0, 0); LOADB(0);
    stB(1, t1);
    MMACL(0);
    asm volatile("s_barrier" ::: "memory");
    LOADA(0, 1);
    if (s2) { stA(0, 0, t2); stA(0, 1, t2); }
    MMACL(1);
    if (s2) { asm volatile("s_waitcnt vmcnt(4)" ::: "memory"); }
    else    { asm volatile("s_waitcnt vmcnt(0)" ::: "memory"); }
    asm volatile("s_barrier" ::: "memory");
    LOADA(1, 0); LOADB(1);
    if (s2) stB(0, t2);
    MMACL(0);
    asm volatile("s_barrier" ::: "memory");
    LOADA(1, 1);
    if (s2) { stA(1, 0, t3); stA(1, 1, t3); }
    MMACL(1);
    if (s2) { asm volatile("s_waitcnt vmcnt(4)" ::: "memory"); }
    asm volatile("s_barrier" ::: "memory");
  }
#undef LOADA
#undef LOADB
#undef MMACL
#undef RDA
#undef RDB

  #pragma unroll
  for (int qm = 0; qm < 2; ++qm)
    #pragma unroll
    for (int fm = 0; fm < 4; ++fm)
      #pragma unroll
      for (int r = 0; r < 4; ++r) {
        const long long row = m0 + qm * 128 + wr64 + fm * 16 + l4 * 4 + r;
        #pragma unroll
        for (int fn = 0; fn < 2; ++fn) {
          const int lc = wc32 + fn * 16 + l15;
          Cp[row * (long long)ldc + n0 + lc] = acc[qm][fm][fn][r];
        }
      }
}

// ---------------------------------------------------------------------------
// 2-phase bf16 MFMA GEMM (bf16 B via global_load_lds only).
// ---------------------------------------------------------------------------
constexpr int E_BIAS = 1, E_RES = 2, E_RELU = 4, E_WF32 = 8, E_WB16 = 16;

template<int BM, int BN, int WM, int WN, int EPI>
__global__ __launch_bounds__(256)
void gemm_bf16(const u16* __restrict__ A, const u16* __restrict__ Bw,
               const float* __restrict__ bias, const float* __restrict__ res,
               float* __restrict__ C, u16* __restrict__ Cb,
               int K, int lda, int ldb, int ldc, int nbz2,
               long long sA1, long long sA2, long long sB1, long long sB2,
               long long sC1, long long sC2, float alpha)
{
  constexpr int SM = BM / WM, SN = BN / WN;
  constexpr int FM = SM / 16, FN = SN / 16;
  constexpr int PA = BM / 64, PB = BN / 64;
  __shared__ __align__(16) u16 As[2][BM * 32];
  __shared__ __align__(16) u16 Bs[2][BN * 32];

  const int gx = gridDim.x, gy = gridDim.y;
  const int nwg = gx * gy * gridDim.z;
  const int flat = (blockIdx.z * gy + blockIdx.y) * gx + blockIdx.x;
  const int qq = nwg >> 3, rr = nwg & 7;
  const int xcd = flat & 7, lid = flat >> 3;
  const int wg = (xcd < rr ? xcd * (qq + 1) : rr * (qq + 1) + (xcd - rr) * qq) + lid;
  const int bx = wg % gx;
  const int tmp1 = wg / gx;
  const int by = tmp1 % gy, bz = tmp1 / gy;

  const int t = threadIdx.x;
  const int w = t >> 6, l = t & 63;
  const int wr = w / WN, wc = w % WN;
  const int m0 = by * BM, n0 = bx * BN;
  const long long offA = (long long)(bz / nbz2) * sA1 + (long long)(bz % nbz2) * sA2;
  const long long offB = (long long)(bz / nbz2) * sB1 + (long long)(bz % nbz2) * sB2;
  const long long offC = (long long)(bz / nbz2) * sC1 + (long long)(bz % nbz2) * sC2;
  const u16* Ab = A + offA;
  const u16* Bb = Bw + offB;

  const int srow = t >> 2;
  const int sk   = (t & 3) * 8;

  auto stageA = [&](int buf, int k0) {
    #pragma unroll
    for (int p = 0; p < PA; ++p)
      gload16(&Ab[(long long)(m0 + p * 64 + srow) * lda + k0 + sk],
              &As[buf][p * 2048 + w * 512]);
  };
  auto stageB = [&](int buf, int k0) {
    #pragma unroll
    for (int p = 0; p < PB; ++p)
      gload16(&Bb[(long long)(n0 + p * 64 + srow) * ldb + k0 + sk],
              &Bs[buf][p * 2048 + w * 512]);
  };

  f32x4 acc[FM][FN] = {};

  stageA(0, 0);
  stageB(0, 0);

  int cur = 0;
  for (int k0 = 0; k0 < K; k0 += 32) {
    __syncthreads();
    const bool pf = (k0 + 32 < K);
    if (pf) {
      stageA(cur ^ 1, k0 + 32);
      stageB(cur ^ 1, k0 + 32);
    }

    bf16x8 af[FM], bfr[FN];
    #pragma unroll
    for (int i = 0; i < FM; ++i)
      af[i] = *reinterpret_cast<const bf16x8*>(
          &As[cur][(wr * SM + i * 16 + (l & 15)) * 32 + (l >> 4) * 8]);
    #pragma unroll
    for (int j = 0; j < FN; ++j)
      bfr[j] = *reinterpret_cast<const bf16x8*>(
          &Bs[cur][(wc * SN + j * 16 + (l & 15)) * 32 + (l >> 4) * 8]);
    #pragma unroll
    for (int i = 0; i < FM; ++i)
      #pragma unroll
      for (int j = 0; j < FN; ++j)
        acc[i][j] = __builtin_amdgcn_mfma_f32_16x16x32_bf16(af[i], bfr[j], acc[i][j], 0, 0, 0);
    cur ^= 1;
  }

  const int c_l = l & 15, r_l4 = (l >> 4) * 4;
  #pragma unroll
  for (int i = 0; i < FM; ++i) {
    #pragma unroll
    for (int r = 0; r < 4; ++r) {
      const long long row = m0 + wr * SM + i * 16 + r_l4 + r;
      #pragma unroll
      for (int j = 0; j < FN; ++j) {
        const int col = n0 + wc * SN + j * 16 + c_l;
        float v = acc[i][j][r] * alpha;
        if (EPI & E_BIAS) v += bias[col];
        if (EPI & E_RES)  v += res[row * (long long)ldc + col];
        if (EPI & E_RELU) v = fmaxf(v, 0.f);
        const long long co = offC + row * (long long)ldc + col;
        if (EPI & E_WF32) C[co] = v;
        if (EPI & E_WB16) Cb[co] = f2b(v);
      }
    }
  }
}

// ---------------------------------------------------------------------------
// vox f32 [B][NV][D] -> vb bf16 [B][NV][D]  AND  vt bf16 [B][D][NV]
// ---------------------------------------------------------------------------
__global__ __launch_bounds__(256)
void vox_prep(const float* __restrict__ in, u16* __restrict__ vb,
              u16* __restrict__ vt)
{
  __shared__ u16 tile[64][68];
  const int b = blockIdx.z;
  const int n0 = blockIdx.y * 64;
  const int d0 = blockIdx.x * 64;
  const int t = threadIdx.x;
  const int tr = t >> 4;
  const int tc = (t & 15) * 4;
  const float* ib = in + (long long)b * NV * D;
  u16* vbb = vb + (long long)b * NV * D;
  u16* vtb = vt + (long long)b * NV * D;
  #pragma unroll
  for (int p = 0; p < 4; ++p) {
    int r = tr + p * 16;
    float4 x = *reinterpret_cast<const float4*>(&ib[(long long)(n0 + r) * D + d0 + tc]);
    u16x4 o = {f2b(x.x), f2b(x.y), f2b(x.z), f2b(x.w)};
    *reinterpret_cast<u16x4*>(&vbb[(long long)(n0 + r) * D + d0 + tc]) = o;
    *reinterpret_cast<u16x4*>(&tile[r][tc]) = o;
  }
  __syncthreads();
  #pragma unroll
  for (int p = 0; p < 4; ++p) {
    int c = tr + p * 16;
    u16x4 o = {tile[tc + 0][c], tile[tc + 1][c], tile[tc + 2][c], tile[tc + 3][c]};
    *reinterpret_cast<u16x4*>(&vtb[(long long)(d0 + c) * NV + n0 + tc]) = o;
  }
}

// ---------------------------------------------------------------------------
struct Cvt7 { const float* s[7]; u16* d[7]; int cum[8]; };

__global__ __launch_bounds__(256)
void cvt_multi(Cvt7 a)
{
  const int bidx = blockIdx.x;
  int seg = 0;
  #pragma unroll
  for (int k = 1; k < 7; ++k) if (bidx >= a.cum[k]) seg = k;
  const long long off = ((long long)(bidx - a.cum[seg]) * 256 + threadIdx.x) * 4;
  float4 x = *reinterpret_cast<const float4*>(a.s[seg] + off);
  u16x4 o = {f2b(x.x), f2b(x.y), f2b(x.z), f2b(x.w)};
  *reinterpret_cast<u16x4*>(a.d[seg] + off) = o;
}

__global__ __launch_bounds__(256)
void cvt_add_bf16(const float* __restrict__ a, const float* __restrict__ b,
                  u16* __restrict__ out)
{
  const long long i = ((long long)blockIdx.x * 256 + threadIdx.x) * 4;
  float4 x = *reinterpret_cast<const float4*>(&a[i]);
  float4 y = *reinterpret_cast<const float4*>(&b[i]);
  u16x4 o = {f2b(x.x + y.x), f2b(x.y + y.y), f2b(x.z + y.z), f2b(x.w + y.w)};
  *reinterpret_cast<u16x4*>(&out[i]) = o;
}

__global__ __launch_bounds__(256)
void transpose_u16(const u16* __restrict__ in, u16* __restrict__ out,
                   int R, int C, int ldin, long long sbin, long long sbout)
{
  __shared__ u16 tile[32][34];
  const int b = blockIdx.z;
  const int r0 = blockIdx.y * 32, c0 = blockIdx.x * 32;
  const int tx = threadIdx.x & 31, ty = threadIdx.x >> 5;
  const u16* ib = in + (long long)b * sbin;
  u16* ob = out + (long long)b * sbout;
  #pragma unroll
  for (int p = 0; p < 4; ++p) {
    int r = ty + p * 8;
    tile[r][tx] = ib[(long long)(r0 + r) * ldin + c0 + tx];
  }
  __syncthreads();
  #pragma unroll
  for (int p = 0; p < 4; ++p) {
    int c = ty + p * 8;
    ob[(long long)(c0 + c) * R + r0 + tx] = tile[tx][c];
  }
}

// ---------------------------------------------------------------------------
// Fused masked softmax (rows of LT=512, bf16 scores) + head-mean.
// One block per (b,q); thread t owns elements 2t, 2t+1 (vectorized).
// ---------------------------------------------------------------------------
__global__ __launch_bounds__(256)
void txt_softmax_mean(const u16* __restrict__ sc, const int* __restrict__ mask,
                      u16* __restrict__ wout, float* __restrict__ out1)
{
  __shared__ float red[8];
  const int t = threadIdx.x, l = t & 63, w = t >> 6;
  const int bq = blockIdx.x;
  const int b = bq >> 8, q = bq & 255;
  const int* mr = mask + b * LT;
  const int2 mm = *reinterpret_cast<const int2*>(&mr[2 * t]);
  const bool msk0 = mm.x != 0, msk1 = mm.y != 0;
  float a0 = 0.f, a1 = 0.f;
  for (int h = 0; h < H; ++h) {
    const long long ro = (((long long)(b * H + h)) * NQ + q) * LT;
    const u16* sr = sc + ro;
    const u16x2 sv = *reinterpret_cast<const u16x2*>(&sr[2 * t]);
    float x0 = msk0 ? -INFINITY : b2f(sv[0]);
    float x1 = msk1 ? -INFINITY : b2f(sv[1]);
    float mx = fmaxf(x0, x1);
    #pragma unroll
    for (int o = 32; o > 0; o >>= 1) mx = fmaxf(mx, __shfl_xor(mx, o, 64));
    if (l == 0) red[w] = mx;
    __syncthreads();
    mx = fmaxf(fmaxf(red[0], red[1]), fmaxf(red[2], red[3]));
    float e0 = __expf(x0 - mx), e1 = __expf(x1 - mx);
    float s = e0 + e1;
    #pragma unroll
    for (int o = 32; o > 0; o >>= 1) s += __shfl_xor(s, o, 64);
    if (l == 0) red[4 + w] = s;
    __syncthreads();
    s = red[4] + red[5] + red[6] + red[7];
    const float inv = 1.f / s;
    const float w0 = e0 * inv, w1 = e1 * inv;
    u16x2 wv = {f2b(w0), f2b(w1)};
    *reinterpret_cast<u16x2*>(&wout[ro + 2 * t]) = wv;
    a0 += w0; a1 += w1;
  }
  float2 o2 = {a0 * (1.f / H), a1 * (1.f / H)};
  *reinterpret_cast<float2*>(&out1[(long long)bq * LT + 2 * t]) = o2;
}

// ---------------------------------------------------------------------------
__global__ __launch_bounds__(256)
void ln_kernel(const float* __restrict__ x, const float* __restrict__ g,
               const float* __restrict__ bia, float* __restrict__ y,
               u16* __restrict__ yb, float scale)
{
  __shared__ float tmp[256];
  const int t = threadIdx.x;
  const long long off = (long long)blockIdx.x * D;
  float4 x4 = *reinterpret_cast<const float4*>(&x[off + t * 4]);
  tmp[t] = x4.x + x4.y + x4.z + x4.w;
  __syncthreads();
  for (int o = 128; o > 0; o >>= 1) { if (t < o) tmp[t] += tmp[t + o]; __syncthreads(); }
  const float mean = tmp[0] * (1.f / D);
  __syncthreads();
  float d0 = x4.x - mean, d1 = x4.y - mean, d2 = x4.z - mean, d3 = x4.w - mean;
  tmp[t] = d0 * d0 + d1 * d1 + d2 * d2 + d3 * d3;
  __syncthreads();
  for (int o = 128; o > 0; o >>= 1) { if (t < o) tmp[t] += tmp[t + o]; __syncthreads(); }
  const float rs = rsqrtf(tmp[0] * (1.f / D) + 1e-5f);
  float4 g4 = *reinterpret_cast<const float4*>(&g[t * 4]);
  float4 b4 = *reinterpret_cast<const float4*>(&bia[t * 4]);
  float o0 = (d0 * rs * g4.x + b4.x) * scale;
  float o1 = (d1 * rs * g4.y + b4.y) * scale;
  float o2 = (d2 * rs * g4.z + b4.z) * scale;
  float o3 = (d3 * rs * g4.w + b4.w) * scale;
  if (y) {
    float4 o4 = {o0, o1, o2, o3};
    *reinterpret_cast<float4*>(&y[off + t * 4]) = o4;
  }
  if (yb) {
    u16x4 ob = {f2b(o0), f2b(o1), f2b(o2), f2b(o3)};
    *reinterpret_cast<u16x4*>(&yb[off + t * 4]) = ob;
  }
}

// ---------------------------------------------------------------------------
__global__ __launch_bounds__(256)
void vox_softmax(float* __restrict__ s, const int* __restrict__ mask,
                 u16* __restrict__ wb)
{
  __shared__ float tmp[256];
  const int t = threadIdx.x;
  const int row = blockIdx.x, b = row / NQ;
  float* sr = s + (long long)row * NV;
  u16* wr = wb + (long long)row * NV;
  const int* mr = mask + b * NV;
  float vals[16];
  float lm = -INFINITY;
  #pragma unroll
  for (int j = 0; j < 16; ++j) {
    int n = t + j * 256;
    float x = mr[n] ? -INFINITY : sr[n];
    vals[j] = x;
    lm = fmaxf(lm, x);
  }
  tmp[t] = lm;
  __syncthreads();
  for (int o = 128; o > 0; o >>= 1) { if (t < o) tmp[t] = fmaxf(tmp[t], tmp[t + o]); __syncthreads(); }
  const float mx = tmp[0];
  __syncthreads();
  float ls = 0.f;
  #pragma unroll
  for (int j = 0; j < 16; ++j) { vals[j] = __expf(vals[j] - mx); ls += vals[j]; }
  tmp[t] = ls;
  __syncthreads();
  for (int o = 128; o > 0; o >>= 1) { if (t < o) tmp[t] += tmp[t + o]; __syncthreads(); }
  const float inv = 1.f / tmp[0];
  #pragma unroll
  for (int j = 0; j < 16; ++j) {
    float v = vals[j] * inv;
    sr[t + j * 256] = v;
    wr[t + j * 256] = f2b(v);
  }
}

__global__ __launch_bounds__(256)
void splitk_reduce(const float* __restrict__ part, float* __restrict__ out)
{
  const long long i = ((long long)blockIdx.x * 256 + threadIdx.x) * 4;
  const long long nd = (long long)NQ * D;
  const long long b = i / nd;
  const long long o = i - b * nd;
  const float* p = part + b * 4 * nd + o;
  float4 s0 = *reinterpret_cast<const float4*>(&p[0]);
  float4 s1 = *reinterpret_cast<const float4*>(&p[nd]);
  float4 s2 = *reinterpret_cast<const float4*>(&p[2 * nd]);
  float4 s3 = *reinterpret_cast<const float4*>(&p[3 * nd]);
  float4 r = {s0.x + s1.x + s2.x + s3.x, s0.y + s1.y + s2.y + s3.y,
              s0.z + s1.z + s2.z + s3.z, s0.w + s1.w + s2.w + s3.w};
  *reinterpret_cast<float4*>(&out[i]) = r;
}

// ---------------------------------------------------------------------------
extern "C" void kernel_launch(void* const* d_in, const int* in_sizes, int n_in,
                              void* d_out, int out_size, void* d_ws, size_t ws_size,
                              hipStream_t stream)
{
  const float* tgt   = (const float*)d_in[0];
  const float* mtxt  = (const float*)d_in[1];
  const float* vox   = (const float*)d_in[2];
  const float* qpos  = (const float*)d_in[3];
  const int*   mtx_m = (const int*)d_in[4];
  const int*   vox_m = (const int*)d_in[5];
  const float* Wq = (const float*)d_in[6];  const float* bq = (const float*)d_in[7];
  const float* Wk = (const float*)d_in[8];  const float* bk = (const float*)d_in[9];
  const float* Wv = (const float*)d_in[10]; const float* bv = (const float*)d_in[11];
  const float* Wo = (const float*)d_in[12]; const float* bo = (const float*)d_in[13];
  const float* W1 = (const float*)d_in[14]; const float* b1 = (const float*)d_in[15];
  const float* W2 = (const float*)d_in[16]; const float* b2 = (const float*)d_in[17];
  const float* ln1g = (const float*)d_in[18]; const float* ln1b = (const float*)d_in[19];
  const float* ln2g = (const float*)d_in[20]; const float* ln2b = (const float*)d_in[21];

  float* out0 = (float*)d_out;                       // attn_output  [B,NQ,D]
  float* out1 = out0 + (long long)B * NQ * D;        // txt_cross    [B,NQ,LT]
  float* out2 = out1 + (long long)B * NQ * LT;       // attn_weights [B,NQ,NV]

  char* base = (char*)d_ws;
  constexpr size_t MB = 1ull << 20;
  u16*   kvW   = (u16*)(base + 0 * MB);     // 16  [Wk;Wv] stacked
  u16*   Wq_b  = (u16*)(base + 16 * MB);    // 2
  u16*   Wo_b  = (u16*)(base + 18 * MB);    // 2
  u16*   W1_b  = (u16*)(base + 20 * MB);    // 4
  u16*   W2_b  = (u16*)(base + 24 * MB);    // 4
  u16*   tq_b  = (u16*)(base + 28 * MB);    // 4
  u16*   q_b   = (u16*)(base + 32 * MB);    // 4
  u16*   kv_b  = (u16*)(base + 36 * MB);    // 16  [B*LT][2048]
  u16*   vT_b  = (u16*)(base + 52 * MB);    // 8
  u16*   ctx_b = (u16*)(base + 60 * MB);    // 4
  float* x1p   = (float*)(base + 64 * MB);  // 8
  float* x1f   = (float*)(base + 72 * MB);  // 8
  u16*   x1_b  = (u16*)(base + 80 * MB);    // 4
  u16*   ff1_b = (u16*)(base + 84 * MB);    // 8
  float* x2p   = (float*)(base + 92 * MB);  // 8
  u16*   x2s_b = (u16*)(base + 100 * MB);   // 4
  u16*   mtxt_b = (u16*)(base + 104 * MB);  // 32  dead after kv256b
  u16*   scb   = (u16*)(base + 136 * MB);   // 32  bf16 scores, dead after softmax
  u16*   w_b    = (u16*)(base + 200 * MB);  // 32  dead after ctx gemm
  u16*   vox_b  = (u16*)(base + 104 * MB);  // 64  overlays mtxt_b + scb head
  u16*   voxT_b = (u16*)(base + 168 * MB);  // 64  overlays scb tail + w_b
  u16*   wvox_b = (u16*)(base + 0 * MB);    // 16  overlays kvW (dead)
  float* part   = (float*)(base + 16 * MB); // 32  overlays Wq..q_b (dead)

  const dim3 blk(256);
  const long long sQ = (long long)NQ * D;
  const long long sSC = (long long)NQ * LT;
  const long long nd = (long long)NQ * D;

  // 1) conversions: fused weights + memory_txt; tq = tgt + qpos
  Cvt7 ca;
  ca.s[0] = Wq;   ca.d[0] = Wq_b;
  ca.s[1] = Wk;   ca.d[1] = kvW;
  ca.s[2] = Wv;   ca.d[2] = kvW + (long long)D * FTXT;
  ca.s[3] = Wo;   ca.d[3] = Wo_b;
  ca.s[4] = W1;   ca.d[4] = W1_b;
  ca.s[5] = W2;   ca.d[5] = W2_b;
  ca.s[6] = mtxt; ca.d[6] = mtxt_b;
  ca.cum[0] = 0;     ca.cum[1] = 1024;  ca.cum[2] = 5120;  ca.cum[3] = 9216;
  ca.cum[4] = 10240; ca.cum[5] = 12288; ca.cum[6] = 14336; ca.cum[7] = 30720;
  cvt_multi<<<dim3(30720), blk, 0, stream>>>(ca);
  cvt_add_bf16<<<dim3((B * NQ * D) / 1024), blk, 0, stream>>>(tgt, qpos, tq_b);

  // 2) q projection (2-phase) + kv projection (8-phase 256x128, full K)
  gemm_bf16<64,64,2,2, E_BIAS|E_WB16><<<dim3(D/64, (B*NQ)/64, 1), blk, 0, stream>>>(
      tq_b, Wq_b, bq, nullptr, nullptr, q_b, D, D, D, D, 1, 0,0,0,0,0,0, 1.f);
  gemm_kv256b<<<dim3(16, 16), dim3(512), 0, stream>>>(mtxt_b, kvW, bk, bv, kv_b);

  // 3) vT[b][d][l] = v[b][l][d]
  transpose_u16<<<dim3(D/32, LT/32, B), blk, 0, stream>>>(
      kv_b + 1024, vT_b, LT, D, 2048, (long long)LT * 2048, (long long)D * LT);

  // 4) scores = q . k / 8  -> bf16
  gemm_bf16<128,128,2,2, E_WB16><<<dim3(LT/128, NQ/128, B*H), blk, 0, stream>>>(
      q_b, kv_b, nullptr, nullptr, nullptr, scb, HD, D, 2048, LT, H,
      sQ, HD, (long long)LT * 2048, HD, (long long)H * sSC, sSC, 0.125f);

  // 5) fused softmax + head-mean (bf16 scores in)
  txt_softmax_mean<<<dim3(B*NQ), blk, 0, stream>>>(scb, mtx_m, w_b, out1);

  // 6) ctx = w_h @ v_h
  gemm_bf16<64,64,2,2, E_WB16><<<dim3(HD/64, NQ/64, B*H), blk, 0, stream>>>(
      w_b, vT_b, nullptr, nullptr, nullptr, ctx_b, LT, LT, LT, D, H,
      (long long)H * sSC, sSC, (long long)D * LT, (long long)HD * LT, sQ, HD, 1.f);

  // 7) vox -> vox_b + voxT_b (one f32 read)
  vox_prep<<<dim3(D/64, NV/64, B), blk, 0, stream>>>(vox, vox_b, voxT_b);

  // 8) x1p = tgt + ctx @ Wo^T + bo
  gemm_bf16<64,64,2,2, E_BIAS|E_RES|E_WF32><<<dim3(D/64, (B*NQ)/64, 1), blk, 0, stream>>>(
      ctx_b, Wo_b, bo, tgt, x1p, nullptr, D, D, D, D, 1, 0,0,0,0,0,0, 1.f);

  // 9) LN1
  ln_kernel<<<dim3(B*NQ), blk, 0, stream>>>(x1p, ln1g, ln1b, x1f, x1_b, 1.f);

  // 10) ff1 = relu(x1 @ W1^T + b1)
  gemm_bf16<128,64,2,2, E_BIAS|E_RELU|E_WB16><<<dim3(DFF/64, (B*NQ)/128, 1), blk, 0, stream>>>(
      x1_b, W1_b, b1, nullptr, nullptr, ff1_b, D, D, D, DFF, 1, 0,0,0,0,0,0, 1.f);

  // 11) x2p = x1 + ff1 @ W2^T + b2
  gemm_bf16<64,64,2,2, E_BIAS|E_RES|E_WF32><<<dim3(D/64, (B*NQ)/64, 1), blk, 0, stream>>>(
      ff1_b, W2_b, b2, x1f, x2p, nullptr, DFF, DFF, DFF, D, 1, 0,0,0,0,0,0, 1.f);

  // 12) LN2 -> x2s (bf16, /sqrt(D))
  ln_kernel<<<dim3(B*NQ), blk, 0, stream>>>(x2p, ln2g, ln2b, nullptr, x2s_b, 0.03125f);

  // 13) out2 = x2s @ vox_b^T  (8-phase 256x128)
  gemm8<1><<<dim3(NV/128, 1, B), dim3(512), 0, stream>>>(
      x2s_b, vox_b, out2, D, D, D, NV, 0,
      sQ, (long long)NV * D, (long long)NQ * NV, 0);

  // 14) masked softmax in place; bf16 weights
  vox_softmax<<<dim3(B*NQ), blk, 0, stream>>>(out2, vox_m, wvox_b);

  // 15) out0 partials: 8-phase split-K=4 + reduce
  gemm8<4><<<dim3(D/128, 1, B*4), dim3(512), 0, stream>>>(
      wvox_b, voxT_b, part, NV/4, NV, NV, D, NV/4,
      (long long)NQ * NV, (long long)D * NV, 4 * nd, nd);
  splitk_reduce<<<dim3((B * NQ * D) / 1024), blk, 0, stream>>>(part, out0);
}

// Round 12
// 414.695 us; speedup vs baseline: 1.2339x; 1.0071x over previous
//
#include <hip/hip_runtime.h>
#include <math.h>

typedef unsigned short u16;
typedef unsigned int u32;
typedef __bf16 bf16x8 __attribute__((ext_vector_type(8)));
typedef float f32x4 __attribute__((ext_vector_type(4)));
typedef u16 u16x4 __attribute__((ext_vector_type(4)));
typedef u16 u16x2 __attribute__((ext_vector_type(2)));

constexpr int B = 8, NQ = 256, LT = 512, NV = 4096;
constexpr int D = 1024, H = 16, DFF = 2048, FTXT = 4096, HD = 64;

__device__ __forceinline__ u16 f2b(float f) {
  u32 u = __builtin_bit_cast(u32, f);
  return (u16)((u + 0x7fffu + ((u >> 16) & 1u)) >> 16);   // RNE
}
__device__ __forceinline__ float b2f(u16 b) {
  u32 u = ((u32)b) << 16;
  return __builtin_bit_cast(float, u);
}
__device__ __forceinline__ void gload16(const void* g, void* l) {
  __builtin_amdgcn_global_load_lds(
      (const __attribute__((address_space(1))) u32*)g,
      (__attribute__((address_space(3))) u32*)l, 16, 0, 0);
}

// ===========================================================================
// 8-phase 256x128 machinery, R12 deep-B schedule:
// LDS 128 KiB: A 4 slabs [2tile][2h][128][64], B 4 slabs (tile&3)[128][64].
// Body = 4 k-tiles (2 sub-iters x 4 phases). Stages: P1 stB(t+2), P2 stA(t+2),
// waits vmcnt(6) at P2/P4 draining loads 2-3 phases old (>= HBM latency).
// XOR-swizzle slot^(row&7).
// ===========================================================================

// --- KV projection: full K=4096, bf16 out + bias ---
__global__ __launch_bounds__(512, 2)
void gemm_kv256b(const u16* __restrict__ A, const u16* __restrict__ Bw,
                 const float* __restrict__ bk_, const float* __restrict__ bv_,
                 u16* __restrict__ Cb)
{
  __shared__ __align__(16) u16 As[4 * 8192];
  __shared__ __align__(16) u16 Bs[4 * 8192];

  const int gx = 16;
  const int flat = blockIdx.y * gx + blockIdx.x;
  const int qq = 256 >> 3;
  const int xcd = flat & 7, lid = flat >> 3;
  const int wg = xcd * qq + lid;
  const int bx = wg % gx;
  const int by = wg / gx;
  const int m0 = by * 256, n0 = bx * 128;
  const float* bias = (n0 < 1024) ? (bk_ + n0) : (bv_ + (n0 - 1024));

  const int t = threadIdx.x;
  const int w = t >> 6, l = t & 63;
  const int wr64 = (w >> 2) * 64;
  const int wc32 = (w & 3) * 32;
  const int l15 = l & 15, l4 = l >> 4, l7 = l & 7;

  auto stAh = [&](int db, int h, int tile) {   // 2 gloads, slab db*2+h
    const long long kk = (long long)tile * 64 + (((t & 7) ^ ((t >> 3) & 7)) * 8);
    #pragma unroll
    for (int i = 0; i < 2; ++i)
      gload16(&A[(long long)(m0 + h * 128 + (t >> 3) + 64 * i) * 4096 + kk],
              &As[(db * 2 + h) * 8192 + (w * 8 + 64 * i) * 64]);
  };
  auto stB = [&](int bs, int tile) {           // 2 gloads, slab bs
    const long long kk = (long long)tile * 64 + (((t & 7) ^ ((t >> 3) & 7)) * 8);
    #pragma unroll
    for (int i = 0; i < 2; ++i)
      gload16(&Bw[(long long)(n0 + (t >> 3) + 64 * i) * 4096 + kk],
              &Bs[bs * 8192 + (w * 8 + 64 * i) * 64]);
  };

#define RDA(db,qm,fm,ks) \
  (*reinterpret_cast<const bf16x8*>(&As[((db)*2+(qm))*8192 + \
      (wr64 + (fm)*16 + l15)*64 + ((((ks)*4 + l4) ^ l7) * 8)]))
#define RDB(bs,fn,ks) \
  (*reinterpret_cast<const bf16x8*>(&Bs[(bs)*8192 + \
      (wc32 + (fn)*16 + l15)*64 + ((((ks)*4 + l4) ^ l7) * 8)]))

  f32x4 acc[2][4][2] = {};
  bf16x8 a_[4][2];
  bf16x8 b_[2][2];

#define LOADA(db, qm)                                                        \
  do {                                                                       \
    _Pragma("unroll")                                                        \
    for (int fm_ = 0; fm_ < 4; ++fm_) {                                      \
      a_[fm_][0] = RDA(db, qm, fm_, 0);                                      \
      a_[fm_][1] = RDA(db, qm, fm_, 1);                                      \
    }                                                                        \
  } while (0)
#define LOADB(bs)                                                            \
  do {                                                                       \
    b_[0][0] = RDB(bs, 0, 0); b_[0][1] = RDB(bs, 0, 1);                      \
    b_[1][0] = RDB(bs, 1, 0); b_[1][1] = RDB(bs, 1, 1);                      \
  } while (0)
#define MMACL(qm)                                                            \
  do {                                                                       \
    asm volatile("s_barrier" ::: "memory");                                  \
    __builtin_amdgcn_s_setprio(1);                                           \
    _Pragma("unroll")                                                        \
    for (int fm_ = 0; fm_ < 4; ++fm_) {                                      \
      _Pragma("unroll")                                                      \
      for (int fn_ = 0; fn_ < 2; ++fn_) {                                    \
        acc[qm][fm_][fn_] = __builtin_amdgcn_mfma_f32_16x16x32_bf16(         \
            a_[fm_][0], b_[fn_][0], acc[qm][fm_][fn_], 0, 0, 0);             \
        acc[qm][fm_][fn_] = __builtin_amdgcn_mfma_f32_16x16x32_bf16(         \
            a_[fm_][1], b_[fn_][1], acc[qm][fm_][fn_], 0, 0, 0);             \
      }                                                                      \
    }                                                                        \
    __builtin_amdgcn_s_setprio(0);                                           \
  } while (0)
#define BAR asm volatile("s_barrier" ::: "memory")
#define WAIT6 asm volatile("s_waitcnt vmcnt(6)" ::: "memory")
#define WAIT0 asm volatile("s_waitcnt vmcnt(0)" ::: "memory")

  // prologue: B(0),A(0),B(1),A(1) = 12 loads; drain oldest 6 (B0+A0)
  stB(0, 0); stAh(0, 0, 0); stAh(0, 1, 0);
  stB(1, 1); stAh(1, 0, 1); stAh(1, 1, 1);
  WAIT6;
  BAR;

  for (int bb = 0; bb < 16; ++bb) {
    const int base = 4 * bb;
    const bool more = (bb < 15);
    // ---- sub-iter jA: tiles base (Bs0), base+1 (Bs1) ----
    LOADA(0, 0); LOADB(0);
    stB(2, base + 2);
    MMACL(0);
    BAR;
    LOADA(0, 1);
    stAh(0, 0, base + 2); stAh(0, 1, base + 2);
    MMACL(1);
    WAIT6;
    BAR;
    LOADA(1, 0); LOADB(1);
    stB(3, base + 3);
    MMACL(0);
    BAR;
    LOADA(1, 1);
    stAh(1, 0, base + 3); stAh(1, 1, base + 3);
    MMACL(1);
    WAIT6;
    BAR;
    // ---- sub-iter jB: tiles base+2 (Bs2), base+3 (Bs3) ----
    LOADA(0, 0); LOADB(2);
    if (more) stB(0, base + 4);
    MMACL(0);
    BAR;
    LOADA(0, 1);
    if (more) { stAh(0, 0, base + 4); stAh(0, 1, base + 4); }
    MMACL(1);
    if (more) { WAIT6; } else { WAIT0; }
    BAR;
    LOADA(1, 0); LOADB(3);
    if (more) stB(1, base + 5);
    MMACL(0);
    BAR;
    LOADA(1, 1);
    if (more) { stAh(1, 0, base + 5); stAh(1, 1, base + 5); }
    MMACL(1);
    if (more) { WAIT6; } else { WAIT0; }
    BAR;
  }
#undef LOADA
#undef LOADB
#undef MMACL
#undef RDA
#undef RDB
#undef BAR
#undef WAIT6
#undef WAIT0

  #pragma unroll
  for (int qm = 0; qm < 2; ++qm)
    #pragma unroll
    for (int fm = 0; fm < 4; ++fm)
      #pragma unroll
      for (int r = 0; r < 4; ++r) {
        const long long row = m0 + qm * 128 + wr64 + fm * 16 + l4 * 4 + r;
        #pragma unroll
        for (int fn = 0; fn < 2; ++fn) {
          const int lc = wc32 + fn * 16 + l15;
          Cb[row * 2048 + n0 + lc] = f2b(acc[qm][fm][fn][r] + bias[lc]);
        }
      }
}

// --- Generalized deep-B 8-phase 256x128: C f32 = A@Bw^T, batch + split-K.
//     Ksub must be a multiple of 256. ---
template<int NZ2>
__global__ __launch_bounds__(512, 2)
void gemm8(const u16* __restrict__ A, const u16* __restrict__ Bw,
           float* __restrict__ C,
           int Ksub, int lda, int ldb, int ldc, int kstep,
           long long sA1, long long sB1, long long sC1, long long sC2)
{
  __shared__ __align__(16) u16 As[4 * 8192];
  __shared__ __align__(16) u16 Bs[4 * 8192];

  const int gx = gridDim.x, gy = gridDim.y;
  const int nwg = gx * gy * gridDim.z;
  const int flat = (blockIdx.z * gy + blockIdx.y) * gx + blockIdx.x;
  const int qq = nwg >> 3, rr = nwg & 7;
  const int xcd = flat & 7, lid = flat >> 3;
  const int wg = (xcd < rr ? xcd * (qq + 1) : rr * (qq + 1) + (xcd - rr) * qq) + lid;
  const int bx = wg % gx;
  const int tmp1 = wg / gx;
  const int by = tmp1 % gy, bz = tmp1 / gy;
  const int z1 = bz / NZ2, z2 = bz % NZ2;
  const int m0 = by * 256, n0 = bx * 128;
  const long long kbase = (long long)z2 * kstep;
  const u16* Ab = A + (long long)z1 * sA1;
  const u16* Bb = Bw + (long long)z1 * sB1;
  float* Cp = C + (long long)z1 * sC1 + (long long)z2 * sC2;

  const int t = threadIdx.x;
  const int w = t >> 6, l = t & 63;
  const int wr64 = (w >> 2) * 64;
  const int wc32 = (w & 3) * 32;
  const int l15 = l & 15, l4 = l >> 4, l7 = l & 7;

  auto stAh = [&](int db, int h, int tile) {
    const long long kk = kbase + (long long)tile * 64 + (((t & 7) ^ ((t >> 3) & 7)) * 8);
    #pragma unroll
    for (int i = 0; i < 2; ++i)
      gload16(&Ab[(long long)(m0 + h * 128 + (t >> 3) + 64 * i) * lda + kk],
              &As[(db * 2 + h) * 8192 + (w * 8 + 64 * i) * 64]);
  };
  auto stB = [&](int bs, int tile) {
    const long long kk = kbase + (long long)tile * 64 + (((t & 7) ^ ((t >> 3) & 7)) * 8);
    #pragma unroll
    for (int i = 0; i < 2; ++i)
      gload16(&Bb[(long long)(n0 + (t >> 3) + 64 * i) * ldb + kk],
              &Bs[bs * 8192 + (w * 8 + 64 * i) * 64]);
  };

#define RDA(db,qm,fm,ks) \
  (*reinterpret_cast<const bf16x8*>(&As[((db)*2+(qm))*8192 + \
      (wr64 + (fm)*16 + l15)*64 + ((((ks)*4 + l4) ^ l7) * 8)]))
#define RDB(bs,fn,ks) \
  (*reinterpret_cast<const bf16x8*>(&Bs[(bs)*8192 + \
      (wc32 + (fn)*16 + l15)*64 + ((((ks)*4 + l4) ^ l7) * 8)]))

  f32x4 acc[2][4][2] = {};
  bf16x8 a_[4][2];
  bf16x8 b_[2][2];

#define LOADA(db, qm)                                                        \
  do {                                                                       \
    _Pragma("unroll")                                                        \
    for (int fm_ = 0; fm_ < 4; ++fm_) {                                      \
      a_[fm_][0] = RDA(db, qm, fm_, 0);                                      \
      a_[fm_][1] = RDA(db, qm, fm_, 1);                                      \
    }                                                                        \
  } while (0)
#define LOADB(bs)                                                            \
  do {                                                                       \
    b_[0][0] = RDB(bs, 0, 0); b_[0][1] = RDB(bs, 0, 1);                      \
    b_[1][0] = RDB(bs, 1, 0); b_[1][1] = RDB(bs, 1, 1);                      \
  } while (0)
#define MMACL(qm)                                                            \
  do {                                                                       \
    asm volatile("s_barrier" ::: "memory");                                  \
    __builtin_amdgcn_s_setprio(1);                                           \
    _Pragma("unroll")                                                        \
    for (int fm_ = 0; fm_ < 4; ++fm_) {                                      \
      _Pragma("unroll")                                                      \
      for (int fn_ = 0; fn_ < 2; ++fn_) {                                    \
        acc[qm][fm_][fn_] = __builtin_amdgcn_mfma_f32_16x16x32_bf16(         \
            a_[fm_][0], b_[fn_][0], acc[qm][fm_][fn_], 0, 0, 0);             \
        acc[qm][fm_][fn_] = __builtin_amdgcn_mfma_f32_16x16x32_bf16(         \
            a_[fm_][1], b_[fn_][1], acc[qm][fm_][fn_], 0, 0, 0);             \
      }                                                                      \
    }                                                                        \
    __builtin_amdgcn_s_setprio(0);                                           \
  } while (0)
#define BAR asm volatile("s_barrier" ::: "memory")
#define WAIT6 asm volatile("s_waitcnt vmcnt(6)" ::: "memory")
#define WAIT0 asm volatile("s_waitcnt vmcnt(0)" ::: "memory")

  stB(0, 0); stAh(0, 0, 0); stAh(0, 1, 0);
  stB(1, 1); stAh(1, 0, 1); stAh(1, 1, 1);
  WAIT6;
  BAR;

  const int nbody = Ksub >> 8;   // 4 tiles per body
  for (int bb = 0; bb < nbody; ++bb) {
    const int base = 4 * bb;
    const bool more = (bb < nbody - 1);
    LOADA(0, 0); LOADB(0);
    stB(2, base + 2);
    MMACL(0);
    BAR;
    LOADA(0, 1);
    stAh(0, 0, base + 2); stAh(0, 1, base + 2);
    MMACL(1);
    WAIT6;
    BAR;
    LOADA(1, 0); LOADB(1);
    stB(3, base + 3);
    MMACL(0);
    BAR;
    LOADA(1, 1);
    stAh(1, 0, base + 3); stAh(1, 1, base + 3);
    MMACL(1);
    WAIT6;
    BAR;
    LOADA(0, 0); LOADB(2);
    if (more) stB(0, base + 4);
    MMACL(0);
    BAR;
    LOADA(0, 1);
    if (more) { stAh(0, 0, base + 4); stAh(0, 1, base + 4); }
    MMACL(1);
    if (more) { WAIT6; } else { WAIT0; }
    BAR;
    LOADA(1, 0); LOADB(3);
    if (more) stB(1, base + 5);
    MMACL(0);
    BAR;
    LOADA(1, 1);
    if (more) { stAh(1, 0, base + 5); stAh(1, 1, base + 5); }
    MMACL(1);
    if (more) { WAIT6; } else { WAIT0; }
    BAR;
  }
#undef LOADA
#undef LOADB
#undef MMACL
#undef RDA
#undef RDB
#undef BAR
#undef WAIT6
#undef WAIT0

  #pragma unroll
  for (int qm = 0; qm < 2; ++qm)
    #pragma unroll
    for (int fm = 0; fm < 4; ++fm)
      #pragma unroll
      for (int r = 0; r < 4; ++r) {
        const long long row = m0 + qm * 128 + wr64 + fm * 16 + l4 * 4 + r;
        #pragma unroll
        for (int fn = 0; fn < 2; ++fn) {
          const int lc = wc32 + fn * 16 + l15;
          Cp[row * (long long)ldc + n0 + lc] = acc[qm][fm][fn][r];
        }
      }
}

// ---------------------------------------------------------------------------
// 2-phase bf16 MFMA GEMM (bf16 B via global_load_lds only).
// ---------------------------------------------------------------------------
constexpr int E_BIAS = 1, E_RES = 2, E_RELU = 4, E_WF32 = 8, E_WB16 = 16;

template<int BM, int BN, int WM, int WN, int EPI>
__global__ __launch_bounds__(256)
void gemm_bf16(const u16* __restrict__ A, const u16* __restrict__ Bw,
               const float* __restrict__ bias, const float* __restrict__ res,
               float* __restrict__ C, u16* __restrict__ Cb,
               int K, int lda, int ldb, int ldc, int nbz2,
               long long sA1, long long sA2, long long sB1, long long sB2,
               long long sC1, long long sC2, float alpha)
{
  constexpr int SM = BM / WM, SN = BN / WN;
  constexpr int FM = SM / 16, FN = SN / 16;
  constexpr int PA = BM / 64, PB = BN / 64;
  __shared__ __align__(16) u16 As[2][BM * 32];
  __shared__ __align__(16) u16 Bs[2][BN * 32];

  const int gx = gridDim.x, gy = gridDim.y;
  const int nwg = gx * gy * gridDim.z;
  const int flat = (blockIdx.z * gy + blockIdx.y) * gx + blockIdx.x;
  const int qq = nwg >> 3, rr = nwg & 7;
  const int xcd = flat & 7, lid = flat >> 3;
  const int wg = (xcd < rr ? xcd * (qq + 1) : rr * (qq + 1) + (xcd - rr) * qq) + lid;
  const int bx = wg % gx;
  const int tmp1 = wg / gx;
  const int by = tmp1 % gy, bz = tmp1 / gy;

  const int t = threadIdx.x;
  const int w = t >> 6, l = t & 63;
  const int wr = w / WN, wc = w % WN;
  const int m0 = by * BM, n0 = bx * BN;
  const long long offA = (long long)(bz / nbz2) * sA1 + (long long)(bz % nbz2) * sA2;
  const long long offB = (long long)(bz / nbz2) * sB1 + (long long)(bz % nbz2) * sB2;
  const long long offC = (long long)(bz / nbz2) * sC1 + (long long)(bz % nbz2) * sC2;
  const u16* Ab = A + offA;
  const u16* Bb = Bw + offB;

  const int srow = t >> 2;
  const int sk   = (t & 3) * 8;

  auto stageA = [&](int buf, int k0) {
    #pragma unroll
    for (int p = 0; p < PA; ++p)
      gload16(&Ab[(long long)(m0 + p * 64 + srow) * lda + k0 + sk],
              &As[buf][p * 2048 + w * 512]);
  };
  auto stageB = [&](int buf, int k0) {
    #pragma unroll
    for (int p = 0; p < PB; ++p)
      gload16(&Bb[(long long)(n0 + p * 64 + srow) * ldb + k0 + sk],
              &Bs[buf][p * 2048 + w * 512]);
  };

  f32x4 acc[FM][FN] = {};

  stageA(0, 0);
  stageB(0, 0);

  int cur = 0;
  for (int k0 = 0; k0 < K; k0 += 32) {
    __syncthreads();
    const bool pf = (k0 + 32 < K);
    if (pf) {
      stageA(cur ^ 1, k0 + 32);
      stageB(cur ^ 1, k0 + 32);
    }

    bf16x8 af[FM], bfr[FN];
    #pragma unroll
    for (int i = 0; i < FM; ++i)
      af[i] = *reinterpret_cast<const bf16x8*>(
          &As[cur][(wr * SM + i * 16 + (l & 15)) * 32 + (l >> 4) * 8]);
    #pragma unroll
    for (int j = 0; j < FN; ++j)
      bfr[j] = *reinterpret_cast<const bf16x8*>(
          &Bs[cur][(wc * SN + j * 16 + (l & 15)) * 32 + (l >> 4) * 8]);
    #pragma unroll
    for (int i = 0; i < FM; ++i)
      #pragma unroll
      for (int j = 0; j < FN; ++j)
        acc[i][j] = __builtin_amdgcn_mfma_f32_16x16x32_bf16(af[i], bfr[j], acc[i][j], 0, 0, 0);
    cur ^= 1;
  }

  const int c_l = l & 15, r_l4 = (l >> 4) * 4;
  #pragma unroll
  for (int i = 0; i < FM; ++i) {
    #pragma unroll
    for (int r = 0; r < 4; ++r) {
      const long long row = m0 + wr * SM + i * 16 + r_l4 + r;
      #pragma unroll
      for (int j = 0; j < FN; ++j) {
        const int col = n0 + wc * SN + j * 16 + c_l;
        float v = acc[i][j][r] * alpha;
        if (EPI & E_BIAS) v += bias[col];
        if (EPI & E_RES)  v += res[row * (long long)ldc + col];
        if (EPI & E_RELU) v = fmaxf(v, 0.f);
        const long long co = offC + row * (long long)ldc + col;
        if (EPI & E_WF32) C[co] = v;
        if (EPI & E_WB16) Cb[co] = f2b(v);
      }
    }
  }
}

// ---------------------------------------------------------------------------
// vox f32 [B][NV][D] -> vb bf16 [B][NV][D]  AND  vt bf16 [B][D][NV]
// ---------------------------------------------------------------------------
__global__ __launch_bounds__(256)
void vox_prep(const float* __restrict__ in, u16* __restrict__ vb,
              u16* __restrict__ vt)
{
  __shared__ u16 tile[64][68];
  const int b = blockIdx.z;
  const int n0 = blockIdx.y * 64;
  const int d0 = blockIdx.x * 64;
  const int t = threadIdx.x;
  const int tr = t >> 4;
  const int tc = (t & 15) * 4;
  const float* ib = in + (long long)b * NV * D;
  u16* vbb = vb + (long long)b * NV * D;
  u16* vtb = vt + (long long)b * NV * D;
  #pragma unroll
  for (int p = 0; p < 4; ++p) {
    int r = tr + p * 16;
    float4 x = *reinterpret_cast<const float4*>(&ib[(long long)(n0 + r) * D + d0 + tc]);
    u16x4 o = {f2b(x.x), f2b(x.y), f2b(x.z), f2b(x.w)};
    *reinterpret_cast<u16x4*>(&vbb[(long long)(n0 + r) * D + d0 + tc]) = o;
    *reinterpret_cast<u16x4*>(&tile[r][tc]) = o;
  }
  __syncthreads();
  #pragma unroll
  for (int p = 0; p < 4; ++p) {
    int c = tr + p * 16;
    u16x4 o = {tile[tc + 0][c], tile[tc + 1][c], tile[tc + 2][c], tile[tc + 3][c]};
    *reinterpret_cast<u16x4*>(&vtb[(long long)(d0 + c) * NV + n0 + tc]) = o;
  }
}

// ---------------------------------------------------------------------------
struct Cvt7 { const float* s[7]; u16* d[7]; int cum[8]; };

__global__ __launch_bounds__(256)
void cvt_multi(Cvt7 a)
{
  const int bidx = blockIdx.x;
  int seg = 0;
  #pragma unroll
  for (int k = 1; k < 7; ++k) if (bidx >= a.cum[k]) seg = k;
  const long long off = ((long long)(bidx - a.cum[seg]) * 256 + threadIdx.x) * 4;
  float4 x = *reinterpret_cast<const float4*>(a.s[seg] + off);
  u16x4 o = {f2b(x.x), f2b(x.y), f2b(x.z), f2b(x.w)};
  *reinterpret_cast<u16x4*>(a.d[seg] + off) = o;
}

__global__ __launch_bounds__(256)
void cvt_add_bf16(const float* __restrict__ a, const float* __restrict__ b,
                  u16* __restrict__ out)
{
  const long long i = ((long long)blockIdx.x * 256 + threadIdx.x) * 4;
  float4 x = *reinterpret_cast<const float4*>(&a[i]);
  float4 y = *reinterpret_cast<const float4*>(&b[i]);
  u16x4 o = {f2b(x.x + y.x), f2b(x.y + y.y), f2b(x.z + y.z), f2b(x.w + y.w)};
  *reinterpret_cast<u16x4*>(&out[i]) = o;
}

__global__ __launch_bounds__(256)
void transpose_u16(const u16* __restrict__ in, u16* __restrict__ out,
                   int R, int C, int ldin, long long sbin, long long sbout)
{
  __shared__ u16 tile[32][34];
  const int b = blockIdx.z;
  const int r0 = blockIdx.y * 32, c0 = blockIdx.x * 32;
  const int tx = threadIdx.x & 31, ty = threadIdx.x >> 5;
  const u16* ib = in + (long long)b * sbin;
  u16* ob = out + (long long)b * sbout;
  #pragma unroll
  for (int p = 0; p < 4; ++p) {
    int r = ty + p * 8;
    tile[r][tx] = ib[(long long)(r0 + r) * ldin + c0 + tx];
  }
  __syncthreads();
  #pragma unroll
  for (int p = 0; p < 4; ++p) {
    int c = ty + p * 8;
    ob[(long long)(c0 + c) * R + r0 + tx] = tile[tx][c];
  }
}

// ---------------------------------------------------------------------------
__global__ __launch_bounds__(256)
void txt_softmax_mean(const u16* __restrict__ sc, const int* __restrict__ mask,
                      u16* __restrict__ wout, float* __restrict__ out1)
{
  __shared__ float red[8];
  const int t = threadIdx.x, l = t & 63, w = t >> 6;
  const int bq = blockIdx.x;
  const int b = bq >> 8, q = bq & 255;
  const int* mr = mask + b * LT;
  const int2 mm = *reinterpret_cast<const int2*>(&mr[2 * t]);
  const bool msk0 = mm.x != 0, msk1 = mm.y != 0;
  float a0 = 0.f, a1 = 0.f;
  for (int h = 0; h < H; ++h) {
    const long long ro = (((long long)(b * H + h)) * NQ + q) * LT;
    const u16* sr = sc + ro;
    const u16x2 sv = *reinterpret_cast<const u16x2*>(&sr[2 * t]);
    float x0 = msk0 ? -INFINITY : b2f(sv[0]);
    float x1 = msk1 ? -INFINITY : b2f(sv[1]);
    float mx = fmaxf(x0, x1);
    #pragma unroll
    for (int o = 32; o > 0; o >>= 1) mx = fmaxf(mx, __shfl_xor(mx, o, 64));
    if (l == 0) red[w] = mx;
    __syncthreads();
    mx = fmaxf(fmaxf(red[0], red[1]), fmaxf(red[2], red[3]));
    float e0 = __expf(x0 - mx), e1 = __expf(x1 - mx);
    float s = e0 + e1;
    #pragma unroll
    for (int o = 32; o > 0; o >>= 1) s += __shfl_xor(s, o, 64);
    if (l == 0) red[4 + w] = s;
    __syncthreads();
    s = red[4] + red[5] + red[6] + red[7];
    const float inv = 1.f / s;
    const float w0 = e0 * inv, w1 = e1 * inv;
    u16x2 wv = {f2b(w0), f2b(w1)};
    *reinterpret_cast<u16x2*>(&wout[ro + 2 * t]) = wv;
    a0 += w0; a1 += w1;
  }
  float2 o2 = {a0 * (1.f / H), a1 * (1.f / H)};
  *reinterpret_cast<float2*>(&out1[(long long)bq * LT + 2 * t]) = o2;
}

// ---------------------------------------------------------------------------
__global__ __launch_bounds__(256)
void ln_kernel(const float* __restrict__ x, const float* __restrict__ g,
               const float* __restrict__ bia, float* __restrict__ y,
               u16* __restrict__ yb, float scale)
{
  __shared__ float tmp[256];
  const int t = threadIdx.x;
  const long long off = (long long)blockIdx.x * D;
  float4 x4 = *reinterpret_cast<const float4*>(&x[off + t * 4]);
  tmp[t] = x4.x + x4.y + x4.z + x4.w;
  __syncthreads();
  for (int o = 128; o > 0; o >>= 1) { if (t < o) tmp[t] += tmp[t + o]; __syncthreads(); }
  const float mean = tmp[0] * (1.f / D);
  __syncthreads();
  float d0 = x4.x - mean, d1 = x4.y - mean, d2 = x4.z - mean, d3 = x4.w - mean;
  tmp[t] = d0 * d0 + d1 * d1 + d2 * d2 + d3 * d3;
  __syncthreads();
  for (int o = 128; o > 0; o >>= 1) { if (t < o) tmp[t] += tmp[t + o]; __syncthreads(); }
  const float rs = rsqrtf(tmp[0] * (1.f / D) + 1e-5f);
  float4 g4 = *reinterpret_cast<const float4*>(&g[t * 4]);
  float4 b4 = *reinterpret_cast<const float4*>(&bia[t * 4]);
  float o0 = (d0 * rs * g4.x + b4.x) * scale;
  float o1 = (d1 * rs * g4.y + b4.y) * scale;
  float o2 = (d2 * rs * g4.z + b4.z) * scale;
  float o3 = (d3 * rs * g4.w + b4.w) * scale;
  if (y) {
    float4 o4 = {o0, o1, o2, o3};
    *reinterpret_cast<float4*>(&y[off + t * 4]) = o4;
  }
  if (yb) {
    u16x4 ob = {f2b(o0), f2b(o1), f2b(o2), f2b(o3)};
    *reinterpret_cast<u16x4*>(&yb[off + t * 4]) = ob;
  }
}

// ---------------------------------------------------------------------------
__global__ __launch_bounds__(256)
void vox_softmax(float* __restrict__ s, const int* __restrict__ mask,
                 u16* __restrict__ wb)
{
  __shared__ float tmp[256];
  const int t = threadIdx.x;
  const int row = blockIdx.x, b = row / NQ;
  float* sr = s + (long long)row * NV;
  u16* wr = wb + (long long)row * NV;
  const int* mr = mask + b * NV;
  float vals[16];
  float lm = -INFINITY;
  #pragma unroll
  for (int j = 0; j < 16; ++j) {
    int n = t + j * 256;
    float x = mr[n] ? -INFINITY : sr[n];
    vals[j] = x;
    lm = fmaxf(lm, x);
  }
  tmp[t] = lm;
  __syncthreads();
  for (int o = 128; o > 0; o >>= 1) { if (t < o) tmp[t] = fmaxf(tmp[t], tmp[t + o]); __syncthreads(); }
  const float mx = tmp[0];
  __syncthreads();
  float ls = 0.f;
  #pragma unroll
  for (int j = 0; j < 16; ++j) { vals[j] = __expf(vals[j] - mx); ls += vals[j]; }
  tmp[t] = ls;
  __syncthreads();
  for (int o = 128; o > 0; o >>= 1) { if (t < o) tmp[t] += tmp[t + o]; __syncthreads(); }
  const float inv = 1.f / tmp[0];
  #pragma unroll
  for (int j = 0; j < 16; ++j) {
    float v = vals[j] * inv;
    sr[t + j * 256] = v;
    wr[t + j * 256] = f2b(v);
  }
}

__global__ __launch_bounds__(256)
void splitk_reduce(const float* __restrict__ part, float* __restrict__ out)
{
  const long long i = ((long long)blockIdx.x * 256 + threadIdx.x) * 4;
  const long long nd = (long long)NQ * D;
  const long long b = i / nd;
  const long long o = i - b * nd;
  const float* p = part + b * 4 * nd + o;
  float4 s0 = *reinterpret_cast<const float4*>(&p[0]);
  float4 s1 = *reinterpret_cast<const float4*>(&p[nd]);
  float4 s2 = *reinterpret_cast<const float4*>(&p[2 * nd]);
  float4 s3 = *reinterpret_cast<const float4*>(&p[3 * nd]);
  float4 r = {s0.x + s1.x + s2.x + s3.x, s0.y + s1.y + s2.y + s3.y,
              s0.z + s1.z + s2.z + s3.z, s0.w + s1.w + s2.w + s3.w};
  *reinterpret_cast<float4*>(&out[i]) = r;
}

// ---------------------------------------------------------------------------
extern "C" void kernel_launch(void* const* d_in, const int* in_sizes, int n_in,
                              void* d_out, int out_size, void* d_ws, size_t ws_size,
                              hipStream_t stream)
{
  const float* tgt   = (const float*)d_in[0];
  const float* mtxt  = (const float*)d_in[1];
  const float* vox   = (const float*)d_in[2];
  const float* qpos  = (const float*)d_in[3];
  const int*   mtx_m = (const int*)d_in[4];
  const int*   vox_m = (const int*)d_in[5];
  const float* Wq = (const float*)d_in[6];  const float* bq = (const float*)d_in[7];
  const float* Wk = (const float*)d_in[8];  const float* bk = (const float*)d_in[9];
  const float* Wv = (const float*)d_in[10]; const float* bv = (const float*)d_in[11];
  const float* Wo = (const float*)d_in[12]; const float* bo = (const float*)d_in[13];
  const float* W1 = (const float*)d_in[14]; const float* b1 = (const float*)d_in[15];
  const float* W2 = (const float*)d_in[16]; const float* b2 = (const float*)d_in[17];
  const float* ln1g = (const float*)d_in[18]; const float* ln1b = (const float*)d_in[19];
  const float* ln2g = (const float*)d_in[20]; const float* ln2b = (const float*)d_in[21];

  float* out0 = (float*)d_out;                       // attn_output  [B,NQ,D]
  float* out1 = out0 + (long long)B * NQ * D;        // txt_cross    [B,NQ,LT]
  float* out2 = out1 + (long long)B * NQ * LT;       // attn_weights [B,NQ,NV]

  char* base = (char*)d_ws;
  constexpr size_t MB = 1ull << 20;
  u16*   kvW   = (u16*)(base + 0 * MB);     // 16  [Wk;Wv] stacked
  u16*   Wq_b  = (u16*)(base + 16 * MB);    // 2
  u16*   Wo_b  = (u16*)(base + 18 * MB);    // 2
  u16*   W1_b  = (u16*)(base + 20 * MB);    // 4
  u16*   W2_b  = (u16*)(base + 24 * MB);    // 4
  u16*   tq_b  = (u16*)(base + 28 * MB);    // 4
  u16*   q_b   = (u16*)(base + 32 * MB);    // 4
  u16*   kv_b  = (u16*)(base + 36 * MB);    // 16  [B*LT][2048]
  u16*   vT_b  = (u16*)(base + 52 * MB);    // 8
  u16*   ctx_b = (u16*)(base + 60 * MB);    // 4
  float* x1p   = (float*)(base + 64 * MB);  // 8
  float* x1f   = (float*)(base + 72 * MB);  // 8
  u16*   x1_b  = (u16*)(base + 80 * MB);    // 4
  u16*   ff1_b = (u16*)(base + 84 * MB);    // 8
  float* x2p   = (float*)(base + 92 * MB);  // 8
  u16*   x2s_b = (u16*)(base + 100 * MB);   // 4
  u16*   mtxt_b = (u16*)(base + 104 * MB);  // 32  dead after kv256b
  u16*   scb   = (u16*)(base + 136 * MB);   // 32  bf16 scores, dead after softmax
  u16*   w_b    = (u16*)(base + 200 * MB);  // 32  dead after ctx gemm
  u16*   vox_b  = (u16*)(base + 104 * MB);  // 64  overlays mtxt_b + scb head
  u16*   voxT_b = (u16*)(base + 168 * MB);  // 64  overlays scb tail + w_b
  u16*   wvox_b = (u16*)(base + 0 * MB);    // 16  overlays kvW (dead)
  float* part   = (float*)(base + 16 * MB); // 32  overlays Wq..q_b (dead)

  const dim3 blk(256);
  const long long sQ = (long long)NQ * D;
  const long long sSC = (long long)NQ * LT;
  const long long nd = (long long)NQ * D;

  // 1) conversions: fused weights + memory_txt; tq = tgt + qpos
  Cvt7 ca;
  ca.s[0] = Wq;   ca.d[0] = Wq_b;
  ca.s[1] = Wk;   ca.d[1] = kvW;
  ca.s[2] = Wv;   ca.d[2] = kvW + (long long)D * FTXT;
  ca.s[3] = Wo;   ca.d[3] = Wo_b;
  ca.s[4] = W1;   ca.d[4] = W1_b;
  ca.s[5] = W2;   ca.d[5] = W2_b;
  ca.s[6] = mtxt; ca.d[6] = mtxt_b;
  ca.cum[0] = 0;     ca.cum[1] = 1024;  ca.cum[2] = 5120;  ca.cum[3] = 9216;
  ca.cum[4] = 10240; ca.cum[5] = 12288; ca.cum[6] = 14336; ca.cum[7] = 30720;
  cvt_multi<<<dim3(30720), blk, 0, stream>>>(ca);
  cvt_add_bf16<<<dim3((B * NQ * D) / 1024), blk, 0, stream>>>(tgt, qpos, tq_b);

  // 2) q projection (2-phase) + kv projection (deep-B 8-phase, full K)
  gemm_bf16<64,64,2,2, E_BIAS|E_WB16><<<dim3(D/64, (B*NQ)/64, 1), blk, 0, stream>>>(
      tq_b, Wq_b, bq, nullptr, nullptr, q_b, D, D, D, D, 1, 0,0,0,0,0,0, 1.f);
  gemm_kv256b<<<dim3(16, 16), dim3(512), 0, stream>>>(mtxt_b, kvW, bk, bv, kv_b);

  // 3) vT[b][d][l] = v[b][l][d]
  transpose_u16<<<dim3(D/32, LT/32, B), blk, 0, stream>>>(
      kv_b + 1024, vT_b, LT, D, 2048, (long long)LT * 2048, (long long)D * LT);

  // 4) scores = q . k / 8  -> bf16
  gemm_bf16<128,128,2,2, E_WB16><<<dim3(LT/128, NQ/128, B*H), blk, 0, stream>>>(
      q_b, kv_b, nullptr, nullptr, nullptr, scb, HD, D, 2048, LT, H,
      sQ, HD, (long long)LT * 2048, HD, (long long)H * sSC, sSC, 0.125f);

  // 5) fused softmax + head-mean (bf16 scores in)
  txt_softmax_mean<<<dim3(B*NQ), blk, 0, stream>>>(scb, mtx_m, w_b, out1);

  // 6) ctx = w_h @ v_h
  gemm_bf16<64,64,2,2, E_WB16><<<dim3(HD/64, NQ/64, B*H), blk, 0, stream>>>(
      w_b, vT_b, nullptr, nullptr, nullptr, ctx_b, LT, LT, LT, D, H,
      (long long)H * sSC, sSC, (long long)D * LT, (long long)HD * LT, sQ, HD, 1.f);

  // 7) vox -> vox_b + voxT_b (one f32 read)
  vox_prep<<<dim3(D/64, NV/64, B), blk, 0, stream>>>(vox, vox_b, voxT_b);

  // 8) x1p = tgt + ctx @ Wo^T + bo
  gemm_bf16<64,64,2,2, E_BIAS|E_RES|E_WF32><<<dim3(D/64, (B*NQ)/64, 1), blk, 0, stream>>>(
      ctx_b, Wo_b, bo, tgt, x1p, nullptr, D, D, D, D, 1, 0,0,0,0,0,0, 1.f);

  // 9) LN1
  ln_kernel<<<dim3(B*NQ), blk, 0, stream>>>(x1p, ln1g, ln1b, x1f, x1_b, 1.f);

  // 10) ff1 = relu(x1 @ W1^T + b1)
  gemm_bf16<128,64,2,2, E_BIAS|E_RELU|E_WB16><<<dim3(DFF/64, (B*NQ)/128, 1), blk, 0, stream>>>(
      x1_b, W1_b, b1, nullptr, nullptr, ff1_b, D, D, D, DFF, 1, 0,0,0,0,0,0, 1.f);

  // 11) x2p = x1 + ff1 @ W2^T + b2
  gemm_bf16<64,64,2,2, E_BIAS|E_RES|E_WF32><<<dim3(D/64, (B*NQ)/64, 1), blk, 0, stream>>>(
      ff1_b, W2_b, b2, x1f, x2p, nullptr, DFF, DFF, DFF, D, 1, 0,0,0,0,0,0, 1.f);

  // 12) LN2 -> x2s (bf16, /sqrt(D))
  ln_kernel<<<dim3(B*NQ), blk, 0, stream>>>(x2p, ln2g, ln2b, nullptr, x2s_b, 0.03125f);

  // 13) out2 = x2s @ vox_b^T  (deep-B 8-phase)
  gemm8<1><<<dim3(NV/128, 1, B), dim3(512), 0, stream>>>(
      x2s_b, vox_b, out2, D, D, D, NV, 0,
      sQ, (long long)NV * D, (long long)NQ * NV, 0);

  // 14) masked softmax in place; bf16 weights
  vox_softmax<<<dim3(B*NQ), blk, 0, stream>>>(out2, vox_m, wvox_b);

  // 15) out0 partials: deep-B 8-phase split-K=4 + reduce
  gemm8<4><<<dim3(D/128, 1, B*4), dim3(512), 0, stream>>>(
      wvox_b, voxT_b, part, NV/4, NV, NV, D, NV/4,
      (long long)NQ * NV, (long long)D * NV, 4 * nd, nd);
  splitk_reduce<<<dim3((B * NQ * D) / 1024), blk, 0, stream>>>(part, out0);
}

// Round 13
// 403.830 us; speedup vs baseline: 1.2671x; 1.0269x over previous
//
#include <hip/hip_runtime.h>
#include <math.h>

typedef unsigned short u16;
typedef unsigned int u32;
typedef __bf16 bf16x8 __attribute__((ext_vector_type(8)));
typedef float f32x4 __attribute__((ext_vector_type(4)));
typedef u16 u16x4 __attribute__((ext_vector_type(4)));
typedef u16 u16x2 __attribute__((ext_vector_type(2)));

constexpr int B = 8, NQ = 256, LT = 512, NV = 4096;
constexpr int D = 1024, H = 16, DFF = 2048, FTXT = 4096, HD = 64;

__device__ __forceinline__ u16 f2b(float f) {
  u32 u = __builtin_bit_cast(u32, f);
  return (u16)((u + 0x7fffu + ((u >> 16) & 1u)) >> 16);   // RNE
}
__device__ __forceinline__ float b2f(u16 b) {
  u32 u = ((u32)b) << 16;
  return __builtin_bit_cast(float, u);
}
__device__ __forceinline__ void gload16(const void* g, void* l) {
  __builtin_amdgcn_global_load_lds(
      (const __attribute__((address_space(1))) u32*)g,
      (__attribute__((address_space(3))) u32*)l, 16, 0, 0);
}

// ===========================================================================
// KV projection, R13 merged-phase schedule: one phase per k-tile.
// kv[4096][2048] = mtxt[4096][4096] @ kvW[2048][4096]^T + bias, bf16 out.
// 512 thr = 8 waves (2x4), 256x128 tile, BK=64, nt=64.
// LDS 144 KiB: A 3 slabs [256][64], B 3 slabs [128][64] (mod-3 rotation),
// XOR-swizzle slot^(row&7) both-sides.
// Per phase: 20 ds_read_b128, stage tile t+2 (6 gloads), 32 MFMA,
// ONE vmcnt(6) + ONE barrier. Prologue 12 loads -> vmcnt(6).
// ===========================================================================
__global__ __launch_bounds__(512, 2)
void gemm_kv256b(const u16* __restrict__ A, const u16* __restrict__ Bw,
                 const float* __restrict__ bk_, const float* __restrict__ bv_,
                 u16* __restrict__ Cb)
{
  __shared__ __align__(16) u16 As[3 * 16384];   // 3 x [256][64]
  __shared__ __align__(16) u16 Bs[3 * 8192];    // 3 x [128][64]

  const int gx = 16;
  const int flat = blockIdx.y * gx + blockIdx.x;
  const int qq = 256 >> 3;
  const int xcd = flat & 7, lid = flat >> 3;
  const int wg = xcd * qq + lid;
  const int bx = wg % gx;
  const int by = wg / gx;
  const int m0 = by * 256, n0 = bx * 128;
  const float* bias = (n0 < 1024) ? (bk_ + n0) : (bv_ + (n0 - 1024));

  const int t = threadIdx.x;
  const int w = t >> 6, l = t & 63;
  const int wr64 = (w >> 2) * 64;
  const int wc32 = (w & 3) * 32;
  const int l15 = l & 15, l4 = l >> 4, l7 = l & 7;

  auto stA = [&](int slab, int tile) {   // 4 gloads: all 256 rows
    const long long kk = (long long)tile * 64 + (((t & 7) ^ ((t >> 3) & 7)) * 8);
    #pragma unroll
    for (int i = 0; i < 4; ++i)
      gload16(&A[(long long)(m0 + (t >> 3) + 64 * i) * 4096 + kk],
              &As[slab * 16384 + (w * 8 + 64 * i) * 64]);
  };
  auto stB = [&](int slab, int tile) {   // 2 gloads: 128 rows
    const long long kk = (long long)tile * 64 + (((t & 7) ^ ((t >> 3) & 7)) * 8);
    #pragma unroll
    for (int i = 0; i < 2; ++i)
      gload16(&Bw[(long long)(n0 + (t >> 3) + 64 * i) * 4096 + kk],
              &Bs[slab * 8192 + (w * 8 + 64 * i) * 64]);
  };

#define RDA(sl,qm,fm,ks) \
  (*reinterpret_cast<const bf16x8*>(&As[(sl)*16384 + \
      ((qm)*128 + wr64 + (fm)*16 + l15)*64 + ((((ks)*4 + l4) ^ l7) * 8)]))
#define RDB(sl,fn,ks) \
  (*reinterpret_cast<const bf16x8*>(&Bs[(sl)*8192 + \
      (wc32 + (fn)*16 + l15)*64 + ((((ks)*4 + l4) ^ l7) * 8)]))

  f32x4 acc[2][4][2] = {};   // [qm][fm][fn]
  bf16x8 a_[2][4][2];        // [qm][fm][ks]
  bf16x8 b_[2][2];           // [fn][ks]

#define BAR asm volatile("s_barrier" ::: "memory")
#define WAIT6 asm volatile("s_waitcnt vmcnt(6)" ::: "memory")
#define WAIT0 asm volatile("s_waitcnt vmcnt(0)" ::: "memory")

  // prologue: tile0 (6 loads) then tile1 (6); drain oldest 6 (tile0)
  stA(0, 0); stB(0, 0);
  stA(1, 1); stB(1, 1);
  WAIT6;
  BAR;

  int s0 = 0, s1 = 1, s2 = 2;
  for (int tt = 0; tt < 64; ++tt) {
    // read whole tile's fragments from slab s0
    #pragma unroll
    for (int qm = 0; qm < 2; ++qm)
      #pragma unroll
      for (int fm = 0; fm < 4; ++fm) {
        a_[qm][fm][0] = RDA(s0, qm, fm, 0);
        a_[qm][fm][1] = RDA(s0, qm, fm, 1);
      }
    b_[0][0] = RDB(s0, 0, 0); b_[0][1] = RDB(s0, 0, 1);
    b_[1][0] = RDB(s0, 1, 0); b_[1][1] = RDB(s0, 1, 1);

    if (tt < 62) { stA(s2, tt + 2); stB(s2, tt + 2); }

    __builtin_amdgcn_s_setprio(1);
    #pragma unroll
    for (int qm = 0; qm < 2; ++qm)
      #pragma unroll
      for (int fm = 0; fm < 4; ++fm)
        #pragma unroll
        for (int fn = 0; fn < 2; ++fn) {
          acc[qm][fm][fn] = __builtin_amdgcn_mfma_f32_16x16x32_bf16(
              a_[qm][fm][0], b_[fn][0], acc[qm][fm][fn], 0, 0, 0);
          acc[qm][fm][fn] = __builtin_amdgcn_mfma_f32_16x16x32_bf16(
              a_[qm][fm][1], b_[fn][1], acc[qm][fm][fn], 0, 0, 0);
        }
    __builtin_amdgcn_s_setprio(0);

    if (tt < 62)       { WAIT6; }
    else if (tt == 62) { WAIT0; }
    BAR;

    const int tmp = s0; s0 = s1; s1 = s2; s2 = tmp;
  }
#undef RDA
#undef RDB
#undef BAR
#undef WAIT6
#undef WAIT0

  #pragma unroll
  for (int qm = 0; qm < 2; ++qm)
    #pragma unroll
    for (int fm = 0; fm < 4; ++fm)
      #pragma unroll
      for (int r = 0; r < 4; ++r) {
        const long long row = m0 + qm * 128 + wr64 + fm * 16 + l4 * 4 + r;
        #pragma unroll
        for (int fn = 0; fn < 2; ++fn) {
          const int lc = wc32 + fn * 16 + l15;
          Cb[row * 2048 + n0 + lc] = f2b(acc[qm][fm][fn][r] + bias[lc]);
        }
      }
}

// --- Generalized deep-B 8-phase 256x128 (R12 schedule, unchanged):
//     C f32 = A@Bw^T, batch + split-K. Ksub must be a multiple of 256. ---
template<int NZ2>
__global__ __launch_bounds__(512, 2)
void gemm8(const u16* __restrict__ A, const u16* __restrict__ Bw,
           float* __restrict__ C,
           int Ksub, int lda, int ldb, int ldc, int kstep,
           long long sA1, long long sB1, long long sC1, long long sC2)
{
  __shared__ __align__(16) u16 As[4 * 8192];
  __shared__ __align__(16) u16 Bs[4 * 8192];

  const int gx = gridDim.x, gy = gridDim.y;
  const int nwg = gx * gy * gridDim.z;
  const int flat = (blockIdx.z * gy + blockIdx.y) * gx + blockIdx.x;
  const int qq = nwg >> 3, rr = nwg & 7;
  const int xcd = flat & 7, lid = flat >> 3;
  const int wg = (xcd < rr ? xcd * (qq + 1) : rr * (qq + 1) + (xcd - rr) * qq) + lid;
  const int bx = wg % gx;
  const int tmp1 = wg / gx;
  const int by = tmp1 % gy, bz = tmp1 / gy;
  const int z1 = bz / NZ2, z2 = bz % NZ2;
  const int m0 = by * 256, n0 = bx * 128;
  const long long kbase = (long long)z2 * kstep;
  const u16* Ab = A + (long long)z1 * sA1;
  const u16* Bb = Bw + (long long)z1 * sB1;
  float* Cp = C + (long long)z1 * sC1 + (long long)z2 * sC2;

  const int t = threadIdx.x;
  const int w = t >> 6, l = t & 63;
  const int wr64 = (w >> 2) * 64;
  const int wc32 = (w & 3) * 32;
  const int l15 = l & 15, l4 = l >> 4, l7 = l & 7;

  auto stAh = [&](int db, int h, int tile) {
    const long long kk = kbase + (long long)tile * 64 + (((t & 7) ^ ((t >> 3) & 7)) * 8);
    #pragma unroll
    for (int i = 0; i < 2; ++i)
      gload16(&Ab[(long long)(m0 + h * 128 + (t >> 3) + 64 * i) * lda + kk],
              &As[(db * 2 + h) * 8192 + (w * 8 + 64 * i) * 64]);
  };
  auto stB = [&](int bs, int tile) {
    const long long kk = kbase + (long long)tile * 64 + (((t & 7) ^ ((t >> 3) & 7)) * 8);
    #pragma unroll
    for (int i = 0; i < 2; ++i)
      gload16(&Bb[(long long)(n0 + (t >> 3) + 64 * i) * ldb + kk],
              &Bs[bs * 8192 + (w * 8 + 64 * i) * 64]);
  };

#define RDA(db,qm,fm,ks) \
  (*reinterpret_cast<const bf16x8*>(&As[((db)*2+(qm))*8192 + \
      (wr64 + (fm)*16 + l15)*64 + ((((ks)*4 + l4) ^ l7) * 8)]))
#define RDB(bs,fn,ks) \
  (*reinterpret_cast<const bf16x8*>(&Bs[(bs)*8192 + \
      (wc32 + (fn)*16 + l15)*64 + ((((ks)*4 + l4) ^ l7) * 8)]))

  f32x4 acc[2][4][2] = {};
  bf16x8 a_[4][2];
  bf16x8 b_[2][2];

#define LOADA(db, qm)                                                        \
  do {                                                                       \
    _Pragma("unroll")                                                        \
    for (int fm_ = 0; fm_ < 4; ++fm_) {                                      \
      a_[fm_][0] = RDA(db, qm, fm_, 0);                                      \
      a_[fm_][1] = RDA(db, qm, fm_, 1);                                      \
    }                                                                        \
  } while (0)
#define LOADB(bs)                                                            \
  do {                                                                       \
    b_[0][0] = RDB(bs, 0, 0); b_[0][1] = RDB(bs, 0, 1);                      \
    b_[1][0] = RDB(bs, 1, 0); b_[1][1] = RDB(bs, 1, 1);                      \
  } while (0)
#define MMACL(qm)                                                            \
  do {                                                                       \
    asm volatile("s_barrier" ::: "memory");                                  \
    __builtin_amdgcn_s_setprio(1);                                           \
    _Pragma("unroll")                                                        \
    for (int fm_ = 0; fm_ < 4; ++fm_) {                                      \
      _Pragma("unroll")                                                      \
      for (int fn_ = 0; fn_ < 2; ++fn_) {                                    \
        acc[qm][fm_][fn_] = __builtin_amdgcn_mfma_f32_16x16x32_bf16(         \
            a_[fm_][0], b_[fn_][0], acc[qm][fm_][fn_], 0, 0, 0);             \
        acc[qm][fm_][fn_] = __builtin_amdgcn_mfma_f32_16x16x32_bf16(         \
            a_[fm_][1], b_[fn_][1], acc[qm][fm_][fn_], 0, 0, 0);             \
      }                                                                      \
    }                                                                        \
    __builtin_amdgcn_s_setprio(0);                                           \
  } while (0)
#define BAR asm volatile("s_barrier" ::: "memory")
#define WAIT6 asm volatile("s_waitcnt vmcnt(6)" ::: "memory")
#define WAIT0 asm volatile("s_waitcnt vmcnt(0)" ::: "memory")

  stB(0, 0); stAh(0, 0, 0); stAh(0, 1, 0);
  stB(1, 1); stAh(1, 0, 1); stAh(1, 1, 1);
  WAIT6;
  BAR;

  const int nbody = Ksub >> 8;   // 4 tiles per body
  for (int bb = 0; bb < nbody; ++bb) {
    const int base = 4 * bb;
    const bool more = (bb < nbody - 1);
    LOADA(0, 0); LOADB(0);
    stB(2, base + 2);
    MMACL(0);
    BAR;
    LOADA(0, 1);
    stAh(0, 0, base + 2); stAh(0, 1, base + 2);
    MMACL(1);
    WAIT6;
    BAR;
    LOADA(1, 0); LOADB(1);
    stB(3, base + 3);
    MMACL(0);
    BAR;
    LOADA(1, 1);
    stAh(1, 0, base + 3); stAh(1, 1, base + 3);
    MMACL(1);
    WAIT6;
    BAR;
    LOADA(0, 0); LOADB(2);
    if (more) stB(0, base + 4);
    MMACL(0);
    BAR;
    LOADA(0, 1);
    if (more) { stAh(0, 0, base + 4); stAh(0, 1, base + 4); }
    MMACL(1);
    if (more) { WAIT6; } else { WAIT0; }
    BAR;
    LOADA(1, 0); LOADB(3);
    if (more) stB(1, base + 5);
    MMACL(0);
    BAR;
    LOADA(1, 1);
    if (more) { stAh(1, 0, base + 5); stAh(1, 1, base + 5); }
    MMACL(1);
    if (more) { WAIT6; } else { WAIT0; }
    BAR;
  }
#undef LOADA
#undef LOADB
#undef MMACL
#undef RDA
#undef RDB
#undef BAR
#undef WAIT6
#undef WAIT0

  #pragma unroll
  for (int qm = 0; qm < 2; ++qm)
    #pragma unroll
    for (int fm = 0; fm < 4; ++fm)
      #pragma unroll
      for (int r = 0; r < 4; ++r) {
        const long long row = m0 + qm * 128 + wr64 + fm * 16 + l4 * 4 + r;
        #pragma unroll
        for (int fn = 0; fn < 2; ++fn) {
          const int lc = wc32 + fn * 16 + l15;
          Cp[row * (long long)ldc + n0 + lc] = acc[qm][fm][fn][r];
        }
      }
}

// ---------------------------------------------------------------------------
// 2-phase bf16 MFMA GEMM (bf16 B via global_load_lds only).
// ---------------------------------------------------------------------------
constexpr int E_BIAS = 1, E_RES = 2, E_RELU = 4, E_WF32 = 8, E_WB16 = 16;

template<int BM, int BN, int WM, int WN, int EPI>
__global__ __launch_bounds__(256)
void gemm_bf16(const u16* __restrict__ A, const u16* __restrict__ Bw,
               const float* __restrict__ bias, const float* __restrict__ res,
               float* __restrict__ C, u16* __restrict__ Cb,
               int K, int lda, int ldb, int ldc, int nbz2,
               long long sA1, long long sA2, long long sB1, long long sB2,
               long long sC1, long long sC2, float alpha)
{
  constexpr int SM = BM / WM, SN = BN / WN;
  constexpr int FM = SM / 16, FN = SN / 16;
  constexpr int PA = BM / 64, PB = BN / 64;
  __shared__ __align__(16) u16 As[2][BM * 32];
  __shared__ __align__(16) u16 Bs[2][BN * 32];

  const int gx = gridDim.x, gy = gridDim.y;
  const int nwg = gx * gy * gridDim.z;
  const int flat = (blockIdx.z * gy + blockIdx.y) * gx + blockIdx.x;
  const int qq = nwg >> 3, rr = nwg & 7;
  const int xcd = flat & 7, lid = flat >> 3;
  const int wg = (xcd < rr ? xcd * (qq + 1) : rr * (qq + 1) + (xcd - rr) * qq) + lid;
  const int bx = wg % gx;
  const int tmp1 = wg / gx;
  const int by = tmp1 % gy, bz = tmp1 / gy;

  const int t = threadIdx.x;
  const int w = t >> 6, l = t & 63;
  const int wr = w / WN, wc = w % WN;
  const int m0 = by * BM, n0 = bx * BN;
  const long long offA = (long long)(bz / nbz2) * sA1 + (long long)(bz % nbz2) * sA2;
  const long long offB = (long long)(bz / nbz2) * sB1 + (long long)(bz % nbz2) * sB2;
  const long long offC = (long long)(bz / nbz2) * sC1 + (long long)(bz % nbz2) * sC2;
  const u16* Ab = A + offA;
  const u16* Bb = Bw + offB;

  const int srow = t >> 2;
  const int sk   = (t & 3) * 8;

  auto stageA = [&](int buf, int k0) {
    #pragma unroll
    for (int p = 0; p < PA; ++p)
      gload16(&Ab[(long long)(m0 + p * 64 + srow) * lda + k0 + sk],
              &As[buf][p * 2048 + w * 512]);
  };
  auto stageB = [&](int buf, int k0) {
    #pragma unroll
    for (int p = 0; p < PB; ++p)
      gload16(&Bb[(long long)(n0 + p * 64 + srow) * ldb + k0 + sk],
              &Bs[buf][p * 2048 + w * 512]);
  };

  f32x4 acc[FM][FN] = {};

  stageA(0, 0);
  stageB(0, 0);

  int cur = 0;
  for (int k0 = 0; k0 < K; k0 += 32) {
    __syncthreads();
    const bool pf = (k0 + 32 < K);
    if (pf) {
      stageA(cur ^ 1, k0 + 32);
      stageB(cur ^ 1, k0 + 32);
    }

    bf16x8 af[FM], bfr[FN];
    #pragma unroll
    for (int i = 0; i < FM; ++i)
      af[i] = *reinterpret_cast<const bf16x8*>(
          &As[cur][(wr * SM + i * 16 + (l & 15)) * 32 + (l >> 4) * 8]);
    #pragma unroll
    for (int j = 0; j < FN; ++j)
      bfr[j] = *reinterpret_cast<const bf16x8*>(
          &Bs[cur][(wc * SN + j * 16 + (l & 15)) * 32 + (l >> 4) * 8]);
    #pragma unroll
    for (int i = 0; i < FM; ++i)
      #pragma unroll
      for (int j = 0; j < FN; ++j)
        acc[i][j] = __builtin_amdgcn_mfma_f32_16x16x32_bf16(af[i], bfr[j], acc[i][j], 0, 0, 0);
    cur ^= 1;
  }

  const int c_l = l & 15, r_l4 = (l >> 4) * 4;
  #pragma unroll
  for (int i = 0; i < FM; ++i) {
    #pragma unroll
    for (int r = 0; r < 4; ++r) {
      const long long row = m0 + wr * SM + i * 16 + r_l4 + r;
      #pragma unroll
      for (int j = 0; j < FN; ++j) {
        const int col = n0 + wc * SN + j * 16 + c_l;
        float v = acc[i][j][r] * alpha;
        if (EPI & E_BIAS) v += bias[col];
        if (EPI & E_RES)  v += res[row * (long long)ldc + col];
        if (EPI & E_RELU) v = fmaxf(v, 0.f);
        const long long co = offC + row * (long long)ldc + col;
        if (EPI & E_WF32) C[co] = v;
        if (EPI & E_WB16) Cb[co] = f2b(v);
      }
    }
  }
}

// ---------------------------------------------------------------------------
// vox f32 [B][NV][D] -> vb bf16 [B][NV][D]  AND  vt bf16 [B][D][NV]
// ---------------------------------------------------------------------------
__global__ __launch_bounds__(256)
void vox_prep(const float* __restrict__ in, u16* __restrict__ vb,
              u16* __restrict__ vt)
{
  __shared__ u16 tile[64][68];
  const int b = blockIdx.z;
  const int n0 = blockIdx.y * 64;
  const int d0 = blockIdx.x * 64;
  const int t = threadIdx.x;
  const int tr = t >> 4;
  const int tc = (t & 15) * 4;
  const float* ib = in + (long long)b * NV * D;
  u16* vbb = vb + (long long)b * NV * D;
  u16* vtb = vt + (long long)b * NV * D;
  #pragma unroll
  for (int p = 0; p < 4; ++p) {
    int r = tr + p * 16;
    float4 x = *reinterpret_cast<const float4*>(&ib[(long long)(n0 + r) * D + d0 + tc]);
    u16x4 o = {f2b(x.x), f2b(x.y), f2b(x.z), f2b(x.w)};
    *reinterpret_cast<u16x4*>(&vbb[(long long)(n0 + r) * D + d0 + tc]) = o;
    *reinterpret_cast<u16x4*>(&tile[r][tc]) = o;
  }
  __syncthreads();
  #pragma unroll
  for (int p = 0; p < 4; ++p) {
    int c = tr + p * 16;
    u16x4 o = {tile[tc + 0][c], tile[tc + 1][c], tile[tc + 2][c], tile[tc + 3][c]};
    *reinterpret_cast<u16x4*>(&vtb[(long long)(d0 + c) * NV + n0 + tc]) = o;
  }
}

// ---------------------------------------------------------------------------
struct Cvt7 { const float* s[7]; u16* d[7]; int cum[8]; };

__global__ __launch_bounds__(256)
void cvt_multi(Cvt7 a)
{
  const int bidx = blockIdx.x;
  int seg = 0;
  #pragma unroll
  for (int k = 1; k < 7; ++k) if (bidx >= a.cum[k]) seg = k;
  const long long off = ((long long)(bidx - a.cum[seg]) * 256 + threadIdx.x) * 4;
  float4 x = *reinterpret_cast<const float4*>(a.s[seg] + off);
  u16x4 o = {f2b(x.x), f2b(x.y), f2b(x.z), f2b(x.w)};
  *reinterpret_cast<u16x4*>(a.d[seg] + off) = o;
}

__global__ __launch_bounds__(256)
void cvt_add_bf16(const float* __restrict__ a, const float* __restrict__ b,
                  u16* __restrict__ out)
{
  const long long i = ((long long)blockIdx.x * 256 + threadIdx.x) * 4;
  float4 x = *reinterpret_cast<const float4*>(&a[i]);
  float4 y = *reinterpret_cast<const float4*>(&b[i]);
  u16x4 o = {f2b(x.x + y.x), f2b(x.y + y.y), f2b(x.z + y.z), f2b(x.w + y.w)};
  *reinterpret_cast<u16x4*>(&out[i]) = o;
}

__global__ __launch_bounds__(256)
void transpose_u16(const u16* __restrict__ in, u16* __restrict__ out,
                   int R, int C, int ldin, long long sbin, long long sbout)
{
  __shared__ u16 tile[32][34];
  const int b = blockIdx.z;
  const int r0 = blockIdx.y * 32, c0 = blockIdx.x * 32;
  const int tx = threadIdx.x & 31, ty = threadIdx.x >> 5;
  const u16* ib = in + (long long)b * sbin;
  u16* ob = out + (long long)b * sbout;
  #pragma unroll
  for (int p = 0; p < 4; ++p) {
    int r = ty + p * 8;
    tile[r][tx] = ib[(long long)(r0 + r) * ldin + c0 + tx];
  }
  __syncthreads();
  #pragma unroll
  for (int p = 0; p < 4; ++p) {
    int c = ty + p * 8;
    ob[(long long)(c0 + c) * R + r0 + tx] = tile[tx][c];
  }
}

// ---------------------------------------------------------------------------
__global__ __launch_bounds__(256)
void txt_softmax_mean(const u16* __restrict__ sc, const int* __restrict__ mask,
                      u16* __restrict__ wout, float* __restrict__ out1)
{
  __shared__ float red[8];
  const int t = threadIdx.x, l = t & 63, w = t >> 6;
  const int bq = blockIdx.x;
  const int b = bq >> 8, q = bq & 255;
  const int* mr = mask + b * LT;
  const int2 mm = *reinterpret_cast<const int2*>(&mr[2 * t]);
  const bool msk0 = mm.x != 0, msk1 = mm.y != 0;
  float a0 = 0.f, a1 = 0.f;
  for (int h = 0; h < H; ++h) {
    const long long ro = (((long long)(b * H + h)) * NQ + q) * LT;
    const u16* sr = sc + ro;
    const u16x2 sv = *reinterpret_cast<const u16x2*>(&sr[2 * t]);
    float x0 = msk0 ? -INFINITY : b2f(sv[0]);
    float x1 = msk1 ? -INFINITY : b2f(sv[1]);
    float mx = fmaxf(x0, x1);
    #pragma unroll
    for (int o = 32; o > 0; o >>= 1) mx = fmaxf(mx, __shfl_xor(mx, o, 64));
    if (l == 0) red[w] = mx;
    __syncthreads();
    mx = fmaxf(fmaxf(red[0], red[1]), fmaxf(red[2], red[3]));
    float e0 = __expf(x0 - mx), e1 = __expf(x1 - mx);
    float s = e0 + e1;
    #pragma unroll
    for (int o = 32; o > 0; o >>= 1) s += __shfl_xor(s, o, 64);
    if (l == 0) red[4 + w] = s;
    __syncthreads();
    s = red[4] + red[5] + red[6] + red[7];
    const float inv = 1.f / s;
    const float w0 = e0 * inv, w1 = e1 * inv;
    u16x2 wv = {f2b(w0), f2b(w1)};
    *reinterpret_cast<u16x2*>(&wout[ro + 2 * t]) = wv;
    a0 += w0; a1 += w1;
  }
  float2 o2 = {a0 * (1.f / H), a1 * (1.f / H)};
  *reinterpret_cast<float2*>(&out1[(long long)bq * LT + 2 * t]) = o2;
}

// ---------------------------------------------------------------------------
__global__ __launch_bounds__(256)
void ln_kernel(const float* __restrict__ x, const float* __restrict__ g,
               const float* __restrict__ bia, float* __restrict__ y,
               u16* __restrict__ yb, float scale)
{
  __shared__ float tmp[256];
  const int t = threadIdx.x;
  const long long off = (long long)blockIdx.x * D;
  float4 x4 = *reinterpret_cast<const float4*>(&x[off + t * 4]);
  tmp[t] = x4.x + x4.y + x4.z + x4.w;
  __syncthreads();
  for (int o = 128; o > 0; o >>= 1) { if (t < o) tmp[t] += tmp[t + o]; __syncthreads(); }
  const float mean = tmp[0] * (1.f / D);
  __syncthreads();
  float d0 = x4.x - mean, d1 = x4.y - mean, d2 = x4.z - mean, d3 = x4.w - mean;
  tmp[t] = d0 * d0 + d1 * d1 + d2 * d2 + d3 * d3;
  __syncthreads();
  for (int o = 128; o > 0; o >>= 1) { if (t < o) tmp[t] += tmp[t + o]; __syncthreads(); }
  const float rs = rsqrtf(tmp[0] * (1.f / D) + 1e-5f);
  float4 g4 = *reinterpret_cast<const float4*>(&g[t * 4]);
  float4 b4 = *reinterpret_cast<const float4*>(&bia[t * 4]);
  float o0 = (d0 * rs * g4.x + b4.x) * scale;
  float o1 = (d1 * rs * g4.y + b4.y) * scale;
  float o2 = (d2 * rs * g4.z + b4.z) * scale;
  float o3 = (d3 * rs * g4.w + b4.w) * scale;
  if (y) {
    float4 o4 = {o0, o1, o2, o3};
    *reinterpret_cast<float4*>(&y[off + t * 4]) = o4;
  }
  if (yb) {
    u16x4 ob = {f2b(o0), f2b(o1), f2b(o2), f2b(o3)};
    *reinterpret_cast<u16x4*>(&yb[off + t * 4]) = ob;
  }
}

// ---------------------------------------------------------------------------
__global__ __launch_bounds__(256)
void vox_softmax(float* __restrict__ s, const int* __restrict__ mask,
                 u16* __restrict__ wb)
{
  __shared__ float tmp[256];
  const int t = threadIdx.x;
  const int row = blockIdx.x, b = row / NQ;
  float* sr = s + (long long)row * NV;
  u16* wr = wb + (long long)row * NV;
  const int* mr = mask + b * NV;
  float vals[16];
  float lm = -INFINITY;
  #pragma unroll
  for (int j = 0; j < 16; ++j) {
    int n = t + j * 256;
    float x = mr[n] ? -INFINITY : sr[n];
    vals[j] = x;
    lm = fmaxf(lm, x);
  }
  tmp[t] = lm;
  __syncthreads();
  for (int o = 128; o > 0; o >>= 1) { if (t < o) tmp[t] = fmaxf(tmp[t], tmp[t + o]); __syncthreads(); }
  const float mx = tmp[0];
  __syncthreads();
  float ls = 0.f;
  #pragma unroll
  for (int j = 0; j < 16; ++j) { vals[j] = __expf(vals[j] - mx); ls += vals[j]; }
  tmp[t] = ls;
  __syncthreads();
  for (int o = 128; o > 0; o >>= 1) { if (t < o) tmp[t] += tmp[t + o]; __syncthreads(); }
  const float inv = 1.f / tmp[0];
  #pragma unroll
  for (int j = 0; j < 16; ++j) {
    float v = vals[j] * inv;
    sr[t + j * 256] = v;
    wr[t + j * 256] = f2b(v);
  }
}

__global__ __launch_bounds__(256)
void splitk_reduce(const float* __restrict__ part, float* __restrict__ out)
{
  const long long i = ((long long)blockIdx.x * 256 + threadIdx.x) * 4;
  const long long nd = (long long)NQ * D;
  const long long b = i / nd;
  const long long o = i - b * nd;
  const float* p = part + b * 4 * nd + o;
  float4 s0 = *reinterpret_cast<const float4*>(&p[0]);
  float4 s1 = *reinterpret_cast<const float4*>(&p[nd]);
  float4 s2 = *reinterpret_cast<const float4*>(&p[2 * nd]);
  float4 s3 = *reinterpret_cast<const float4*>(&p[3 * nd]);
  float4 r = {s0.x + s1.x + s2.x + s3.x, s0.y + s1.y + s2.y + s3.y,
              s0.z + s1.z + s2.z + s3.z, s0.w + s1.w + s2.w + s3.w};
  *reinterpret_cast<float4*>(&out[i]) = r;
}

// ---------------------------------------------------------------------------
extern "C" void kernel_launch(void* const* d_in, const int* in_sizes, int n_in,
                              void* d_out, int out_size, void* d_ws, size_t ws_size,
                              hipStream_t stream)
{
  const float* tgt   = (const float*)d_in[0];
  const float* mtxt  = (const float*)d_in[1];
  const float* vox   = (const float*)d_in[2];
  const float* qpos  = (const float*)d_in[3];
  const int*   mtx_m = (const int*)d_in[4];
  const int*   vox_m = (const int*)d_in[5];
  const float* Wq = (const float*)d_in[6];  const float* bq = (const float*)d_in[7];
  const float* Wk = (const float*)d_in[8];  const float* bk = (const float*)d_in[9];
  const float* Wv = (const float*)d_in[10]; const float* bv = (const float*)d_in[11];
  const float* Wo = (const float*)d_in[12]; const float* bo = (const float*)d_in[13];
  const float* W1 = (const float*)d_in[14]; const float* b1 = (const float*)d_in[15];
  const float* W2 = (const float*)d_in[16]; const float* b2 = (const float*)d_in[17];
  const float* ln1g = (const float*)d_in[18]; const float* ln1b = (const float*)d_in[19];
  const float* ln2g = (const float*)d_in[20]; const float* ln2b = (const float*)d_in[21];

  float* out0 = (float*)d_out;                       // attn_output  [B,NQ,D]
  float* out1 = out0 + (long long)B * NQ * D;        // txt_cross    [B,NQ,LT]
  float* out2 = out1 + (long long)B * NQ * LT;       // attn_weights [B,NQ,NV]

  char* base = (char*)d_ws;
  constexpr size_t MB = 1ull << 20;
  u16*   kvW   = (u16*)(base + 0 * MB);     // 16  [Wk;Wv] stacked
  u16*   Wq_b  = (u16*)(base + 16 * MB);    // 2
  u16*   Wo_b  = (u16*)(base + 18 * MB);    // 2
  u16*   W1_b  = (u16*)(base + 20 * MB);    // 4
  u16*   W2_b  = (u16*)(base + 24 * MB);    // 4
  u16*   tq_b  = (u16*)(base + 28 * MB);    // 4
  u16*   q_b   = (u16*)(base + 32 * MB);    // 4
  u16*   kv_b  = (u16*)(base + 36 * MB);    // 16  [B*LT][2048]
  u16*   vT_b  = (u16*)(base + 52 * MB);    // 8
  u16*   ctx_b = (u16*)(base + 60 * MB);    // 4
  float* x1p   = (float*)(base + 64 * MB);  // 8
  float* x1f   = (float*)(base + 72 * MB);  // 8
  u16*   x1_b  = (u16*)(base + 80 * MB);    // 4
  u16*   ff1_b = (u16*)(base + 84 * MB);    // 8
  float* x2p   = (float*)(base + 92 * MB);  // 8
  u16*   x2s_b = (u16*)(base + 100 * MB);   // 4
  u16*   mtxt_b = (u16*)(base + 104 * MB);  // 32  dead after kv256b
  u16*   scb   = (u16*)(base + 136 * MB);   // 32  bf16 scores, dead after softmax
  u16*   w_b    = (u16*)(base + 200 * MB);  // 32  dead after ctx gemm
  u16*   vox_b  = (u16*)(base + 104 * MB);  // 64  overlays mtxt_b + scb head
  u16*   voxT_b = (u16*)(base + 168 * MB);  // 64  overlays scb tail + w_b
  u16*   wvox_b = (u16*)(base + 0 * MB);    // 16  overlays kvW (dead)
  float* part   = (float*)(base + 16 * MB); // 32  overlays Wq..q_b (dead)

  const dim3 blk(256);
  const long long sQ = (long long)NQ * D;
  const long long sSC = (long long)NQ * LT;
  const long long nd = (long long)NQ * D;

  // 1) conversions: fused weights + memory_txt; tq = tgt + qpos
  Cvt7 ca;
  ca.s[0] = Wq;   ca.d[0] = Wq_b;
  ca.s[1] = Wk;   ca.d[1] = kvW;
  ca.s[2] = Wv;   ca.d[2] = kvW + (long long)D * FTXT;
  ca.s[3] = Wo;   ca.d[3] = Wo_b;
  ca.s[4] = W1;   ca.d[4] = W1_b;
  ca.s[5] = W2;   ca.d[5] = W2_b;
  ca.s[6] = mtxt; ca.d[6] = mtxt_b;
  ca.cum[0] = 0;     ca.cum[1] = 1024;  ca.cum[2] = 5120;  ca.cum[3] = 9216;
  ca.cum[4] = 10240; ca.cum[5] = 12288; ca.cum[6] = 14336; ca.cum[7] = 30720;
  cvt_multi<<<dim3(30720), blk, 0, stream>>>(ca);
  cvt_add_bf16<<<dim3((B * NQ * D) / 1024), blk, 0, stream>>>(tgt, qpos, tq_b);

  // 2) q projection (2-phase) + kv projection (merged-phase, full K)
  gemm_bf16<64,64,2,2, E_BIAS|E_WB16><<<dim3(D/64, (B*NQ)/64, 1), blk, 0, stream>>>(
      tq_b, Wq_b, bq, nullptr, nullptr, q_b, D, D, D, D, 1, 0,0,0,0,0,0, 1.f);
  gemm_kv256b<<<dim3(16, 16), dim3(512), 0, stream>>>(mtxt_b, kvW, bk, bv, kv_b);

  // 3) vT[b][d][l] = v[b][l][d]
  transpose_u16<<<dim3(D/32, LT/32, B), blk, 0, stream>>>(
      kv_b + 1024, vT_b, LT, D, 2048, (long long)LT * 2048, (long long)D * LT);

  // 4) scores = q . k / 8  -> bf16
  gemm_bf16<128,128,2,2, E_WB16><<<dim3(LT/128, NQ/128, B*H), blk, 0, stream>>>(
      q_b, kv_b, nullptr, nullptr, nullptr, scb, HD, D, 2048, LT, H,
      sQ, HD, (long long)LT * 2048, HD, (long long)H * sSC, sSC, 0.125f);

  // 5) fused softmax + head-mean (bf16 scores in)
  txt_softmax_mean<<<dim3(B*NQ), blk, 0, stream>>>(scb, mtx_m, w_b, out1);

  // 6) ctx = w_h @ v_h
  gemm_bf16<64,64,2,2, E_WB16><<<dim3(HD/64, NQ/64, B*H), blk, 0, stream>>>(
      w_b, vT_b, nullptr, nullptr, nullptr, ctx_b, LT, LT, LT, D, H,
      (long long)H * sSC, sSC, (long long)D * LT, (long long)HD * LT, sQ, HD, 1.f);

  // 7) vox -> vox_b + voxT_b (one f32 read)
  vox_prep<<<dim3(D/64, NV/64, B), blk, 0, stream>>>(vox, vox_b, voxT_b);

  // 8) x1p = tgt + ctx @ Wo^T + bo
  gemm_bf16<64,64,2,2, E_BIAS|E_RES|E_WF32><<<dim3(D/64, (B*NQ)/64, 1), blk, 0, stream>>>(
      ctx_b, Wo_b, bo, tgt, x1p, nullptr, D, D, D, D, 1, 0,0,0,0,0,0, 1.f);

  // 9) LN1
  ln_kernel<<<dim3(B*NQ), blk, 0, stream>>>(x1p, ln1g, ln1b, x1f, x1_b, 1.f);

  // 10) ff1 = relu(x1 @ W1^T + b1)
  gemm_bf16<128,64,2,2, E_BIAS|E_RELU|E_WB16><<<dim3(DFF/64, (B*NQ)/128, 1), blk, 0, stream>>>(
      x1_b, W1_b, b1, nullptr, nullptr, ff1_b, D, D, D, DFF, 1, 0,0,0,0,0,0, 1.f);

  // 11) x2p = x1 + ff1 @ W2^T + b2
  gemm_bf16<64,64,2,2, E_BIAS|E_RES|E_WF32><<<dim3(D/64, (B*NQ)/64, 1), blk, 0, stream>>>(
      ff1_b, W2_b, b2, x1f, x2p, nullptr, DFF, DFF, DFF, D, 1, 0,0,0,0,0,0, 1.f);

  // 12) LN2 -> x2s (bf16, /sqrt(D))
  ln_kernel<<<dim3(B*NQ), blk, 0, stream>>>(x2p, ln2g, ln2b, nullptr, x2s_b, 0.03125f);

  // 13) out2 = x2s @ vox_b^T  (deep-B 8-phase)
  gemm8<1><<<dim3(NV/128, 1, B), dim3(512), 0, stream>>>(
      x2s_b, vox_b, out2, D, D, D, NV, 0,
      sQ, (long long)NV * D, (long long)NQ * NV, 0);

  // 14) masked softmax in place; bf16 weights
  vox_softmax<<<dim3(B*NQ), blk, 0, stream>>>(out2, vox_m, wvox_b);

  // 15) out0 partials: deep-B 8-phase split-K=4 + reduce
  gemm8<4><<<dim3(D/128, 1, B*4), dim3(512), 0, stream>>>(
      wvox_b, voxT_b, part, NV/4, NV, NV, D, NV/4,
      (long long)NQ * NV, (long long)D * NV, 4 * nd, nd);
  splitk_reduce<<<dim3((B * NQ * D) / 1024), blk, 0, stream>>>(part, out0);
}

// Round 14
// 401.661 us; speedup vs baseline: 1.2740x; 1.0054x over previous
//
#include <hip/hip_runtime.h>
#include <math.h>

typedef unsigned short u16;
typedef unsigned int u32;
typedef __bf16 bf16x8 __attribute__((ext_vector_type(8)));
typedef float f32x4 __attribute__((ext_vector_type(4)));
typedef u16 u16x4 __attribute__((ext_vector_type(4)));
typedef u16 u16x2 __attribute__((ext_vector_type(2)));

constexpr int B = 8, NQ = 256, LT = 512, NV = 4096;
constexpr int D = 1024, H = 16, DFF = 2048, FTXT = 4096, HD = 64;

__device__ __forceinline__ u16 f2b(float f) {
  u32 u = __builtin_bit_cast(u32, f);
  return (u16)((u + 0x7fffu + ((u >> 16) & 1u)) >> 16);   // RNE
}
__device__ __forceinline__ float b2f(u16 b) {
  u32 u = ((u32)b) << 16;
  return __builtin_bit_cast(float, u);
}
__device__ __forceinline__ void gload16(const void* g, void* l) {
  __builtin_amdgcn_global_load_lds(
      (const __attribute__((address_space(1))) u32*)g,
      (__attribute__((address_space(3))) u32*)l, 16, 0, 0);
}

// ===========================================================================
// Merged-phase 256x128 schedule (R13-verified): one phase per k-tile.
// LDS 144 KiB: A 3 slabs [256][64], B 3 slabs [128][64] (mod-3 rotation),
// XOR-swizzle slot^(row&7). Per phase: 20 ds_read_b128, stage tile t+2
// (6 gloads), 32 MFMA, ONE vmcnt(6) + ONE barrier. Prologue 12 -> vmcnt(6).
// ===========================================================================

// --- KV projection: full K=4096, bf16 out + bias (R13, unchanged) ---
__global__ __launch_bounds__(512, 2)
void gemm_kv256b(const u16* __restrict__ A, const u16* __restrict__ Bw,
                 const float* __restrict__ bk_, const float* __restrict__ bv_,
                 u16* __restrict__ Cb)
{
  __shared__ __align__(16) u16 As[3 * 16384];
  __shared__ __align__(16) u16 Bs[3 * 8192];

  const int gx = 16;
  const int flat = blockIdx.y * gx + blockIdx.x;
  const int qq = 256 >> 3;
  const int xcd = flat & 7, lid = flat >> 3;
  const int wg = xcd * qq + lid;
  const int bx = wg % gx;
  const int by = wg / gx;
  const int m0 = by * 256, n0 = bx * 128;
  const float* bias = (n0 < 1024) ? (bk_ + n0) : (bv_ + (n0 - 1024));

  const int t = threadIdx.x;
  const int w = t >> 6, l = t & 63;
  const int wr64 = (w >> 2) * 64;
  const int wc32 = (w & 3) * 32;
  const int l15 = l & 15, l4 = l >> 4, l7 = l & 7;

  auto stA = [&](int slab, int tile) {
    const long long kk = (long long)tile * 64 + (((t & 7) ^ ((t >> 3) & 7)) * 8);
    #pragma unroll
    for (int i = 0; i < 4; ++i)
      gload16(&A[(long long)(m0 + (t >> 3) + 64 * i) * 4096 + kk],
              &As[slab * 16384 + (w * 8 + 64 * i) * 64]);
  };
  auto stB = [&](int slab, int tile) {
    const long long kk = (long long)tile * 64 + (((t & 7) ^ ((t >> 3) & 7)) * 8);
    #pragma unroll
    for (int i = 0; i < 2; ++i)
      gload16(&Bw[(long long)(n0 + (t >> 3) + 64 * i) * 4096 + kk],
              &Bs[slab * 8192 + (w * 8 + 64 * i) * 64]);
  };

#define RDA(sl,qm,fm,ks) \
  (*reinterpret_cast<const bf16x8*>(&As[(sl)*16384 + \
      ((qm)*128 + wr64 + (fm)*16 + l15)*64 + ((((ks)*4 + l4) ^ l7) * 8)]))
#define RDB(sl,fn,ks) \
  (*reinterpret_cast<const bf16x8*>(&Bs[(sl)*8192 + \
      (wc32 + (fn)*16 + l15)*64 + ((((ks)*4 + l4) ^ l7) * 8)]))

  f32x4 acc[2][4][2] = {};
  bf16x8 a_[2][4][2];
  bf16x8 b_[2][2];

#define BAR asm volatile("s_barrier" ::: "memory")
#define WAIT6 asm volatile("s_waitcnt vmcnt(6)" ::: "memory")
#define WAIT0 asm volatile("s_waitcnt vmcnt(0)" ::: "memory")

  stA(0, 0); stB(0, 0);
  stA(1, 1); stB(1, 1);
  WAIT6;
  BAR;

  int s0 = 0, s1 = 1, s2 = 2;
  for (int tt = 0; tt < 64; ++tt) {
    #pragma unroll
    for (int qm = 0; qm < 2; ++qm)
      #pragma unroll
      for (int fm = 0; fm < 4; ++fm) {
        a_[qm][fm][0] = RDA(s0, qm, fm, 0);
        a_[qm][fm][1] = RDA(s0, qm, fm, 1);
      }
    b_[0][0] = RDB(s0, 0, 0); b_[0][1] = RDB(s0, 0, 1);
    b_[1][0] = RDB(s0, 1, 0); b_[1][1] = RDB(s0, 1, 1);

    if (tt < 62) { stA(s2, tt + 2); stB(s2, tt + 2); }

    __builtin_amdgcn_s_setprio(1);
    #pragma unroll
    for (int qm = 0; qm < 2; ++qm)
      #pragma unroll
      for (int fm = 0; fm < 4; ++fm)
        #pragma unroll
        for (int fn = 0; fn < 2; ++fn) {
          acc[qm][fm][fn] = __builtin_amdgcn_mfma_f32_16x16x32_bf16(
              a_[qm][fm][0], b_[fn][0], acc[qm][fm][fn], 0, 0, 0);
          acc[qm][fm][fn] = __builtin_amdgcn_mfma_f32_16x16x32_bf16(
              a_[qm][fm][1], b_[fn][1], acc[qm][fm][fn], 0, 0, 0);
        }
    __builtin_amdgcn_s_setprio(0);

    if (tt < 62)       { WAIT6; }
    else if (tt == 62) { WAIT0; }
    BAR;

    const int tmp = s0; s0 = s1; s1 = s2; s2 = tmp;
  }
#undef RDA
#undef RDB
#undef BAR
#undef WAIT6
#undef WAIT0

  #pragma unroll
  for (int qm = 0; qm < 2; ++qm)
    #pragma unroll
    for (int fm = 0; fm < 4; ++fm)
      #pragma unroll
      for (int r = 0; r < 4; ++r) {
        const long long row = m0 + qm * 128 + wr64 + fm * 16 + l4 * 4 + r;
        #pragma unroll
        for (int fn = 0; fn < 2; ++fn) {
          const int lc = wc32 + fn * 16 + l15;
          Cb[row * 2048 + n0 + lc] = f2b(acc[qm][fm][fn][r] + bias[lc]);
        }
      }
}

// --- Generalized merged-phase 256x128: C f32 = A@Bw^T, batch + split-K.
//     Ksub must be a multiple of 128 (nt = Ksub/64 >= 2). ---
template<int NZ2>
__global__ __launch_bounds__(512, 2)
void gemm8(const u16* __restrict__ A, const u16* __restrict__ Bw,
           float* __restrict__ C,
           int Ksub, int lda, int ldb, int ldc, int kstep,
           long long sA1, long long sB1, long long sC1, long long sC2)
{
  __shared__ __align__(16) u16 As[3 * 16384];
  __shared__ __align__(16) u16 Bs[3 * 8192];

  const int gx = gridDim.x, gy = gridDim.y;
  const int nwg = gx * gy * gridDim.z;
  const int flat = (blockIdx.z * gy + blockIdx.y) * gx + blockIdx.x;
  const int qq = nwg >> 3, rr = nwg & 7;
  const int xcd = flat & 7, lid = flat >> 3;
  const int wg = (xcd < rr ? xcd * (qq + 1) : rr * (qq + 1) + (xcd - rr) * qq) + lid;
  const int bx = wg % gx;
  const int tmp1 = wg / gx;
  const int by = tmp1 % gy, bz = tmp1 / gy;
  const int z1 = bz / NZ2, z2 = bz % NZ2;
  const int m0 = by * 256, n0 = bx * 128;
  const long long kbase = (long long)z2 * kstep;
  const u16* Ab = A + (long long)z1 * sA1;
  const u16* Bb = Bw + (long long)z1 * sB1;
  float* Cp = C + (long long)z1 * sC1 + (long long)z2 * sC2;

  const int t = threadIdx.x;
  const int w = t >> 6, l = t & 63;
  const int wr64 = (w >> 2) * 64;
  const int wc32 = (w & 3) * 32;
  const int l15 = l & 15, l4 = l >> 4, l7 = l & 7;

  auto stA = [&](int slab, int tile) {
    const long long kk = kbase + (long long)tile * 64 + (((t & 7) ^ ((t >> 3) & 7)) * 8);
    #pragma unroll
    for (int i = 0; i < 4; ++i)
      gload16(&Ab[(long long)(m0 + (t >> 3) + 64 * i) * lda + kk],
              &As[slab * 16384 + (w * 8 + 64 * i) * 64]);
  };
  auto stB = [&](int slab, int tile) {
    const long long kk = kbase + (long long)tile * 64 + (((t & 7) ^ ((t >> 3) & 7)) * 8);
    #pragma unroll
    for (int i = 0; i < 2; ++i)
      gload16(&Bb[(long long)(n0 + (t >> 3) + 64 * i) * ldb + kk],
              &Bs[slab * 8192 + (w * 8 + 64 * i) * 64]);
  };

#define RDA(sl,qm,fm,ks) \
  (*reinterpret_cast<const bf16x8*>(&As[(sl)*16384 + \
      ((qm)*128 + wr64 + (fm)*16 + l15)*64 + ((((ks)*4 + l4) ^ l7) * 8)]))
#define RDB(sl,fn,ks) \
  (*reinterpret_cast<const bf16x8*>(&Bs[(sl)*8192 + \
      (wc32 + (fn)*16 + l15)*64 + ((((ks)*4 + l4) ^ l7) * 8)]))

  f32x4 acc[2][4][2] = {};
  bf16x8 a_[2][4][2];
  bf16x8 b_[2][2];

#define BAR asm volatile("s_barrier" ::: "memory")
#define WAIT6 asm volatile("s_waitcnt vmcnt(6)" ::: "memory")
#define WAIT0 asm volatile("s_waitcnt vmcnt(0)" ::: "memory")

  stA(0, 0); stB(0, 0);
  stA(1, 1); stB(1, 1);
  WAIT6;
  BAR;

  const int nt = Ksub >> 6;
  int s0 = 0, s1 = 1, s2 = 2;
  for (int tt = 0; tt < nt; ++tt) {
    #pragma unroll
    for (int qm = 0; qm < 2; ++qm)
      #pragma unroll
      for (int fm = 0; fm < 4; ++fm) {
        a_[qm][fm][0] = RDA(s0, qm, fm, 0);
        a_[qm][fm][1] = RDA(s0, qm, fm, 1);
      }
    b_[0][0] = RDB(s0, 0, 0); b_[0][1] = RDB(s0, 0, 1);
    b_[1][0] = RDB(s0, 1, 0); b_[1][1] = RDB(s0, 1, 1);

    if (tt < nt - 2) { stA(s2, tt + 2); stB(s2, tt + 2); }

    __builtin_amdgcn_s_setprio(1);
    #pragma unroll
    for (int qm = 0; qm < 2; ++qm)
      #pragma unroll
      for (int fm = 0; fm < 4; ++fm)
        #pragma unroll
        for (int fn = 0; fn < 2; ++fn) {
          acc[qm][fm][fn] = __builtin_amdgcn_mfma_f32_16x16x32_bf16(
              a_[qm][fm][0], b_[fn][0], acc[qm][fm][fn], 0, 0, 0);
          acc[qm][fm][fn] = __builtin_amdgcn_mfma_f32_16x16x32_bf16(
              a_[qm][fm][1], b_[fn][1], acc[qm][fm][fn], 0, 0, 0);
        }
    __builtin_amdgcn_s_setprio(0);

    if (tt < nt - 2)       { WAIT6; }
    else if (tt == nt - 2) { WAIT0; }
    BAR;

    const int tmp = s0; s0 = s1; s1 = s2; s2 = tmp;
  }
#undef RDA
#undef RDB
#undef BAR
#undef WAIT6
#undef WAIT0

  #pragma unroll
  for (int qm = 0; qm < 2; ++qm)
    #pragma unroll
    for (int fm = 0; fm < 4; ++fm)
      #pragma unroll
      for (int r = 0; r < 4; ++r) {
        const long long row = m0 + qm * 128 + wr64 + fm * 16 + l4 * 4 + r;
        #pragma unroll
        for (int fn = 0; fn < 2; ++fn) {
          const int lc = wc32 + fn * 16 + l15;
          Cp[row * (long long)ldc + n0 + lc] = acc[qm][fm][fn][r];
        }
      }
}

// ---------------------------------------------------------------------------
// 2-phase bf16 MFMA GEMM (bf16 B via global_load_lds only).
// ---------------------------------------------------------------------------
constexpr int E_BIAS = 1, E_RES = 2, E_RELU = 4, E_WF32 = 8, E_WB16 = 16;

template<int BM, int BN, int WM, int WN, int EPI>
__global__ __launch_bounds__(256)
void gemm_bf16(const u16* __restrict__ A, const u16* __restrict__ Bw,
               const float* __restrict__ bias, const float* __restrict__ res,
               float* __restrict__ C, u16* __restrict__ Cb,
               int K, int lda, int ldb, int ldc, int nbz2,
               long long sA1, long long sA2, long long sB1, long long sB2,
               long long sC1, long long sC2, float alpha)
{
  constexpr int SM = BM / WM, SN = BN / WN;
  constexpr int FM = SM / 16, FN = SN / 16;
  constexpr int PA = BM / 64, PB = BN / 64;
  __shared__ __align__(16) u16 As[2][BM * 32];
  __shared__ __align__(16) u16 Bs[2][BN * 32];

  const int gx = gridDim.x, gy = gridDim.y;
  const int nwg = gx * gy * gridDim.z;
  const int flat = (blockIdx.z * gy + blockIdx.y) * gx + blockIdx.x;
  const int qq = nwg >> 3, rr = nwg & 7;
  const int xcd = flat & 7, lid = flat >> 3;
  const int wg = (xcd < rr ? xcd * (qq + 1) : rr * (qq + 1) + (xcd - rr) * qq) + lid;
  const int bx = wg % gx;
  const int tmp1 = wg / gx;
  const int by = tmp1 % gy, bz = tmp1 / gy;

  const int t = threadIdx.x;
  const int w = t >> 6, l = t & 63;
  const int wr = w / WN, wc = w % WN;
  const int m0 = by * BM, n0 = bx * BN;
  const long long offA = (long long)(bz / nbz2) * sA1 + (long long)(bz % nbz2) * sA2;
  const long long offB = (long long)(bz / nbz2) * sB1 + (long long)(bz % nbz2) * sB2;
  const long long offC = (long long)(bz / nbz2) * sC1 + (long long)(bz % nbz2) * sC2;
  const u16* Ab = A + offA;
  const u16* Bb = Bw + offB;

  const int srow = t >> 2;
  const int sk   = (t & 3) * 8;

  auto stageA = [&](int buf, int k0) {
    #pragma unroll
    for (int p = 0; p < PA; ++p)
      gload16(&Ab[(long long)(m0 + p * 64 + srow) * lda + k0 + sk],
              &As[buf][p * 2048 + w * 512]);
  };
  auto stageB = [&](int buf, int k0) {
    #pragma unroll
    for (int p = 0; p < PB; ++p)
      gload16(&Bb[(long long)(n0 + p * 64 + srow) * ldb + k0 + sk],
              &Bs[buf][p * 2048 + w * 512]);
  };

  f32x4 acc[FM][FN] = {};

  stageA(0, 0);
  stageB(0, 0);

  int cur = 0;
  for (int k0 = 0; k0 < K; k0 += 32) {
    __syncthreads();
    const bool pf = (k0 + 32 < K);
    if (pf) {
      stageA(cur ^ 1, k0 + 32);
      stageB(cur ^ 1, k0 + 32);
    }

    bf16x8 af[FM], bfr[FN];
    #pragma unroll
    for (int i = 0; i < FM; ++i)
      af[i] = *reinterpret_cast<const bf16x8*>(
          &As[cur][(wr * SM + i * 16 + (l & 15)) * 32 + (l >> 4) * 8]);
    #pragma unroll
    for (int j = 0; j < FN; ++j)
      bfr[j] = *reinterpret_cast<const bf16x8*>(
          &Bs[cur][(wc * SN + j * 16 + (l & 15)) * 32 + (l >> 4) * 8]);
    #pragma unroll
    for (int i = 0; i < FM; ++i)
      #pragma unroll
      for (int j = 0; j < FN; ++j)
        acc[i][j] = __builtin_amdgcn_mfma_f32_16x16x32_bf16(af[i], bfr[j], acc[i][j], 0, 0, 0);
    cur ^= 1;
  }

  const int c_l = l & 15, r_l4 = (l >> 4) * 4;
  #pragma unroll
  for (int i = 0; i < FM; ++i) {
    #pragma unroll
    for (int r = 0; r < 4; ++r) {
      const long long row = m0 + wr * SM + i * 16 + r_l4 + r;
      #pragma unroll
      for (int j = 0; j < FN; ++j) {
        const int col = n0 + wc * SN + j * 16 + c_l;
        float v = acc[i][j][r] * alpha;
        if (EPI & E_BIAS) v += bias[col];
        if (EPI & E_RES)  v += res[row * (long long)ldc + col];
        if (EPI & E_RELU) v = fmaxf(v, 0.f);
        const long long co = offC + row * (long long)ldc + col;
        if (EPI & E_WF32) C[co] = v;
        if (EPI & E_WB16) Cb[co] = f2b(v);
      }
    }
  }
}

// ---------------------------------------------------------------------------
// vox f32 [B][NV][D] -> vb bf16 [B][NV][D]  AND  vt bf16 [B][D][NV]
// ---------------------------------------------------------------------------
__global__ __launch_bounds__(256)
void vox_prep(const float* __restrict__ in, u16* __restrict__ vb,
              u16* __restrict__ vt)
{
  __shared__ u16 tile[64][68];
  const int b = blockIdx.z;
  const int n0 = blockIdx.y * 64;
  const int d0 = blockIdx.x * 64;
  const int t = threadIdx.x;
  const int tr = t >> 4;
  const int tc = (t & 15) * 4;
  const float* ib = in + (long long)b * NV * D;
  u16* vbb = vb + (long long)b * NV * D;
  u16* vtb = vt + (long long)b * NV * D;
  #pragma unroll
  for (int p = 0; p < 4; ++p) {
    int r = tr + p * 16;
    float4 x = *reinterpret_cast<const float4*>(&ib[(long long)(n0 + r) * D + d0 + tc]);
    u16x4 o = {f2b(x.x), f2b(x.y), f2b(x.z), f2b(x.w)};
    *reinterpret_cast<u16x4*>(&vbb[(long long)(n0 + r) * D + d0 + tc]) = o;
    *reinterpret_cast<u16x4*>(&tile[r][tc]) = o;
  }
  __syncthreads();
  #pragma unroll
  for (int p = 0; p < 4; ++p) {
    int c = tr + p * 16;
    u16x4 o = {tile[tc + 0][c], tile[tc + 1][c], tile[tc + 2][c], tile[tc + 3][c]};
    *reinterpret_cast<u16x4*>(&vtb[(long long)(d0 + c) * NV + n0 + tc]) = o;
  }
}

// ---------------------------------------------------------------------------
struct Cvt7 { const float* s[7]; u16* d[7]; int cum[8]; };

__global__ __launch_bounds__(256)
void cvt_multi(Cvt7 a)
{
  const int bidx = blockIdx.x;
  int seg = 0;
  #pragma unroll
  for (int k = 1; k < 7; ++k) if (bidx >= a.cum[k]) seg = k;
  const long long off = ((long long)(bidx - a.cum[seg]) * 256 + threadIdx.x) * 4;
  float4 x = *reinterpret_cast<const float4*>(a.s[seg] + off);
  u16x4 o = {f2b(x.x), f2b(x.y), f2b(x.z), f2b(x.w)};
  *reinterpret_cast<u16x4*>(a.d[seg] + off) = o;
}

__global__ __launch_bounds__(256)
void cvt_add_bf16(const float* __restrict__ a, const float* __restrict__ b,
                  u16* __restrict__ out)
{
  const long long i = ((long long)blockIdx.x * 256 + threadIdx.x) * 4;
  float4 x = *reinterpret_cast<const float4*>(&a[i]);
  float4 y = *reinterpret_cast<const float4*>(&b[i]);
  u16x4 o = {f2b(x.x + y.x), f2b(x.y + y.y), f2b(x.z + y.z), f2b(x.w + y.w)};
  *reinterpret_cast<u16x4*>(&out[i]) = o;
}

__global__ __launch_bounds__(256)
void transpose_u16(const u16* __restrict__ in, u16* __restrict__ out,
                   int R, int C, int ldin, long long sbin, long long sbout)
{
  __shared__ u16 tile[32][34];
  const int b = blockIdx.z;
  const int r0 = blockIdx.y * 32, c0 = blockIdx.x * 32;
  const int tx = threadIdx.x & 31, ty = threadIdx.x >> 5;
  const u16* ib = in + (long long)b * sbin;
  u16* ob = out + (long long)b * sbout;
  #pragma unroll
  for (int p = 0; p < 4; ++p) {
    int r = ty + p * 8;
    tile[r][tx] = ib[(long long)(r0 + r) * ldin + c0 + tx];
  }
  __syncthreads();
  #pragma unroll
  for (int p = 0; p < 4; ++p) {
    int c = ty + p * 8;
    ob[(long long)(c0 + c) * R + r0 + tx] = tile[tx][c];
  }
}

// ---------------------------------------------------------------------------
__global__ __launch_bounds__(256)
void txt_softmax_mean(const u16* __restrict__ sc, const int* __restrict__ mask,
                      u16* __restrict__ wout, float* __restrict__ out1)
{
  __shared__ float red[8];
  const int t = threadIdx.x, l = t & 63, w = t >> 6;
  const int bq = blockIdx.x;
  const int b = bq >> 8, q = bq & 255;
  const int* mr = mask + b * LT;
  const int2 mm = *reinterpret_cast<const int2*>(&mr[2 * t]);
  const bool msk0 = mm.x != 0, msk1 = mm.y != 0;
  float a0 = 0.f, a1 = 0.f;
  for (int h = 0; h < H; ++h) {
    const long long ro = (((long long)(b * H + h)) * NQ + q) * LT;
    const u16* sr = sc + ro;
    const u16x2 sv = *reinterpret_cast<const u16x2*>(&sr[2 * t]);
    float x0 = msk0 ? -INFINITY : b2f(sv[0]);
    float x1 = msk1 ? -INFINITY : b2f(sv[1]);
    float mx = fmaxf(x0, x1);
    #pragma unroll
    for (int o = 32; o > 0; o >>= 1) mx = fmaxf(mx, __shfl_xor(mx, o, 64));
    if (l == 0) red[w] = mx;
    __syncthreads();
    mx = fmaxf(fmaxf(red[0], red[1]), fmaxf(red[2], red[3]));
    float e0 = __expf(x0 - mx), e1 = __expf(x1 - mx);
    float s = e0 + e1;
    #pragma unroll
    for (int o = 32; o > 0; o >>= 1) s += __shfl_xor(s, o, 64);
    if (l == 0) red[4 + w] = s;
    __syncthreads();
    s = red[4] + red[5] + red[6] + red[7];
    const float inv = 1.f / s;
    const float w0 = e0 * inv, w1 = e1 * inv;
    u16x2 wv = {f2b(w0), f2b(w1)};
    *reinterpret_cast<u16x2*>(&wout[ro + 2 * t]) = wv;
    a0 += w0; a1 += w1;
  }
  float2 o2 = {a0 * (1.f / H), a1 * (1.f / H)};
  *reinterpret_cast<float2*>(&out1[(long long)bq * LT + 2 * t]) = o2;
}

// ---------------------------------------------------------------------------
__global__ __launch_bounds__(256)
void ln_kernel(const float* __restrict__ x, const float* __restrict__ g,
               const float* __restrict__ bia, float* __restrict__ y,
               u16* __restrict__ yb, float scale)
{
  __shared__ float tmp[256];
  const int t = threadIdx.x;
  const long long off = (long long)blockIdx.x * D;
  float4 x4 = *reinterpret_cast<const float4*>(&x[off + t * 4]);
  tmp[t] = x4.x + x4.y + x4.z + x4.w;
  __syncthreads();
  for (int o = 128; o > 0; o >>= 1) { if (t < o) tmp[t] += tmp[t + o]; __syncthreads(); }
  const float mean = tmp[0] * (1.f / D);
  __syncthreads();
  float d0 = x4.x - mean, d1 = x4.y - mean, d2 = x4.z - mean, d3 = x4.w - mean;
  tmp[t] = d0 * d0 + d1 * d1 + d2 * d2 + d3 * d3;
  __syncthreads();
  for (int o = 128; o > 0; o >>= 1) { if (t < o) tmp[t] += tmp[t + o]; __syncthreads(); }
  const float rs = rsqrtf(tmp[0] * (1.f / D) + 1e-5f);
  float4 g4 = *reinterpret_cast<const float4*>(&g[t * 4]);
  float4 b4 = *reinterpret_cast<const float4*>(&bia[t * 4]);
  float o0 = (d0 * rs * g4.x + b4.x) * scale;
  float o1 = (d1 * rs * g4.y + b4.y) * scale;
  float o2 = (d2 * rs * g4.z + b4.z) * scale;
  float o3 = (d3 * rs * g4.w + b4.w) * scale;
  if (y) {
    float4 o4 = {o0, o1, o2, o3};
    *reinterpret_cast<float4*>(&y[off + t * 4]) = o4;
  }
  if (yb) {
    u16x4 ob = {f2b(o0), f2b(o1), f2b(o2), f2b(o3)};
    *reinterpret_cast<u16x4*>(&yb[off + t * 4]) = ob;
  }
}

// ---------------------------------------------------------------------------
__global__ __launch_bounds__(256)
void vox_softmax(float* __restrict__ s, const int* __restrict__ mask,
                 u16* __restrict__ wb)
{
  __shared__ float tmp[256];
  const int t = threadIdx.x;
  const int row = blockIdx.x, b = row / NQ;
  float* sr = s + (long long)row * NV;
  u16* wr = wb + (long long)row * NV;
  const int* mr = mask + b * NV;
  float vals[16];
  float lm = -INFINITY;
  #pragma unroll
  for (int j = 0; j < 16; ++j) {
    int n = t + j * 256;
    float x = mr[n] ? -INFINITY : sr[n];
    vals[j] = x;
    lm = fmaxf(lm, x);
  }
  tmp[t] = lm;
  __syncthreads();
  for (int o = 128; o > 0; o >>= 1) { if (t < o) tmp[t] = fmaxf(tmp[t], tmp[t + o]); __syncthreads(); }
  const float mx = tmp[0];
  __syncthreads();
  float ls = 0.f;
  #pragma unroll
  for (int j = 0; j < 16; ++j) { vals[j] = __expf(vals[j] - mx); ls += vals[j]; }
  tmp[t] = ls;
  __syncthreads();
  for (int o = 128; o > 0; o >>= 1) { if (t < o) tmp[t] += tmp[t + o]; __syncthreads(); }
  const float inv = 1.f / tmp[0];
  #pragma unroll
  for (int j = 0; j < 16; ++j) {
    float v = vals[j] * inv;
    sr[t + j * 256] = v;
    wr[t + j * 256] = f2b(v);
  }
}

__global__ __launch_bounds__(256)
void splitk_reduce(const float* __restrict__ part, float* __restrict__ out)
{
  const long long i = ((long long)blockIdx.x * 256 + threadIdx.x) * 4;
  const long long nd = (long long)NQ * D;
  const long long b = i / nd;
  const long long o = i - b * nd;
  const float* p = part + b * 4 * nd + o;
  float4 s0 = *reinterpret_cast<const float4*>(&p[0]);
  float4 s1 = *reinterpret_cast<const float4*>(&p[nd]);
  float4 s2 = *reinterpret_cast<const float4*>(&p[2 * nd]);
  float4 s3 = *reinterpret_cast<const float4*>(&p[3 * nd]);
  float4 r = {s0.x + s1.x + s2.x + s3.x, s0.y + s1.y + s2.y + s3.y,
              s0.z + s1.z + s2.z + s3.z, s0.w + s1.w + s2.w + s3.w};
  *reinterpret_cast<float4*>(&out[i]) = r;
}

// ---------------------------------------------------------------------------
extern "C" void kernel_launch(void* const* d_in, const int* in_sizes, int n_in,
                              void* d_out, int out_size, void* d_ws, size_t ws_size,
                              hipStream_t stream)
{
  const float* tgt   = (const float*)d_in[0];
  const float* mtxt  = (const float*)d_in[1];
  const float* vox   = (const float*)d_in[2];
  const float* qpos  = (const float*)d_in[3];
  const int*   mtx_m = (const int*)d_in[4];
  const int*   vox_m = (const int*)d_in[5];
  const float* Wq = (const float*)d_in[6];  const float* bq = (const float*)d_in[7];
  const float* Wk = (const float*)d_in[8];  const float* bk = (const float*)d_in[9];
  const float* Wv = (const float*)d_in[10]; const float* bv = (const float*)d_in[11];
  const float* Wo = (const float*)d_in[12]; const float* bo = (const float*)d_in[13];
  const float* W1 = (const float*)d_in[14]; const float* b1 = (const float*)d_in[15];
  const float* W2 = (const float*)d_in[16]; const float* b2 = (const float*)d_in[17];
  const float* ln1g = (const float*)d_in[18]; const float* ln1b = (const float*)d_in[19];
  const float* ln2g = (const float*)d_in[20]; const float* ln2b = (const float*)d_in[21];

  float* out0 = (float*)d_out;                       // attn_output  [B,NQ,D]
  float* out1 = out0 + (long long)B * NQ * D;        // txt_cross    [B,NQ,LT]
  float* out2 = out1 + (long long)B * NQ * LT;       // attn_weights [B,NQ,NV]

  char* base = (char*)d_ws;
  constexpr size_t MB = 1ull << 20;
  u16*   kvW   = (u16*)(base + 0 * MB);     // 16  [Wk;Wv] stacked
  u16*   Wq_b  = (u16*)(base + 16 * MB);    // 2
  u16*   Wo_b  = (u16*)(base + 18 * MB);    // 2
  u16*   W1_b  = (u16*)(base + 20 * MB);    // 4
  u16*   W2_b  = (u16*)(base + 24 * MB);    // 4
  u16*   tq_b  = (u16*)(base + 28 * MB);    // 4
  u16*   q_b   = (u16*)(base + 32 * MB);    // 4
  u16*   kv_b  = (u16*)(base + 36 * MB);    // 16  [B*LT][2048]
  u16*   vT_b  = (u16*)(base + 52 * MB);    // 8
  u16*   ctx_b = (u16*)(base + 60 * MB);    // 4
  float* x1p   = (float*)(base + 64 * MB);  // 8
  float* x1f   = (float*)(base + 72 * MB);  // 8
  u16*   x1_b  = (u16*)(base + 80 * MB);    // 4
  u16*   ff1_b = (u16*)(base + 84 * MB);    // 8
  float* x2p   = (float*)(base + 92 * MB);  // 8
  u16*   x2s_b = (u16*)(base + 100 * MB);   // 4
  u16*   mtxt_b = (u16*)(base + 104 * MB);  // 32  dead after kv256b
  u16*   scb   = (u16*)(base + 136 * MB);   // 32  bf16 scores, dead after softmax
  u16*   w_b    = (u16*)(base + 200 * MB);  // 32  dead after ctx gemm
  u16*   vox_b  = (u16*)(base + 104 * MB);  // 64  overlays mtxt_b + scb head
  u16*   voxT_b = (u16*)(base + 168 * MB);  // 64  overlays scb tail + w_b
  u16*   wvox_b = (u16*)(base + 0 * MB);    // 16  overlays kvW (dead)
  float* part   = (float*)(base + 16 * MB); // 32  overlays Wq..q_b (dead)

  const dim3 blk(256);
  const long long sQ = (long long)NQ * D;
  const long long sSC = (long long)NQ * LT;
  const long long nd = (long long)NQ * D;

  // 1) conversions: fused weights + memory_txt; tq = tgt + qpos
  Cvt7 ca;
  ca.s[0] = Wq;   ca.d[0] = Wq_b;
  ca.s[1] = Wk;   ca.d[1] = kvW;
  ca.s[2] = Wv;   ca.d[2] = kvW + (long long)D * FTXT;
  ca.s[3] = Wo;   ca.d[3] = Wo_b;
  ca.s[4] = W1;   ca.d[4] = W1_b;
  ca.s[5] = W2;   ca.d[5] = W2_b;
  ca.s[6] = mtxt; ca.d[6] = mtxt_b;
  ca.cum[0] = 0;     ca.cum[1] = 1024;  ca.cum[2] = 5120;  ca.cum[3] = 9216;
  ca.cum[4] = 10240; ca.cum[5] = 12288; ca.cum[6] = 14336; ca.cum[7] = 30720;
  cvt_multi<<<dim3(30720), blk, 0, stream>>>(ca);
  cvt_add_bf16<<<dim3((B * NQ * D) / 1024), blk, 0, stream>>>(tgt, qpos, tq_b);

  // 2) q projection (2-phase) + kv projection (merged-phase, full K)
  gemm_bf16<64,64,2,2, E_BIAS|E_WB16><<<dim3(D/64, (B*NQ)/64, 1), blk, 0, stream>>>(
      tq_b, Wq_b, bq, nullptr, nullptr, q_b, D, D, D, D, 1, 0,0,0,0,0,0, 1.f);
  gemm_kv256b<<<dim3(16, 16), dim3(512), 0, stream>>>(mtxt_b, kvW, bk, bv, kv_b);

  // 3) vT[b][d][l] = v[b][l][d]
  transpose_u16<<<dim3(D/32, LT/32, B), blk, 0, stream>>>(
      kv_b + 1024, vT_b, LT, D, 2048, (long long)LT * 2048, (long long)D * LT);

  // 4) scores = q . k / 8  -> bf16
  gemm_bf16<128,128,2,2, E_WB16><<<dim3(LT/128, NQ/128, B*H), blk, 0, stream>>>(
      q_b, kv_b, nullptr, nullptr, nullptr, scb, HD, D, 2048, LT, H,
      sQ, HD, (long long)LT * 2048, HD, (long long)H * sSC, sSC, 0.125f);

  // 5) fused softmax + head-mean (bf16 scores in)
  txt_softmax_mean<<<dim3(B*NQ), blk, 0, stream>>>(scb, mtx_m, w_b, out1);

  // 6) ctx = w_h @ v_h
  gemm_bf16<64,64,2,2, E_WB16><<<dim3(HD/64, NQ/64, B*H), blk, 0, stream>>>(
      w_b, vT_b, nullptr, nullptr, nullptr, ctx_b, LT, LT, LT, D, H,
      (long long)H * sSC, sSC, (long long)D * LT, (long long)HD * LT, sQ, HD, 1.f);

  // 7) vox -> vox_b + voxT_b (one f32 read)
  vox_prep<<<dim3(D/64, NV/64, B), blk, 0, stream>>>(vox, vox_b, voxT_b);

  // 8) x1p = tgt + ctx @ Wo^T + bo
  gemm_bf16<64,64,2,2, E_BIAS|E_RES|E_WF32><<<dim3(D/64, (B*NQ)/64, 1), blk, 0, stream>>>(
      ctx_b, Wo_b, bo, tgt, x1p, nullptr, D, D, D, D, 1, 0,0,0,0,0,0, 1.f);

  // 9) LN1
  ln_kernel<<<dim3(B*NQ), blk, 0, stream>>>(x1p, ln1g, ln1b, x1f, x1_b, 1.f);

  // 10) ff1 = relu(x1 @ W1^T + b1)
  gemm_bf16<128,64,2,2, E_BIAS|E_RELU|E_WB16><<<dim3(DFF/64, (B*NQ)/128, 1), blk, 0, stream>>>(
      x1_b, W1_b, b1, nullptr, nullptr, ff1_b, D, D, D, DFF, 1, 0,0,0,0,0,0, 1.f);

  // 11) x2p = x1 + ff1 @ W2^T + b2
  gemm_bf16<64,64,2,2, E_BIAS|E_RES|E_WF32><<<dim3(D/64, (B*NQ)/64, 1), blk, 0, stream>>>(
      ff1_b, W2_b, b2, x1f, x2p, nullptr, DFF, DFF, DFF, D, 1, 0,0,0,0,0,0, 1.f);

  // 12) LN2 -> x2s (bf16, /sqrt(D))
  ln_kernel<<<dim3(B*NQ), blk, 0, stream>>>(x2p, ln2g, ln2b, nullptr, x2s_b, 0.03125f);

  // 13) out2 = x2s @ vox_b^T  (merged-phase)
  gemm8<1><<<dim3(NV/128, 1, B), dim3(512), 0, stream>>>(
      x2s_b, vox_b, out2, D, D, D, NV, 0,
      sQ, (long long)NV * D, (long long)NQ * NV, 0);

  // 14) masked softmax in place; bf16 weights
  vox_softmax<<<dim3(B*NQ), blk, 0, stream>>>(out2, vox_m, wvox_b);

  // 15) out0 partials: merged-phase split-K=4 + reduce
  gemm8<4><<<dim3(D/128, 1, B*4), dim3(512), 0, stream>>>(
      wvox_b, voxT_b, part, NV/4, NV, NV, D, NV/4,
      (long long)NQ * NV, (long long)D * NV, 4 * nd, nd);
  splitk_reduce<<<dim3((B * NQ * D) / 1024), blk, 0, stream>>>(part, out0);
}

// Round 15
// 396.420 us; speedup vs baseline: 1.2908x; 1.0132x over previous
//
#include <hip/hip_runtime.h>
#include <math.h>

typedef unsigned short u16;
typedef unsigned int u32;
typedef __bf16 bf16x8 __attribute__((ext_vector_type(8)));
typedef float f32x4 __attribute__((ext_vector_type(4)));
typedef u16 u16x4 __attribute__((ext_vector_type(4)));
typedef u16 u16x2 __attribute__((ext_vector_type(2)));

constexpr int B = 8, NQ = 256, LT = 512, NV = 4096;
constexpr int D = 1024, H = 16, DFF = 2048, FTXT = 4096, HD = 64;

__device__ __forceinline__ u16 f2b(float f) {
  u32 u = __builtin_bit_cast(u32, f);
  return (u16)((u + 0x7fffu + ((u >> 16) & 1u)) >> 16);   // RNE
}
__device__ __forceinline__ float b2f(u16 b) {
  u32 u = ((u32)b) << 16;
  return __builtin_bit_cast(float, u);
}
__device__ __forceinline__ void gload16(const void* g, void* l) {
  __builtin_amdgcn_global_load_lds(
      (const __attribute__((address_space(1))) u32*)g,
      (__attribute__((address_space(3))) u32*)l, 16, 0, 0);
}

// ===========================================================================
// Merged-phase 256x128 schedule (R13-verified), R15: 4x2 wave grid
// (wave tile 64x64 -> 8 A + 8 B ds_read_b128 per tile, -20% LDS traffic).
// LDS 144 KiB: A 3 slabs [256][64], B 3 slabs [128][64] (mod-3 rotation),
// XOR-swizzle slot^(row&7). One vmcnt(6) + one barrier per k-tile.
// ===========================================================================

// --- KV projection: full K=4096. K-half blocks write kv_b (+bias bf16);
//     V-half blocks write vT_b[b][d][l] directly (fused transpose). ---
__global__ __launch_bounds__(512, 2)
void gemm_kv256b(const u16* __restrict__ A, const u16* __restrict__ Bw,
                 const float* __restrict__ bk_, const float* __restrict__ bv_,
                 u16* __restrict__ Cb, u16* __restrict__ vT)
{
  __shared__ __align__(16) u16 As[3 * 16384];
  __shared__ __align__(16) u16 Bs[3 * 8192];

  const int gx = 16;
  const int flat = blockIdx.y * gx + blockIdx.x;
  const int qq = 256 >> 3;
  const int xcd = flat & 7, lid = flat >> 3;
  const int wg = xcd * qq + lid;
  const int bx = wg % gx;
  const int by = wg / gx;
  const int m0 = by * 256, n0 = bx * 128;
  const float* bias = (n0 < 1024) ? (bk_ + n0) : (bv_ + (n0 - 1024));

  const int t = threadIdx.x;
  const int w = t >> 6, l = t & 63;
  const int wr64 = (w >> 1) * 64;        // 4 row-groups
  const int wc64 = (w & 1) * 64;         // 2 col-groups
  const int l15 = l & 15, l4 = l >> 4, l7 = l & 7;

  auto stA = [&](int slab, int tile) {
    const long long kk = (long long)tile * 64 + (((t & 7) ^ ((t >> 3) & 7)) * 8);
    #pragma unroll
    for (int i = 0; i < 4; ++i)
      gload16(&A[(long long)(m0 + (t >> 3) + 64 * i) * 4096 + kk],
              &As[slab * 16384 + (w * 8 + 64 * i) * 64]);
  };
  auto stB = [&](int slab, int tile) {
    const long long kk = (long long)tile * 64 + (((t & 7) ^ ((t >> 3) & 7)) * 8);
    #pragma unroll
    for (int i = 0; i < 2; ++i)
      gload16(&Bw[(long long)(n0 + (t >> 3) + 64 * i) * 4096 + kk],
              &Bs[slab * 8192 + (w * 8 + 64 * i) * 64]);
  };

#define RDA(sl,fm,ks) \
  (*reinterpret_cast<const bf16x8*>(&As[(sl)*16384 + \
      (wr64 + (fm)*16 + l15)*64 + ((((ks)*4 + l4) ^ l7) * 8)]))
#define RDB(sl,fn,ks) \
  (*reinterpret_cast<const bf16x8*>(&Bs[(sl)*8192 + \
      (wc64 + (fn)*16 + l15)*64 + ((((ks)*4 + l4) ^ l7) * 8)]))

  f32x4 acc[4][4] = {};   // [fm][fn]
  bf16x8 a_[4][2];
  bf16x8 b_[4][2];

#define BAR asm volatile("s_barrier" ::: "memory")
#define WAIT6 asm volatile("s_waitcnt vmcnt(6)" ::: "memory")
#define WAIT0 asm volatile("s_waitcnt vmcnt(0)" ::: "memory")

  stA(0, 0); stB(0, 0);
  stA(1, 1); stB(1, 1);
  WAIT6;
  BAR;

  int s0 = 0, s1 = 1, s2 = 2;
  for (int tt = 0; tt < 64; ++tt) {
    #pragma unroll
    for (int f = 0; f < 4; ++f) {
      a_[f][0] = RDA(s0, f, 0); a_[f][1] = RDA(s0, f, 1);
      b_[f][0] = RDB(s0, f, 0); b_[f][1] = RDB(s0, f, 1);
    }

    if (tt < 62) { stA(s2, tt + 2); stB(s2, tt + 2); }

    __builtin_amdgcn_s_setprio(1);
    #pragma unroll
    for (int fm = 0; fm < 4; ++fm)
      #pragma unroll
      for (int fn = 0; fn < 4; ++fn) {
        acc[fm][fn] = __builtin_amdgcn_mfma_f32_16x16x32_bf16(
            a_[fm][0], b_[fn][0], acc[fm][fn], 0, 0, 0);
        acc[fm][fn] = __builtin_amdgcn_mfma_f32_16x16x32_bf16(
            a_[fm][1], b_[fn][1], acc[fm][fn], 0, 0, 0);
      }
    __builtin_amdgcn_s_setprio(0);

    if (tt < 62)       { WAIT6; }
    else if (tt == 62) { WAIT0; }
    BAR;

    const int tmp = s0; s0 = s1; s1 = s2; s2 = tmp;
  }
#undef RDA
#undef RDB
#undef BAR
#undef WAIT6
#undef WAIT0

  if (n0 < 1024) {
    // K half: bf16 kv_b[row][n0+lc] (+bias)
    #pragma unroll
    for (int fm = 0; fm < 4; ++fm)
      #pragma unroll
      for (int r = 0; r < 4; ++r) {
        const long long row = m0 + wr64 + fm * 16 + l4 * 4 + r;
        #pragma unroll
        for (int fn = 0; fn < 4; ++fn) {
          const int lc = wc64 + fn * 16 + l15;
          Cb[row * 2048 + n0 + lc] = f2b(acc[fm][fn][r] + bias[lc]);
        }
      }
  } else {
    // V half: write transposed vT[b][d][l] directly (u16x4 over 4 rows)
    #pragma unroll
    for (int fm = 0; fm < 4; ++fm) {
      const int row0 = m0 + wr64 + fm * 16 + l4 * 4;
      const int bb = row0 >> 9;
      const int l0 = row0 & 511;
      #pragma unroll
      for (int fn = 0; fn < 4; ++fn) {
        const int lc = wc64 + fn * 16 + l15;
        const int d = n0 + lc - 1024;
        const float bi = bias[lc];
        u16x4 o = {f2b(acc[fm][fn][0] + bi), f2b(acc[fm][fn][1] + bi),
                   f2b(acc[fm][fn][2] + bi), f2b(acc[fm][fn][3] + bi)};
        *reinterpret_cast<u16x4*>(&vT[((long long)bb * D + d) * LT + l0]) = o;
      }
    }
  }
}

// --- Generalized merged-phase 256x128 (4x2 wave grid): C f32 = A@Bw^T,
//     batch + split-K. Ksub must be a multiple of 128. ---
template<int NZ2>
__global__ __launch_bounds__(512, 2)
void gemm8(const u16* __restrict__ A, const u16* __restrict__ Bw,
           float* __restrict__ C,
           int Ksub, int lda, int ldb, int ldc, int kstep,
           long long sA1, long long sB1, long long sC1, long long sC2)
{
  __shared__ __align__(16) u16 As[3 * 16384];
  __shared__ __align__(16) u16 Bs[3 * 8192];

  const int gx = gridDim.x, gy = gridDim.y;
  const int nwg = gx * gy * gridDim.z;
  const int flat = (blockIdx.z * gy + blockIdx.y) * gx + blockIdx.x;
  const int qq = nwg >> 3, rr = nwg & 7;
  const int xcd = flat & 7, lid = flat >> 3;
  const int wg = (xcd < rr ? xcd * (qq + 1) : rr * (qq + 1) + (xcd - rr) * qq) + lid;
  const int bx = wg % gx;
  const int tmp1 = wg / gx;
  const int by = tmp1 % gy, bz = tmp1 / gy;
  const int z1 = bz / NZ2, z2 = bz % NZ2;
  const int m0 = by * 256, n0 = bx * 128;
  const long long kbase = (long long)z2 * kstep;
  const u16* Ab = A + (long long)z1 * sA1;
  const u16* Bb = Bw + (long long)z1 * sB1;
  float* Cp = C + (long long)z1 * sC1 + (long long)z2 * sC2;

  const int t = threadIdx.x;
  const int w = t >> 6, l = t & 63;
  const int wr64 = (w >> 1) * 64;
  const int wc64 = (w & 1) * 64;
  const int l15 = l & 15, l4 = l >> 4, l7 = l & 7;

  auto stA = [&](int slab, int tile) {
    const long long kk = kbase + (long long)tile * 64 + (((t & 7) ^ ((t >> 3) & 7)) * 8);
    #pragma unroll
    for (int i = 0; i < 4; ++i)
      gload16(&Ab[(long long)(m0 + (t >> 3) + 64 * i) * lda + kk],
              &As[slab * 16384 + (w * 8 + 64 * i) * 64]);
  };
  auto stB = [&](int slab, int tile) {
    const long long kk = kbase + (long long)tile * 64 + (((t & 7) ^ ((t >> 3) & 7)) * 8);
    #pragma unroll
    for (int i = 0; i < 2; ++i)
      gload16(&Bb[(long long)(n0 + (t >> 3) + 64 * i) * ldb + kk],
              &Bs[slab * 8192 + (w * 8 + 64 * i) * 64]);
  };

#define RDA(sl,fm,ks) \
  (*reinterpret_cast<const bf16x8*>(&As[(sl)*16384 + \
      (wr64 + (fm)*16 + l15)*64 + ((((ks)*4 + l4) ^ l7) * 8)]))
#define RDB(sl,fn,ks) \
  (*reinterpret_cast<const bf16x8*>(&Bs[(sl)*8192 + \
      (wc64 + (fn)*16 + l15)*64 + ((((ks)*4 + l4) ^ l7) * 8)]))

  f32x4 acc[4][4] = {};
  bf16x8 a_[4][2];
  bf16x8 b_[4][2];

#define BAR asm volatile("s_barrier" ::: "memory")
#define WAIT6 asm volatile("s_waitcnt vmcnt(6)" ::: "memory")
#define WAIT0 asm volatile("s_waitcnt vmcnt(0)" ::: "memory")

  stA(0, 0); stB(0, 0);
  stA(1, 1); stB(1, 1);
  WAIT6;
  BAR;

  const int nt = Ksub >> 6;
  int s0 = 0, s1 = 1, s2 = 2;
  for (int tt = 0; tt < nt; ++tt) {
    #pragma unroll
    for (int f = 0; f < 4; ++f) {
      a_[f][0] = RDA(s0, f, 0); a_[f][1] = RDA(s0, f, 1);
      b_[f][0] = RDB(s0, f, 0); b_[f][1] = RDB(s0, f, 1);
    }

    if (tt < nt - 2) { stA(s2, tt + 2); stB(s2, tt + 2); }

    __builtin_amdgcn_s_setprio(1);
    #pragma unroll
    for (int fm = 0; fm < 4; ++fm)
      #pragma unroll
      for (int fn = 0; fn < 4; ++fn) {
        acc[fm][fn] = __builtin_amdgcn_mfma_f32_16x16x32_bf16(
            a_[fm][0], b_[fn][0], acc[fm][fn], 0, 0, 0);
        acc[fm][fn] = __builtin_amdgcn_mfma_f32_16x16x32_bf16(
            a_[fm][1], b_[fn][1], acc[fm][fn], 0, 0, 0);
      }
    __builtin_amdgcn_s_setprio(0);

    if (tt < nt - 2)       { WAIT6; }
    else if (tt == nt - 2) { WAIT0; }
    BAR;

    const int tmp = s0; s0 = s1; s1 = s2; s2 = tmp;
  }
#undef RDA
#undef RDB
#undef BAR
#undef WAIT6
#undef WAIT0

  #pragma unroll
  for (int fm = 0; fm < 4; ++fm)
    #pragma unroll
    for (int r = 0; r < 4; ++r) {
      const long long row = m0 + wr64 + fm * 16 + l4 * 4 + r;
      #pragma unroll
      for (int fn = 0; fn < 4; ++fn) {
        const int lc = wc64 + fn * 16 + l15;
        Cp[row * (long long)ldc + n0 + lc] = acc[fm][fn][r];
      }
    }
}

// ---------------------------------------------------------------------------
// 2-phase bf16 MFMA GEMM (bf16 B via global_load_lds only).
// ---------------------------------------------------------------------------
constexpr int E_BIAS = 1, E_RES = 2, E_RELU = 4, E_WF32 = 8, E_WB16 = 16;

template<int BM, int BN, int WM, int WN, int EPI>
__global__ __launch_bounds__(256)
void gemm_bf16(const u16* __restrict__ A, const u16* __restrict__ Bw,
               const float* __restrict__ bias, const float* __restrict__ res,
               float* __restrict__ C, u16* __restrict__ Cb,
               int K, int lda, int ldb, int ldc, int nbz2,
               long long sA1, long long sA2, long long sB1, long long sB2,
               long long sC1, long long sC2, float alpha)
{
  constexpr int SM = BM / WM, SN = BN / WN;
  constexpr int FM = SM / 16, FN = SN / 16;
  constexpr int PA = BM / 64, PB = BN / 64;
  __shared__ __align__(16) u16 As[2][BM * 32];
  __shared__ __align__(16) u16 Bs[2][BN * 32];

  const int gx = gridDim.x, gy = gridDim.y;
  const int nwg = gx * gy * gridDim.z;
  const int flat = (blockIdx.z * gy + blockIdx.y) * gx + blockIdx.x;
  const int qq = nwg >> 3, rr = nwg & 7;
  const int xcd = flat & 7, lid = flat >> 3;
  const int wg = (xcd < rr ? xcd * (qq + 1) : rr * (qq + 1) + (xcd - rr) * qq) + lid;
  const int bx = wg % gx;
  const int tmp1 = wg / gx;
  const int by = tmp1 % gy, bz = tmp1 / gy;

  const int t = threadIdx.x;
  const int w = t >> 6, l = t & 63;
  const int wr = w / WN, wc = w % WN;
  const int m0 = by * BM, n0 = bx * BN;
  const long long offA = (long long)(bz / nbz2) * sA1 + (long long)(bz % nbz2) * sA2;
  const long long offB = (long long)(bz / nbz2) * sB1 + (long long)(bz % nbz2) * sB2;
  const long long offC = (long long)(bz / nbz2) * sC1 + (long long)(bz % nbz2) * sC2;
  const u16* Ab = A + offA;
  const u16* Bb = Bw + offB;

  const int srow = t >> 2;
  const int sk   = (t & 3) * 8;

  auto stageA = [&](int buf, int k0) {
    #pragma unroll
    for (int p = 0; p < PA; ++p)
      gload16(&Ab[(long long)(m0 + p * 64 + srow) * lda + k0 + sk],
              &As[buf][p * 2048 + w * 512]);
  };
  auto stageB = [&](int buf, int k0) {
    #pragma unroll
    for (int p = 0; p < PB; ++p)
      gload16(&Bb[(long long)(n0 + p * 64 + srow) * ldb + k0 + sk],
              &Bs[buf][p * 2048 + w * 512]);
  };

  f32x4 acc[FM][FN] = {};

  stageA(0, 0);
  stageB(0, 0);

  int cur = 0;
  for (int k0 = 0; k0 < K; k0 += 32) {
    __syncthreads();
    const bool pf = (k0 + 32 < K);
    if (pf) {
      stageA(cur ^ 1, k0 + 32);
      stageB(cur ^ 1, k0 + 32);
    }

    bf16x8 af[FM], bfr[FN];
    #pragma unroll
    for (int i = 0; i < FM; ++i)
      af[i] = *reinterpret_cast<const bf16x8*>(
          &As[cur][(wr * SM + i * 16 + (l & 15)) * 32 + (l >> 4) * 8]);
    #pragma unroll
    for (int j = 0; j < FN; ++j)
      bfr[j] = *reinterpret_cast<const bf16x8*>(
          &Bs[cur][(wc * SN + j * 16 + (l & 15)) * 32 + (l >> 4) * 8]);
    #pragma unroll
    for (int i = 0; i < FM; ++i)
      #pragma unroll
      for (int j = 0; j < FN; ++j)
        acc[i][j] = __builtin_amdgcn_mfma_f32_16x16x32_bf16(af[i], bfr[j], acc[i][j], 0, 0, 0);
    cur ^= 1;
  }

  const int c_l = l & 15, r_l4 = (l >> 4) * 4;
  #pragma unroll
  for (int i = 0; i < FM; ++i) {
    #pragma unroll
    for (int r = 0; r < 4; ++r) {
      const long long row = m0 + wr * SM + i * 16 + r_l4 + r;
      #pragma unroll
      for (int j = 0; j < FN; ++j) {
        const int col = n0 + wc * SN + j * 16 + c_l;
        float v = acc[i][j][r] * alpha;
        if (EPI & E_BIAS) v += bias[col];
        if (EPI & E_RES)  v += res[row * (long long)ldc + col];
        if (EPI & E_RELU) v = fmaxf(v, 0.f);
        const long long co = offC + row * (long long)ldc + col;
        if (EPI & E_WF32) C[co] = v;
        if (EPI & E_WB16) Cb[co] = f2b(v);
      }
    }
  }
}

// ---------------------------------------------------------------------------
// vox f32 [B][NV][D] -> vb bf16 [B][NV][D]  AND  vt bf16 [B][D][NV]
// ---------------------------------------------------------------------------
__global__ __launch_bounds__(256)
void vox_prep(const float* __restrict__ in, u16* __restrict__ vb,
              u16* __restrict__ vt)
{
  __shared__ u16 tile[64][68];
  const int b = blockIdx.z;
  const int n0 = blockIdx.y * 64;
  const int d0 = blockIdx.x * 64;
  const int t = threadIdx.x;
  const int tr = t >> 4;
  const int tc = (t & 15) * 4;
  const float* ib = in + (long long)b * NV * D;
  u16* vbb = vb + (long long)b * NV * D;
  u16* vtb = vt + (long long)b * NV * D;
  #pragma unroll
  for (int p = 0; p < 4; ++p) {
    int r = tr + p * 16;
    float4 x = *reinterpret_cast<const float4*>(&ib[(long long)(n0 + r) * D + d0 + tc]);
    u16x4 o = {f2b(x.x), f2b(x.y), f2b(x.z), f2b(x.w)};
    *reinterpret_cast<u16x4*>(&vbb[(long long)(n0 + r) * D + d0 + tc]) = o;
    *reinterpret_cast<u16x4*>(&tile[r][tc]) = o;
  }
  __syncthreads();
  #pragma unroll
  for (int p = 0; p < 4; ++p) {
    int c = tr + p * 16;
    u16x4 o = {tile[tc + 0][c], tile[tc + 1][c], tile[tc + 2][c], tile[tc + 3][c]};
    *reinterpret_cast<u16x4*>(&vtb[(long long)(d0 + c) * NV + n0 + tc]) = o;
  }
}

// ---------------------------------------------------------------------------
// fused multi-segment f32 -> bf16 conversion; segment 7 adds two sources.
// ---------------------------------------------------------------------------
struct Cvt8 { const float* s[8]; const float* s2[8]; u16* d[8]; int cum[9]; };

__global__ __launch_bounds__(256)
void cvt_multi(Cvt8 a)
{
  const int bidx = blockIdx.x;
  int seg = 0;
  #pragma unroll
  for (int k = 1; k < 8; ++k) if (bidx >= a.cum[k]) seg = k;
  const long long off = ((long long)(bidx - a.cum[seg]) * 256 + threadIdx.x) * 4;
  float4 x = *reinterpret_cast<const float4*>(a.s[seg] + off);
  if (a.s2[seg]) {
    float4 y = *reinterpret_cast<const float4*>(a.s2[seg] + off);
    x.x += y.x; x.y += y.y; x.z += y.z; x.w += y.w;
  }
  u16x4 o = {f2b(x.x), f2b(x.y), f2b(x.z), f2b(x.w)};
  *reinterpret_cast<u16x4*>(a.d[seg] + off) = o;
}

// ---------------------------------------------------------------------------
__global__ __launch_bounds__(256)
void txt_softmax_mean(const u16* __restrict__ sc, const int* __restrict__ mask,
                      u16* __restrict__ wout, float* __restrict__ out1)
{
  __shared__ float red[8];
  const int t = threadIdx.x, l = t & 63, w = t >> 6;
  const int bq = blockIdx.x;
  const int b = bq >> 8, q = bq & 255;
  const int* mr = mask + b * LT;
  const int2 mm = *reinterpret_cast<const int2*>(&mr[2 * t]);
  const bool msk0 = mm.x != 0, msk1 = mm.y != 0;
  float a0 = 0.f, a1 = 0.f;
  for (int h = 0; h < H; ++h) {
    const long long ro = (((long long)(b * H + h)) * NQ + q) * LT;
    const u16* sr = sc + ro;
    const u16x2 sv = *reinterpret_cast<const u16x2*>(&sr[2 * t]);
    float x0 = msk0 ? -INFINITY : b2f(sv[0]);
    float x1 = msk1 ? -INFINITY : b2f(sv[1]);
    float mx = fmaxf(x0, x1);
    #pragma unroll
    for (int o = 32; o > 0; o >>= 1) mx = fmaxf(mx, __shfl_xor(mx, o, 64));
    if (l == 0) red[w] = mx;
    __syncthreads();
    mx = fmaxf(fmaxf(red[0], red[1]), fmaxf(red[2], red[3]));
    float e0 = __expf(x0 - mx), e1 = __expf(x1 - mx);
    float s = e0 + e1;
    #pragma unroll
    for (int o = 32; o > 0; o >>= 1) s += __shfl_xor(s, o, 64);
    if (l == 0) red[4 + w] = s;
    __syncthreads();
    s = red[4] + red[5] + red[6] + red[7];
    const float inv = 1.f / s;
    const float w0 = e0 * inv, w1 = e1 * inv;
    u16x2 wv = {f2b(w0), f2b(w1)};
    *reinterpret_cast<u16x2*>(&wout[ro + 2 * t]) = wv;
    a0 += w0; a1 += w1;
  }
  float2 o2 = {a0 * (1.f / H), a1 * (1.f / H)};
  *reinterpret_cast<float2*>(&out1[(long long)bq * LT + 2 * t]) = o2;
}

// ---------------------------------------------------------------------------
__global__ __launch_bounds__(256)
void ln_kernel(const float* __restrict__ x, const float* __restrict__ g,
               const float* __restrict__ bia, float* __restrict__ y,
               u16* __restrict__ yb, float scale)
{
  __shared__ float tmp[256];
  const int t = threadIdx.x;
  const long long off = (long long)blockIdx.x * D;
  float4 x4 = *reinterpret_cast<const float4*>(&x[off + t * 4]);
  tmp[t] = x4.x + x4.y + x4.z + x4.w;
  __syncthreads();
  for (int o = 128; o > 0; o >>= 1) { if (t < o) tmp[t] += tmp[t + o]; __syncthreads(); }
  const float mean = tmp[0] * (1.f / D);
  __syncthreads();
  float d0 = x4.x - mean, d1 = x4.y - mean, d2 = x4.z - mean, d3 = x4.w - mean;
  tmp[t] = d0 * d0 + d1 * d1 + d2 * d2 + d3 * d3;
  __syncthreads();
  for (int o = 128; o > 0; o >>= 1) { if (t < o) tmp[t] += tmp[t + o]; __syncthreads(); }
  const float rs = rsqrtf(tmp[0] * (1.f / D) + 1e-5f);
  float4 g4 = *reinterpret_cast<const float4*>(&g[t * 4]);
  float4 b4 = *reinterpret_cast<const float4*>(&bia[t * 4]);
  float o0 = (d0 * rs * g4.x + b4.x) * scale;
  float o1 = (d1 * rs * g4.y + b4.y) * scale;
  float o2 = (d2 * rs * g4.z + b4.z) * scale;
  float o3 = (d3 * rs * g4.w + b4.w) * scale;
  if (y) {
    float4 o4 = {o0, o1, o2, o3};
    *reinterpret_cast<float4*>(&y[off + t * 4]) = o4;
  }
  if (yb) {
    u16x4 ob = {f2b(o0), f2b(o1), f2b(o2), f2b(o3)};
    *reinterpret_cast<u16x4*>(&yb[off + t * 4]) = ob;
  }
}

// ---------------------------------------------------------------------------
__global__ __launch_bounds__(256)
void vox_softmax(float* __restrict__ s, const int* __restrict__ mask,
                 u16* __restrict__ wb)
{
  __shared__ float tmp[256];
  const int t = threadIdx.x;
  const int row = blockIdx.x, b = row / NQ;
  float* sr = s + (long long)row * NV;
  u16* wr = wb + (long long)row * NV;
  const int* mr = mask + b * NV;
  float vals[16];
  float lm = -INFINITY;
  #pragma unroll
  for (int j = 0; j < 16; ++j) {
    int n = t + j * 256;
    float x = mr[n] ? -INFINITY : sr[n];
    vals[j] = x;
    lm = fmaxf(lm, x);
  }
  tmp[t] = lm;
  __syncthreads();
  for (int o = 128; o > 0; o >>= 1) { if (t < o) tmp[t] = fmaxf(tmp[t], tmp[t + o]); __syncthreads(); }
  const float mx = tmp[0];
  __syncthreads();
  float ls = 0.f;
  #pragma unroll
  for (int j = 0; j < 16; ++j) { vals[j] = __expf(vals[j] - mx); ls += vals[j]; }
  tmp[t] = ls;
  __syncthreads();
  for (int o = 128; o > 0; o >>= 1) { if (t < o) tmp[t] += tmp[t + o]; __syncthreads(); }
  const float inv = 1.f / tmp[0];
  #pragma unroll
  for (int j = 0; j < 16; ++j) {
    float v = vals[j] * inv;
    sr[t + j * 256] = v;
    wr[t + j * 256] = f2b(v);
  }
}

__global__ __launch_bounds__(256)
void splitk_reduce(const float* __restrict__ part, float* __restrict__ out)
{
  const long long i = ((long long)blockIdx.x * 256 + threadIdx.x) * 4;
  const long long nd = (long long)NQ * D;
  const long long b = i / nd;
  const long long o = i - b * nd;
  const float* p = part + b * 4 * nd + o;
  float4 s0 = *reinterpret_cast<const float4*>(&p[0]);
  float4 s1 = *reinterpret_cast<const float4*>(&p[nd]);
  float4 s2 = *reinterpret_cast<const float4*>(&p[2 * nd]);
  float4 s3 = *reinterpret_cast<const float4*>(&p[3 * nd]);
  float4 r = {s0.x + s1.x + s2.x + s3.x, s0.y + s1.y + s2.y + s3.y,
              s0.z + s1.z + s2.z + s3.z, s0.w + s1.w + s2.w + s3.w};
  *reinterpret_cast<float4*>(&out[i]) = r;
}

// ---------------------------------------------------------------------------
extern "C" void kernel_launch(void* const* d_in, const int* in_sizes, int n_in,
                              void* d_out, int out_size, void* d_ws, size_t ws_size,
                              hipStream_t stream)
{
  const float* tgt   = (const float*)d_in[0];
  const float* mtxt  = (const float*)d_in[1];
  const float* vox   = (const float*)d_in[2];
  const float* qpos  = (const float*)d_in[3];
  const int*   mtx_m = (const int*)d_in[4];
  const int*   vox_m = (const int*)d_in[5];
  const float* Wq = (const float*)d_in[6];  const float* bq = (const float*)d_in[7];
  const float* Wk = (const float*)d_in[8];  const float* bk = (const float*)d_in[9];
  const float* Wv = (const float*)d_in[10]; const float* bv = (const float*)d_in[11];
  const float* Wo = (const float*)d_in[12]; const float* bo = (const float*)d_in[13];
  const float* W1 = (const float*)d_in[14]; const float* b1 = (const float*)d_in[15];
  const float* W2 = (const float*)d_in[16]; const float* b2 = (const float*)d_in[17];
  const float* ln1g = (const float*)d_in[18]; const float* ln1b = (const float*)d_in[19];
  const float* ln2g = (const float*)d_in[20]; const float* ln2b = (const float*)d_in[21];

  float* out0 = (float*)d_out;                       // attn_output  [B,NQ,D]
  float* out1 = out0 + (long long)B * NQ * D;        // txt_cross    [B,NQ,LT]
  float* out2 = out1 + (long long)B * NQ * LT;       // attn_weights [B,NQ,NV]

  char* base = (char*)d_ws;
  constexpr size_t MB = 1ull << 20;
  u16*   kvW   = (u16*)(base + 0 * MB);     // 16  [Wk;Wv] stacked
  u16*   Wq_b  = (u16*)(base + 16 * MB);    // 2
  u16*   Wo_b  = (u16*)(base + 18 * MB);    // 2
  u16*   W1_b  = (u16*)(base + 20 * MB);    // 4
  u16*   W2_b  = (u16*)(base + 24 * MB);    // 4
  u16*   tq_b  = (u16*)(base + 28 * MB);    // 4
  u16*   q_b   = (u16*)(base + 32 * MB);    // 4
  u16*   kv_b  = (u16*)(base + 36 * MB);    // 16  [B*LT][2048] (K half used)
  u16*   vT_b  = (u16*)(base + 52 * MB);    // 8   [B][D][LT]
  u16*   ctx_b = (u16*)(base + 60 * MB);    // 4
  float* x1p   = (float*)(base + 64 * MB);  // 8
  float* x1f   = (float*)(base + 72 * MB);  // 8
  u16*   x1_b  = (u16*)(base + 80 * MB);    // 4
  u16*   ff1_b = (u16*)(base + 84 * MB);    // 8
  float* x2p   = (float*)(base + 92 * MB);  // 8
  u16*   x2s_b = (u16*)(base + 100 * MB);   // 4
  u16*   mtxt_b = (u16*)(base + 104 * MB);  // 32  dead after kv256b
  u16*   scb   = (u16*)(base + 136 * MB);   // 32  bf16 scores, dead after softmax
  u16*   w_b    = (u16*)(base + 200 * MB);  // 32  dead after ctx gemm
  u16*   vox_b  = (u16*)(base + 104 * MB);  // 64  overlays mtxt_b + scb head
  u16*   voxT_b = (u16*)(base + 168 * MB);  // 64  overlays scb tail + w_b
  u16*   wvox_b = (u16*)(base + 0 * MB);    // 16  overlays kvW (dead)
  float* part   = (float*)(base + 16 * MB); // 32  overlays Wq..q_b (dead)

  const dim3 blk(256);
  const long long sQ = (long long)NQ * D;
  const long long sSC = (long long)NQ * LT;
  const long long nd = (long long)NQ * D;

  // 1) conversions: fused weights + memory_txt + (tgt+qpos)
  Cvt8 ca;
  for (int i = 0; i < 8; ++i) ca.s2[i] = nullptr;
  ca.s[0] = Wq;   ca.d[0] = Wq_b;
  ca.s[1] = Wk;   ca.d[1] = kvW;
  ca.s[2] = Wv;   ca.d[2] = kvW + (long long)D * FTXT;
  ca.s[3] = Wo;   ca.d[3] = Wo_b;
  ca.s[4] = W1;   ca.d[4] = W1_b;
  ca.s[5] = W2;   ca.d[5] = W2_b;
  ca.s[6] = mtxt; ca.d[6] = mtxt_b;
  ca.s[7] = tgt;  ca.s2[7] = qpos; ca.d[7] = tq_b;
  ca.cum[0] = 0;     ca.cum[1] = 1024;  ca.cum[2] = 5120;  ca.cum[3] = 9216;
  ca.cum[4] = 10240; ca.cum[5] = 12288; ca.cum[6] = 14336; ca.cum[7] = 30720;
  ca.cum[8] = 32768;
  cvt_multi<<<dim3(32768), blk, 0, stream>>>(ca);

  // 2) q projection (2-phase) + kv projection (merged-phase; V -> vT fused)
  gemm_bf16<64,64,2,2, E_BIAS|E_WB16><<<dim3(D/64, (B*NQ)/64, 1), blk, 0, stream>>>(
      tq_b, Wq_b, bq, nullptr, nullptr, q_b, D, D, D, D, 1, 0,0,0,0,0,0, 1.f);
  gemm_kv256b<<<dim3(16, 16), dim3(512), 0, stream>>>(mtxt_b, kvW, bk, bv, kv_b, vT_b);

  // 3) scores = q . k / 8  -> bf16
  gemm_bf16<128,128,2,2, E_WB16><<<dim3(LT/128, NQ/128, B*H), blk, 0, stream>>>(
      q_b, kv_b, nullptr, nullptr, nullptr, scb, HD, D, 2048, LT, H,
      sQ, HD, (long long)LT * 2048, HD, (long long)H * sSC, sSC, 0.125f);

  // 4) fused softmax + head-mean (bf16 scores in)
  txt_softmax_mean<<<dim3(B*NQ), blk, 0, stream>>>(scb, mtx_m, w_b, out1);

  // 5) ctx = w_h @ v_h
  gemm_bf16<64,64,2,2, E_WB16><<<dim3(HD/64, NQ/64, B*H), blk, 0, stream>>>(
      w_b, vT_b, nullptr, nullptr, nullptr, ctx_b, LT, LT, LT, D, H,
      (long long)H * sSC, sSC, (long long)D * LT, (long long)HD * LT, sQ, HD, 1.f);

  // 6) vox -> vox_b + voxT_b (one f32 read)
  vox_prep<<<dim3(D/64, NV/64, B), blk, 0, stream>>>(vox, vox_b, voxT_b);

  // 7) x1p = tgt + ctx @ Wo^T + bo
  gemm_bf16<64,64,2,2, E_BIAS|E_RES|E_WF32><<<dim3(D/64, (B*NQ)/64, 1), blk, 0, stream>>>(
      ctx_b, Wo_b, bo, tgt, x1p, nullptr, D, D, D, D, 1, 0,0,0,0,0,0, 1.f);

  // 8) LN1
  ln_kernel<<<dim3(B*NQ), blk, 0, stream>>>(x1p, ln1g, ln1b, x1f, x1_b, 1.f);

  // 9) ff1 = relu(x1 @ W1^T + b1)
  gemm_bf16<128,64,2,2, E_BIAS|E_RELU|E_WB16><<<dim3(DFF/64, (B*NQ)/128, 1), blk, 0, stream>>>(
      x1_b, W1_b, b1, nullptr, nullptr, ff1_b, D, D, D, DFF, 1, 0,0,0,0,0,0, 1.f);

  // 10) x2p = x1 + ff1 @ W2^T + b2
  gemm_bf16<64,64,2,2, E_BIAS|E_RES|E_WF32><<<dim3(D/64, (B*NQ)/64, 1), blk, 0, stream>>>(
      ff1_b, W2_b, b2, x1f, x2p, nullptr, DFF, DFF, DFF, D, 1, 0,0,0,0,0,0, 1.f);

  // 11) LN2 -> x2s (bf16, /sqrt(D))
  ln_kernel<<<dim3(B*NQ), blk, 0, stream>>>(x2p, ln2g, ln2b, nullptr, x2s_b, 0.03125f);

  // 12) out2 = x2s @ vox_b^T  (merged-phase)
  gemm8<1><<<dim3(NV/128, 1, B), dim3(512), 0, stream>>>(
      x2s_b, vox_b, out2, D, D, D, NV, 0,
      sQ, (long long)NV * D, (long long)NQ * NV, 0);

  // 13) masked softmax in place; bf16 weights
  vox_softmax<<<dim3(B*NQ), blk, 0, stream>>>(out2, vox_m, wvox_b);

  // 14) out0 partials: merged-phase split-K=4 + reduce
  gemm8<4><<<dim3(D/128, 1, B*4), dim3(512), 0, stream>>>(
      wvox_b, voxT_b, part, NV/4, NV, NV, D, NV/4,
      (long long)NQ * NV, (long long)D * NV, 4 * nd, nd);
  splitk_reduce<<<dim3((B * NQ * D) / 1024), blk, 0, stream>>>(part, out0);
}